// Round 5
// baseline (413.780 us; speedup 1.0000x reference)
//
#include <hip/hip_runtime.h>
#include <math.h>

typedef __attribute__((ext_vector_type(8)))  short bf16x8;
typedef __attribute__((ext_vector_type(8)))  unsigned short u16x8;
typedef __attribute__((ext_vector_type(16))) float f32x16;

__device__ __forceinline__ unsigned short f2bf(float f) {
    unsigned u = __float_as_uint(f);
    unsigned r = (u + 0x7FFFu + ((u >> 16) & 1u)) >> 16;
    return (unsigned short)r;
}
__device__ __forceinline__ float bf2f(unsigned short h) {
    return __uint_as_float(((unsigned)h) << 16);
}
__device__ __forceinline__ unsigned pack2(unsigned short a, unsigned short b) {
    return (unsigned)a | ((unsigned)b << 16);
}
__device__ __forceinline__ float fast_tanh(float x) {
    float e = __expf(2.f * x);
    return 1.f - 2.f / (e + 1.f);
}

__device__ __forceinline__ void bilin_setup(int y, int x, int Hi, int Wi,
                                            int& i00, int& i01, int& i10, int& i11,
                                            float& wy, float& wx)
{
    float fy = 0.5f * y - 0.25f;
    float fx = 0.5f * x - 0.25f;
    float y0f = floorf(fy), x0f = floorf(fx);
    wy = fy - y0f; wx = fx - x0f;
    int yA = (int)y0f, xA = (int)x0f;
    int yB = yA + 1, xB = xA + 1;
    yA = yA < 0 ? 0 : (yA > Hi - 1 ? Hi - 1 : yA);
    yB = yB < 0 ? 0 : (yB > Hi - 1 ? Hi - 1 : yB);
    xA = xA < 0 ? 0 : (xA > Wi - 1 ? Wi - 1 : xA);
    xB = xB < 0 ? 0 : (xB > Wi - 1 ? Wi - 1 : xB);
    i00 = yA * Wi + xA; i01 = yA * Wi + xB;
    i10 = yB * Wi + xA; i11 = yB * Wi + xB;
}

// 2x upsample w/ half-pixel centers: fixed parity weights, no floorf needed.
// v=2k: srcs {k-1,k} w=0.75 on k ; v=2k+1: srcs {k,k+1} w=0.25 on k+1
__device__ __forceinline__ void up2_setup(int v, int Hi, int& i0, int& i1, float& w)
{
    int a = (v - 1) >> 1;           // arithmetic shift: v=0 -> -1
    i0 = a < 0 ? 0 : a;
    int b = a + 1;
    i1 = b > Hi - 1 ? Hi - 1 : b;
    w = (v & 1) ? 0.25f : 0.75f;
}

__device__ __forceinline__ u16x8 bilin8(const unsigned short* __restrict__ sb,
                                        int i00, int i01, int i10, int i11,
                                        float wy, float wx, int stride)
{
    u16x8 v00 = *(const u16x8*)(sb + (size_t)i00 * stride);
    u16x8 v01 = *(const u16x8*)(sb + (size_t)i01 * stride);
    u16x8 v10 = *(const u16x8*)(sb + (size_t)i10 * stride);
    u16x8 v11 = *(const u16x8*)(sb + (size_t)i11 * stride);
    float w00 = (1.f - wy) * (1.f - wx), w01 = (1.f - wy) * wx;
    float w10 = wy * (1.f - wx),         w11 = wy * wx;
    u16x8 r;
#pragma unroll
    for (int j = 0; j < 8; ++j)
        r[j] = f2bf(w00 * bf2f(v00[j]) + w01 * bf2f(v01[j]) +
                    w10 * bf2f(v10[j]) + w11 * bf2f(v11[j]));
    return r;
}

// y-interp composite coefficients: ALPH[cls][py][dy][dr]
//   cls: 0 = top (i=0), 1 = interior, 2 = bottom (i=last)
//   out row y = 2i+py, conv tap dy reads upsampled row v = y+dy-1,
//   which is a lerp of low-res rows i-1+dr (dr = 0..2).
//   Derived from half-pixel bilinear w/ edge clamp + conv zero-pad.
__device__ const float ALPH[3][2][3][3] = {
    { { {0.f,0.f,0.f},      {0.f,1.f,0.f},       {0.f,0.75f,0.25f} },
      { {0.f,1.f,0.f},      {0.f,0.75f,0.25f},   {0.f,0.25f,0.75f} } },
    { { {0.75f,0.25f,0.f},  {0.25f,0.75f,0.f},   {0.f,0.75f,0.25f} },
      { {0.25f,0.75f,0.f},  {0.f,0.75f,0.25f},   {0.f,0.25f,0.75f} } },
    { { {0.75f,0.25f,0.f},  {0.25f,0.75f,0.f},   {0.f,1.f,0.f} },
      { {0.25f,0.75f,0.f},  {0.f,1.f,0.f},       {0.f,0.f,0.f} } }
};

// ---------------------------------------------------------------------------
// img [8][15][256][256] fp32 -> imgT [b][y][x][16] bf16 (ch15 = 0)
// ---------------------------------------------------------------------------
__global__ void imgT_bf16(const float* __restrict__ img, unsigned short* __restrict__ dst)
{
    int idx = blockIdx.x * 256 + threadIdx.x;
    if (idx >= 8 * 256 * 256) return;
    int x = idx & 255, y = (idx >> 8) & 255, b = idx >> 16;
    unsigned short v[16];
#pragma unroll
    for (int c = 0; c < 15; ++c)
        v[c] = f2bf(img[(size_t)(b * 15 + c) * 65536 + y * 256 + x]);
    v[15] = 0;
    uint4 lo = make_uint4(pack2(v[0], v[1]), pack2(v[2], v[3]), pack2(v[4], v[5]), pack2(v[6], v[7]));
    uint4 hi = make_uint4(pack2(v[8], v[9]), pack2(v[10], v[11]), pack2(v[12], v[13]), pack2(v[14], v[15]));
    *(uint4*)(dst + (size_t)idx * 16)     = lo;
    *(uint4*)(dst + (size_t)idx * 16 + 8) = hi;
}

// ---------------------------------------------------------------------------
// Mega weight-pack: all packs in one dispatch (incl. y-composite tables for
// conv9 AND conv8).
// ---------------------------------------------------------------------------
__device__ __forceinline__ void pack33(const float* __restrict__ w,
                                       unsigned short* __restrict__ dst,
                                       int i, int Cin, int Cout)
{
    int KST = Cin >> 4, MT = Cout >> 5;
    int j = i & 7;
    int lane = (i >> 3) & 63;
    int t = i >> 9;
    int mt = t % MT; t /= MT;
    int kst = t % KST;
    int s = t / KST;
    int oc = mt * 32 + (lane & 31);
    int ci = kst * 16 + (lane >> 5) * 8 + j;
    dst[i] = f2bf(w[(oc * Cin + ci) * 9 + s]);
}

__global__ void wprep_mega(const float* __restrict__ w9, const float* __restrict__ w8,
                           const float* __restrict__ w1, const float* __restrict__ wi,
                           const float* __restrict__ wo, const float* __restrict__ w2,
                           const float* __restrict__ w3, const float* __restrict__ w4,
                           const float* __restrict__ w5, const float* __restrict__ w6,
                           const float* __restrict__ w7,
                           unsigned short* __restrict__ wpk9, unsigned short* __restrict__ wpk8,
                           unsigned short* __restrict__ wpk1, unsigned short* __restrict__ wpki,
                           unsigned short* __restrict__ wpko, unsigned short* __restrict__ wpk2,
                           unsigned short* __restrict__ wpk3, unsigned short* __restrict__ wpk4,
                           unsigned short* __restrict__ wpk5, unsigned short* __restrict__ wpk6,
                           unsigned short* __restrict__ wpk7, unsigned short* __restrict__ wpk9e,
                           unsigned short* __restrict__ wpk8e)
{
    int idx = blockIdx.x * 256 + threadIdx.x;
    if (idx < 27648)       pack33(w9, wpk9, idx, 48, 64);
    else if (idx < 46080)  pack33(w8, wpk8, idx - 27648, 64, 32);
    else if (idx < 58880) {
        int i = idx - 46080;
        int j = i & 7;
        int lane = (i >> 3) & 63;
        int s = i >> 9;                 // 0..24
        int oc = lane & 31;
        int ci = (lane >> 5) * 8 + j;   // 0..15
        float v = 0.f;
        if (oc < 16 && ci < 15) v = w1[((oc * 15 + ci) * 5 + s / 5) * 5 + s % 5];
        wpk1[i] = f2bf(v);
    } else if (idx < 63488) {
        int i = idx - 58880;
        int j = i & 7;
        int lane = (i >> 3) & 63;
        int s = i >> 9;                 // 0..8
        int oc = lane & 31;
        int ci = (lane >> 5) * 8 + j;
        float v = 0.f;
        if (oc < 16 && ci < 15) v = wi[((oc * 15 + ci) * 3 + s / 3) * 3 + s % 3];
        wpki[i] = f2bf(v);
    } else if (idx < 68096) {
        int i = idx - 63488;
        int j = i & 7;
        int lane = (i >> 3) & 63;
        int s = i >> 9;
        int oc = lane & 31;
        int ci = (lane >> 5) * 8 + j;
        float v = 0.f;
        if (oc < 3) v = wo[((oc * 16 + ci) * 3 + s / 3) * 3 + s % 3];
        wpko[i] = f2bf(v);
    }
    else if (idx < 72704)  pack33(w2, wpk2, idx - 68096, 16, 32);
    else if (idx < 81920)  pack33(w3, wpk3, idx - 72704, 32, 32);
    else if (idx < 91136)  pack33(w4, wpk4, idx - 81920, 32, 32);
    else if (idx < 109568) pack33(w5, wpk5, idx - 91136, 32, 64);
    else if (idx < 137216) pack33(w6, wpk6, idx - 109568, 96, 32);
    else if (idx < 155648) pack33(w7, wpk7, idx - 137216, 64, 32);
    else if (idx < 266240) {
        // conv9 y-composite tables: [cls][py][s=dr*3+dx][kst][half] x 512
        int i = idx - 155648;
        int j = i & 7;
        int lane = (i >> 3) & 63;
        int t = i >> 9;                 // 0..215
        int half = t & 1; t >>= 1;
        int kst  = t & 1; t >>= 1;
        int s    = t % 9; t /= 9;
        int py   = t & 1;
        int cls  = t >> 1;              // 0..2
        int dr = s / 3, dx = s % 3;
        int oc = half * 32 + (lane & 31);
        int ci = kst * 16 + (lane >> 5) * 8 + j;   // x8 channels 0..31
        float v = 0.f;
#pragma unroll
        for (int dy = 0; dy < 3; ++dy)
            v += ALPH[cls][py][dy][dr] * w9[((oc * 48 + ci) * 3 + dy) * 3 + dx];
        wpk9e[i] = f2bf(v);
    }
    else if (idx < 321536) {
        // conv8 y-composite tables (up channels 0..31): [cls][py][s][kst] x 512
        int i = idx - 266240;
        int j = i & 7;
        int lane = (i >> 3) & 63;
        int t = i >> 9;                 // 0..107
        int kst = t & 1; t >>= 1;
        int s   = t % 9; t /= 9;
        int py  = t & 1;
        int cls = t >> 1;               // 0..2
        int dr = s / 3, dx = s % 3;
        int oc = lane & 31;
        int ci = kst * 16 + (lane >> 5) * 8 + j;   // up channels 0..31
        float v = 0.f;
#pragma unroll
        for (int dy = 0; dy < 3; ++dy)
            v += ALPH[cls][py][dy][dr] * w8[((oc * 64 + ci) * 3 + dy) * 3 + dx];
        wpk8e[i] = f2bf(v);
    }
}

// ---------------------------------------------------------------------------
// Generic NHWC bf16 MFMA conv (3x3, pad 1, relu -> NHWC bf16).
// POOL=1: input is [8, 2H, 2W, CIN]; staging applies 2x2 maxpool on the fly.
// ---------------------------------------------------------------------------
template<int CIN, int COUT, int H, int W, int ROWS, int POOL>
__global__ __launch_bounds__(256)
void convN_mfma(const unsigned short* __restrict__ in,
                const unsigned short* __restrict__ wpk,
                const float* __restrict__ bias,
                unsigned short* __restrict__ out)
{
    constexpr int G = CIN / 8;
    constexpr int KST = CIN / 16;
    constexpr int MT = COUT / 32;
    constexpr int TR = ROWS + 2;
    constexpr int TWd = W + 2;
    constexpr int PS = TR * TWd * 8 + 8;
    __shared__ __align__(16) unsigned short smem[G * PS];

    const int tid  = threadIdx.x;
    const int lane = tid & 63;
    const int wv   = tid >> 6;
    const int q    = lane >> 5;
    const int y0   = blockIdx.x * ROWS;
    const int b    = blockIdx.y;

    for (int i = tid; i < G * TR * TWd; i += 256) {
        int g = i % G;
        int u = (i / G) % TWd;
        int t = i / (G * TWd);
        int yg = y0 + t - 1, xg = u - 1;
        u16x8 v = {0, 0, 0, 0, 0, 0, 0, 0};
        if (yg >= 0 && yg < H && xg >= 0 && xg < W) {
            if (POOL) {
                const unsigned short* q0 =
                    in + (((size_t)(b * 2 * H + 2 * yg) * 2 * W + 2 * xg) * CIN + g * 8);
                u16x8 a0 = *(const u16x8*)q0;
                u16x8 a1 = *(const u16x8*)(q0 + CIN);
                u16x8 a2 = *(const u16x8*)(q0 + (size_t)2 * W * CIN);
                u16x8 a3 = *(const u16x8*)(q0 + (size_t)2 * W * CIN + CIN);
#pragma unroll
                for (int j = 0; j < 8; ++j)
                    v[j] = f2bf(fmaxf(fmaxf(bf2f(a0[j]), bf2f(a1[j])),
                                      fmaxf(bf2f(a2[j]), bf2f(a3[j]))));
            } else {
                v = *(const u16x8*)(in + (((size_t)(b * H + yg) * W + xg) * CIN + g * 8));
            }
        }
        *(u16x8*)(&smem[g * PS + (t * TWd + u) * 8]) = v;
    }
    __syncthreads();

    const int p = wv * 32 + (lane & 31);
    const int r = p / W;
    const int x = p % W;

    f32x16 acc[MT];
#pragma unroll
    for (int mt = 0; mt < MT; ++mt)
#pragma unroll
        for (int i = 0; i < 16; ++i) acc[mt][i] = 0.f;

    const unsigned short* wbase = wpk + lane * 8;

#pragma unroll
    for (int s = 0; s < 9; ++s) {
        const int dy = s / 3, dx = s % 3;
#pragma unroll
        for (int kst = 0; kst < KST; ++kst) {
            const int g = kst * 2 + q;
            bf16x8 bfrag = *(const bf16x8*)(&smem[g * PS + ((r + dy) * TWd + (x + dx)) * 8]);
#pragma unroll
            for (int mt = 0; mt < MT; ++mt) {
                bf16x8 a = *(const bf16x8*)(wbase + ((s * KST + kst) * MT + mt) * 512);
                acc[mt] = __builtin_amdgcn_mfma_f32_32x32x16_bf16(a, bfrag, acc[mt], 0, 0, 0);
            }
        }
    }

    size_t base = ((size_t)(b * H + y0 + r) * W + x) * COUT;
#pragma unroll
    for (int mt = 0; mt < MT; ++mt)
#pragma unroll
        for (int rg = 0; rg < 4; ++rg) {
            int oc = mt * 32 + 8 * rg + 4 * q;
            unsigned short s0 = f2bf(fmaxf(acc[mt][rg * 4 + 0] + bias[oc + 0], 0.f));
            unsigned short s1 = f2bf(fmaxf(acc[mt][rg * 4 + 1] + bias[oc + 1], 0.f));
            unsigned short s2 = f2bf(fmaxf(acc[mt][rg * 4 + 2] + bias[oc + 2], 0.f));
            unsigned short s3 = f2bf(fmaxf(acc[mt][rg * 4 + 3] + bias[oc + 3], 0.f));
            *(uint2*)(out + base + oc) = make_uint2(pack2(s0, s1), pack2(s2, s3));
        }
}

// ---------------------------------------------------------------------------
// convU: 3x3 conv with FUSED upsample+concat staging (decoder stages 6,7).
// ---------------------------------------------------------------------------
template<int UPC, int CSKIP, int COUT, int H, int W, int ROWS>
__global__ __launch_bounds__(256)
void convU_mfma(const unsigned short* __restrict__ up,
                const unsigned short* __restrict__ skip,
                const unsigned short* __restrict__ wpk,
                const float* __restrict__ bias,
                unsigned short* __restrict__ out)
{
    constexpr int CIN = UPC + CSKIP;
    constexpr int G = CIN / 8;
    constexpr int GU = UPC / 8;
    constexpr int KST = CIN / 16;
    constexpr int MT = COUT / 32;
    constexpr int TR = ROWS + 2;
    constexpr int TWd = W + 2;
    constexpr int PS = TR * TWd * 8 + 8;
    __shared__ __align__(16) unsigned short smem[G * PS];

    const int tid  = threadIdx.x;
    const int lane = tid & 63;
    const int wv   = tid >> 6;
    const int q    = lane >> 5;
    const int y0   = blockIdx.x * ROWS;
    const int b    = blockIdx.y;

    for (int i = tid; i < G * TR * TWd; i += 256) {
        int g = i % G;
        int u = (i / G) % TWd;
        int t = i / (G * TWd);
        int yg = y0 + t - 1, xg = u - 1;
        u16x8 v = {0, 0, 0, 0, 0, 0, 0, 0};
        if (yg >= 0 && yg < H && xg >= 0 && xg < W) {
            if (g < GU) {
                int i00, i01, i10, i11; float wy, wx;
                bilin_setup(yg, xg, H / 2, W / 2, i00, i01, i10, i11, wy, wx);
                v = bilin8(up + (size_t)b * (H / 2) * (W / 2) * UPC + g * 8,
                           i00, i01, i10, i11, wy, wx, UPC);
            } else {
                v = *(const u16x8*)(skip + (((size_t)(b * H + yg) * W + xg) * CSKIP
                                            + (g - GU) * 8));
            }
        }
        *(u16x8*)(&smem[g * PS + (t * TWd + u) * 8]) = v;
    }
    __syncthreads();

    const int p = wv * 32 + (lane & 31);
    const int r = p / W;
    const int x = p % W;

    f32x16 acc[MT];
#pragma unroll
    for (int mt = 0; mt < MT; ++mt)
#pragma unroll
        for (int i = 0; i < 16; ++i) acc[mt][i] = 0.f;

    const unsigned short* wbase = wpk + lane * 8;

#pragma unroll
    for (int s = 0; s < 9; ++s) {
        const int dy = s / 3, dx = s % 3;
#pragma unroll
        for (int kst = 0; kst < KST; ++kst) {
            const int g = kst * 2 + q;
            bf16x8 bfrag = *(const bf16x8*)(&smem[g * PS + ((r + dy) * TWd + (x + dx)) * 8]);
#pragma unroll
            for (int mt = 0; mt < MT; ++mt) {
                bf16x8 a = *(const bf16x8*)(wbase + ((s * KST + kst) * MT + mt) * 512);
                acc[mt] = __builtin_amdgcn_mfma_f32_32x32x16_bf16(a, bfrag, acc[mt], 0, 0, 0);
            }
        }
    }

    size_t base = ((size_t)(b * H + y0 + r) * W + x) * COUT;
#pragma unroll
    for (int mt = 0; mt < MT; ++mt)
#pragma unroll
        for (int rg = 0; rg < 4; ++rg) {
            int oc = mt * 32 + 8 * rg + 4 * q;
            unsigned short s0 = f2bf(fmaxf(acc[mt][rg * 4 + 0] + bias[oc + 0], 0.f));
            unsigned short s1 = f2bf(fmaxf(acc[mt][rg * 4 + 1] + bias[oc + 1], 0.f));
            unsigned short s2 = f2bf(fmaxf(acc[mt][rg * 4 + 2] + bias[oc + 2], 0.f));
            unsigned short s3 = f2bf(fmaxf(acc[mt][rg * 4 + 3] + bias[oc + 3], 0.f));
            *(uint2*)(out + base + oc) = make_uint2(pack2(s0, s1), pack2(s2, s3));
        }
}

// ---------------------------------------------------------------------------
// Fused conv1 (5x5, relu -> x1t NHWC bf16) + conv_i (3x3 -> xin NCHW bf16).
// ---------------------------------------------------------------------------
__global__ __launch_bounds__(256)
void conv1i_mfma(const unsigned short* __restrict__ imgT,
                 const unsigned short* __restrict__ wpk1,
                 const unsigned short* __restrict__ wpki,
                 const float* __restrict__ b1, const float* __restrict__ bi,
                 unsigned short* __restrict__ x1t, unsigned short* __restrict__ xin)
{
    __shared__ __align__(16) unsigned short smem[2 * 5 * 132 * 8];

    const int tid  = threadIdx.x;
    const int lane = tid & 63;
    const int wv   = tid >> 6;
    const int n    = lane & 31;
    const int q    = lane >> 5;
    const int y    = blockIdx.x >> 1;
    const int x0   = (blockIdx.x & 1) * 128;
    const int b    = blockIdx.y;

    for (int i = tid; i < 5 * 132 * 2; i += 256) {
        int r   = i / 264;
        int rem = i - r * 264;
        int xi  = rem >> 1;
        int g   = rem & 1;
        int yg = y + r - 2;
        int xg = x0 - 2 + xi;
        uint4 v = make_uint4(0, 0, 0, 0);
        if (yg >= 0 && yg < 256 && xg >= 0 && xg < 256)
            v = *(const uint4*)(imgT + (((size_t)(b * 256 + yg) * 256 + xg) * 16 + g * 8));
        *(uint4*)(&smem[((g * 5 + r) * 132 + xi) * 8]) = v;
    }
    __syncthreads();

    f32x16 acc1, acci;
#pragma unroll
    for (int i = 0; i < 16; ++i) { acc1[i] = 0.f; acci[i] = 0.f; }

    const int pxl = wv * 32 + n;
    const unsigned short* wb1 = wpk1 + lane * 8;
    const unsigned short* wbi = wpki + lane * 8;

#pragma unroll
    for (int s = 0; s < 25; ++s) {
        const int dy = s / 5, dx = s % 5;
        bf16x8 bfrag = *(const bf16x8*)(&smem[((q * 5 + dy) * 132 + pxl + dx) * 8]);
        bf16x8 a = *(const bf16x8*)(wb1 + s * 512);
        acc1 = __builtin_amdgcn_mfma_f32_32x32x16_bf16(a, bfrag, acc1, 0, 0, 0);
    }
#pragma unroll
    for (int s = 0; s < 9; ++s) {
        const int dy = s / 3, dx = s % 3;
        bf16x8 bfrag = *(const bf16x8*)(&smem[((q * 5 + dy + 1) * 132 + pxl + dx + 1) * 8]);
        bf16x8 a = *(const bf16x8*)(wbi + s * 512);
        acci = __builtin_amdgcn_mfma_f32_32x32x16_bf16(a, bfrag, acci, 0, 0, 0);
    }

    const int px = x0 + pxl;
    size_t base1 = ((size_t)(b * 256 + y) * 256 + px) * 16;
#pragma unroll
    for (int rg = 0; rg < 2; ++rg) {
        int oc = 8 * rg + 4 * q;
        unsigned short s0 = f2bf(fmaxf(acc1[rg * 4 + 0] + b1[oc + 0], 0.f));
        unsigned short s1 = f2bf(fmaxf(acc1[rg * 4 + 1] + b1[oc + 1], 0.f));
        unsigned short s2 = f2bf(fmaxf(acc1[rg * 4 + 2] + b1[oc + 2], 0.f));
        unsigned short s3 = f2bf(fmaxf(acc1[rg * 4 + 3] + b1[oc + 3], 0.f));
        *(uint2*)(x1t + base1 + oc) = make_uint2(pack2(s0, s1), pack2(s2, s3));
    }
#pragma unroll
    for (int reg = 0; reg < 8; ++reg) {
        int row = (reg & 3) + 8 * (reg >> 2) + 4 * q;
        xin[((size_t)(b * 16 + row) * 256 + y) * 256 + px] = f2bf(acci[reg] + bi[row]);
    }
}

// ---------------------------------------------------------------------------
// conv8 MFMA, y-composite version (port of the round-4 conv9f change):
//  - up path (x7t) staged as 3 LOW-RES rows, x-lerp only; y interp folded
//    into composite A tables wpk8e[cls][py] (cls = top/interior/bottom).
//  - skip path (x2t) unchanged: 4 full-res rows, original wpk8 kst 2,3.
//  - LDS 29.7KB (was 33.9); MFMA count unchanged (36/thread).
// ---------------------------------------------------------------------------
__global__ __launch_bounds__(256)
void conv8_mfma(const unsigned short* __restrict__ x7t,
                const unsigned short* __restrict__ x2t,
                const unsigned short* __restrict__ wpk8,   // original (skip ksts)
                const unsigned short* __restrict__ wpk8e,  // composite up tables
                const float* __restrict__ bias,
                unsigned short* __restrict__ x8t)
{
    constexpr int PSU = 3 * 66 * 8 + 8;   // 1592 shorts per up plane
    constexpr int PSS = 4 * 66 * 8 + 8;   // 2120 shorts per skip plane
    constexpr int SOFF = 4 * PSU;         // 6368
    __shared__ __align__(16) unsigned short smem[4 * PSU + 4 * PSS]; // 29696 B

    const int tid  = threadIdx.x;
    const int lane = tid & 63;
    const int wv   = tid >> 6;
    const int n    = lane & 31;
    const int q    = lane >> 5;
    const int x0   = (blockIdx.x & 1) * 64;
    const int yp   = blockIdx.x >> 1;       // low-res row i, 0..63
    const int b    = blockIdx.y;

    for (int i = tid; i < 792 + 1056; i += 256) {
        if (i < 792) {
            // up part: 4 planes x 3 low-res rows x 66 cols, x-lerp only
            int g   = i & 3;
            int rem = i >> 2;           // 0..197
            int xi  = rem % 66;
            int t8  = rem / 66;         // 0..2  (low-res row yp-1+t8)
            int r   = yp - 1 + t8;
            int xg  = x0 - 1 + xi;
            u16x8 v = {0, 0, 0, 0, 0, 0, 0, 0};
            if (r >= 0 && r < 64 && xg >= 0 && xg < 128) {
                int ix0, ix1; float wx;
                up2_setup(xg, 64, ix0, ix1, wx);
                const unsigned short* S = x7t + ((size_t)(b * 64 + r) * 64) * 32 + g * 8;
                u16x8 a0 = *(const u16x8*)(S + ix0 * 32);
                u16x8 a1 = *(const u16x8*)(S + ix1 * 32);
                float w1x = 1.f - wx;
#pragma unroll
                for (int j = 0; j < 8; ++j)
                    v[j] = f2bf(w1x * bf2f(a0[j]) + wx * bf2f(a1[j]));
            }
            *(u16x8*)(&smem[g * PSU + (t8 * 66 + xi) * 8]) = v;
        } else {
            // skip part: 4 planes x 4 full-res rows x 66 cols, pure copy
            int jI  = i - 792;
            int g   = jI & 3;
            int rem = jI >> 2;          // 0..263
            int xi  = rem % 66;
            int t   = rem / 66;         // 0..3
            int yg  = 2 * yp + t - 1;
            int xg  = x0 - 1 + xi;
            uint4 v = make_uint4(0, 0, 0, 0);
            if (yg >= 0 && yg < 128 && xg >= 0 && xg < 128)
                v = *(const uint4*)(x2t + (((size_t)(b * 128 + yg) * 128 + xg) * 32 + g * 8));
            *(uint4*)(&smem[SOFF + g * PSS + (t * 66 + xi) * 8]) = v;
        }
    }
    __syncthreads();

    const int rr  = wv >> 1;                // output row parity py
    const int pxl = (wv & 1) * 32 + n;

    f32x16 acc;
#pragma unroll
    for (int i = 0; i < 16; ++i) acc[i] = 0.f;

    const int cls = (yp == 0) ? 0 : ((yp == 63) ? 2 : 1);
    const unsigned short* wE = wpk8e + (size_t)(cls * 2 + rr) * 9216 + lane * 8;
    const unsigned short* wS = wpk8 + lane * 8;

#pragma unroll
    for (int s = 0; s < 9; ++s) {
        const int dr = s / 3, dxx = s % 3;
        // up: kst 0,1 — B rows are low-res (shared by both parities)
#pragma unroll
        for (int kst = 0; kst < 2; ++kst) {
            const int g = kst * 2 + q;
            bf16x8 bfrag = *(const bf16x8*)(&smem[g * PSU + (dr * 66 + pxl + dxx) * 8]);
            bf16x8 a = *(const bf16x8*)(wE + (s * 2 + kst) * 512);
            acc = __builtin_amdgcn_mfma_f32_32x32x16_bf16(a, bfrag, acc, 0, 0, 0);
        }
        // skip: kst 2,3 — full-res rows, original weights, row base = rr
#pragma unroll
        for (int kst = 0; kst < 2; ++kst) {
            const int g = kst * 2 + q;
            bf16x8 bfrag = *(const bf16x8*)(&smem[SOFF + g * PSS + ((rr + dr) * 66 + pxl + dxx) * 8]);
            bf16x8 a = *(const bf16x8*)(wS + (s * 4 + kst + 2) * 512);
            acc = __builtin_amdgcn_mfma_f32_32x32x16_bf16(a, bfrag, acc, 0, 0, 0);
        }
    }

    size_t base = ((size_t)(b * 128 + 2 * yp + rr) * 128 + x0 + pxl) * 32;
#pragma unroll
    for (int rg = 0; rg < 4; ++rg) {
        int oc0 = 8 * rg + 4 * q;
        unsigned short s0 = f2bf(fmaxf(acc[rg * 4 + 0] + bias[oc0 + 0], 0.f));
        unsigned short s1 = f2bf(fmaxf(acc[rg * 4 + 1] + bias[oc0 + 1], 0.f));
        unsigned short s2 = f2bf(fmaxf(acc[rg * 4 + 2] + bias[oc0 + 2], 0.f));
        unsigned short s3 = f2bf(fmaxf(acc[rg * 4 + 3] + bias[oc0 + 3], 0.f));
        *(uint2*)(x8t + base + oc0) = make_uint2(pack2(s0, s1), pack2(s2, s3));
    }
}

// ---------------------------------------------------------------------------
// conv9 MFMA, y-composite version (unchanged from round 4).
// ---------------------------------------------------------------------------
__global__ __launch_bounds__(256)
void conv9f_mfma(const unsigned short* __restrict__ x8t,
                 const unsigned short* __restrict__ x1t,
                 const unsigned short* __restrict__ wpk,     // original (kst=2 slice used)
                 const unsigned short* __restrict__ wpk9e,   // composite tables
                 const float* __restrict__ bias,
                 unsigned short* __restrict__ fm)
{
    constexpr int PS8X = 3 * 66 * 8 + 8;   // 1592 shorts per x8 plane
    constexpr int PS1  = 4 * 66 * 8 + 8;   // 2120 shorts per x1 plane
    constexpr int X1OFF = 4 * PS8X;        // 6368
    __shared__ __align__(16) unsigned short smem[4 * PS8X + 2 * PS1];  // 21216 B

    const int tid  = threadIdx.x;
    const int lane = tid & 63;
    const int wv   = tid >> 6;
    const int n    = lane & 31;
    const int q    = lane >> 5;
    const int x0   = (blockIdx.x & 3) * 64;
    const int yp   = blockIdx.x >> 2;       // 0..127 (= low-res row i)
    const int b    = blockIdx.y;

    for (int i = tid; i < 792 + 528; i += 256) {
        if (i < 792) {
            // x8 part: 4 planes x 3 low-res rows x 66 cols, x-lerp only
            int g   = i & 3;
            int rem = i >> 2;           // 0..197
            int xi  = rem % 66;
            int t8  = rem / 66;         // 0..2  (low-res row i-1+t8)
            int r   = yp - 1 + t8;
            int xg  = x0 - 1 + xi;
            u16x8 v = {0, 0, 0, 0, 0, 0, 0, 0};
            if (r >= 0 && r < 128 && xg >= 0 && xg < 256) {
                int ix0, ix1; float wx;
                up2_setup(xg, 128, ix0, ix1, wx);
                const unsigned short* S = x8t + ((size_t)(b * 128 + r) * 128) * 32 + g * 8;
                u16x8 a0 = *(const u16x8*)(S + ix0 * 32);
                u16x8 a1 = *(const u16x8*)(S + ix1 * 32);
                float w1x = 1.f - wx;
#pragma unroll
                for (int j = 0; j < 8; ++j)
                    v[j] = f2bf(w1x * bf2f(a0[j]) + wx * bf2f(a1[j]));
            }
            *(u16x8*)(&smem[g * PS8X + (t8 * 66 + xi) * 8]) = v;
        } else {
            // x1 part: 2 planes x 4 full-res rows x 66 cols, pure copy
            int jI  = i - 792;
            int g   = jI & 1;
            int rem = jI >> 1;          // 0..263
            int xi  = rem % 66;
            int t   = rem / 66;         // 0..3
            int yg  = 2 * yp + t - 1;
            int xg  = x0 - 1 + xi;
            uint4 v = make_uint4(0, 0, 0, 0);
            if (yg >= 0 && yg < 256 && xg >= 0 && xg < 256)
                v = *(const uint4*)(x1t + (((size_t)(b * 256 + yg) * 256 + xg) * 16 + g * 8));
            *(uint4*)(&smem[X1OFF + g * PS1 + (t * 66 + xi) * 8]) = v;
        }
    }
    __syncthreads();

    const int rr  = wv >> 1;                 // output row parity py
    const int pxl = (wv & 1) * 32 + n;

    f32x16 acc0, acc1;
#pragma unroll
    for (int i = 0; i < 16; ++i) { acc0[i] = 0.f; acc1[i] = 0.f; }

    const int cls = (yp == 0) ? 0 : ((yp == 127) ? 2 : 1);
    const unsigned short* wE  = wpk9e + (size_t)(cls * 2 + rr) * 18432 + lane * 8;
    const unsigned short* w2b = wpk + lane * 8;

#pragma unroll
    for (int s = 0; s < 9; ++s) {
        const int dr = s / 3, dxx = s % 3;
        // x8 part: kst 0,1 — B rows are low-res (shared by both parities)
#pragma unroll
        for (int kst = 0; kst < 2; ++kst) {
            const int g = kst * 2 + q;
            bf16x8 bfrag = *(const bf16x8*)(&smem[g * PS8X + (dr * 66 + pxl + dxx) * 8]);
            bf16x8 a0 = *(const bf16x8*)(wE + ((s * 2 + kst) * 2 + 0) * 512);
            bf16x8 a1 = *(const bf16x8*)(wE + ((s * 2 + kst) * 2 + 1) * 512);
            acc0 = __builtin_amdgcn_mfma_f32_32x32x16_bf16(a0, bfrag, acc0, 0, 0, 0);
            acc1 = __builtin_amdgcn_mfma_f32_32x32x16_bf16(a1, bfrag, acc1, 0, 0, 0);
        }
        // x1 part: kst=2 — full-res rows, original weights, row base = rr
        {
            bf16x8 bfrag = *(const bf16x8*)(&smem[X1OFF + q * PS1 + ((rr + dr) * 66 + pxl + dxx) * 8]);
            bf16x8 a0 = *(const bf16x8*)(w2b + ((s * 3 + 2) * 2 + 0) * 512);
            bf16x8 a1 = *(const bf16x8*)(w2b + ((s * 3 + 2) * 2 + 1) * 512);
            acc0 = __builtin_amdgcn_mfma_f32_32x32x16_bf16(a0, bfrag, acc0, 0, 0, 0);
            acc1 = __builtin_amdgcn_mfma_f32_32x32x16_bf16(a1, bfrag, acc1, 0, 0, 0);
        }
    }

    // --- epilogue: LDS transpose -> vectorized NCHW stores ---
    __syncthreads();                       // staging buffer is now dead
    unsigned short* lout = smem;           // [64 oc][128 px] = 8192 shorts
    const int pb = rr * 64 + pxl + q * 512;   // px index + 4q row fold (4*128)
#pragma unroll
    for (int reg = 0; reg < 16; ++reg) {
        const int rbase = (reg & 3) + 8 * (reg >> 2);     // compile-time
        lout[rbase * 128 + pb]        = f2bf(fast_tanh(acc0[reg] + bias[rbase + 4 * q]));
        lout[(rbase + 32) * 128 + pb] = f2bf(fast_tanh(acc1[reg] + bias[rbase + 4 * q + 32]));
    }
    __syncthreads();

    const size_t fmb = (size_t)b * 64 * 65536 + (size_t)(2 * yp) * 256 + x0;
    for (int i = tid; i < 1024; i += 256) {
        int oc  = i >> 4;
        int p0  = (i & 15) * 8;        // 0..120
        int rr2 = p0 >> 6;             // output row within pair
        int pl  = p0 & 63;             // x within 64-px strip
        uint4 v = *(const uint4*)(lout + oc * 128 + p0);
        *(uint4*)(fm + fmb + (size_t)oc * 65536 + rr2 * 256 + pl) = v;
    }
}

// ---------------------------------------------------------------------------
// Segmented W-direction LRNN pair -> rnnW NCHW bf16 (conflict-free LDS).
// ---------------------------------------------------------------------------
__device__ __forceinline__ int X2C(int x) { return x + (x >> 5); }

__global__ __launch_bounds__(256)
void lrnn_w_seg(const unsigned short* __restrict__ X, const unsigned short* __restrict__ FM,
                unsigned short* __restrict__ rnnW)
{
    __shared__ float tx[3][16][264];
    __shared__ unsigned short outm[2][16][256];
    __shared__ float segres[2][16][8][4];
    __shared__ float hin[2][16][8][2];

    const int tid = threadIdx.x;
    const int bid = blockIdx.x;
    const int yt = bid & 15;
    const int c  = (bid >> 4) & 15;
    const int b  = bid >> 8;
    const int y0 = yt * 16;

    const size_t xb  = ((size_t)(b * 16 + c) * 256 + y0) * 256;
    const size_t p1b = ((size_t)(b * 64 + c) * 256 + y0) * 256;
    const size_t p2b = ((size_t)(b * 64 + 32 + c) * 256 + y0) * 256;

    for (int i = tid; i < 1536; i += 256) {
        int s = i >> 9;
        int r = i & 511;
        int y = r >> 5;
        int g = r & 31;
        const unsigned short* sp = (s == 0) ? (X + xb) : (s == 1 ? FM + p1b : FM + p2b);
        u16x8 v = *(const u16x8*)(sp + (size_t)y * 256 + g * 8);
        int c0 = X2C(g * 8);
#pragma unroll
        for (int j = 0; j < 8; ++j) tx[s][y][c0 + j] = bf2f(v[j]);
    }
    __syncthreads();

    const int y  = tid & 15;
    const int sg = (tid >> 4) & 7;
    const int d  = tid >> 7;

    {   // pass 1
        float h1 = 0.f, h2 = 0.f, A1 = 1.f, A2 = 1.f;
        if (d == 0) {
            int cs = X2C(sg * 32);
#pragma unroll
            for (int i = 0; i < 32; ++i) {
                float xv = tx[0][y][cs + i], p1 = tx[1][y][cs + i], p2 = tx[2][y][cs + i];
                h1 = fmaf(p1, h1 - xv, xv); A1 *= p1;
                h2 = fmaf(p2, h2 - xv, xv); A2 *= p2;
            }
        } else {
            int cs = X2C(255 - sg * 32);
#pragma unroll
            for (int i = 0; i < 32; ++i) {
                float xv = tx[0][y][cs - i], p1 = tx[1][y][cs - i], p2 = tx[2][y][cs - i];
                h1 = fmaf(p1, h1 - xv, xv); A1 *= p1;
                h2 = fmaf(p2, h2 - xv, xv); A2 *= p2;
            }
        }
        segres[d][y][sg][0] = h1; segres[d][y][sg][1] = A1;
        segres[d][y][sg][2] = h2; segres[d][y][sg][3] = A2;
    }
    __syncthreads();

    if (tid < 32) {
        int yy = tid & 15, dd = tid >> 4;
        float c1 = 0.f, c2 = 0.f;
        for (int s = 0; s < 8; ++s) {
            hin[dd][yy][s][0] = c1;
            hin[dd][yy][s][1] = c2;
            c1 = segres[dd][yy][s][0] + segres[dd][yy][s][1] * c1;
            c2 = segres[dd][yy][s][2] + segres[dd][yy][s][3] * c2;
        }
    }
    __syncthreads();

    {   // pass 2
        float h1 = hin[d][y][sg][0], h2 = hin[d][y][sg][1];
        if (d == 0) {
            int cs = X2C(sg * 32);
            int xs = sg * 32;
#pragma unroll
            for (int i = 0; i < 32; ++i) {
                float xv = tx[0][y][cs + i], p1 = tx[1][y][cs + i], p2 = tx[2][y][cs + i];
                h1 = fmaf(p1, h1 - xv, xv);
                h2 = fmaf(p2, h2 - xv, xv);
                outm[0][y][xs + i] = f2bf(fmaxf(h1, h2));
            }
        } else {
            int cs = X2C(255 - sg * 32);
#pragma unroll
            for (int i = 0; i < 32; ++i) {
                int t = sg * 32 + i;
                float xv = tx[0][y][cs - i], p1 = tx[1][y][cs - i], p2 = tx[2][y][cs - i];
                h1 = fmaf(p1, h1 - xv, xv);
                h2 = fmaf(p2, h2 - xv, xv);
                outm[1][y][t] = f2bf(fmaxf(h1, h2));
            }
        }
    }
    __syncthreads();

    for (int i = tid; i < 4096; i += 256) {
        int x = i & 255, yy = i >> 8;
        float m = fmaxf(bf2f(outm[0][yy][x]), bf2f(outm[1][yy][x]));
        rnnW[xb + (size_t)yy * 256 + x] = f2bf(m);
    }
}

// ---------------------------------------------------------------------------
// Segmented H-direction LRNN pair -> rnnH NCHW bf16 (conflict-free LDS).
// ---------------------------------------------------------------------------
__global__ __launch_bounds__(256)
void lrnn_h_seg(const unsigned short* __restrict__ X, const unsigned short* __restrict__ FM,
                unsigned short* __restrict__ rnnH)
{
    __shared__ float tx[3][264][17];
    __shared__ unsigned short outm[2][256][16];
    __shared__ float segres[2][16][8][4];
    __shared__ float hin[2][16][8][2];

    const int tid = threadIdx.x;
    const int bid = blockIdx.x;
    const int xt = bid & 15;
    const int c  = (bid >> 4) & 15;
    const int b  = bid >> 8;
    const int x0 = xt * 16;

    const size_t xb  = (size_t)(b * 16 + c) * 65536 + x0;
    const size_t p1b = (size_t)(b * 64 + 16 + c) * 65536 + x0;
    const size_t p2b = (size_t)(b * 64 + 48 + c) * 65536 + x0;

    for (int i = tid; i < 1536; i += 256) {
        int s = i >> 9;
        int r = i & 511;
        int y = r >> 1;
        int g = r & 1;
        const unsigned short* sp = (s == 0) ? (X + xb) : (s == 1 ? FM + p1b : FM + p2b);
        u16x8 v = *(const u16x8*)(sp + (size_t)y * 256 + g * 8);
        int pr = y + (y >> 5);
#pragma unroll
        for (int j = 0; j < 8; ++j) tx[s][pr][g * 8 + j] = bf2f(v[j]);
    }
    __syncthreads();

    const int x  = tid & 15;
    const int sg = (tid >> 4) & 7;
    const int d  = tid >> 7;

    {   // pass 1
        float h1 = 0.f, h2 = 0.f, A1 = 1.f, A2 = 1.f;
        if (d == 0) {
            int rs = X2C(sg * 32);
#pragma unroll
            for (int i = 0; i < 32; ++i) {
                float xv = tx[0][rs + i][x], p1 = tx[1][rs + i][x], p2 = tx[2][rs + i][x];
                h1 = fmaf(p1, h1 - xv, xv); A1 *= p1;
                h2 = fmaf(p2, h2 - xv, xv); A2 *= p2;
            }
        } else {
            int rs = X2C(255 - sg * 32);
#pragma unroll
            for (int i = 0; i < 32; ++i) {
                float xv = tx[0][rs - i][x], p1 = tx[1][rs - i][x], p2 = tx[2][rs - i][x];
                h1 = fmaf(p1, h1 - xv, xv); A1 *= p1;
                h2 = fmaf(p2, h2 - xv, xv); A2 *= p2;
            }
        }
        segres[d][x][sg][0] = h1; segres[d][x][sg][1] = A1;
        segres[d][x][sg][2] = h2; segres[d][x][sg][3] = A2;
    }
    __syncthreads();

    if (tid < 32) {
        int xx = tid & 15, dd = tid >> 4;
        float c1 = 0.f, c2 = 0.f;
        for (int s = 0; s < 8; ++s) {
            hin[dd][xx][s][0] = c1;
            hin[dd][xx][s][1] = c2;
            c1 = segres[dd][xx][s][0] + segres[dd][xx][s][1] * c1;
            c2 = segres[dd][xx][s][2] + segres[dd][xx][s][3] * c2;
        }
    }
    __syncthreads();

    {   // pass 2
        float h1 = hin[d][x][sg][0], h2 = hin[d][x][sg][1];
        if (d == 0) {
            int rs = X2C(sg * 32);
            int ys = sg * 32;
#pragma unroll
            for (int i = 0; i < 32; ++i) {
                float xv = tx[0][rs + i][x], p1 = tx[1][rs + i][x], p2 = tx[2][rs + i][x];
                h1 = fmaf(p1, h1 - xv, xv);
                h2 = fmaf(p2, h2 - xv, xv);
                outm[0][ys + i][x] = f2bf(fmaxf(h1, h2));
            }
        } else {
            int rs = X2C(255 - sg * 32);
#pragma unroll
            for (int i = 0; i < 32; ++i) {
                int t = sg * 32 + i;
                float xv = tx[0][rs - i][x], p1 = tx[1][rs - i][x], p2 = tx[2][rs - i][x];
                h1 = fmaf(p1, h1 - xv, xv);
                h2 = fmaf(p2, h2 - xv, xv);
                outm[1][t][x] = f2bf(fmaxf(h1, h2));
            }
        }
    }
    __syncthreads();

    for (int i = tid; i < 4096; i += 256) {
        int xx = i & 15, yy = i >> 4;
        float m = fmaxf(bf2f(outm[0][yy][xx]), bf2f(outm[1][yy][xx]));
        rnnH[xb + (size_t)yy * 256 + xx] = f2bf(m);
    }
}

// ---------------------------------------------------------------------------
// Output head MFMA: max(rnnW, rnnH) from NCHW bf16 -> 3x3 conv (Cin16,
// Cout3), sigmoid -> d_out NCHW fp32.
// Staging vectorized this round: u16x8 loads per (ch,row,chunk), scalar
// fallback only at edge chunks; bf16 max via bit-select (no re-round).
// ---------------------------------------------------------------------------
__global__ __launch_bounds__(256)
void convo_mfma(const unsigned short* __restrict__ rnnW,
                const unsigned short* __restrict__ rnnH,
                const unsigned short* __restrict__ wpko,
                const float* __restrict__ bo,
                float* __restrict__ outp)
{
    __shared__ __align__(16) unsigned short smem[2 * 3 * 130 * 8];

    const int tid  = threadIdx.x;
    const int lane = tid & 63;
    const int wv   = tid >> 6;
    const int n    = lane & 31;
    const int q    = lane >> 5;
    const int y    = blockIdx.x >> 1;
    const int x0   = (blockIdx.x & 1) * 128;
    const int b    = blockIdx.y;

    for (int i = tid; i < 3 * 16 * 17; i += 256) {
        int ch  = i & 15;
        int t   = i >> 4;          // 0..50
        int c   = t % 17;
        int r   = t / 17;          // 0..2
        int xi0 = c * 8;
        int yg  = y + r - 1;
        int g = ch >> 3, j = ch & 7;
        unsigned short* sb = &smem[((g * 3 + r) * 130) * 8 + j];
        if (yg >= 0 && yg < 256) {
            size_t off = (size_t)(b * 16 + ch) * 65536 + (size_t)yg * 256;
            int xg0 = x0 - 1 + xi0;
            if (xg0 >= 0 && xg0 + 7 < 256 && xi0 + 7 < 130) {
                u16x8 a  = *(const u16x8*)(rnnW + off + xg0);
                u16x8 bv = *(const u16x8*)(rnnH + off + xg0);
#pragma unroll
                for (int k = 0; k < 8; ++k)
                    sb[(xi0 + k) * 8] = bf2f(a[k]) >= bf2f(bv[k]) ? a[k] : bv[k];
            } else {
#pragma unroll
                for (int k = 0; k < 8; ++k) {
                    int xi = xi0 + k;
                    if (xi >= 130) break;
                    int xg = x0 - 1 + xi;
                    unsigned short m = 0;
                    if (xg >= 0 && xg < 256) {
                        unsigned short a = rnnW[off + xg], bvv = rnnH[off + xg];
                        m = bf2f(a) >= bf2f(bvv) ? a : bvv;
                    }
                    sb[xi * 8] = m;
                }
            }
        } else {
#pragma unroll
            for (int k = 0; k < 8; ++k) {
                int xi = xi0 + k;
                if (xi >= 130) break;
                sb[xi * 8] = 0;
            }
        }
    }
    __syncthreads();

    f32x16 acc;
#pragma unroll
    for (int i = 0; i < 16; ++i) acc[i] = 0.f;

    const int pxl = wv * 32 + n;
    const unsigned short* wbase = wpko + lane * 8;

#pragma unroll
    for (int s = 0; s < 9; ++s) {
        const int dy = s / 3, dx = s % 3;
        bf16x8 bfrag = *(const bf16x8*)(&smem[((q * 3 + dy) * 130 + pxl + dx) * 8]);
        bf16x8 a = *(const bf16x8*)(wbase + s * 512);
        acc = __builtin_amdgcn_mfma_f32_32x32x16_bf16(a, bfrag, acc, 0, 0, 0);
    }

    const int px = x0 + pxl;
    if (q == 0) {
#pragma unroll
        for (int oc = 0; oc < 3; ++oc) {
            float r = acc[oc] + bo[oc];
            outp[((size_t)(b * 3 + oc) * 256 + y) * 256 + px] = 1.f / (1.f + __expf(-r));
        }
    }
}

// ---------------------------------------------------------------------------
extern "C" void kernel_launch(void* const* d_in, const int* in_sizes, int n_in,
                              void* d_out, int out_size, void* d_ws, size_t ws_size,
                              hipStream_t stream)
{
    const float* img = (const float*)d_in[0];
    const float* w1 = (const float*)d_in[1];  const float* b1 = (const float*)d_in[2];
    const float* w2 = (const float*)d_in[3];  const float* b2 = (const float*)d_in[4];
    const float* w3 = (const float*)d_in[5];  const float* b3 = (const float*)d_in[6];
    const float* w4 = (const float*)d_in[7];  const float* b4 = (const float*)d_in[8];
    const float* w5 = (const float*)d_in[9];  const float* b5 = (const float*)d_in[10];
    const float* w6 = (const float*)d_in[11]; const float* b6 = (const float*)d_in[12];
    const float* w7 = (const float*)d_in[13]; const float* b7 = (const float*)d_in[14];
    const float* w8 = (const float*)d_in[15]; const float* b8 = (const float*)d_in[16];
    const float* w9 = (const float*)d_in[17]; const float* b9 = (const float*)d_in[18];
    const float* wi = (const float*)d_in[19]; const float* bi = (const float*)d_in[20];
    const float* wo = (const float*)d_in[21]; const float* bo = (const float*)d_in[22];

    char* wsb = (char*)d_ws;
    const size_t MB = (size_t)(1u << 20);
    unsigned short* imgT  = (unsigned short*)(wsb);             // [0,16) dead after conv1i
    unsigned short* x1t   = (unsigned short*)(wsb + 16 * MB);   // [16,32) till conv9f
    unsigned short* x2t   = (unsigned short*)(wsb + 32 * MB);   // [32,40) till conv8
    unsigned short* x3t   = (unsigned short*)(wsb + 40 * MB);   // [40,42) till conv7
    unsigned short* x4t   = (unsigned short*)(wsb + 42 * MB);   // [42,42.5) till conv6
    unsigned short* x5t   = (unsigned short*)(wsb + 43 * MB);   // [43,43.25)
    unsigned short* x6t   = (unsigned short*)(wsb + 46 * MB);   // [46,46.5)
    unsigned short* x7t   = (unsigned short*)(wsb + 51 * MB);   // [51,53) till conv8
    unsigned short* x8t   = (unsigned short*)(wsb + 70 * MB);   // [70,78) till conv9f
    unsigned short* fm16  = (unsigned short*)(wsb + 112 * MB);  // [112,176) NCHW bf16
    unsigned short* xin16 = (unsigned short*)(wsb + 176 * MB);  // [176,192) NCHW bf16
    unsigned short* rnnW  = (unsigned short*)(wsb);             // [0,16)  (imgT dead)
    unsigned short* rnnH  = (unsigned short*)(wsb + 16 * MB);   // [16,32) (x1t dead)
    unsigned short* wpk9 = (unsigned short*)(wsb + 192 * MB);
    unsigned short* wpk8 = wpk9 + 27648;
    unsigned short* wpk1 = wpk8 + 18432;
    unsigned short* wpki = wpk1 + 12800;
    unsigned short* wpko = wpki + 4608;
    unsigned short* wpk2 = wpko + 4608;
    unsigned short* wpk3 = wpk2 + 4608;
    unsigned short* wpk4 = wpk3 + 9216;
    unsigned short* wpk5 = wpk4 + 9216;
    unsigned short* wpk6 = wpk5 + 18432;
    unsigned short* wpk7 = wpk6 + 27648;
    unsigned short* wpk9e = wpk7 + 18432;    // 110592 shorts (conv9 composite)
    unsigned short* wpk8e = wpk9e + 110592;  // 55296 shorts (conv8 composite)
    float* outp = (float*)d_out;

    // --- single weight-pack dispatch + img transpose ---
    wprep_mega<<<1256, 256, 0, stream>>>(w9, w8, w1, wi, wo, w2, w3, w4, w5, w6, w7,
                                         wpk9, wpk8, wpk1, wpki, wpko,
                                         wpk2, wpk3, wpk4, wpk5, wpk6, wpk7,
                                         wpk9e, wpk8e);
    imgT_bf16<<<2048, 256, 0, stream>>>(img, imgT);

    // --- fused conv1 (relu -> x1t NHWC) + input projection (xin16 NCHW bf16) ---
    { dim3 grd(512, 8);
      conv1i_mfma<<<grd, 256, 0, stream>>>(imgT, wpk1, wpki, b1, bi, x1t, xin16); }

    // --- encoder: pools fused into conv staging ---
    convN_mfma<16, 32, 128, 128, 1, 1><<<dim3(128, 8), 256, 0, stream>>>(x1t, wpk2, b2, x2t);
    convN_mfma<32, 32, 64, 64, 2, 1><<<dim3(32, 8), 256, 0, stream>>>(x2t, wpk3, b3, x3t);
    convN_mfma<32, 32, 32, 32, 4, 1><<<dim3(8, 8), 256, 0, stream>>>(x3t, wpk4, b4, x4t);
    convN_mfma<32, 64, 16, 16, 8, 1><<<dim3(2, 8), 256, 0, stream>>>(x4t, wpk5, b5, x5t);

    // --- decoder: upcat fused into conv6/conv7/conv8 staging ---
    convU_mfma<64, 32, 32, 32, 32, 4><<<dim3(8, 8), 256, 0, stream>>>(x5t, x4t, wpk6, b6, x6t);
    convU_mfma<32, 32, 32, 64, 64, 2><<<dim3(32, 8), 256, 0, stream>>>(x6t, x3t, wpk7, b7, x7t);
    { dim3 grd(128, 8);
      conv8_mfma<<<grd, 256, 0, stream>>>(x7t, x2t, wpk8, wpk8e, b8, x8t); }

    // --- stage 9: y-composite conv9 (512 blocks) ---
    { dim3 grd(512, 8);
      conv9f_mfma<<<grd, 256, 0, stream>>>(x8t, x1t, wpk9, wpk9e, b9, fm16); }

    // --- spatial RNN: segmented scans ---
    lrnn_w_seg<<<2048, 256, 0, stream>>>(xin16, fm16, rnnW);
    lrnn_h_seg<<<2048, 256, 0, stream>>>(xin16, fm16, rnnH);

    // --- output head ---
    { dim3 grd(512, 8);
      convo_mfma<<<grd, 256, 0, stream>>>(rnnW, rnnH, wpko, bo, outp); }
}

// Round 6
// 388.789 us; speedup vs baseline: 1.0643x; 1.0643x over previous
//
#include <hip/hip_runtime.h>
#include <math.h>

typedef __attribute__((ext_vector_type(8)))  short bf16x8;
typedef __attribute__((ext_vector_type(8)))  unsigned short u16x8;
typedef __attribute__((ext_vector_type(16))) float f32x16;

__device__ __forceinline__ unsigned short f2bf(float f) {
    unsigned u = __float_as_uint(f);
    unsigned r = (u + 0x7FFFu + ((u >> 16) & 1u)) >> 16;
    return (unsigned short)r;
}
__device__ __forceinline__ float bf2f(unsigned short h) {
    return __uint_as_float(((unsigned)h) << 16);
}
__device__ __forceinline__ unsigned pack2(unsigned short a, unsigned short b) {
    return (unsigned)a | ((unsigned)b << 16);
}
__device__ __forceinline__ float fast_tanh(float x) {
    float e = __expf(2.f * x);
    return 1.f - 2.f / (e + 1.f);
}

__device__ __forceinline__ void bilin_setup(int y, int x, int Hi, int Wi,
                                            int& i00, int& i01, int& i10, int& i11,
                                            float& wy, float& wx)
{
    float fy = 0.5f * y - 0.25f;
    float fx = 0.5f * x - 0.25f;
    float y0f = floorf(fy), x0f = floorf(fx);
    wy = fy - y0f; wx = fx - x0f;
    int yA = (int)y0f, xA = (int)x0f;
    int yB = yA + 1, xB = xA + 1;
    yA = yA < 0 ? 0 : (yA > Hi - 1 ? Hi - 1 : yA);
    yB = yB < 0 ? 0 : (yB > Hi - 1 ? Hi - 1 : yB);
    xA = xA < 0 ? 0 : (xA > Wi - 1 ? Wi - 1 : xA);
    xB = xB < 0 ? 0 : (xB > Wi - 1 ? Wi - 1 : xB);
    i00 = yA * Wi + xA; i01 = yA * Wi + xB;
    i10 = yB * Wi + xA; i11 = yB * Wi + xB;
}

// 2x upsample w/ half-pixel centers: fixed parity weights, no floorf needed.
// v=2k: srcs {k-1,k} w=0.75 on k ; v=2k+1: srcs {k,k+1} w=0.25 on k+1
__device__ __forceinline__ void up2_setup(int v, int Hi, int& i0, int& i1, float& w)
{
    int a = (v - 1) >> 1;           // arithmetic shift: v=0 -> -1
    i0 = a < 0 ? 0 : a;
    int b = a + 1;
    i1 = b > Hi - 1 ? Hi - 1 : b;
    w = (v & 1) ? 0.25f : 0.75f;
}

__device__ __forceinline__ u16x8 bilin8(const unsigned short* __restrict__ sb,
                                        int i00, int i01, int i10, int i11,
                                        float wy, float wx, int stride)
{
    u16x8 v00 = *(const u16x8*)(sb + (size_t)i00 * stride);
    u16x8 v01 = *(const u16x8*)(sb + (size_t)i01 * stride);
    u16x8 v10 = *(const u16x8*)(sb + (size_t)i10 * stride);
    u16x8 v11 = *(const u16x8*)(sb + (size_t)i11 * stride);
    float w00 = (1.f - wy) * (1.f - wx), w01 = (1.f - wy) * wx;
    float w10 = wy * (1.f - wx),         w11 = wy * wx;
    u16x8 r;
#pragma unroll
    for (int j = 0; j < 8; ++j)
        r[j] = f2bf(w00 * bf2f(v00[j]) + w01 * bf2f(v01[j]) +
                    w10 * bf2f(v10[j]) + w11 * bf2f(v11[j]));
    return r;
}

// y-interp composite coefficients: ALPH[cls][py][dy][dr]
//   cls: 0 = top (i=0), 1 = interior, 2 = bottom (i=last)
//   out row y = 2i+py, conv tap dy reads upsampled row v = y+dy-1,
//   which is a lerp of low-res rows i-1+dr (dr = 0..2).
//   Derived from half-pixel bilinear w/ edge clamp + conv zero-pad.
__device__ const float ALPH[3][2][3][3] = {
    { { {0.f,0.f,0.f},      {0.f,1.f,0.f},       {0.f,0.75f,0.25f} },
      { {0.f,1.f,0.f},      {0.f,0.75f,0.25f},   {0.f,0.25f,0.75f} } },
    { { {0.75f,0.25f,0.f},  {0.25f,0.75f,0.f},   {0.f,0.75f,0.25f} },
      { {0.25f,0.75f,0.f},  {0.f,0.75f,0.25f},   {0.f,0.25f,0.75f} } },
    { { {0.75f,0.25f,0.f},  {0.25f,0.75f,0.f},   {0.f,1.f,0.f} },
      { {0.25f,0.75f,0.f},  {0.f,1.f,0.f},       {0.f,0.f,0.f} } }
};

// ---------------------------------------------------------------------------
// img [8][15][256][256] fp32 -> imgT [b][y][x][16] bf16 (ch15 = 0)
// ---------------------------------------------------------------------------
__global__ void imgT_bf16(const float* __restrict__ img, unsigned short* __restrict__ dst)
{
    int idx = blockIdx.x * 256 + threadIdx.x;
    if (idx >= 8 * 256 * 256) return;
    int x = idx & 255, y = (idx >> 8) & 255, b = idx >> 16;
    unsigned short v[16];
#pragma unroll
    for (int c = 0; c < 15; ++c)
        v[c] = f2bf(img[(size_t)(b * 15 + c) * 65536 + y * 256 + x]);
    v[15] = 0;
    uint4 lo = make_uint4(pack2(v[0], v[1]), pack2(v[2], v[3]), pack2(v[4], v[5]), pack2(v[6], v[7]));
    uint4 hi = make_uint4(pack2(v[8], v[9]), pack2(v[10], v[11]), pack2(v[12], v[13]), pack2(v[14], v[15]));
    *(uint4*)(dst + (size_t)idx * 16)     = lo;
    *(uint4*)(dst + (size_t)idx * 16 + 8) = hi;
}

// ---------------------------------------------------------------------------
// Mega weight-pack: all packs in one dispatch (incl. y-composite tables for
// conv9 AND conv8).
// ---------------------------------------------------------------------------
__device__ __forceinline__ void pack33(const float* __restrict__ w,
                                       unsigned short* __restrict__ dst,
                                       int i, int Cin, int Cout)
{
    int KST = Cin >> 4, MT = Cout >> 5;
    int j = i & 7;
    int lane = (i >> 3) & 63;
    int t = i >> 9;
    int mt = t % MT; t /= MT;
    int kst = t % KST;
    int s = t / KST;
    int oc = mt * 32 + (lane & 31);
    int ci = kst * 16 + (lane >> 5) * 8 + j;
    dst[i] = f2bf(w[(oc * Cin + ci) * 9 + s]);
}

__global__ void wprep_mega(const float* __restrict__ w9, const float* __restrict__ w8,
                           const float* __restrict__ w1, const float* __restrict__ wi,
                           const float* __restrict__ wo, const float* __restrict__ w2,
                           const float* __restrict__ w3, const float* __restrict__ w4,
                           const float* __restrict__ w5, const float* __restrict__ w6,
                           const float* __restrict__ w7,
                           unsigned short* __restrict__ wpk9, unsigned short* __restrict__ wpk8,
                           unsigned short* __restrict__ wpk1, unsigned short* __restrict__ wpki,
                           unsigned short* __restrict__ wpko, unsigned short* __restrict__ wpk2,
                           unsigned short* __restrict__ wpk3, unsigned short* __restrict__ wpk4,
                           unsigned short* __restrict__ wpk5, unsigned short* __restrict__ wpk6,
                           unsigned short* __restrict__ wpk7, unsigned short* __restrict__ wpk9e,
                           unsigned short* __restrict__ wpk8e)
{
    int idx = blockIdx.x * 256 + threadIdx.x;
    if (idx < 27648)       pack33(w9, wpk9, idx, 48, 64);
    else if (idx < 46080)  pack33(w8, wpk8, idx - 27648, 64, 32);
    else if (idx < 58880) {
        int i = idx - 46080;
        int j = i & 7;
        int lane = (i >> 3) & 63;
        int s = i >> 9;                 // 0..24
        int oc = lane & 31;
        int ci = (lane >> 5) * 8 + j;   // 0..15
        float v = 0.f;
        if (oc < 16 && ci < 15) v = w1[((oc * 15 + ci) * 5 + s / 5) * 5 + s % 5];
        wpk1[i] = f2bf(v);
    } else if (idx < 63488) {
        int i = idx - 58880;
        int j = i & 7;
        int lane = (i >> 3) & 63;
        int s = i >> 9;                 // 0..8
        int oc = lane & 31;
        int ci = (lane >> 5) * 8 + j;
        float v = 0.f;
        if (oc < 16 && ci < 15) v = wi[((oc * 15 + ci) * 3 + s / 3) * 3 + s % 3];
        wpki[i] = f2bf(v);
    } else if (idx < 68096) {
        int i = idx - 63488;
        int j = i & 7;
        int lane = (i >> 3) & 63;
        int s = i >> 9;
        int oc = lane & 31;
        int ci = (lane >> 5) * 8 + j;
        float v = 0.f;
        if (oc < 3) v = wo[((oc * 16 + ci) * 3 + s / 3) * 3 + s % 3];
        wpko[i] = f2bf(v);
    }
    else if (idx < 72704)  pack33(w2, wpk2, idx - 68096, 16, 32);
    else if (idx < 81920)  pack33(w3, wpk3, idx - 72704, 32, 32);
    else if (idx < 91136)  pack33(w4, wpk4, idx - 81920, 32, 32);
    else if (idx < 109568) pack33(w5, wpk5, idx - 91136, 32, 64);
    else if (idx < 137216) pack33(w6, wpk6, idx - 109568, 96, 32);
    else if (idx < 155648) pack33(w7, wpk7, idx - 137216, 64, 32);
    else if (idx < 266240) {
        // conv9 y-composite tables: [cls][py][s=dr*3+dx][kst][half] x 512
        int i = idx - 155648;
        int j = i & 7;
        int lane = (i >> 3) & 63;
        int t = i >> 9;                 // 0..215
        int half = t & 1; t >>= 1;
        int kst  = t & 1; t >>= 1;
        int s    = t % 9; t /= 9;
        int py   = t & 1;
        int cls  = t >> 1;              // 0..2
        int dr = s / 3, dx = s % 3;
        int oc = half * 32 + (lane & 31);
        int ci = kst * 16 + (lane >> 5) * 8 + j;   // x8 channels 0..31
        float v = 0.f;
#pragma unroll
        for (int dy = 0; dy < 3; ++dy)
            v += ALPH[cls][py][dy][dr] * w9[((oc * 48 + ci) * 3 + dy) * 3 + dx];
        wpk9e[i] = f2bf(v);
    }
    else if (idx < 321536) {
        // conv8 y-composite tables (up channels 0..31): [cls][py][s][kst] x 512
        int i = idx - 266240;
        int j = i & 7;
        int lane = (i >> 3) & 63;
        int t = i >> 9;                 // 0..107
        int kst = t & 1; t >>= 1;
        int s   = t % 9; t /= 9;
        int py  = t & 1;
        int cls = t >> 1;               // 0..2
        int dr = s / 3, dx = s % 3;
        int oc = lane & 31;
        int ci = kst * 16 + (lane >> 5) * 8 + j;   // up channels 0..31
        float v = 0.f;
#pragma unroll
        for (int dy = 0; dy < 3; ++dy)
            v += ALPH[cls][py][dy][dr] * w8[((oc * 64 + ci) * 3 + dy) * 3 + dx];
        wpk8e[i] = f2bf(v);
    }
}

// ---------------------------------------------------------------------------
// Generic NHWC bf16 MFMA conv (3x3, pad 1, relu -> NHWC bf16).
// POOL=1: input is [8, 2H, 2W, CIN]; staging applies 2x2 maxpool on the fly.
// ---------------------------------------------------------------------------
template<int CIN, int COUT, int H, int W, int ROWS, int POOL>
__global__ __launch_bounds__(256)
void convN_mfma(const unsigned short* __restrict__ in,
                const unsigned short* __restrict__ wpk,
                const float* __restrict__ bias,
                unsigned short* __restrict__ out)
{
    constexpr int G = CIN / 8;
    constexpr int KST = CIN / 16;
    constexpr int MT = COUT / 32;
    constexpr int TR = ROWS + 2;
    constexpr int TWd = W + 2;
    constexpr int PS = TR * TWd * 8 + 8;
    __shared__ __align__(16) unsigned short smem[G * PS];

    const int tid  = threadIdx.x;
    const int lane = tid & 63;
    const int wv   = tid >> 6;
    const int q    = lane >> 5;
    const int y0   = blockIdx.x * ROWS;
    const int b    = blockIdx.y;

    for (int i = tid; i < G * TR * TWd; i += 256) {
        int g = i % G;
        int u = (i / G) % TWd;
        int t = i / (G * TWd);
        int yg = y0 + t - 1, xg = u - 1;
        u16x8 v = {0, 0, 0, 0, 0, 0, 0, 0};
        if (yg >= 0 && yg < H && xg >= 0 && xg < W) {
            if (POOL) {
                const unsigned short* q0 =
                    in + (((size_t)(b * 2 * H + 2 * yg) * 2 * W + 2 * xg) * CIN + g * 8);
                u16x8 a0 = *(const u16x8*)q0;
                u16x8 a1 = *(const u16x8*)(q0 + CIN);
                u16x8 a2 = *(const u16x8*)(q0 + (size_t)2 * W * CIN);
                u16x8 a3 = *(const u16x8*)(q0 + (size_t)2 * W * CIN + CIN);
#pragma unroll
                for (int j = 0; j < 8; ++j)
                    v[j] = f2bf(fmaxf(fmaxf(bf2f(a0[j]), bf2f(a1[j])),
                                      fmaxf(bf2f(a2[j]), bf2f(a3[j]))));
            } else {
                v = *(const u16x8*)(in + (((size_t)(b * H + yg) * W + xg) * CIN + g * 8));
            }
        }
        *(u16x8*)(&smem[g * PS + (t * TWd + u) * 8]) = v;
    }
    __syncthreads();

    const int p = wv * 32 + (lane & 31);
    const int r = p / W;
    const int x = p % W;

    f32x16 acc[MT];
#pragma unroll
    for (int mt = 0; mt < MT; ++mt)
#pragma unroll
        for (int i = 0; i < 16; ++i) acc[mt][i] = 0.f;

    const unsigned short* wbase = wpk + lane * 8;

#pragma unroll
    for (int s = 0; s < 9; ++s) {
        const int dy = s / 3, dx = s % 3;
#pragma unroll
        for (int kst = 0; kst < KST; ++kst) {
            const int g = kst * 2 + q;
            bf16x8 bfrag = *(const bf16x8*)(&smem[g * PS + ((r + dy) * TWd + (x + dx)) * 8]);
#pragma unroll
            for (int mt = 0; mt < MT; ++mt) {
                bf16x8 a = *(const bf16x8*)(wbase + ((s * KST + kst) * MT + mt) * 512);
                acc[mt] = __builtin_amdgcn_mfma_f32_32x32x16_bf16(a, bfrag, acc[mt], 0, 0, 0);
            }
        }
    }

    size_t base = ((size_t)(b * H + y0 + r) * W + x) * COUT;
#pragma unroll
    for (int mt = 0; mt < MT; ++mt)
#pragma unroll
        for (int rg = 0; rg < 4; ++rg) {
            int oc = mt * 32 + 8 * rg + 4 * q;
            unsigned short s0 = f2bf(fmaxf(acc[mt][rg * 4 + 0] + bias[oc + 0], 0.f));
            unsigned short s1 = f2bf(fmaxf(acc[mt][rg * 4 + 1] + bias[oc + 1], 0.f));
            unsigned short s2 = f2bf(fmaxf(acc[mt][rg * 4 + 2] + bias[oc + 2], 0.f));
            unsigned short s3 = f2bf(fmaxf(acc[mt][rg * 4 + 3] + bias[oc + 3], 0.f));
            *(uint2*)(out + base + oc) = make_uint2(pack2(s0, s1), pack2(s2, s3));
        }
}

// ---------------------------------------------------------------------------
// convU: 3x3 conv with FUSED upsample+concat staging (decoder stages 6,7).
// ---------------------------------------------------------------------------
template<int UPC, int CSKIP, int COUT, int H, int W, int ROWS>
__global__ __launch_bounds__(256)
void convU_mfma(const unsigned short* __restrict__ up,
                const unsigned short* __restrict__ skip,
                const unsigned short* __restrict__ wpk,
                const float* __restrict__ bias,
                unsigned short* __restrict__ out)
{
    constexpr int CIN = UPC + CSKIP;
    constexpr int G = CIN / 8;
    constexpr int GU = UPC / 8;
    constexpr int KST = CIN / 16;
    constexpr int MT = COUT / 32;
    constexpr int TR = ROWS + 2;
    constexpr int TWd = W + 2;
    constexpr int PS = TR * TWd * 8 + 8;
    __shared__ __align__(16) unsigned short smem[G * PS];

    const int tid  = threadIdx.x;
    const int lane = tid & 63;
    const int wv   = tid >> 6;
    const int q    = lane >> 5;
    const int y0   = blockIdx.x * ROWS;
    const int b    = blockIdx.y;

    for (int i = tid; i < G * TR * TWd; i += 256) {
        int g = i % G;
        int u = (i / G) % TWd;
        int t = i / (G * TWd);
        int yg = y0 + t - 1, xg = u - 1;
        u16x8 v = {0, 0, 0, 0, 0, 0, 0, 0};
        if (yg >= 0 && yg < H && xg >= 0 && xg < W) {
            if (g < GU) {
                int i00, i01, i10, i11; float wy, wx;
                bilin_setup(yg, xg, H / 2, W / 2, i00, i01, i10, i11, wy, wx);
                v = bilin8(up + (size_t)b * (H / 2) * (W / 2) * UPC + g * 8,
                           i00, i01, i10, i11, wy, wx, UPC);
            } else {
                v = *(const u16x8*)(skip + (((size_t)(b * H + yg) * W + xg) * CSKIP
                                            + (g - GU) * 8));
            }
        }
        *(u16x8*)(&smem[g * PS + (t * TWd + u) * 8]) = v;
    }
    __syncthreads();

    const int p = wv * 32 + (lane & 31);
    const int r = p / W;
    const int x = p % W;

    f32x16 acc[MT];
#pragma unroll
    for (int mt = 0; mt < MT; ++mt)
#pragma unroll
        for (int i = 0; i < 16; ++i) acc[mt][i] = 0.f;

    const unsigned short* wbase = wpk + lane * 8;

#pragma unroll
    for (int s = 0; s < 9; ++s) {
        const int dy = s / 3, dx = s % 3;
#pragma unroll
        for (int kst = 0; kst < KST; ++kst) {
            const int g = kst * 2 + q;
            bf16x8 bfrag = *(const bf16x8*)(&smem[g * PS + ((r + dy) * TWd + (x + dx)) * 8]);
#pragma unroll
            for (int mt = 0; mt < MT; ++mt) {
                bf16x8 a = *(const bf16x8*)(wbase + ((s * KST + kst) * MT + mt) * 512);
                acc[mt] = __builtin_amdgcn_mfma_f32_32x32x16_bf16(a, bfrag, acc[mt], 0, 0, 0);
            }
        }
    }

    size_t base = ((size_t)(b * H + y0 + r) * W + x) * COUT;
#pragma unroll
    for (int mt = 0; mt < MT; ++mt)
#pragma unroll
        for (int rg = 0; rg < 4; ++rg) {
            int oc = mt * 32 + 8 * rg + 4 * q;
            unsigned short s0 = f2bf(fmaxf(acc[mt][rg * 4 + 0] + bias[oc + 0], 0.f));
            unsigned short s1 = f2bf(fmaxf(acc[mt][rg * 4 + 1] + bias[oc + 1], 0.f));
            unsigned short s2 = f2bf(fmaxf(acc[mt][rg * 4 + 2] + bias[oc + 2], 0.f));
            unsigned short s3 = f2bf(fmaxf(acc[mt][rg * 4 + 3] + bias[oc + 3], 0.f));
            *(uint2*)(out + base + oc) = make_uint2(pack2(s0, s1), pack2(s2, s3));
        }
}

// ---------------------------------------------------------------------------
// Fused conv1 (5x5, relu -> x1t NHWC bf16) + conv_i (3x3 -> xin NCHW bf16).
// ---------------------------------------------------------------------------
__global__ __launch_bounds__(256)
void conv1i_mfma(const unsigned short* __restrict__ imgT,
                 const unsigned short* __restrict__ wpk1,
                 const unsigned short* __restrict__ wpki,
                 const float* __restrict__ b1, const float* __restrict__ bi,
                 unsigned short* __restrict__ x1t, unsigned short* __restrict__ xin)
{
    __shared__ __align__(16) unsigned short smem[2 * 5 * 132 * 8];

    const int tid  = threadIdx.x;
    const int lane = tid & 63;
    const int wv   = tid >> 6;
    const int n    = lane & 31;
    const int q    = lane >> 5;
    const int y    = blockIdx.x >> 1;
    const int x0   = (blockIdx.x & 1) * 128;
    const int b    = blockIdx.y;

    for (int i = tid; i < 5 * 132 * 2; i += 256) {
        int r   = i / 264;
        int rem = i - r * 264;
        int xi  = rem >> 1;
        int g   = rem & 1;
        int yg = y + r - 2;
        int xg = x0 - 2 + xi;
        uint4 v = make_uint4(0, 0, 0, 0);
        if (yg >= 0 && yg < 256 && xg >= 0 && xg < 256)
            v = *(const uint4*)(imgT + (((size_t)(b * 256 + yg) * 256 + xg) * 16 + g * 8));
        *(uint4*)(&smem[((g * 5 + r) * 132 + xi) * 8]) = v;
    }
    __syncthreads();

    f32x16 acc1, acci;
#pragma unroll
    for (int i = 0; i < 16; ++i) { acc1[i] = 0.f; acci[i] = 0.f; }

    const int pxl = wv * 32 + n;
    const unsigned short* wb1 = wpk1 + lane * 8;
    const unsigned short* wbi = wpki + lane * 8;

#pragma unroll
    for (int s = 0; s < 25; ++s) {
        const int dy = s / 5, dx = s % 5;
        bf16x8 bfrag = *(const bf16x8*)(&smem[((q * 5 + dy) * 132 + pxl + dx) * 8]);
        bf16x8 a = *(const bf16x8*)(wb1 + s * 512);
        acc1 = __builtin_amdgcn_mfma_f32_32x32x16_bf16(a, bfrag, acc1, 0, 0, 0);
    }
#pragma unroll
    for (int s = 0; s < 9; ++s) {
        const int dy = s / 3, dx = s % 3;
        bf16x8 bfrag = *(const bf16x8*)(&smem[((q * 5 + dy + 1) * 132 + pxl + dx + 1) * 8]);
        bf16x8 a = *(const bf16x8*)(wbi + s * 512);
        acci = __builtin_amdgcn_mfma_f32_32x32x16_bf16(a, bfrag, acci, 0, 0, 0);
    }

    const int px = x0 + pxl;
    size_t base1 = ((size_t)(b * 256 + y) * 256 + px) * 16;
#pragma unroll
    for (int rg = 0; rg < 2; ++rg) {
        int oc = 8 * rg + 4 * q;
        unsigned short s0 = f2bf(fmaxf(acc1[rg * 4 + 0] + b1[oc + 0], 0.f));
        unsigned short s1 = f2bf(fmaxf(acc1[rg * 4 + 1] + b1[oc + 1], 0.f));
        unsigned short s2 = f2bf(fmaxf(acc1[rg * 4 + 2] + b1[oc + 2], 0.f));
        unsigned short s3 = f2bf(fmaxf(acc1[rg * 4 + 3] + b1[oc + 3], 0.f));
        *(uint2*)(x1t + base1 + oc) = make_uint2(pack2(s0, s1), pack2(s2, s3));
    }
#pragma unroll
    for (int reg = 0; reg < 8; ++reg) {
        int row = (reg & 3) + 8 * (reg >> 2) + 4 * q;
        xin[((size_t)(b * 16 + row) * 256 + y) * 256 + px] = f2bf(acci[reg] + bi[row]);
    }
}

// ---------------------------------------------------------------------------
// conv8 MFMA, y-composite version (unchanged from round 5).
// ---------------------------------------------------------------------------
__global__ __launch_bounds__(256)
void conv8_mfma(const unsigned short* __restrict__ x7t,
                const unsigned short* __restrict__ x2t,
                const unsigned short* __restrict__ wpk8,   // original (skip ksts)
                const unsigned short* __restrict__ wpk8e,  // composite up tables
                const float* __restrict__ bias,
                unsigned short* __restrict__ x8t)
{
    constexpr int PSU = 3 * 66 * 8 + 8;   // 1592 shorts per up plane
    constexpr int PSS = 4 * 66 * 8 + 8;   // 2120 shorts per skip plane
    constexpr int SOFF = 4 * PSU;         // 6368
    __shared__ __align__(16) unsigned short smem[4 * PSU + 4 * PSS]; // 29696 B

    const int tid  = threadIdx.x;
    const int lane = tid & 63;
    const int wv   = tid >> 6;
    const int n    = lane & 31;
    const int q    = lane >> 5;
    const int x0   = (blockIdx.x & 1) * 64;
    const int yp   = blockIdx.x >> 1;       // low-res row i, 0..63
    const int b    = blockIdx.y;

    for (int i = tid; i < 792 + 1056; i += 256) {
        if (i < 792) {
            // up part: 4 planes x 3 low-res rows x 66 cols, x-lerp only
            int g   = i & 3;
            int rem = i >> 2;           // 0..197
            int xi  = rem % 66;
            int t8  = rem / 66;         // 0..2  (low-res row yp-1+t8)
            int r   = yp - 1 + t8;
            int xg  = x0 - 1 + xi;
            u16x8 v = {0, 0, 0, 0, 0, 0, 0, 0};
            if (r >= 0 && r < 64 && xg >= 0 && xg < 128) {
                int ix0, ix1; float wx;
                up2_setup(xg, 64, ix0, ix1, wx);
                const unsigned short* S = x7t + ((size_t)(b * 64 + r) * 64) * 32 + g * 8;
                u16x8 a0 = *(const u16x8*)(S + ix0 * 32);
                u16x8 a1 = *(const u16x8*)(S + ix1 * 32);
                float w1x = 1.f - wx;
#pragma unroll
                for (int j = 0; j < 8; ++j)
                    v[j] = f2bf(w1x * bf2f(a0[j]) + wx * bf2f(a1[j]));
            }
            *(u16x8*)(&smem[g * PSU + (t8 * 66 + xi) * 8]) = v;
        } else {
            // skip part: 4 planes x 4 full-res rows x 66 cols, pure copy
            int jI  = i - 792;
            int g   = jI & 3;
            int rem = jI >> 2;          // 0..263
            int xi  = rem % 66;
            int t   = rem / 66;         // 0..3
            int yg  = 2 * yp + t - 1;
            int xg  = x0 - 1 + xi;
            uint4 v = make_uint4(0, 0, 0, 0);
            if (yg >= 0 && yg < 128 && xg >= 0 && xg < 128)
                v = *(const uint4*)(x2t + (((size_t)(b * 128 + yg) * 128 + xg) * 32 + g * 8));
            *(uint4*)(&smem[SOFF + g * PSS + (t * 66 + xi) * 8]) = v;
        }
    }
    __syncthreads();

    const int rr  = wv >> 1;                // output row parity py
    const int pxl = (wv & 1) * 32 + n;

    f32x16 acc;
#pragma unroll
    for (int i = 0; i < 16; ++i) acc[i] = 0.f;

    const int cls = (yp == 0) ? 0 : ((yp == 63) ? 2 : 1);
    const unsigned short* wE = wpk8e + (size_t)(cls * 2 + rr) * 9216 + lane * 8;
    const unsigned short* wS = wpk8 + lane * 8;

#pragma unroll
    for (int s = 0; s < 9; ++s) {
        const int dr = s / 3, dxx = s % 3;
        // up: kst 0,1 — B rows are low-res (shared by both parities)
#pragma unroll
        for (int kst = 0; kst < 2; ++kst) {
            const int g = kst * 2 + q;
            bf16x8 bfrag = *(const bf16x8*)(&smem[g * PSU + (dr * 66 + pxl + dxx) * 8]);
            bf16x8 a = *(const bf16x8*)(wE + (s * 2 + kst) * 512);
            acc = __builtin_amdgcn_mfma_f32_32x32x16_bf16(a, bfrag, acc, 0, 0, 0);
        }
        // skip: kst 2,3 — full-res rows, original weights, row base = rr
#pragma unroll
        for (int kst = 0; kst < 2; ++kst) {
            const int g = kst * 2 + q;
            bf16x8 bfrag = *(const bf16x8*)(&smem[SOFF + g * PSS + ((rr + dr) * 66 + pxl + dxx) * 8]);
            bf16x8 a = *(const bf16x8*)(wS + (s * 4 + kst + 2) * 512);
            acc = __builtin_amdgcn_mfma_f32_32x32x16_bf16(a, bfrag, acc, 0, 0, 0);
        }
    }

    size_t base = ((size_t)(b * 128 + 2 * yp + rr) * 128 + x0 + pxl) * 32;
#pragma unroll
    for (int rg = 0; rg < 4; ++rg) {
        int oc0 = 8 * rg + 4 * q;
        unsigned short s0 = f2bf(fmaxf(acc[rg * 4 + 0] + bias[oc0 + 0], 0.f));
        unsigned short s1 = f2bf(fmaxf(acc[rg * 4 + 1] + bias[oc0 + 1], 0.f));
        unsigned short s2 = f2bf(fmaxf(acc[rg * 4 + 2] + bias[oc0 + 2], 0.f));
        unsigned short s3 = f2bf(fmaxf(acc[rg * 4 + 3] + bias[oc0 + 3], 0.f));
        *(uint2*)(x8t + base + oc0) = make_uint2(pack2(s0, s1), pack2(s2, s3));
    }
}

// ---------------------------------------------------------------------------
// conv9 MFMA, y-composite version (unchanged from round 4).
// ---------------------------------------------------------------------------
__global__ __launch_bounds__(256)
void conv9f_mfma(const unsigned short* __restrict__ x8t,
                 const unsigned short* __restrict__ x1t,
                 const unsigned short* __restrict__ wpk,     // original (kst=2 slice used)
                 const unsigned short* __restrict__ wpk9e,   // composite tables
                 const float* __restrict__ bias,
                 unsigned short* __restrict__ fm)
{
    constexpr int PS8X = 3 * 66 * 8 + 8;   // 1592 shorts per x8 plane
    constexpr int PS1  = 4 * 66 * 8 + 8;   // 2120 shorts per x1 plane
    constexpr int X1OFF = 4 * PS8X;        // 6368
    __shared__ __align__(16) unsigned short smem[4 * PS8X + 2 * PS1];  // 21216 B

    const int tid  = threadIdx.x;
    const int lane = tid & 63;
    const int wv   = tid >> 6;
    const int n    = lane & 31;
    const int q    = lane >> 5;
    const int x0   = (blockIdx.x & 3) * 64;
    const int yp   = blockIdx.x >> 2;       // 0..127 (= low-res row i)
    const int b    = blockIdx.y;

    for (int i = tid; i < 792 + 528; i += 256) {
        if (i < 792) {
            // x8 part: 4 planes x 3 low-res rows x 66 cols, x-lerp only
            int g   = i & 3;
            int rem = i >> 2;           // 0..197
            int xi  = rem % 66;
            int t8  = rem / 66;         // 0..2  (low-res row i-1+t8)
            int r   = yp - 1 + t8;
            int xg  = x0 - 1 + xi;
            u16x8 v = {0, 0, 0, 0, 0, 0, 0, 0};
            if (r >= 0 && r < 128 && xg >= 0 && xg < 256) {
                int ix0, ix1; float wx;
                up2_setup(xg, 128, ix0, ix1, wx);
                const unsigned short* S = x8t + ((size_t)(b * 128 + r) * 128) * 32 + g * 8;
                u16x8 a0 = *(const u16x8*)(S + ix0 * 32);
                u16x8 a1 = *(const u16x8*)(S + ix1 * 32);
                float w1x = 1.f - wx;
#pragma unroll
                for (int j = 0; j < 8; ++j)
                    v[j] = f2bf(w1x * bf2f(a0[j]) + wx * bf2f(a1[j]));
            }
            *(u16x8*)(&smem[g * PS8X + (t8 * 66 + xi) * 8]) = v;
        } else {
            // x1 part: 2 planes x 4 full-res rows x 66 cols, pure copy
            int jI  = i - 792;
            int g   = jI & 1;
            int rem = jI >> 1;          // 0..263
            int xi  = rem % 66;
            int t   = rem / 66;         // 0..3
            int yg  = 2 * yp + t - 1;
            int xg  = x0 - 1 + xi;
            uint4 v = make_uint4(0, 0, 0, 0);
            if (yg >= 0 && yg < 256 && xg >= 0 && xg < 256)
                v = *(const uint4*)(x1t + (((size_t)(b * 256 + yg) * 256 + xg) * 16 + g * 8));
            *(uint4*)(&smem[X1OFF + g * PS1 + (t * 66 + xi) * 8]) = v;
        }
    }
    __syncthreads();

    const int rr  = wv >> 1;                 // output row parity py
    const int pxl = (wv & 1) * 32 + n;

    f32x16 acc0, acc1;
#pragma unroll
    for (int i = 0; i < 16; ++i) { acc0[i] = 0.f; acc1[i] = 0.f; }

    const int cls = (yp == 0) ? 0 : ((yp == 127) ? 2 : 1);
    const unsigned short* wE  = wpk9e + (size_t)(cls * 2 + rr) * 18432 + lane * 8;
    const unsigned short* w2b = wpk + lane * 8;

#pragma unroll
    for (int s = 0; s < 9; ++s) {
        const int dr = s / 3, dxx = s % 3;
        // x8 part: kst 0,1 — B rows are low-res (shared by both parities)
#pragma unroll
        for (int kst = 0; kst < 2; ++kst) {
            const int g = kst * 2 + q;
            bf16x8 bfrag = *(const bf16x8*)(&smem[g * PS8X + (dr * 66 + pxl + dxx) * 8]);
            bf16x8 a0 = *(const bf16x8*)(wE + ((s * 2 + kst) * 2 + 0) * 512);
            bf16x8 a1 = *(const bf16x8*)(wE + ((s * 2 + kst) * 2 + 1) * 512);
            acc0 = __builtin_amdgcn_mfma_f32_32x32x16_bf16(a0, bfrag, acc0, 0, 0, 0);
            acc1 = __builtin_amdgcn_mfma_f32_32x32x16_bf16(a1, bfrag, acc1, 0, 0, 0);
        }
        // x1 part: kst=2 — full-res rows, original weights, row base = rr
        {
            bf16x8 bfrag = *(const bf16x8*)(&smem[X1OFF + q * PS1 + ((rr + dr) * 66 + pxl + dxx) * 8]);
            bf16x8 a0 = *(const bf16x8*)(w2b + ((s * 3 + 2) * 2 + 0) * 512);
            bf16x8 a1 = *(const bf16x8*)(w2b + ((s * 3 + 2) * 2 + 1) * 512);
            acc0 = __builtin_amdgcn_mfma_f32_32x32x16_bf16(a0, bfrag, acc0, 0, 0, 0);
            acc1 = __builtin_amdgcn_mfma_f32_32x32x16_bf16(a1, bfrag, acc1, 0, 0, 0);
        }
    }

    // --- epilogue: LDS transpose -> vectorized NCHW stores ---
    __syncthreads();                       // staging buffer is now dead
    unsigned short* lout = smem;           // [64 oc][128 px] = 8192 shorts
    const int pb = rr * 64 + pxl + q * 512;   // px index + 4q row fold (4*128)
#pragma unroll
    for (int reg = 0; reg < 16; ++reg) {
        const int rbase = (reg & 3) + 8 * (reg >> 2);     // compile-time
        lout[rbase * 128 + pb]        = f2bf(fast_tanh(acc0[reg] + bias[rbase + 4 * q]));
        lout[(rbase + 32) * 128 + pb] = f2bf(fast_tanh(acc1[reg] + bias[rbase + 4 * q + 32]));
    }
    __syncthreads();

    const size_t fmb = (size_t)b * 64 * 65536 + (size_t)(2 * yp) * 256 + x0;
    for (int i = tid; i < 1024; i += 256) {
        int oc  = i >> 4;
        int p0  = (i & 15) * 8;        // 0..120
        int rr2 = p0 >> 6;             // output row within pair
        int pl  = p0 & 63;             // x within 64-px strip
        uint4 v = *(const uint4*)(lout + oc * 128 + p0);
        *(uint4*)(fm + fmb + (size_t)oc * 65536 + rr2 * 256 + pl) = v;
    }
}

// ---------------------------------------------------------------------------
// Segmented W-direction LRNN pair -> rnnW NCHW bf16 (conflict-free LDS).
// ---------------------------------------------------------------------------
__device__ __forceinline__ int X2C(int x) { return x + (x >> 5); }

__global__ __launch_bounds__(256)
void lrnn_w_seg(const unsigned short* __restrict__ X, const unsigned short* __restrict__ FM,
                unsigned short* __restrict__ rnnW)
{
    __shared__ float tx[3][16][264];
    __shared__ unsigned short outm[2][16][256];
    __shared__ float segres[2][16][8][4];
    __shared__ float hin[2][16][8][2];

    const int tid = threadIdx.x;
    const int bid = blockIdx.x;
    const int yt = bid & 15;
    const int c  = (bid >> 4) & 15;
    const int b  = bid >> 8;
    const int y0 = yt * 16;

    const size_t xb  = ((size_t)(b * 16 + c) * 256 + y0) * 256;
    const size_t p1b = ((size_t)(b * 64 + c) * 256 + y0) * 256;
    const size_t p2b = ((size_t)(b * 64 + 32 + c) * 256 + y0) * 256;

    for (int i = tid; i < 1536; i += 256) {
        int s = i >> 9;
        int r = i & 511;
        int y = r >> 5;
        int g = r & 31;
        const unsigned short* sp = (s == 0) ? (X + xb) : (s == 1 ? FM + p1b : FM + p2b);
        u16x8 v = *(const u16x8*)(sp + (size_t)y * 256 + g * 8);
        int c0 = X2C(g * 8);
#pragma unroll
        for (int j = 0; j < 8; ++j) tx[s][y][c0 + j] = bf2f(v[j]);
    }
    __syncthreads();

    const int y  = tid & 15;
    const int sg = (tid >> 4) & 7;
    const int d  = tid >> 7;

    {   // pass 1
        float h1 = 0.f, h2 = 0.f, A1 = 1.f, A2 = 1.f;
        if (d == 0) {
            int cs = X2C(sg * 32);
#pragma unroll
            for (int i = 0; i < 32; ++i) {
                float xv = tx[0][y][cs + i], p1 = tx[1][y][cs + i], p2 = tx[2][y][cs + i];
                h1 = fmaf(p1, h1 - xv, xv); A1 *= p1;
                h2 = fmaf(p2, h2 - xv, xv); A2 *= p2;
            }
        } else {
            int cs = X2C(255 - sg * 32);
#pragma unroll
            for (int i = 0; i < 32; ++i) {
                float xv = tx[0][y][cs - i], p1 = tx[1][y][cs - i], p2 = tx[2][y][cs - i];
                h1 = fmaf(p1, h1 - xv, xv); A1 *= p1;
                h2 = fmaf(p2, h2 - xv, xv); A2 *= p2;
            }
        }
        segres[d][y][sg][0] = h1; segres[d][y][sg][1] = A1;
        segres[d][y][sg][2] = h2; segres[d][y][sg][3] = A2;
    }
    __syncthreads();

    if (tid < 32) {
        int yy = tid & 15, dd = tid >> 4;
        float c1 = 0.f, c2 = 0.f;
        for (int s = 0; s < 8; ++s) {
            hin[dd][yy][s][0] = c1;
            hin[dd][yy][s][1] = c2;
            c1 = segres[dd][yy][s][0] + segres[dd][yy][s][1] * c1;
            c2 = segres[dd][yy][s][2] + segres[dd][yy][s][3] * c2;
        }
    }
    __syncthreads();

    {   // pass 2
        float h1 = hin[d][y][sg][0], h2 = hin[d][y][sg][1];
        if (d == 0) {
            int cs = X2C(sg * 32);
            int xs = sg * 32;
#pragma unroll
            for (int i = 0; i < 32; ++i) {
                float xv = tx[0][y][cs + i], p1 = tx[1][y][cs + i], p2 = tx[2][y][cs + i];
                h1 = fmaf(p1, h1 - xv, xv);
                h2 = fmaf(p2, h2 - xv, xv);
                outm[0][y][xs + i] = f2bf(fmaxf(h1, h2));
            }
        } else {
            int cs = X2C(255 - sg * 32);
#pragma unroll
            for (int i = 0; i < 32; ++i) {
                int t = sg * 32 + i;
                float xv = tx[0][y][cs - i], p1 = tx[1][y][cs - i], p2 = tx[2][y][cs - i];
                h1 = fmaf(p1, h1 - xv, xv);
                h2 = fmaf(p2, h2 - xv, xv);
                outm[1][y][t] = f2bf(fmaxf(h1, h2));
            }
        }
    }
    __syncthreads();

    for (int i = tid; i < 4096; i += 256) {
        int x = i & 255, yy = i >> 8;
        float m = fmaxf(bf2f(outm[0][yy][x]), bf2f(outm[1][yy][x]));
        rnnW[xb + (size_t)yy * 256 + x] = f2bf(m);
    }
}

// ---------------------------------------------------------------------------
// Segmented H-direction LRNN pair; writeback FUSES max with rnnW -> rnnM.
// ---------------------------------------------------------------------------
__global__ __launch_bounds__(256)
void lrnn_h_seg(const unsigned short* __restrict__ X, const unsigned short* __restrict__ FM,
                const unsigned short* __restrict__ rnnW, unsigned short* __restrict__ rnnM)
{
    __shared__ float tx[3][264][17];
    __shared__ unsigned short outm[2][256][16];
    __shared__ float segres[2][16][8][4];
    __shared__ float hin[2][16][8][2];

    const int tid = threadIdx.x;
    const int bid = blockIdx.x;
    const int xt = bid & 15;
    const int c  = (bid >> 4) & 15;
    const int b  = bid >> 8;
    const int x0 = xt * 16;

    const size_t xb  = (size_t)(b * 16 + c) * 65536 + x0;
    const size_t p1b = (size_t)(b * 64 + 16 + c) * 65536 + x0;
    const size_t p2b = (size_t)(b * 64 + 48 + c) * 65536 + x0;

    for (int i = tid; i < 1536; i += 256) {
        int s = i >> 9;
        int r = i & 511;
        int y = r >> 1;
        int g = r & 1;
        const unsigned short* sp = (s == 0) ? (X + xb) : (s == 1 ? FM + p1b : FM + p2b);
        u16x8 v = *(const u16x8*)(sp + (size_t)y * 256 + g * 8);
        int pr = y + (y >> 5);
#pragma unroll
        for (int j = 0; j < 8; ++j) tx[s][pr][g * 8 + j] = bf2f(v[j]);
    }
    __syncthreads();

    const int x  = tid & 15;
    const int sg = (tid >> 4) & 7;
    const int d  = tid >> 7;

    {   // pass 1
        float h1 = 0.f, h2 = 0.f, A1 = 1.f, A2 = 1.f;
        if (d == 0) {
            int rs = X2C(sg * 32);
#pragma unroll
            for (int i = 0; i < 32; ++i) {
                float xv = tx[0][rs + i][x], p1 = tx[1][rs + i][x], p2 = tx[2][rs + i][x];
                h1 = fmaf(p1, h1 - xv, xv); A1 *= p1;
                h2 = fmaf(p2, h2 - xv, xv); A2 *= p2;
            }
        } else {
            int rs = X2C(255 - sg * 32);
#pragma unroll
            for (int i = 0; i < 32; ++i) {
                float xv = tx[0][rs - i][x], p1 = tx[1][rs - i][x], p2 = tx[2][rs - i][x];
                h1 = fmaf(p1, h1 - xv, xv); A1 *= p1;
                h2 = fmaf(p2, h2 - xv, xv); A2 *= p2;
            }
        }
        segres[d][x][sg][0] = h1; segres[d][x][sg][1] = A1;
        segres[d][x][sg][2] = h2; segres[d][x][sg][3] = A2;
    }
    __syncthreads();

    if (tid < 32) {
        int xx = tid & 15, dd = tid >> 4;
        float c1 = 0.f, c2 = 0.f;
        for (int s = 0; s < 8; ++s) {
            hin[dd][xx][s][0] = c1;
            hin[dd][xx][s][1] = c2;
            c1 = segres[dd][xx][s][0] + segres[dd][xx][s][1] * c1;
            c2 = segres[dd][xx][s][2] + segres[dd][xx][s][3] * c2;
        }
    }
    __syncthreads();

    {   // pass 2
        float h1 = hin[d][x][sg][0], h2 = hin[d][x][sg][1];
        if (d == 0) {
            int rs = X2C(sg * 32);
            int ys = sg * 32;
#pragma unroll
            for (int i = 0; i < 32; ++i) {
                float xv = tx[0][rs + i][x], p1 = tx[1][rs + i][x], p2 = tx[2][rs + i][x];
                h1 = fmaf(p1, h1 - xv, xv);
                h2 = fmaf(p2, h2 - xv, xv);
                outm[0][ys + i][x] = f2bf(fmaxf(h1, h2));
            }
        } else {
            int rs = X2C(255 - sg * 32);
#pragma unroll
            for (int i = 0; i < 32; ++i) {
                int t = sg * 32 + i;
                float xv = tx[0][rs - i][x], p1 = tx[1][rs - i][x], p2 = tx[2][rs - i][x];
                h1 = fmaf(p1, h1 - xv, xv);
                h2 = fmaf(p2, h2 - xv, xv);
                outm[1][t][x] = f2bf(fmaxf(h1, h2));
            }
        }
    }
    __syncthreads();

    for (int i = tid; i < 4096; i += 256) {
        int xx = i & 15, yy = i >> 4;
        float m = fmaxf(bf2f(outm[0][yy][xx]), bf2f(outm[1][yy][xx]));
        size_t off = xb + (size_t)yy * 256 + xx;
        m = fmaxf(m, bf2f(rnnW[off]));
        rnnM[off] = f2bf(m);
    }
}

// ---------------------------------------------------------------------------
// Output head MFMA: rnnM (single NCHW bf16 tensor, max already fused) ->
// 3x3 conv (Cin16, Cout3), sigmoid -> d_out NCHW fp32.
// Round-6 restructure: 4 output rows x 128 px per block (halo 1.5x vs 3x),
// staging uses the PROVEN xi-fastest coalesced scalar pattern, single input.
// ---------------------------------------------------------------------------
__global__ __launch_bounds__(256)
void convo_mfma(const unsigned short* __restrict__ rnnM,
                const unsigned short* __restrict__ wpko,
                const float* __restrict__ bo,
                float* __restrict__ outp)
{
    constexpr int PSo = 6 * 130 * 8 + 8;   // 6248 shorts per channel-group plane
    __shared__ __align__(16) unsigned short smem[2 * PSo];   // 24992 B

    const int tid  = threadIdx.x;
    const int lane = tid & 63;
    const int wv   = tid >> 6;
    const int n    = lane & 31;
    const int q    = lane >> 5;
    const int x0   = (blockIdx.x & 1) * 128;
    const int yq   = blockIdx.x >> 1;       // 0..63
    const int b    = blockIdx.y;

    for (int i = tid; i < 6 * 16 * 130; i += 256) {
        int xi = i % 130;          // fastest: consecutive lanes -> consecutive x
        int t  = i / 130;          // 0..95
        int ch = t & 15;
        int r  = t >> 4;           // 0..5
        int yg = 4 * yq + r - 1;
        int xg = x0 - 1 + xi;
        unsigned short m = 0;
        if (yg >= 0 && yg < 256 && xg >= 0 && xg < 256)
            m = rnnM[(size_t)(b * 16 + ch) * 65536 + (size_t)yg * 256 + xg];
        int g = ch >> 3, j = ch & 7;
        smem[g * PSo + (r * 130 + xi) * 8 + j] = m;
    }
    __syncthreads();

    const unsigned short* wbase = wpko + lane * 8;
    const int y = 4 * yq + wv;              // wave wv owns one output row

#pragma unroll
    for (int xt = 0; xt < 4; ++xt) {
        const int pxl = xt * 32 + n;
        f32x16 acc;
#pragma unroll
        for (int i = 0; i < 16; ++i) acc[i] = 0.f;
#pragma unroll
        for (int s = 0; s < 9; ++s) {
            const int dy = s / 3, dx = s % 3;
            bf16x8 bfrag = *(const bf16x8*)(&smem[q * PSo + ((wv + dy) * 130 + pxl + dx) * 8]);
            bf16x8 a = *(const bf16x8*)(wbase + s * 512);
            acc = __builtin_amdgcn_mfma_f32_32x32x16_bf16(a, bfrag, acc, 0, 0, 0);
        }
        if (q == 0) {
            const int px = x0 + pxl;
#pragma unroll
            for (int oc = 0; oc < 3; ++oc) {
                float r2 = acc[oc] + bo[oc];
                outp[((size_t)(b * 3 + oc) * 256 + y) * 256 + px] = 1.f / (1.f + __expf(-r2));
            }
        }
    }
}

// ---------------------------------------------------------------------------
extern "C" void kernel_launch(void* const* d_in, const int* in_sizes, int n_in,
                              void* d_out, int out_size, void* d_ws, size_t ws_size,
                              hipStream_t stream)
{
    const float* img = (const float*)d_in[0];
    const float* w1 = (const float*)d_in[1];  const float* b1 = (const float*)d_in[2];
    const float* w2 = (const float*)d_in[3];  const float* b2 = (const float*)d_in[4];
    const float* w3 = (const float*)d_in[5];  const float* b3 = (const float*)d_in[6];
    const float* w4 = (const float*)d_in[7];  const float* b4 = (const float*)d_in[8];
    const float* w5 = (const float*)d_in[9];  const float* b5 = (const float*)d_in[10];
    const float* w6 = (const float*)d_in[11]; const float* b6 = (const float*)d_in[12];
    const float* w7 = (const float*)d_in[13]; const float* b7 = (const float*)d_in[14];
    const float* w8 = (const float*)d_in[15]; const float* b8 = (const float*)d_in[16];
    const float* w9 = (const float*)d_in[17]; const float* b9 = (const float*)d_in[18];
    const float* wi = (const float*)d_in[19]; const float* bi = (const float*)d_in[20];
    const float* wo = (const float*)d_in[21]; const float* bo = (const float*)d_in[22];

    char* wsb = (char*)d_ws;
    const size_t MB = (size_t)(1u << 20);
    unsigned short* imgT  = (unsigned short*)(wsb);             // [0,16) dead after conv1i
    unsigned short* x1t   = (unsigned short*)(wsb + 16 * MB);   // [16,32) till conv9f
    unsigned short* x2t   = (unsigned short*)(wsb + 32 * MB);   // [32,40) till conv8
    unsigned short* x3t   = (unsigned short*)(wsb + 40 * MB);   // [40,42) till conv7
    unsigned short* x4t   = (unsigned short*)(wsb + 42 * MB);   // [42,42.5) till conv6
    unsigned short* x5t   = (unsigned short*)(wsb + 43 * MB);   // [43,43.25)
    unsigned short* x6t   = (unsigned short*)(wsb + 46 * MB);   // [46,46.5)
    unsigned short* x7t   = (unsigned short*)(wsb + 51 * MB);   // [51,53) till conv8
    unsigned short* x8t   = (unsigned short*)(wsb + 70 * MB);   // [70,78) till conv9f
    unsigned short* fm16  = (unsigned short*)(wsb + 112 * MB);  // [112,176) NCHW bf16
    unsigned short* xin16 = (unsigned short*)(wsb + 176 * MB);  // [176,192) NCHW bf16
    unsigned short* rnnW  = (unsigned short*)(wsb);             // [0,16)  (imgT dead)
    unsigned short* rnnM  = (unsigned short*)(wsb + 16 * MB);   // [16,32) (x1t dead)
    unsigned short* wpk9 = (unsigned short*)(wsb + 192 * MB);
    unsigned short* wpk8 = wpk9 + 27648;
    unsigned short* wpk1 = wpk8 + 18432;
    unsigned short* wpki = wpk1 + 12800;
    unsigned short* wpko = wpki + 4608;
    unsigned short* wpk2 = wpko + 4608;
    unsigned short* wpk3 = wpk2 + 4608;
    unsigned short* wpk4 = wpk3 + 9216;
    unsigned short* wpk5 = wpk4 + 9216;
    unsigned short* wpk6 = wpk5 + 18432;
    unsigned short* wpk7 = wpk6 + 27648;
    unsigned short* wpk9e = wpk7 + 18432;    // 110592 shorts (conv9 composite)
    unsigned short* wpk8e = wpk9e + 110592;  // 55296 shorts (conv8 composite)
    float* outp = (float*)d_out;

    // --- single weight-pack dispatch + img transpose ---
    wprep_mega<<<1256, 256, 0, stream>>>(w9, w8, w1, wi, wo, w2, w3, w4, w5, w6, w7,
                                         wpk9, wpk8, wpk1, wpki, wpko,
                                         wpk2, wpk3, wpk4, wpk5, wpk6, wpk7,
                                         wpk9e, wpk8e);
    imgT_bf16<<<2048, 256, 0, stream>>>(img, imgT);

    // --- fused conv1 (relu -> x1t NHWC) + input projection (xin16 NCHW bf16) ---
    { dim3 grd(512, 8);
      conv1i_mfma<<<grd, 256, 0, stream>>>(imgT, wpk1, wpki, b1, bi, x1t, xin16); }

    // --- encoder: pools fused into conv staging ---
    convN_mfma<16, 32, 128, 128, 1, 1><<<dim3(128, 8), 256, 0, stream>>>(x1t, wpk2, b2, x2t);
    convN_mfma<32, 32, 64, 64, 2, 1><<<dim3(32, 8), 256, 0, stream>>>(x2t, wpk3, b3, x3t);
    convN_mfma<32, 32, 32, 32, 4, 1><<<dim3(8, 8), 256, 0, stream>>>(x3t, wpk4, b4, x4t);
    convN_mfma<32, 64, 16, 16, 8, 1><<<dim3(2, 8), 256, 0, stream>>>(x4t, wpk5, b5, x5t);

    // --- decoder: upcat fused into conv6/conv7/conv8 staging ---
    convU_mfma<64, 32, 32, 32, 32, 4><<<dim3(8, 8), 256, 0, stream>>>(x5t, x4t, wpk6, b6, x6t);
    convU_mfma<32, 32, 32, 64, 64, 2><<<dim3(32, 8), 256, 0, stream>>>(x6t, x3t, wpk7, b7, x7t);
    { dim3 grd(128, 8);
      conv8_mfma<<<grd, 256, 0, stream>>>(x7t, x2t, wpk8, wpk8e, b8, x8t); }

    // --- stage 9: y-composite conv9 (512 blocks) ---
    { dim3 grd(512, 8);
      conv9f_mfma<<<grd, 256, 0, stream>>>(x8t, x1t, wpk9, wpk9e, b9, fm16); }

    // --- spatial RNN: segmented scans; lrnn_h fuses max(rnnW, rnnH) -> rnnM ---
    lrnn_w_seg<<<2048, 256, 0, stream>>>(xin16, fm16, rnnW);
    lrnn_h_seg<<<2048, 256, 0, stream>>>(xin16, fm16, rnnW, rnnM);

    // --- output head: 4-row blocks, single input tensor ---
    { dim3 grd(128, 8);
      convo_mfma<<<grd, 256, 0, stream>>>(rnnM, wpko, bo, outp); }
}

// Round 7
// 381.151 us; speedup vs baseline: 1.0856x; 1.0200x over previous
//
#include <hip/hip_runtime.h>
#include <math.h>

typedef __attribute__((ext_vector_type(8)))  short bf16x8;
typedef __attribute__((ext_vector_type(8)))  unsigned short u16x8;
typedef __attribute__((ext_vector_type(16))) float f32x16;

__device__ __forceinline__ unsigned short f2bf(float f) {
    unsigned u = __float_as_uint(f);
    unsigned r = (u + 0x7FFFu + ((u >> 16) & 1u)) >> 16;
    return (unsigned short)r;
}
__device__ __forceinline__ float bf2f(unsigned short h) {
    return __uint_as_float(((unsigned)h) << 16);
}
__device__ __forceinline__ unsigned pack2(unsigned short a, unsigned short b) {
    return (unsigned)a | ((unsigned)b << 16);
}
// HW packed f32->bf16 RNE: 1 VALU op converts 2 values (== manual f2bf RNE).
__device__ __forceinline__ unsigned cvtpk2(float a, float b) {
    unsigned r;
    asm("v_cvt_pk_bf16_f32 %0, %1, %2" : "=v"(r) : "v"(a), "v"(b));
    return r;
}
__device__ __forceinline__ float fast_tanh(float x) {
    float e = __expf(2.f * x);
    return 1.f - 2.f / (e + 1.f);
}

__device__ __forceinline__ void bilin_setup(int y, int x, int Hi, int Wi,
                                            int& i00, int& i01, int& i10, int& i11,
                                            float& wy, float& wx)
{
    float fy = 0.5f * y - 0.25f;
    float fx = 0.5f * x - 0.25f;
    float y0f = floorf(fy), x0f = floorf(fx);
    wy = fy - y0f; wx = fx - x0f;
    int yA = (int)y0f, xA = (int)x0f;
    int yB = yA + 1, xB = xA + 1;
    yA = yA < 0 ? 0 : (yA > Hi - 1 ? Hi - 1 : yA);
    yB = yB < 0 ? 0 : (yB > Hi - 1 ? Hi - 1 : yB);
    xA = xA < 0 ? 0 : (xA > Wi - 1 ? Wi - 1 : xA);
    xB = xB < 0 ? 0 : (xB > Wi - 1 ? Wi - 1 : xB);
    i00 = yA * Wi + xA; i01 = yA * Wi + xB;
    i10 = yB * Wi + xA; i11 = yB * Wi + xB;
}

// 2x upsample w/ half-pixel centers: fixed parity weights, no floorf needed.
__device__ __forceinline__ void up2_setup(int v, int Hi, int& i0, int& i1, float& w)
{
    int a = (v - 1) >> 1;           // arithmetic shift: v=0 -> -1
    i0 = a < 0 ? 0 : a;
    int b = a + 1;
    i1 = b > Hi - 1 ? Hi - 1 : b;
    w = (v & 1) ? 0.25f : 0.75f;
}

__device__ __forceinline__ uint4 bilin8u(const unsigned short* __restrict__ sb,
                                         int i00, int i01, int i10, int i11,
                                         float wy, float wx, int stride)
{
    u16x8 v00 = *(const u16x8*)(sb + (size_t)i00 * stride);
    u16x8 v01 = *(const u16x8*)(sb + (size_t)i01 * stride);
    u16x8 v10 = *(const u16x8*)(sb + (size_t)i10 * stride);
    u16x8 v11 = *(const u16x8*)(sb + (size_t)i11 * stride);
    float w00 = (1.f - wy) * (1.f - wx), w01 = (1.f - wy) * wx;
    float w10 = wy * (1.f - wx),         w11 = wy * wx;
    float f[8];
#pragma unroll
    for (int j = 0; j < 8; ++j)
        f[j] = w00 * bf2f(v00[j]) + w01 * bf2f(v01[j]) +
               w10 * bf2f(v10[j]) + w11 * bf2f(v11[j]);
    return make_uint4(cvtpk2(f[0], f[1]), cvtpk2(f[2], f[3]),
                      cvtpk2(f[4], f[5]), cvtpk2(f[6], f[7]));
}

// y-interp composite coefficients: ALPH[cls][py][dy][dr]
__device__ const float ALPH[3][2][3][3] = {
    { { {0.f,0.f,0.f},      {0.f,1.f,0.f},       {0.f,0.75f,0.25f} },
      { {0.f,1.f,0.f},      {0.f,0.75f,0.25f},   {0.f,0.25f,0.75f} } },
    { { {0.75f,0.25f,0.f},  {0.25f,0.75f,0.f},   {0.f,0.75f,0.25f} },
      { {0.25f,0.75f,0.f},  {0.f,0.75f,0.25f},   {0.f,0.25f,0.75f} } },
    { { {0.75f,0.25f,0.f},  {0.25f,0.75f,0.f},   {0.f,1.f,0.f} },
      { {0.25f,0.75f,0.f},  {0.f,1.f,0.f},       {0.f,0.f,0.f} } }
};

// ---------------------------------------------------------------------------
// img [8][15][256][256] fp32 -> imgT [b][y][x][16] bf16 (ch15 = 0)
// ---------------------------------------------------------------------------
__global__ void imgT_bf16(const float* __restrict__ img, unsigned short* __restrict__ dst)
{
    int idx = blockIdx.x * 256 + threadIdx.x;
    if (idx >= 8 * 256 * 256) return;
    int x = idx & 255, y = (idx >> 8) & 255, b = idx >> 16;
    float f[15];
#pragma unroll
    for (int c = 0; c < 15; ++c)
        f[c] = img[(size_t)(b * 15 + c) * 65536 + y * 256 + x];
    uint4 lo = make_uint4(cvtpk2(f[0], f[1]), cvtpk2(f[2], f[3]),
                          cvtpk2(f[4], f[5]), cvtpk2(f[6], f[7]));
    uint4 hi = make_uint4(cvtpk2(f[8], f[9]), cvtpk2(f[10], f[11]),
                          cvtpk2(f[12], f[13]), cvtpk2(f[14], 0.f));
    *(uint4*)(dst + (size_t)idx * 16)     = lo;
    *(uint4*)(dst + (size_t)idx * 16 + 8) = hi;
}

// ---------------------------------------------------------------------------
// Mega weight-pack: all packs in one dispatch (incl. y-composite tables).
// ---------------------------------------------------------------------------
__device__ __forceinline__ void pack33(const float* __restrict__ w,
                                       unsigned short* __restrict__ dst,
                                       int i, int Cin, int Cout)
{
    int KST = Cin >> 4, MT = Cout >> 5;
    int j = i & 7;
    int lane = (i >> 3) & 63;
    int t = i >> 9;
    int mt = t % MT; t /= MT;
    int kst = t % KST;
    int s = t / KST;
    int oc = mt * 32 + (lane & 31);
    int ci = kst * 16 + (lane >> 5) * 8 + j;
    dst[i] = f2bf(w[(oc * Cin + ci) * 9 + s]);
}

__global__ void wprep_mega(const float* __restrict__ w9, const float* __restrict__ w8,
                           const float* __restrict__ w1, const float* __restrict__ wi,
                           const float* __restrict__ wo, const float* __restrict__ w2,
                           const float* __restrict__ w3, const float* __restrict__ w4,
                           const float* __restrict__ w5, const float* __restrict__ w6,
                           const float* __restrict__ w7,
                           unsigned short* __restrict__ wpk9, unsigned short* __restrict__ wpk8,
                           unsigned short* __restrict__ wpk1, unsigned short* __restrict__ wpki,
                           unsigned short* __restrict__ wpko, unsigned short* __restrict__ wpk2,
                           unsigned short* __restrict__ wpk3, unsigned short* __restrict__ wpk4,
                           unsigned short* __restrict__ wpk5, unsigned short* __restrict__ wpk6,
                           unsigned short* __restrict__ wpk7, unsigned short* __restrict__ wpk9e,
                           unsigned short* __restrict__ wpk8e)
{
    int idx = blockIdx.x * 256 + threadIdx.x;
    if (idx < 27648)       pack33(w9, wpk9, idx, 48, 64);
    else if (idx < 46080)  pack33(w8, wpk8, idx - 27648, 64, 32);
    else if (idx < 58880) {
        int i = idx - 46080;
        int j = i & 7;
        int lane = (i >> 3) & 63;
        int s = i >> 9;                 // 0..24
        int oc = lane & 31;
        int ci = (lane >> 5) * 8 + j;   // 0..15
        float v = 0.f;
        if (oc < 16 && ci < 15) v = w1[((oc * 15 + ci) * 5 + s / 5) * 5 + s % 5];
        wpk1[i] = f2bf(v);
    } else if (idx < 63488) {
        int i = idx - 58880;
        int j = i & 7;
        int lane = (i >> 3) & 63;
        int s = i >> 9;                 // 0..8
        int oc = lane & 31;
        int ci = (lane >> 5) * 8 + j;
        float v = 0.f;
        if (oc < 16 && ci < 15) v = wi[((oc * 15 + ci) * 3 + s / 3) * 3 + s % 3];
        wpki[i] = f2bf(v);
    } else if (idx < 68096) {
        int i = idx - 63488;
        int j = i & 7;
        int lane = (i >> 3) & 63;
        int s = i >> 9;
        int oc = lane & 31;
        int ci = (lane >> 5) * 8 + j;
        float v = 0.f;
        if (oc < 3) v = wo[((oc * 16 + ci) * 3 + s / 3) * 3 + s % 3];
        wpko[i] = f2bf(v);
    }
    else if (idx < 72704)  pack33(w2, wpk2, idx - 68096, 16, 32);
    else if (idx < 81920)  pack33(w3, wpk3, idx - 72704, 32, 32);
    else if (idx < 91136)  pack33(w4, wpk4, idx - 81920, 32, 32);
    else if (idx < 109568) pack33(w5, wpk5, idx - 91136, 32, 64);
    else if (idx < 137216) pack33(w6, wpk6, idx - 109568, 96, 32);
    else if (idx < 155648) pack33(w7, wpk7, idx - 137216, 64, 32);
    else if (idx < 266240) {
        // conv9 y-composite tables: [cls][py][s=dr*3+dx][kst][half] x 512
        int i = idx - 155648;
        int j = i & 7;
        int lane = (i >> 3) & 63;
        int t = i >> 9;                 // 0..215
        int half = t & 1; t >>= 1;
        int kst  = t & 1; t >>= 1;
        int s    = t % 9; t /= 9;
        int py   = t & 1;
        int cls  = t >> 1;              // 0..2
        int dr = s / 3, dx = s % 3;
        int oc = half * 32 + (lane & 31);
        int ci = kst * 16 + (lane >> 5) * 8 + j;   // x8 channels 0..31
        float v = 0.f;
#pragma unroll
        for (int dy = 0; dy < 3; ++dy)
            v += ALPH[cls][py][dy][dr] * w9[((oc * 48 + ci) * 3 + dy) * 3 + dx];
        wpk9e[i] = f2bf(v);
    }
    else if (idx < 321536) {
        // conv8 y-composite tables (up channels 0..31): [cls][py][s][kst] x 512
        int i = idx - 266240;
        int j = i & 7;
        int lane = (i >> 3) & 63;
        int t = i >> 9;                 // 0..107
        int kst = t & 1; t >>= 1;
        int s   = t % 9; t /= 9;
        int py  = t & 1;
        int cls = t >> 1;               // 0..2
        int dr = s / 3, dx = s % 3;
        int oc = lane & 31;
        int ci = kst * 16 + (lane >> 5) * 8 + j;   // up channels 0..31
        float v = 0.f;
#pragma unroll
        for (int dy = 0; dy < 3; ++dy)
            v += ALPH[cls][py][dy][dr] * w8[((oc * 64 + ci) * 3 + dy) * 3 + dx];
        wpk8e[i] = f2bf(v);
    }
}

// ---------------------------------------------------------------------------
// Generic NHWC bf16 MFMA conv (3x3, pad 1, relu -> NHWC bf16).
// POOL=1: input is [8, 2H, 2W, CIN]; staging applies 2x2 maxpool on the fly.
// ---------------------------------------------------------------------------
template<int CIN, int COUT, int H, int W, int ROWS, int POOL>
__global__ __launch_bounds__(256)
void convN_mfma(const unsigned short* __restrict__ in,
                const unsigned short* __restrict__ wpk,
                const float* __restrict__ bias,
                unsigned short* __restrict__ out)
{
    constexpr int G = CIN / 8;
    constexpr int KST = CIN / 16;
    constexpr int MT = COUT / 32;
    constexpr int TR = ROWS + 2;
    constexpr int TWd = W + 2;
    constexpr int PS = TR * TWd * 8 + 8;
    __shared__ __align__(16) unsigned short smem[G * PS];

    const int tid  = threadIdx.x;
    const int lane = tid & 63;
    const int wv   = tid >> 6;
    const int q    = lane >> 5;
    const int y0   = blockIdx.x * ROWS;
    const int b    = blockIdx.y;

    for (int i = tid; i < G * TR * TWd; i += 256) {
        int g = i % G;
        int u = (i / G) % TWd;
        int t = i / (G * TWd);
        int yg = y0 + t - 1, xg = u - 1;
        uint4 v = make_uint4(0, 0, 0, 0);
        if (yg >= 0 && yg < H && xg >= 0 && xg < W) {
            if (POOL) {
                const unsigned short* q0 =
                    in + (((size_t)(b * 2 * H + 2 * yg) * 2 * W + 2 * xg) * CIN + g * 8);
                u16x8 a0 = *(const u16x8*)q0;
                u16x8 a1 = *(const u16x8*)(q0 + CIN);
                u16x8 a2 = *(const u16x8*)(q0 + (size_t)2 * W * CIN);
                u16x8 a3 = *(const u16x8*)(q0 + (size_t)2 * W * CIN + CIN);
                float f[8];
#pragma unroll
                for (int j = 0; j < 8; ++j)
                    f[j] = fmaxf(fmaxf(bf2f(a0[j]), bf2f(a1[j])),
                                 fmaxf(bf2f(a2[j]), bf2f(a3[j])));
                v = make_uint4(cvtpk2(f[0], f[1]), cvtpk2(f[2], f[3]),
                               cvtpk2(f[4], f[5]), cvtpk2(f[6], f[7]));
            } else {
                v = *(const uint4*)(in + (((size_t)(b * H + yg) * W + xg) * CIN + g * 8));
            }
        }
        *(uint4*)(&smem[g * PS + (t * TWd + u) * 8]) = v;
    }
    __syncthreads();

    const int p = wv * 32 + (lane & 31);
    const int r = p / W;
    const int x = p % W;

    f32x16 acc[MT];
#pragma unroll
    for (int mt = 0; mt < MT; ++mt)
#pragma unroll
        for (int i = 0; i < 16; ++i) acc[mt][i] = 0.f;

    const unsigned short* wbase = wpk + lane * 8;

#pragma unroll
    for (int s = 0; s < 9; ++s) {
        const int dy = s / 3, dx = s % 3;
#pragma unroll
        for (int kst = 0; kst < KST; ++kst) {
            const int g = kst * 2 + q;
            bf16x8 bfrag = *(const bf16x8*)(&smem[g * PS + ((r + dy) * TWd + (x + dx)) * 8]);
#pragma unroll
            for (int mt = 0; mt < MT; ++mt) {
                bf16x8 a = *(const bf16x8*)(wbase + ((s * KST + kst) * MT + mt) * 512);
                acc[mt] = __builtin_amdgcn_mfma_f32_32x32x16_bf16(a, bfrag, acc[mt], 0, 0, 0);
            }
        }
    }

    size_t base = ((size_t)(b * H + y0 + r) * W + x) * COUT;
#pragma unroll
    for (int mt = 0; mt < MT; ++mt)
#pragma unroll
        for (int rg = 0; rg < 4; ++rg) {
            int oc = mt * 32 + 8 * rg + 4 * q;
            float v0 = fmaxf(acc[mt][rg * 4 + 0] + bias[oc + 0], 0.f);
            float v1 = fmaxf(acc[mt][rg * 4 + 1] + bias[oc + 1], 0.f);
            float v2 = fmaxf(acc[mt][rg * 4 + 2] + bias[oc + 2], 0.f);
            float v3 = fmaxf(acc[mt][rg * 4 + 3] + bias[oc + 3], 0.f);
            *(uint2*)(out + base + oc) = make_uint2(cvtpk2(v0, v1), cvtpk2(v2, v3));
        }
}

// ---------------------------------------------------------------------------
// convU: 3x3 conv with FUSED upsample+concat staging (decoder stages 6,7).
// ---------------------------------------------------------------------------
template<int UPC, int CSKIP, int COUT, int H, int W, int ROWS>
__global__ __launch_bounds__(256)
void convU_mfma(const unsigned short* __restrict__ up,
                const unsigned short* __restrict__ skip,
                const unsigned short* __restrict__ wpk,
                const float* __restrict__ bias,
                unsigned short* __restrict__ out)
{
    constexpr int CIN = UPC + CSKIP;
    constexpr int G = CIN / 8;
    constexpr int GU = UPC / 8;
    constexpr int KST = CIN / 16;
    constexpr int MT = COUT / 32;
    constexpr int TR = ROWS + 2;
    constexpr int TWd = W + 2;
    constexpr int PS = TR * TWd * 8 + 8;
    __shared__ __align__(16) unsigned short smem[G * PS];

    const int tid  = threadIdx.x;
    const int lane = tid & 63;
    const int wv   = tid >> 6;
    const int q    = lane >> 5;
    const int y0   = blockIdx.x * ROWS;
    const int b    = blockIdx.y;

    for (int i = tid; i < G * TR * TWd; i += 256) {
        int g = i % G;
        int u = (i / G) % TWd;
        int t = i / (G * TWd);
        int yg = y0 + t - 1, xg = u - 1;
        uint4 v = make_uint4(0, 0, 0, 0);
        if (yg >= 0 && yg < H && xg >= 0 && xg < W) {
            if (g < GU) {
                int i00, i01, i10, i11; float wy, wx;
                bilin_setup(yg, xg, H / 2, W / 2, i00, i01, i10, i11, wy, wx);
                v = bilin8u(up + (size_t)b * (H / 2) * (W / 2) * UPC + g * 8,
                            i00, i01, i10, i11, wy, wx, UPC);
            } else {
                v = *(const uint4*)(skip + (((size_t)(b * H + yg) * W + xg) * CSKIP
                                            + (g - GU) * 8));
            }
        }
        *(uint4*)(&smem[g * PS + (t * TWd + u) * 8]) = v;
    }
    __syncthreads();

    const int p = wv * 32 + (lane & 31);
    const int r = p / W;
    const int x = p % W;

    f32x16 acc[MT];
#pragma unroll
    for (int mt = 0; mt < MT; ++mt)
#pragma unroll
        for (int i = 0; i < 16; ++i) acc[mt][i] = 0.f;

    const unsigned short* wbase = wpk + lane * 8;

#pragma unroll
    for (int s = 0; s < 9; ++s) {
        const int dy = s / 3, dx = s % 3;
#pragma unroll
        for (int kst = 0; kst < KST; ++kst) {
            const int g = kst * 2 + q;
            bf16x8 bfrag = *(const bf16x8*)(&smem[g * PS + ((r + dy) * TWd + (x + dx)) * 8]);
#pragma unroll
            for (int mt = 0; mt < MT; ++mt) {
                bf16x8 a = *(const bf16x8*)(wbase + ((s * KST + kst) * MT + mt) * 512);
                acc[mt] = __builtin_amdgcn_mfma_f32_32x32x16_bf16(a, bfrag, acc[mt], 0, 0, 0);
            }
        }
    }

    size_t base = ((size_t)(b * H + y0 + r) * W + x) * COUT;
#pragma unroll
    for (int mt = 0; mt < MT; ++mt)
#pragma unroll
        for (int rg = 0; rg < 4; ++rg) {
            int oc = mt * 32 + 8 * rg + 4 * q;
            float v0 = fmaxf(acc[mt][rg * 4 + 0] + bias[oc + 0], 0.f);
            float v1 = fmaxf(acc[mt][rg * 4 + 1] + bias[oc + 1], 0.f);
            float v2 = fmaxf(acc[mt][rg * 4 + 2] + bias[oc + 2], 0.f);
            float v3 = fmaxf(acc[mt][rg * 4 + 3] + bias[oc + 3], 0.f);
            *(uint2*)(out + base + oc) = make_uint2(cvtpk2(v0, v1), cvtpk2(v2, v3));
        }
}

// ---------------------------------------------------------------------------
// Fused conv1 (5x5, relu -> x1t NHWC bf16) + conv_i (3x3 -> xin NCHW bf16).
// ---------------------------------------------------------------------------
__global__ __launch_bounds__(256)
void conv1i_mfma(const unsigned short* __restrict__ imgT,
                 const unsigned short* __restrict__ wpk1,
                 const unsigned short* __restrict__ wpki,
                 const float* __restrict__ b1, const float* __restrict__ bi,
                 unsigned short* __restrict__ x1t, unsigned short* __restrict__ xin)
{
    __shared__ __align__(16) unsigned short smem[2 * 5 * 132 * 8];

    const int tid  = threadIdx.x;
    const int lane = tid & 63;
    const int wv   = tid >> 6;
    const int n    = lane & 31;
    const int q    = lane >> 5;
    const int y    = blockIdx.x >> 1;
    const int x0   = (blockIdx.x & 1) * 128;
    const int b    = blockIdx.y;

    for (int i = tid; i < 5 * 132 * 2; i += 256) {
        int r   = i / 264;
        int rem = i - r * 264;
        int xi  = rem >> 1;
        int g   = rem & 1;
        int yg = y + r - 2;
        int xg = x0 - 2 + xi;
        uint4 v = make_uint4(0, 0, 0, 0);
        if (yg >= 0 && yg < 256 && xg >= 0 && xg < 256)
            v = *(const uint4*)(imgT + (((size_t)(b * 256 + yg) * 256 + xg) * 16 + g * 8));
        *(uint4*)(&smem[((g * 5 + r) * 132 + xi) * 8]) = v;
    }
    __syncthreads();

    f32x16 acc1, acci;
#pragma unroll
    for (int i = 0; i < 16; ++i) { acc1[i] = 0.f; acci[i] = 0.f; }

    const int pxl = wv * 32 + n;
    const unsigned short* wb1 = wpk1 + lane * 8;
    const unsigned short* wbi = wpki + lane * 8;

#pragma unroll
    for (int s = 0; s < 25; ++s) {
        const int dy = s / 5, dx = s % 5;
        bf16x8 bfrag = *(const bf16x8*)(&smem[((q * 5 + dy) * 132 + pxl + dx) * 8]);
        bf16x8 a = *(const bf16x8*)(wb1 + s * 512);
        acc1 = __builtin_amdgcn_mfma_f32_32x32x16_bf16(a, bfrag, acc1, 0, 0, 0);
    }
#pragma unroll
    for (int s = 0; s < 9; ++s) {
        const int dy = s / 3, dx = s % 3;
        bf16x8 bfrag = *(const bf16x8*)(&smem[((q * 5 + dy + 1) * 132 + pxl + dx + 1) * 8]);
        bf16x8 a = *(const bf16x8*)(wbi + s * 512);
        acci = __builtin_amdgcn_mfma_f32_32x32x16_bf16(a, bfrag, acci, 0, 0, 0);
    }

    const int px = x0 + pxl;
    size_t base1 = ((size_t)(b * 256 + y) * 256 + px) * 16;
#pragma unroll
    for (int rg = 0; rg < 2; ++rg) {
        int oc = 8 * rg + 4 * q;
        float v0 = fmaxf(acc1[rg * 4 + 0] + b1[oc + 0], 0.f);
        float v1 = fmaxf(acc1[rg * 4 + 1] + b1[oc + 1], 0.f);
        float v2 = fmaxf(acc1[rg * 4 + 2] + b1[oc + 2], 0.f);
        float v3 = fmaxf(acc1[rg * 4 + 3] + b1[oc + 3], 0.f);
        *(uint2*)(x1t + base1 + oc) = make_uint2(cvtpk2(v0, v1), cvtpk2(v2, v3));
    }
#pragma unroll
    for (int reg = 0; reg < 8; reg += 2) {
        int row = (reg & 3) + 8 * (reg >> 2) + 4 * q;   // reg even: rows row,row+1
        unsigned p = cvtpk2(acci[reg] + bi[row], acci[reg + 1] + bi[row + 1]);
        xin[((size_t)(b * 16 + row)     * 256 + y) * 256 + px] = (unsigned short)p;
        xin[((size_t)(b * 16 + row + 1) * 256 + y) * 256 + px] = (unsigned short)(p >> 16);
    }
}

// ---------------------------------------------------------------------------
// conv8 MFMA, y-composite (round 5) + cvt_pk conversions (this round).
// ---------------------------------------------------------------------------
__global__ __launch_bounds__(256)
void conv8_mfma(const unsigned short* __restrict__ x7t,
                const unsigned short* __restrict__ x2t,
                const unsigned short* __restrict__ wpk8,   // original (skip ksts)
                const unsigned short* __restrict__ wpk8e,  // composite up tables
                const float* __restrict__ bias,
                unsigned short* __restrict__ x8t)
{
    constexpr int PSU = 3 * 66 * 8 + 8;   // 1592 shorts per up plane
    constexpr int PSS = 4 * 66 * 8 + 8;   // 2120 shorts per skip plane
    constexpr int SOFF = 4 * PSU;         // 6368
    __shared__ __align__(16) unsigned short smem[4 * PSU + 4 * PSS]; // 29696 B

    const int tid  = threadIdx.x;
    const int lane = tid & 63;
    const int wv   = tid >> 6;
    const int n    = lane & 31;
    const int q    = lane >> 5;
    const int x0   = (blockIdx.x & 1) * 64;
    const int yp   = blockIdx.x >> 1;       // low-res row i, 0..63
    const int b    = blockIdx.y;

    for (int i = tid; i < 792 + 1056; i += 256) {
        if (i < 792) {
            // up part: 4 planes x 3 low-res rows x 66 cols, x-lerp only
            int g   = i & 3;
            int rem = i >> 2;           // 0..197
            int xi  = rem % 66;
            int t8  = rem / 66;         // 0..2  (low-res row yp-1+t8)
            int r   = yp - 1 + t8;
            int xg  = x0 - 1 + xi;
            uint4 v = make_uint4(0, 0, 0, 0);
            if (r >= 0 && r < 64 && xg >= 0 && xg < 128) {
                int ix0, ix1; float wx;
                up2_setup(xg, 64, ix0, ix1, wx);
                const unsigned short* S = x7t + ((size_t)(b * 64 + r) * 64) * 32 + g * 8;
                u16x8 a0 = *(const u16x8*)(S + ix0 * 32);
                u16x8 a1 = *(const u16x8*)(S + ix1 * 32);
                float w1x = 1.f - wx;
                float f[8];
#pragma unroll
                for (int j = 0; j < 8; ++j)
                    f[j] = w1x * bf2f(a0[j]) + wx * bf2f(a1[j]);
                v = make_uint4(cvtpk2(f[0], f[1]), cvtpk2(f[2], f[3]),
                               cvtpk2(f[4], f[5]), cvtpk2(f[6], f[7]));
            }
            *(uint4*)(&smem[g * PSU + (t8 * 66 + xi) * 8]) = v;
        } else {
            // skip part: 4 planes x 4 full-res rows x 66 cols, pure copy
            int jI  = i - 792;
            int g   = jI & 3;
            int rem = jI >> 2;          // 0..263
            int xi  = rem % 66;
            int t   = rem / 66;         // 0..3
            int yg  = 2 * yp + t - 1;
            int xg  = x0 - 1 + xi;
            uint4 v = make_uint4(0, 0, 0, 0);
            if (yg >= 0 && yg < 128 && xg >= 0 && xg < 128)
                v = *(const uint4*)(x2t + (((size_t)(b * 128 + yg) * 128 + xg) * 32 + g * 8));
            *(uint4*)(&smem[SOFF + g * PSS + (t * 66 + xi) * 8]) = v;
        }
    }
    __syncthreads();

    const int rr  = wv >> 1;                // output row parity py
    const int pxl = (wv & 1) * 32 + n;

    f32x16 acc;
#pragma unroll
    for (int i = 0; i < 16; ++i) acc[i] = 0.f;

    const int cls = (yp == 0) ? 0 : ((yp == 63) ? 2 : 1);
    const unsigned short* wE = wpk8e + (size_t)(cls * 2 + rr) * 9216 + lane * 8;
    const unsigned short* wS = wpk8 + lane * 8;

#pragma unroll
    for (int s = 0; s < 9; ++s) {
        const int dr = s / 3, dxx = s % 3;
#pragma unroll
        for (int kst = 0; kst < 2; ++kst) {
            const int g = kst * 2 + q;
            bf16x8 bfrag = *(const bf16x8*)(&smem[g * PSU + (dr * 66 + pxl + dxx) * 8]);
            bf16x8 a = *(const bf16x8*)(wE + (s * 2 + kst) * 512);
            acc = __builtin_amdgcn_mfma_f32_32x32x16_bf16(a, bfrag, acc, 0, 0, 0);
        }
#pragma unroll
        for (int kst = 0; kst < 2; ++kst) {
            const int g = kst * 2 + q;
            bf16x8 bfrag = *(const bf16x8*)(&smem[SOFF + g * PSS + ((rr + dr) * 66 + pxl + dxx) * 8]);
            bf16x8 a = *(const bf16x8*)(wS + (s * 4 + kst + 2) * 512);
            acc = __builtin_amdgcn_mfma_f32_32x32x16_bf16(a, bfrag, acc, 0, 0, 0);
        }
    }

    size_t base = ((size_t)(b * 128 + 2 * yp + rr) * 128 + x0 + pxl) * 32;
#pragma unroll
    for (int rg = 0; rg < 4; ++rg) {
        int oc0 = 8 * rg + 4 * q;
        float v0 = fmaxf(acc[rg * 4 + 0] + bias[oc0 + 0], 0.f);
        float v1 = fmaxf(acc[rg * 4 + 1] + bias[oc0 + 1], 0.f);
        float v2 = fmaxf(acc[rg * 4 + 2] + bias[oc0 + 2], 0.f);
        float v3 = fmaxf(acc[rg * 4 + 3] + bias[oc0 + 3], 0.f);
        *(uint2*)(x8t + base + oc0) = make_uint2(cvtpk2(v0, v1), cvtpk2(v2, v3));
    }
}

// ---------------------------------------------------------------------------
// conv9 MFMA, y-composite (round 4) + cvt_pk conversions (this round).
// ---------------------------------------------------------------------------
__global__ __launch_bounds__(256)
void conv9f_mfma(const unsigned short* __restrict__ x8t,
                 const unsigned short* __restrict__ x1t,
                 const unsigned short* __restrict__ wpk,     // original (kst=2 slice used)
                 const unsigned short* __restrict__ wpk9e,   // composite tables
                 const float* __restrict__ bias,
                 unsigned short* __restrict__ fm)
{
    constexpr int PS8X = 3 * 66 * 8 + 8;   // 1592 shorts per x8 plane
    constexpr int PS1  = 4 * 66 * 8 + 8;   // 2120 shorts per x1 plane
    constexpr int X1OFF = 4 * PS8X;        // 6368
    __shared__ __align__(16) unsigned short smem[4 * PS8X + 2 * PS1];  // 21216 B

    const int tid  = threadIdx.x;
    const int lane = tid & 63;
    const int wv   = tid >> 6;
    const int n    = lane & 31;
    const int q    = lane >> 5;
    const int x0   = (blockIdx.x & 3) * 64;
    const int yp   = blockIdx.x >> 2;       // 0..127 (= low-res row i)
    const int b    = blockIdx.y;

    for (int i = tid; i < 792 + 528; i += 256) {
        if (i < 792) {
            // x8 part: 4 planes x 3 low-res rows x 66 cols, x-lerp only
            int g   = i & 3;
            int rem = i >> 2;           // 0..197
            int xi  = rem % 66;
            int t8  = rem / 66;         // 0..2  (low-res row i-1+t8)
            int r   = yp - 1 + t8;
            int xg  = x0 - 1 + xi;
            uint4 v = make_uint4(0, 0, 0, 0);
            if (r >= 0 && r < 128 && xg >= 0 && xg < 256) {
                int ix0, ix1; float wx;
                up2_setup(xg, 128, ix0, ix1, wx);
                const unsigned short* S = x8t + ((size_t)(b * 128 + r) * 128) * 32 + g * 8;
                u16x8 a0 = *(const u16x8*)(S + ix0 * 32);
                u16x8 a1 = *(const u16x8*)(S + ix1 * 32);
                float w1x = 1.f - wx;
                float f[8];
#pragma unroll
                for (int j = 0; j < 8; ++j)
                    f[j] = w1x * bf2f(a0[j]) + wx * bf2f(a1[j]);
                v = make_uint4(cvtpk2(f[0], f[1]), cvtpk2(f[2], f[3]),
                               cvtpk2(f[4], f[5]), cvtpk2(f[6], f[7]));
            }
            *(uint4*)(&smem[g * PS8X + (t8 * 66 + xi) * 8]) = v;
        } else {
            // x1 part: 2 planes x 4 full-res rows x 66 cols, pure copy
            int jI  = i - 792;
            int g   = jI & 1;
            int rem = jI >> 1;          // 0..263
            int xi  = rem % 66;
            int t   = rem / 66;         // 0..3
            int yg  = 2 * yp + t - 1;
            int xg  = x0 - 1 + xi;
            uint4 v = make_uint4(0, 0, 0, 0);
            if (yg >= 0 && yg < 256 && xg >= 0 && xg < 256)
                v = *(const uint4*)(x1t + (((size_t)(b * 256 + yg) * 256 + xg) * 16 + g * 8));
            *(uint4*)(&smem[X1OFF + g * PS1 + (t * 66 + xi) * 8]) = v;
        }
    }
    __syncthreads();

    const int rr  = wv >> 1;                 // output row parity py
    const int pxl = (wv & 1) * 32 + n;

    f32x16 acc0, acc1;
#pragma unroll
    for (int i = 0; i < 16; ++i) { acc0[i] = 0.f; acc1[i] = 0.f; }

    const int cls = (yp == 0) ? 0 : ((yp == 127) ? 2 : 1);
    const unsigned short* wE  = wpk9e + (size_t)(cls * 2 + rr) * 18432 + lane * 8;
    const unsigned short* w2b = wpk + lane * 8;

#pragma unroll
    for (int s = 0; s < 9; ++s) {
        const int dr = s / 3, dxx = s % 3;
#pragma unroll
        for (int kst = 0; kst < 2; ++kst) {
            const int g = kst * 2 + q;
            bf16x8 bfrag = *(const bf16x8*)(&smem[g * PS8X + (dr * 66 + pxl + dxx) * 8]);
            bf16x8 a0 = *(const bf16x8*)(wE + ((s * 2 + kst) * 2 + 0) * 512);
            bf16x8 a1 = *(const bf16x8*)(wE + ((s * 2 + kst) * 2 + 1) * 512);
            acc0 = __builtin_amdgcn_mfma_f32_32x32x16_bf16(a0, bfrag, acc0, 0, 0, 0);
            acc1 = __builtin_amdgcn_mfma_f32_32x32x16_bf16(a1, bfrag, acc1, 0, 0, 0);
        }
        {
            bf16x8 bfrag = *(const bf16x8*)(&smem[X1OFF + q * PS1 + ((rr + dr) * 66 + pxl + dxx) * 8]);
            bf16x8 a0 = *(const bf16x8*)(w2b + ((s * 3 + 2) * 2 + 0) * 512);
            bf16x8 a1 = *(const bf16x8*)(w2b + ((s * 3 + 2) * 2 + 1) * 512);
            acc0 = __builtin_amdgcn_mfma_f32_32x32x16_bf16(a0, bfrag, acc0, 0, 0, 0);
            acc1 = __builtin_amdgcn_mfma_f32_32x32x16_bf16(a1, bfrag, acc1, 0, 0, 0);
        }
    }

    // --- epilogue: LDS transpose -> vectorized NCHW stores ---
    __syncthreads();                       // staging buffer is now dead
    unsigned short* lout = smem;           // [64 oc][128 px] = 8192 shorts
    const int pb = rr * 64 + pxl + q * 512;   // px index + 4q row fold (4*128)
#pragma unroll
    for (int reg = 0; reg < 16; reg += 2) {
        const int rb = (reg & 3) + 8 * (reg >> 2);        // pairs -> rows rb, rb+1
        float a0 = fast_tanh(acc0[reg]     + bias[rb + 4 * q]);
        float a1 = fast_tanh(acc0[reg + 1] + bias[rb + 1 + 4 * q]);
        unsigned p0 = cvtpk2(a0, a1);
        lout[rb * 128 + pb]       = (unsigned short)p0;
        lout[(rb + 1) * 128 + pb] = (unsigned short)(p0 >> 16);
        float b0 = fast_tanh(acc1[reg]     + bias[rb + 4 * q + 32]);
        float b1 = fast_tanh(acc1[reg + 1] + bias[rb + 1 + 4 * q + 32]);
        unsigned p1 = cvtpk2(b0, b1);
        lout[(rb + 32) * 128 + pb] = (unsigned short)p1;
        lout[(rb + 33) * 128 + pb] = (unsigned short)(p1 >> 16);
    }
    __syncthreads();

    const size_t fmb = (size_t)b * 64 * 65536 + (size_t)(2 * yp) * 256 + x0;
    for (int i = tid; i < 1024; i += 256) {
        int oc  = i >> 4;
        int p0  = (i & 15) * 8;        // 0..120
        int rr2 = p0 >> 6;             // output row within pair
        int pl  = p0 & 63;             // x within 64-px strip
        uint4 v = *(const uint4*)(lout + oc * 128 + p0);
        *(uint4*)(fm + fmb + (size_t)oc * 65536 + rr2 * 256 + pl) = v;
    }
}

// ---------------------------------------------------------------------------
// Segmented W-direction LRNN pair -> rnnW NCHW bf16 (conflict-free LDS).
// ---------------------------------------------------------------------------
__device__ __forceinline__ int X2C(int x) { return x + (x >> 5); }

__global__ __launch_bounds__(256)
void lrnn_w_seg(const unsigned short* __restrict__ X, const unsigned short* __restrict__ FM,
                unsigned short* __restrict__ rnnW)
{
    __shared__ float tx[3][16][264];
    __shared__ unsigned short outm[2][16][256];
    __shared__ float segres[2][16][8][4];
    __shared__ float hin[2][16][8][2];

    const int tid = threadIdx.x;
    const int bid = blockIdx.x;
    const int yt = bid & 15;
    const int c  = (bid >> 4) & 15;
    const int b  = bid >> 8;
    const int y0 = yt * 16;

    const size_t xb  = ((size_t)(b * 16 + c) * 256 + y0) * 256;
    const size_t p1b = ((size_t)(b * 64 + c) * 256 + y0) * 256;
    const size_t p2b = ((size_t)(b * 64 + 32 + c) * 256 + y0) * 256;

    for (int i = tid; i < 1536; i += 256) {
        int s = i >> 9;
        int r = i & 511;
        int y = r >> 5;
        int g = r & 31;
        const unsigned short* sp = (s == 0) ? (X + xb) : (s == 1 ? FM + p1b : FM + p2b);
        u16x8 v = *(const u16x8*)(sp + (size_t)y * 256 + g * 8);
        int c0 = X2C(g * 8);
#pragma unroll
        for (int j = 0; j < 8; ++j) tx[s][y][c0 + j] = bf2f(v[j]);
    }
    __syncthreads();

    const int y  = tid & 15;
    const int sg = (tid >> 4) & 7;
    const int d  = tid >> 7;

    {   // pass 1
        float h1 = 0.f, h2 = 0.f, A1 = 1.f, A2 = 1.f;
        if (d == 0) {
            int cs = X2C(sg * 32);
#pragma unroll
            for (int i = 0; i < 32; ++i) {
                float xv = tx[0][y][cs + i], p1 = tx[1][y][cs + i], p2 = tx[2][y][cs + i];
                h1 = fmaf(p1, h1 - xv, xv); A1 *= p1;
                h2 = fmaf(p2, h2 - xv, xv); A2 *= p2;
            }
        } else {
            int cs = X2C(255 - sg * 32);
#pragma unroll
            for (int i = 0; i < 32; ++i) {
                float xv = tx[0][y][cs - i], p1 = tx[1][y][cs - i], p2 = tx[2][y][cs - i];
                h1 = fmaf(p1, h1 - xv, xv); A1 *= p1;
                h2 = fmaf(p2, h2 - xv, xv); A2 *= p2;
            }
        }
        segres[d][y][sg][0] = h1; segres[d][y][sg][1] = A1;
        segres[d][y][sg][2] = h2; segres[d][y][sg][3] = A2;
    }
    __syncthreads();

    if (tid < 32) {
        int yy = tid & 15, dd = tid >> 4;
        float c1 = 0.f, c2 = 0.f;
        for (int s = 0; s < 8; ++s) {
            hin[dd][yy][s][0] = c1;
            hin[dd][yy][s][1] = c2;
            c1 = segres[dd][yy][s][0] + segres[dd][yy][s][1] * c1;
            c2 = segres[dd][yy][s][2] + segres[dd][yy][s][3] * c2;
        }
    }
    __syncthreads();

    {   // pass 2 (paired cvt_pk stores)
        float h1 = hin[d][y][sg][0], h2 = hin[d][y][sg][1];
        if (d == 0) {
            int cs = X2C(sg * 32);
            int xs = sg * 32;
#pragma unroll
            for (int i = 0; i < 32; i += 2) {
                float xv = tx[0][y][cs + i], p1 = tx[1][y][cs + i], p2 = tx[2][y][cs + i];
                h1 = fmaf(p1, h1 - xv, xv);
                h2 = fmaf(p2, h2 - xv, xv);
                float m0 = fmaxf(h1, h2);
                xv = tx[0][y][cs + i + 1]; p1 = tx[1][y][cs + i + 1]; p2 = tx[2][y][cs + i + 1];
                h1 = fmaf(p1, h1 - xv, xv);
                h2 = fmaf(p2, h2 - xv, xv);
                float m1 = fmaxf(h1, h2);
                unsigned p = cvtpk2(m0, m1);
                outm[0][y][xs + i]     = (unsigned short)p;
                outm[0][y][xs + i + 1] = (unsigned short)(p >> 16);
            }
        } else {
            int cs = X2C(255 - sg * 32);
#pragma unroll
            for (int i = 0; i < 32; i += 2) {
                int t = sg * 32 + i;
                float xv = tx[0][y][cs - i], p1 = tx[1][y][cs - i], p2 = tx[2][y][cs - i];
                h1 = fmaf(p1, h1 - xv, xv);
                h2 = fmaf(p2, h2 - xv, xv);
                float m0 = fmaxf(h1, h2);
                xv = tx[0][y][cs - i - 1]; p1 = tx[1][y][cs - i - 1]; p2 = tx[2][y][cs - i - 1];
                h1 = fmaf(p1, h1 - xv, xv);
                h2 = fmaf(p2, h2 - xv, xv);
                float m1 = fmaxf(h1, h2);
                unsigned p = cvtpk2(m0, m1);
                outm[1][y][t]     = (unsigned short)p;
                outm[1][y][t + 1] = (unsigned short)(p >> 16);
            }
        }
    }
    __syncthreads();

    // final: thread tid owns x=tid, rows 0..15 (paired conversions)
    {
        const int x = tid;
#pragma unroll
        for (int yy = 0; yy < 16; yy += 2) {
            float m0 = fmaxf(bf2f(outm[0][yy][x]),     bf2f(outm[1][yy][x]));
            float m1 = fmaxf(bf2f(outm[0][yy + 1][x]), bf2f(outm[1][yy + 1][x]));
            unsigned p = cvtpk2(m0, m1);
            rnnW[xb + (size_t)yy * 256 + x]       = (unsigned short)p;
            rnnW[xb + (size_t)(yy + 1) * 256 + x] = (unsigned short)(p >> 16);
        }
    }
}

// ---------------------------------------------------------------------------
// Segmented H-direction LRNN pair; writeback FUSES max with rnnW -> rnnM.
// ---------------------------------------------------------------------------
__global__ __launch_bounds__(256)
void lrnn_h_seg(const unsigned short* __restrict__ X, const unsigned short* __restrict__ FM,
                const unsigned short* __restrict__ rnnW, unsigned short* __restrict__ rnnM)
{
    __shared__ float tx[3][264][17];
    __shared__ unsigned short outm[2][256][16];
    __shared__ float segres[2][16][8][4];
    __shared__ float hin[2][16][8][2];

    const int tid = threadIdx.x;
    const int bid = blockIdx.x;
    const int xt = bid & 15;
    const int c  = (bid >> 4) & 15;
    const int b  = bid >> 8;
    const int x0 = xt * 16;

    const size_t xb  = (size_t)(b * 16 + c) * 65536 + x0;
    const size_t p1b = (size_t)(b * 64 + 16 + c) * 65536 + x0;
    const size_t p2b = (size_t)(b * 64 + 48 + c) * 65536 + x0;

    for (int i = tid; i < 1536; i += 256) {
        int s = i >> 9;
        int r = i & 511;
        int y = r >> 1;
        int g = r & 1;
        const unsigned short* sp = (s == 0) ? (X + xb) : (s == 1 ? FM + p1b : FM + p2b);
        u16x8 v = *(const u16x8*)(sp + (size_t)y * 256 + g * 8);
        int pr = y + (y >> 5);
#pragma unroll
        for (int j = 0; j < 8; ++j) tx[s][pr][g * 8 + j] = bf2f(v[j]);
    }
    __syncthreads();

    const int x  = tid & 15;
    const int sg = (tid >> 4) & 7;
    const int d  = tid >> 7;

    {   // pass 1
        float h1 = 0.f, h2 = 0.f, A1 = 1.f, A2 = 1.f;
        if (d == 0) {
            int rs = X2C(sg * 32);
#pragma unroll
            for (int i = 0; i < 32; ++i) {
                float xv = tx[0][rs + i][x], p1 = tx[1][rs + i][x], p2 = tx[2][rs + i][x];
                h1 = fmaf(p1, h1 - xv, xv); A1 *= p1;
                h2 = fmaf(p2, h2 - xv, xv); A2 *= p2;
            }
        } else {
            int rs = X2C(255 - sg * 32);
#pragma unroll
            for (int i = 0; i < 32; ++i) {
                float xv = tx[0][rs - i][x], p1 = tx[1][rs - i][x], p2 = tx[2][rs - i][x];
                h1 = fmaf(p1, h1 - xv, xv); A1 *= p1;
                h2 = fmaf(p2, h2 - xv, xv); A2 *= p2;
            }
        }
        segres[d][x][sg][0] = h1; segres[d][x][sg][1] = A1;
        segres[d][x][sg][2] = h2; segres[d][x][sg][3] = A2;
    }
    __syncthreads();

    if (tid < 32) {
        int xx = tid & 15, dd = tid >> 4;
        float c1 = 0.f, c2 = 0.f;
        for (int s = 0; s < 8; ++s) {
            hin[dd][xx][s][0] = c1;
            hin[dd][xx][s][1] = c2;
            c1 = segres[dd][xx][s][0] + segres[dd][xx][s][1] * c1;
            c2 = segres[dd][xx][s][2] + segres[dd][xx][s][3] * c2;
        }
    }
    __syncthreads();

    {   // pass 2 (paired cvt_pk stores)
        float h1 = hin[d][x][sg][0], h2 = hin[d][x][sg][1];
        if (d == 0) {
            int rs = X2C(sg * 32);
            int ys = sg * 32;
#pragma unroll
            for (int i = 0; i < 32; i += 2) {
                float xv = tx[0][rs + i][x], p1 = tx[1][rs + i][x], p2 = tx[2][rs + i][x];
                h1 = fmaf(p1, h1 - xv, xv);
                h2 = fmaf(p2, h2 - xv, xv);
                float m0 = fmaxf(h1, h2);
                xv = tx[0][rs + i + 1][x]; p1 = tx[1][rs + i + 1][x]; p2 = tx[2][rs + i + 1][x];
                h1 = fmaf(p1, h1 - xv, xv);
                h2 = fmaf(p2, h2 - xv, xv);
                float m1 = fmaxf(h1, h2);
                unsigned p = cvtpk2(m0, m1);
                outm[0][ys + i][x]     = (unsigned short)p;
                outm[0][ys + i + 1][x] = (unsigned short)(p >> 16);
            }
        } else {
            int rs = X2C(255 - sg * 32);
#pragma unroll
            for (int i = 0; i < 32; i += 2) {
                int t = sg * 32 + i;
                float xv = tx[0][rs - i][x], p1 = tx[1][rs - i][x], p2 = tx[2][rs - i][x];
                h1 = fmaf(p1, h1 - xv, xv);
                h2 = fmaf(p2, h2 - xv, xv);
                float m0 = fmaxf(h1, h2);
                xv = tx[0][rs - i - 1][x]; p1 = tx[1][rs - i - 1][x]; p2 = tx[2][rs - i - 1][x];
                h1 = fmaf(p1, h1 - xv, xv);
                h2 = fmaf(p2, h2 - xv, xv);
                float m1 = fmaxf(h1, h2);
                unsigned p = cvtpk2(m0, m1);
                outm[1][t][x]     = (unsigned short)p;
                outm[1][t + 1][x] = (unsigned short)(p >> 16);
            }
        }
    }
    __syncthreads();

    // final: thread handles xx = tid&15, yy = (tid>>4) + 16k (paired k)
    {
        const int xx = tid & 15;
        const int yy0 = tid >> 4;
#pragma unroll
        for (int k = 0; k < 16; k += 2) {
            int ya = yy0 + 16 * k, yb = yy0 + 16 * (k + 1);
            size_t offA = xb + (size_t)ya * 256 + xx;
            size_t offB = xb + (size_t)yb * 256 + xx;
            float ma = fmaxf(fmaxf(bf2f(outm[0][ya][xx]), bf2f(outm[1][ya][xx])),
                             bf2f(rnnW[offA]));
            float mb = fmaxf(fmaxf(bf2f(outm[0][yb][xx]), bf2f(outm[1][yb][xx])),
                             bf2f(rnnW[offB]));
            unsigned p = cvtpk2(ma, mb);
            rnnM[offA] = (unsigned short)p;
            rnnM[offB] = (unsigned short)(p >> 16);
        }
    }
}

// ---------------------------------------------------------------------------
// Output head MFMA: rnnM -> 3x3 conv (Cin16, Cout3), sigmoid -> fp32 out.
// 4 output rows x 128 px per block; xi-fastest coalesced staging.
// ---------------------------------------------------------------------------
__global__ __launch_bounds__(256)
void convo_mfma(const unsigned short* __restrict__ rnnM,
                const unsigned short* __restrict__ wpko,
                const float* __restrict__ bo,
                float* __restrict__ outp)
{
    constexpr int PSo = 6 * 130 * 8 + 8;   // 6248 shorts per channel-group plane
    __shared__ __align__(16) unsigned short smem[2 * PSo];   // 24992 B

    const int tid  = threadIdx.x;
    const int lane = tid & 63;
    const int wv   = tid >> 6;
    const int n    = lane & 31;
    const int q    = lane >> 5;
    const int x0   = (blockIdx.x & 1) * 128;
    const int yq   = blockIdx.x >> 1;       // 0..63
    const int b    = blockIdx.y;

    for (int i = tid; i < 6 * 16 * 130; i += 256) {
        int xi = i % 130;          // fastest: consecutive lanes -> consecutive x
        int t  = i / 130;          // 0..95
        int ch = t & 15;
        int r  = t >> 4;           // 0..5
        int yg = 4 * yq + r - 1;
        int xg = x0 - 1 + xi;
        unsigned short m = 0;
        if (yg >= 0 && yg < 256 && xg >= 0 && xg < 256)
            m = rnnM[(size_t)(b * 16 + ch) * 65536 + (size_t)yg * 256 + xg];
        int g = ch >> 3, j = ch & 7;
        smem[g * PSo + (r * 130 + xi) * 8 + j] = m;
    }
    __syncthreads();

    const unsigned short* wbase = wpko + lane * 8;
    const int y = 4 * yq + wv;              // wave wv owns one output row

#pragma unroll
    for (int xt = 0; xt < 4; ++xt) {
        const int pxl = xt * 32 + n;
        f32x16 acc;
#pragma unroll
        for (int i = 0; i < 16; ++i) acc[i] = 0.f;
#pragma unroll
        for (int s = 0; s < 9; ++s) {
            const int dy = s / 3, dx = s % 3;
            bf16x8 bfrag = *(const bf16x8*)(&smem[q * PSo + ((wv + dy) * 130 + pxl + dx) * 8]);
            bf16x8 a = *(const bf16x8*)(wbase + s * 512);
            acc = __builtin_amdgcn_mfma_f32_32x32x16_bf16(a, bfrag, acc, 0, 0, 0);
        }
        if (q == 0) {
            const int px = x0 + pxl;
#pragma unroll
            for (int oc = 0; oc < 3; ++oc) {
                float r2 = acc[oc] + bo[oc];
                outp[((size_t)(b * 3 + oc) * 256 + y) * 256 + px] = 1.f / (1.f + __expf(-r2));
            }
        }
    }
}

// ---------------------------------------------------------------------------
extern "C" void kernel_launch(void* const* d_in, const int* in_sizes, int n_in,
                              void* d_out, int out_size, void* d_ws, size_t ws_size,
                              hipStream_t stream)
{
    const float* img = (const float*)d_in[0];
    const float* w1 = (const float*)d_in[1];  const float* b1 = (const float*)d_in[2];
    const float* w2 = (const float*)d_in[3];  const float* b2 = (const float*)d_in[4];
    const float* w3 = (const float*)d_in[5];  const float* b3 = (const float*)d_in[6];
    const float* w4 = (const float*)d_in[7];  const float* b4 = (const float*)d_in[8];
    const float* w5 = (const float*)d_in[9];  const float* b5 = (const float*)d_in[10];
    const float* w6 = (const float*)d_in[11]; const float* b6 = (const float*)d_in[12];
    const float* w7 = (const float*)d_in[13]; const float* b7 = (const float*)d_in[14];
    const float* w8 = (const float*)d_in[15]; const float* b8 = (const float*)d_in[16];
    const float* w9 = (const float*)d_in[17]; const float* b9 = (const float*)d_in[18];
    const float* wi = (const float*)d_in[19]; const float* bi = (const float*)d_in[20];
    const float* wo = (const float*)d_in[21]; const float* bo = (const float*)d_in[22];

    char* wsb = (char*)d_ws;
    const size_t MB = (size_t)(1u << 20);
    unsigned short* imgT  = (unsigned short*)(wsb);             // [0,16) dead after conv1i
    unsigned short* x1t   = (unsigned short*)(wsb + 16 * MB);   // [16,32) till conv9f
    unsigned short* x2t   = (unsigned short*)(wsb + 32 * MB);   // [32,40) till conv8
    unsigned short* x3t   = (unsigned short*)(wsb + 40 * MB);   // [40,42) till conv7
    unsigned short* x4t   = (unsigned short*)(wsb + 42 * MB);   // [42,42.5) till conv6
    unsigned short* x5t   = (unsigned short*)(wsb + 43 * MB);   // [43,43.25)
    unsigned short* x6t   = (unsigned short*)(wsb + 46 * MB);   // [46,46.5)
    unsigned short* x7t   = (unsigned short*)(wsb + 51 * MB);   // [51,53) till conv8
    unsigned short* x8t   = (unsigned short*)(wsb + 70 * MB);   // [70,78) till conv9f
    unsigned short* fm16  = (unsigned short*)(wsb + 112 * MB);  // [112,176) NCHW bf16
    unsigned short* xin16 = (unsigned short*)(wsb + 176 * MB);  // [176,192) NCHW bf16
    unsigned short* rnnW  = (unsigned short*)(wsb);             // [0,16)  (imgT dead)
    unsigned short* rnnM  = (unsigned short*)(wsb + 16 * MB);   // [16,32) (x1t dead)
    unsigned short* wpk9 = (unsigned short*)(wsb + 192 * MB);
    unsigned short* wpk8 = wpk9 + 27648;
    unsigned short* wpk1 = wpk8 + 18432;
    unsigned short* wpki = wpk1 + 12800;
    unsigned short* wpko = wpki + 4608;
    unsigned short* wpk2 = wpko + 4608;
    unsigned short* wpk3 = wpk2 + 4608;
    unsigned short* wpk4 = wpk3 + 9216;
    unsigned short* wpk5 = wpk4 + 9216;
    unsigned short* wpk6 = wpk5 + 18432;
    unsigned short* wpk7 = wpk6 + 27648;
    unsigned short* wpk9e = wpk7 + 18432;    // 110592 shorts (conv9 composite)
    unsigned short* wpk8e = wpk9e + 110592;  // 55296 shorts (conv8 composite)
    float* outp = (float*)d_out;

    // --- single weight-pack dispatch + img transpose ---
    wprep_mega<<<1256, 256, 0, stream>>>(w9, w8, w1, wi, wo, w2, w3, w4, w5, w6, w7,
                                         wpk9, wpk8, wpk1, wpki, wpko,
                                         wpk2, wpk3, wpk4, wpk5, wpk6, wpk7,
                                         wpk9e, wpk8e);
    imgT_bf16<<<2048, 256, 0, stream>>>(img, imgT);

    // --- fused conv1 (relu -> x1t NHWC) + input projection (xin16 NCHW bf16) ---
    { dim3 grd(512, 8);
      conv1i_mfma<<<grd, 256, 0, stream>>>(imgT, wpk1, wpki, b1, bi, x1t, xin16); }

    // --- encoder: pools fused into conv staging ---
    convN_mfma<16, 32, 128, 128, 1, 1><<<dim3(128, 8), 256, 0, stream>>>(x1t, wpk2, b2, x2t);
    convN_mfma<32, 32, 64, 64, 2, 1><<<dim3(32, 8), 256, 0, stream>>>(x2t, wpk3, b3, x3t);
    convN_mfma<32, 32, 32, 32, 4, 1><<<dim3(8, 8), 256, 0, stream>>>(x3t, wpk4, b4, x4t);
    convN_mfma<32, 64, 16, 16, 8, 1><<<dim3(2, 8), 256, 0, stream>>>(x4t, wpk5, b5, x5t);

    // --- decoder: upcat fused into conv6/conv7/conv8 staging ---
    convU_mfma<64, 32, 32, 32, 32, 4><<<dim3(8, 8), 256, 0, stream>>>(x5t, x4t, wpk6, b6, x6t);
    convU_mfma<32, 32, 32, 64, 64, 2><<<dim3(32, 8), 256, 0, stream>>>(x6t, x3t, wpk7, b7, x7t);
    { dim3 grd(128, 8);
      conv8_mfma<<<grd, 256, 0, stream>>>(x7t, x2t, wpk8, wpk8e, b8, x8t); }

    // --- stage 9: y-composite conv9 (512 blocks) ---
    { dim3 grd(512, 8);
      conv9f_mfma<<<grd, 256, 0, stream>>>(x8t, x1t, wpk9, wpk9e, b9, fm16); }

    // --- spatial RNN: segmented scans; lrnn_h fuses max(rnnW, rnnH) -> rnnM ---
    lrnn_w_seg<<<2048, 256, 0, stream>>>(xin16, fm16, rnnW);
    lrnn_h_seg<<<2048, 256, 0, stream>>>(xin16, fm16, rnnW, rnnM);

    // --- output head: 4-row blocks, single input tensor ---
    { dim3 grd(128, 8);
      convo_mfma<<<grd, 256, 0, stream>>>(rnnM, wpko, bo, outp); }
}

// Round 8
// 356.777 us; speedup vs baseline: 1.1598x; 1.0683x over previous
//
#include <hip/hip_runtime.h>
#include <math.h>

typedef __attribute__((ext_vector_type(8)))  short bf16x8;
typedef __attribute__((ext_vector_type(8)))  unsigned short u16x8;
typedef __attribute__((ext_vector_type(16))) float f32x16;

__device__ __forceinline__ unsigned short f2bf(float f) {
    unsigned u = __float_as_uint(f);
    unsigned r = (u + 0x7FFFu + ((u >> 16) & 1u)) >> 16;
    return (unsigned short)r;
}
__device__ __forceinline__ float bf2f(unsigned short h) {
    return __uint_as_float(((unsigned)h) << 16);
}
__device__ __forceinline__ unsigned pack2(unsigned short a, unsigned short b) {
    return (unsigned)a | ((unsigned)b << 16);
}
// HW packed f32->bf16 RNE: 1 VALU op converts 2 values (== manual f2bf RNE).
__device__ __forceinline__ unsigned cvtpk2(float a, float b) {
    unsigned r;
    asm("v_cvt_pk_bf16_f32 %0, %1, %2" : "=v"(r) : "v"(a), "v"(b));
    return r;
}
__device__ __forceinline__ float fast_tanh(float x) {
    float e = __expf(2.f * x);
    return 1.f - 2.f / (e + 1.f);
}

__device__ __forceinline__ void bilin_setup(int y, int x, int Hi, int Wi,
                                            int& i00, int& i01, int& i10, int& i11,
                                            float& wy, float& wx)
{
    float fy = 0.5f * y - 0.25f;
    float fx = 0.5f * x - 0.25f;
    float y0f = floorf(fy), x0f = floorf(fx);
    wy = fy - y0f; wx = fx - x0f;
    int yA = (int)y0f, xA = (int)x0f;
    int yB = yA + 1, xB = xA + 1;
    yA = yA < 0 ? 0 : (yA > Hi - 1 ? Hi - 1 : yA);
    yB = yB < 0 ? 0 : (yB > Hi - 1 ? Hi - 1 : yB);
    xA = xA < 0 ? 0 : (xA > Wi - 1 ? Wi - 1 : xA);
    xB = xB < 0 ? 0 : (xB > Wi - 1 ? Wi - 1 : xB);
    i00 = yA * Wi + xA; i01 = yA * Wi + xB;
    i10 = yB * Wi + xA; i11 = yB * Wi + xB;
}

// 2x upsample w/ half-pixel centers: fixed parity weights, no floorf needed.
__device__ __forceinline__ void up2_setup(int v, int Hi, int& i0, int& i1, float& w)
{
    int a = (v - 1) >> 1;           // arithmetic shift: v=0 -> -1
    i0 = a < 0 ? 0 : a;
    int b = a + 1;
    i1 = b > Hi - 1 ? Hi - 1 : b;
    w = (v & 1) ? 0.25f : 0.75f;
}

__device__ __forceinline__ uint4 bilin8u(const unsigned short* __restrict__ sb,
                                         int i00, int i01, int i10, int i11,
                                         float wy, float wx, int stride)
{
    u16x8 v00 = *(const u16x8*)(sb + (size_t)i00 * stride);
    u16x8 v01 = *(const u16x8*)(sb + (size_t)i01 * stride);
    u16x8 v10 = *(const u16x8*)(sb + (size_t)i10 * stride);
    u16x8 v11 = *(const u16x8*)(sb + (size_t)i11 * stride);
    float w00 = (1.f - wy) * (1.f - wx), w01 = (1.f - wy) * wx;
    float w10 = wy * (1.f - wx),         w11 = wy * wx;
    float f[8];
#pragma unroll
    for (int j = 0; j < 8; ++j)
        f[j] = w00 * bf2f(v00[j]) + w01 * bf2f(v01[j]) +
               w10 * bf2f(v10[j]) + w11 * bf2f(v11[j]);
    return make_uint4(cvtpk2(f[0], f[1]), cvtpk2(f[2], f[3]),
                      cvtpk2(f[4], f[5]), cvtpk2(f[6], f[7]));
}

// y-interp composite coefficients: ALPH[cls][py][dy][dr]
__device__ const float ALPH[3][2][3][3] = {
    { { {0.f,0.f,0.f},      {0.f,1.f,0.f},       {0.f,0.75f,0.25f} },
      { {0.f,1.f,0.f},      {0.f,0.75f,0.25f},   {0.f,0.25f,0.75f} } },
    { { {0.75f,0.25f,0.f},  {0.25f,0.75f,0.f},   {0.f,0.75f,0.25f} },
      { {0.25f,0.75f,0.f},  {0.f,0.75f,0.25f},   {0.f,0.25f,0.75f} } },
    { { {0.75f,0.25f,0.f},  {0.25f,0.75f,0.f},   {0.f,1.f,0.f} },
      { {0.25f,0.75f,0.f},  {0.f,1.f,0.f},       {0.f,0.f,0.f} } }
};

// ---------------------------------------------------------------------------
// img [8][15][256][256] fp32 -> imgT [b][y][x][16] bf16 (ch15 = 0)
// ---------------------------------------------------------------------------
__global__ void imgT_bf16(const float* __restrict__ img, unsigned short* __restrict__ dst)
{
    int idx = blockIdx.x * 256 + threadIdx.x;
    if (idx >= 8 * 256 * 256) return;
    int x = idx & 255, y = (idx >> 8) & 255, b = idx >> 16;
    float f[15];
#pragma unroll
    for (int c = 0; c < 15; ++c)
        f[c] = img[(size_t)(b * 15 + c) * 65536 + y * 256 + x];
    uint4 lo = make_uint4(cvtpk2(f[0], f[1]), cvtpk2(f[2], f[3]),
                          cvtpk2(f[4], f[5]), cvtpk2(f[6], f[7]));
    uint4 hi = make_uint4(cvtpk2(f[8], f[9]), cvtpk2(f[10], f[11]),
                          cvtpk2(f[12], f[13]), cvtpk2(f[14], 0.f));
    *(uint4*)(dst + (size_t)idx * 16)     = lo;
    *(uint4*)(dst + (size_t)idx * 16 + 8) = hi;
}

// ---------------------------------------------------------------------------
// Mega weight-pack: all packs in one dispatch (incl. y-composite tables).
// ---------------------------------------------------------------------------
__device__ __forceinline__ void pack33(const float* __restrict__ w,
                                       unsigned short* __restrict__ dst,
                                       int i, int Cin, int Cout)
{
    int KST = Cin >> 4, MT = Cout >> 5;
    int j = i & 7;
    int lane = (i >> 3) & 63;
    int t = i >> 9;
    int mt = t % MT; t /= MT;
    int kst = t % KST;
    int s = t / KST;
    int oc = mt * 32 + (lane & 31);
    int ci = kst * 16 + (lane >> 5) * 8 + j;
    dst[i] = f2bf(w[(oc * Cin + ci) * 9 + s]);
}

__global__ void wprep_mega(const float* __restrict__ w9, const float* __restrict__ w8,
                           const float* __restrict__ w1, const float* __restrict__ wi,
                           const float* __restrict__ wo, const float* __restrict__ w2,
                           const float* __restrict__ w3, const float* __restrict__ w4,
                           const float* __restrict__ w5, const float* __restrict__ w6,
                           const float* __restrict__ w7,
                           unsigned short* __restrict__ wpk9, unsigned short* __restrict__ wpk8,
                           unsigned short* __restrict__ wpk1, unsigned short* __restrict__ wpki,
                           unsigned short* __restrict__ wpko, unsigned short* __restrict__ wpk2,
                           unsigned short* __restrict__ wpk3, unsigned short* __restrict__ wpk4,
                           unsigned short* __restrict__ wpk5, unsigned short* __restrict__ wpk6,
                           unsigned short* __restrict__ wpk7, unsigned short* __restrict__ wpk9e,
                           unsigned short* __restrict__ wpk8e)
{
    int idx = blockIdx.x * 256 + threadIdx.x;
    if (idx < 27648)       pack33(w9, wpk9, idx, 48, 64);
    else if (idx < 46080)  pack33(w8, wpk8, idx - 27648, 64, 32);
    else if (idx < 58880) {
        int i = idx - 46080;
        int j = i & 7;
        int lane = (i >> 3) & 63;
        int s = i >> 9;                 // 0..24
        int oc = lane & 31;
        int ci = (lane >> 5) * 8 + j;   // 0..15
        float v = 0.f;
        if (oc < 16 && ci < 15) v = w1[((oc * 15 + ci) * 5 + s / 5) * 5 + s % 5];
        wpk1[i] = f2bf(v);
    } else if (idx < 63488) {
        int i = idx - 58880;
        int j = i & 7;
        int lane = (i >> 3) & 63;
        int s = i >> 9;                 // 0..8
        int oc = lane & 31;
        int ci = (lane >> 5) * 8 + j;
        float v = 0.f;
        if (oc < 16 && ci < 15) v = wi[((oc * 15 + ci) * 3 + s / 3) * 3 + s % 3];
        wpki[i] = f2bf(v);
    } else if (idx < 68096) {
        int i = idx - 63488;
        int j = i & 7;
        int lane = (i >> 3) & 63;
        int s = i >> 9;
        int oc = lane & 31;
        int ci = (lane >> 5) * 8 + j;
        float v = 0.f;
        if (oc < 3) v = wo[((oc * 16 + ci) * 3 + s / 3) * 3 + s % 3];
        wpko[i] = f2bf(v);
    }
    else if (idx < 72704)  pack33(w2, wpk2, idx - 68096, 16, 32);
    else if (idx < 81920)  pack33(w3, wpk3, idx - 72704, 32, 32);
    else if (idx < 91136)  pack33(w4, wpk4, idx - 81920, 32, 32);
    else if (idx < 109568) pack33(w5, wpk5, idx - 91136, 32, 64);
    else if (idx < 137216) pack33(w6, wpk6, idx - 109568, 96, 32);
    else if (idx < 155648) pack33(w7, wpk7, idx - 137216, 64, 32);
    else if (idx < 266240) {
        // conv9 y-composite tables: [cls][py][s=dr*3+dx][kst][half] x 512
        int i = idx - 155648;
        int j = i & 7;
        int lane = (i >> 3) & 63;
        int t = i >> 9;                 // 0..215
        int half = t & 1; t >>= 1;
        int kst  = t & 1; t >>= 1;
        int s    = t % 9; t /= 9;
        int py   = t & 1;
        int cls  = t >> 1;              // 0..2
        int dr = s / 3, dx = s % 3;
        int oc = half * 32 + (lane & 31);
        int ci = kst * 16 + (lane >> 5) * 8 + j;   // x8 channels 0..31
        float v = 0.f;
#pragma unroll
        for (int dy = 0; dy < 3; ++dy)
            v += ALPH[cls][py][dy][dr] * w9[((oc * 48 + ci) * 3 + dy) * 3 + dx];
        wpk9e[i] = f2bf(v);
    }
    else if (idx < 321536) {
        // conv8 y-composite tables (up channels 0..31): [cls][py][s][kst] x 512
        int i = idx - 266240;
        int j = i & 7;
        int lane = (i >> 3) & 63;
        int t = i >> 9;                 // 0..107
        int kst = t & 1; t >>= 1;
        int s   = t % 9; t /= 9;
        int py  = t & 1;
        int cls = t >> 1;               // 0..2
        int dr = s / 3, dx = s % 3;
        int oc = lane & 31;
        int ci = kst * 16 + (lane >> 5) * 8 + j;   // up channels 0..31
        float v = 0.f;
#pragma unroll
        for (int dy = 0; dy < 3; ++dy)
            v += ALPH[cls][py][dy][dr] * w8[((oc * 64 + ci) * 3 + dy) * 3 + dx];
        wpk8e[i] = f2bf(v);
    }
}

// ---------------------------------------------------------------------------
// Generic NHWC bf16 MFMA conv (3x3, pad 1, relu -> NHWC bf16).
// POOL=1: input is [8, 2H, 2W, CIN]; staging applies 2x2 maxpool on the fly.
// ---------------------------------------------------------------------------
template<int CIN, int COUT, int H, int W, int ROWS, int POOL>
__global__ __launch_bounds__(256)
void convN_mfma(const unsigned short* __restrict__ in,
                const unsigned short* __restrict__ wpk,
                const float* __restrict__ bias,
                unsigned short* __restrict__ out)
{
    constexpr int G = CIN / 8;
    constexpr int KST = CIN / 16;
    constexpr int MT = COUT / 32;
    constexpr int TR = ROWS + 2;
    constexpr int TWd = W + 2;
    constexpr int PS = TR * TWd * 8 + 8;
    __shared__ __align__(16) unsigned short smem[G * PS];

    const int tid  = threadIdx.x;
    const int lane = tid & 63;
    const int wv   = tid >> 6;
    const int q    = lane >> 5;
    const int y0   = blockIdx.x * ROWS;
    const int b    = blockIdx.y;

    for (int i = tid; i < G * TR * TWd; i += 256) {
        int g = i % G;
        int u = (i / G) % TWd;
        int t = i / (G * TWd);
        int yg = y0 + t - 1, xg = u - 1;
        uint4 v = make_uint4(0, 0, 0, 0);
        if (yg >= 0 && yg < H && xg >= 0 && xg < W) {
            if (POOL) {
                const unsigned short* q0 =
                    in + (((size_t)(b * 2 * H + 2 * yg) * 2 * W + 2 * xg) * CIN + g * 8);
                u16x8 a0 = *(const u16x8*)q0;
                u16x8 a1 = *(const u16x8*)(q0 + CIN);
                u16x8 a2 = *(const u16x8*)(q0 + (size_t)2 * W * CIN);
                u16x8 a3 = *(const u16x8*)(q0 + (size_t)2 * W * CIN + CIN);
                float f[8];
#pragma unroll
                for (int j = 0; j < 8; ++j)
                    f[j] = fmaxf(fmaxf(bf2f(a0[j]), bf2f(a1[j])),
                                 fmaxf(bf2f(a2[j]), bf2f(a3[j])));
                v = make_uint4(cvtpk2(f[0], f[1]), cvtpk2(f[2], f[3]),
                               cvtpk2(f[4], f[5]), cvtpk2(f[6], f[7]));
            } else {
                v = *(const uint4*)(in + (((size_t)(b * H + yg) * W + xg) * CIN + g * 8));
            }
        }
        *(uint4*)(&smem[g * PS + (t * TWd + u) * 8]) = v;
    }
    __syncthreads();

    const int p = wv * 32 + (lane & 31);
    const int r = p / W;
    const int x = p % W;

    f32x16 acc[MT];
#pragma unroll
    for (int mt = 0; mt < MT; ++mt)
#pragma unroll
        for (int i = 0; i < 16; ++i) acc[mt][i] = 0.f;

    const unsigned short* wbase = wpk + lane * 8;

#pragma unroll
    for (int s = 0; s < 9; ++s) {
        const int dy = s / 3, dx = s % 3;
#pragma unroll
        for (int kst = 0; kst < KST; ++kst) {
            const int g = kst * 2 + q;
            bf16x8 bfrag = *(const bf16x8*)(&smem[g * PS + ((r + dy) * TWd + (x + dx)) * 8]);
#pragma unroll
            for (int mt = 0; mt < MT; ++mt) {
                bf16x8 a = *(const bf16x8*)(wbase + ((s * KST + kst) * MT + mt) * 512);
                acc[mt] = __builtin_amdgcn_mfma_f32_32x32x16_bf16(a, bfrag, acc[mt], 0, 0, 0);
            }
        }
    }

    size_t base = ((size_t)(b * H + y0 + r) * W + x) * COUT;
#pragma unroll
    for (int mt = 0; mt < MT; ++mt)
#pragma unroll
        for (int rg = 0; rg < 4; ++rg) {
            int oc = mt * 32 + 8 * rg + 4 * q;
            float v0 = fmaxf(acc[mt][rg * 4 + 0] + bias[oc + 0], 0.f);
            float v1 = fmaxf(acc[mt][rg * 4 + 1] + bias[oc + 1], 0.f);
            float v2 = fmaxf(acc[mt][rg * 4 + 2] + bias[oc + 2], 0.f);
            float v3 = fmaxf(acc[mt][rg * 4 + 3] + bias[oc + 3], 0.f);
            *(uint2*)(out + base + oc) = make_uint2(cvtpk2(v0, v1), cvtpk2(v2, v3));
        }
}

// ---------------------------------------------------------------------------
// convU: 3x3 conv with FUSED upsample+concat staging (decoder stages 6,7).
// ---------------------------------------------------------------------------
template<int UPC, int CSKIP, int COUT, int H, int W, int ROWS>
__global__ __launch_bounds__(256)
void convU_mfma(const unsigned short* __restrict__ up,
                const unsigned short* __restrict__ skip,
                const unsigned short* __restrict__ wpk,
                const float* __restrict__ bias,
                unsigned short* __restrict__ out)
{
    constexpr int CIN = UPC + CSKIP;
    constexpr int G = CIN / 8;
    constexpr int GU = UPC / 8;
    constexpr int KST = CIN / 16;
    constexpr int MT = COUT / 32;
    constexpr int TR = ROWS + 2;
    constexpr int TWd = W + 2;
    constexpr int PS = TR * TWd * 8 + 8;
    __shared__ __align__(16) unsigned short smem[G * PS];

    const int tid  = threadIdx.x;
    const int lane = tid & 63;
    const int wv   = tid >> 6;
    const int q    = lane >> 5;
    const int y0   = blockIdx.x * ROWS;
    const int b    = blockIdx.y;

    for (int i = tid; i < G * TR * TWd; i += 256) {
        int g = i % G;
        int u = (i / G) % TWd;
        int t = i / (G * TWd);
        int yg = y0 + t - 1, xg = u - 1;
        uint4 v = make_uint4(0, 0, 0, 0);
        if (yg >= 0 && yg < H && xg >= 0 && xg < W) {
            if (g < GU) {
                int i00, i01, i10, i11; float wy, wx;
                bilin_setup(yg, xg, H / 2, W / 2, i00, i01, i10, i11, wy, wx);
                v = bilin8u(up + (size_t)b * (H / 2) * (W / 2) * UPC + g * 8,
                            i00, i01, i10, i11, wy, wx, UPC);
            } else {
                v = *(const uint4*)(skip + (((size_t)(b * H + yg) * W + xg) * CSKIP
                                            + (g - GU) * 8));
            }
        }
        *(uint4*)(&smem[g * PS + (t * TWd + u) * 8]) = v;
    }
    __syncthreads();

    const int p = wv * 32 + (lane & 31);
    const int r = p / W;
    const int x = p % W;

    f32x16 acc[MT];
#pragma unroll
    for (int mt = 0; mt < MT; ++mt)
#pragma unroll
        for (int i = 0; i < 16; ++i) acc[mt][i] = 0.f;

    const unsigned short* wbase = wpk + lane * 8;

#pragma unroll
    for (int s = 0; s < 9; ++s) {
        const int dy = s / 3, dx = s % 3;
#pragma unroll
        for (int kst = 0; kst < KST; ++kst) {
            const int g = kst * 2 + q;
            bf16x8 bfrag = *(const bf16x8*)(&smem[g * PS + ((r + dy) * TWd + (x + dx)) * 8]);
#pragma unroll
            for (int mt = 0; mt < MT; ++mt) {
                bf16x8 a = *(const bf16x8*)(wbase + ((s * KST + kst) * MT + mt) * 512);
                acc[mt] = __builtin_amdgcn_mfma_f32_32x32x16_bf16(a, bfrag, acc[mt], 0, 0, 0);
            }
        }
    }

    size_t base = ((size_t)(b * H + y0 + r) * W + x) * COUT;
#pragma unroll
    for (int mt = 0; mt < MT; ++mt)
#pragma unroll
        for (int rg = 0; rg < 4; ++rg) {
            int oc = mt * 32 + 8 * rg + 4 * q;
            float v0 = fmaxf(acc[mt][rg * 4 + 0] + bias[oc + 0], 0.f);
            float v1 = fmaxf(acc[mt][rg * 4 + 1] + bias[oc + 1], 0.f);
            float v2 = fmaxf(acc[mt][rg * 4 + 2] + bias[oc + 2], 0.f);
            float v3 = fmaxf(acc[mt][rg * 4 + 3] + bias[oc + 3], 0.f);
            *(uint2*)(out + base + oc) = make_uint2(cvtpk2(v0, v1), cvtpk2(v2, v3));
        }
}

// ---------------------------------------------------------------------------
// Fused conv1 (5x5, relu -> x1t NHWC bf16) + conv_i (3x3 -> xin NCHW bf16).
// ---------------------------------------------------------------------------
__global__ __launch_bounds__(256)
void conv1i_mfma(const unsigned short* __restrict__ imgT,
                 const unsigned short* __restrict__ wpk1,
                 const unsigned short* __restrict__ wpki,
                 const float* __restrict__ b1, const float* __restrict__ bi,
                 unsigned short* __restrict__ x1t, unsigned short* __restrict__ xin)
{
    __shared__ __align__(16) unsigned short smem[2 * 5 * 132 * 8];

    const int tid  = threadIdx.x;
    const int lane = tid & 63;
    const int wv   = tid >> 6;
    const int n    = lane & 31;
    const int q    = lane >> 5;
    const int y    = blockIdx.x >> 1;
    const int x0   = (blockIdx.x & 1) * 128;
    const int b    = blockIdx.y;

    for (int i = tid; i < 5 * 132 * 2; i += 256) {
        int r   = i / 264;
        int rem = i - r * 264;
        int xi  = rem >> 1;
        int g   = rem & 1;
        int yg = y + r - 2;
        int xg = x0 - 2 + xi;
        uint4 v = make_uint4(0, 0, 0, 0);
        if (yg >= 0 && yg < 256 && xg >= 0 && xg < 256)
            v = *(const uint4*)(imgT + (((size_t)(b * 256 + yg) * 256 + xg) * 16 + g * 8));
        *(uint4*)(&smem[((g * 5 + r) * 132 + xi) * 8]) = v;
    }
    __syncthreads();

    f32x16 acc1, acci;
#pragma unroll
    for (int i = 0; i < 16; ++i) { acc1[i] = 0.f; acci[i] = 0.f; }

    const int pxl = wv * 32 + n;
    const unsigned short* wb1 = wpk1 + lane * 8;
    const unsigned short* wbi = wpki + lane * 8;

#pragma unroll
    for (int s = 0; s < 25; ++s) {
        const int dy = s / 5, dx = s % 5;
        bf16x8 bfrag = *(const bf16x8*)(&smem[((q * 5 + dy) * 132 + pxl + dx) * 8]);
        bf16x8 a = *(const bf16x8*)(wb1 + s * 512);
        acc1 = __builtin_amdgcn_mfma_f32_32x32x16_bf16(a, bfrag, acc1, 0, 0, 0);
    }
#pragma unroll
    for (int s = 0; s < 9; ++s) {
        const int dy = s / 3, dx = s % 3;
        bf16x8 bfrag = *(const bf16x8*)(&smem[((q * 5 + dy + 1) * 132 + pxl + dx + 1) * 8]);
        bf16x8 a = *(const bf16x8*)(wbi + s * 512);
        acci = __builtin_amdgcn_mfma_f32_32x32x16_bf16(a, bfrag, acci, 0, 0, 0);
    }

    const int px = x0 + pxl;
    size_t base1 = ((size_t)(b * 256 + y) * 256 + px) * 16;
#pragma unroll
    for (int rg = 0; rg < 2; ++rg) {
        int oc = 8 * rg + 4 * q;
        float v0 = fmaxf(acc1[rg * 4 + 0] + b1[oc + 0], 0.f);
        float v1 = fmaxf(acc1[rg * 4 + 1] + b1[oc + 1], 0.f);
        float v2 = fmaxf(acc1[rg * 4 + 2] + b1[oc + 2], 0.f);
        float v3 = fmaxf(acc1[rg * 4 + 3] + b1[oc + 3], 0.f);
        *(uint2*)(x1t + base1 + oc) = make_uint2(cvtpk2(v0, v1), cvtpk2(v2, v3));
    }
#pragma unroll
    for (int reg = 0; reg < 8; reg += 2) {
        int row = (reg & 3) + 8 * (reg >> 2) + 4 * q;   // reg even: rows row,row+1
        unsigned p = cvtpk2(acci[reg] + bi[row], acci[reg + 1] + bi[row + 1]);
        xin[((size_t)(b * 16 + row)     * 256 + y) * 256 + px] = (unsigned short)p;
        xin[((size_t)(b * 16 + row + 1) * 256 + y) * 256 + px] = (unsigned short)(p >> 16);
    }
}

// ---------------------------------------------------------------------------
// conv8 MFMA, y-composite + cvt_pk (unchanged from round 7).
// ---------------------------------------------------------------------------
__global__ __launch_bounds__(256)
void conv8_mfma(const unsigned short* __restrict__ x7t,
                const unsigned short* __restrict__ x2t,
                const unsigned short* __restrict__ wpk8,   // original (skip ksts)
                const unsigned short* __restrict__ wpk8e,  // composite up tables
                const float* __restrict__ bias,
                unsigned short* __restrict__ x8t)
{
    constexpr int PSU = 3 * 66 * 8 + 8;   // 1592 shorts per up plane
    constexpr int PSS = 4 * 66 * 8 + 8;   // 2120 shorts per skip plane
    constexpr int SOFF = 4 * PSU;         // 6368
    __shared__ __align__(16) unsigned short smem[4 * PSU + 4 * PSS]; // 29696 B

    const int tid  = threadIdx.x;
    const int lane = tid & 63;
    const int wv   = tid >> 6;
    const int n    = lane & 31;
    const int q    = lane >> 5;
    const int x0   = (blockIdx.x & 1) * 64;
    const int yp   = blockIdx.x >> 1;       // low-res row i, 0..63
    const int b    = blockIdx.y;

    for (int i = tid; i < 792 + 1056; i += 256) {
        if (i < 792) {
            // up part: 4 planes x 3 low-res rows x 66 cols, x-lerp only
            int g   = i & 3;
            int rem = i >> 2;           // 0..197
            int xi  = rem % 66;
            int t8  = rem / 66;         // 0..2  (low-res row yp-1+t8)
            int r   = yp - 1 + t8;
            int xg  = x0 - 1 + xi;
            uint4 v = make_uint4(0, 0, 0, 0);
            if (r >= 0 && r < 64 && xg >= 0 && xg < 128) {
                int ix0, ix1; float wx;
                up2_setup(xg, 64, ix0, ix1, wx);
                const unsigned short* S = x7t + ((size_t)(b * 64 + r) * 64) * 32 + g * 8;
                u16x8 a0 = *(const u16x8*)(S + ix0 * 32);
                u16x8 a1 = *(const u16x8*)(S + ix1 * 32);
                float w1x = 1.f - wx;
                float f[8];
#pragma unroll
                for (int j = 0; j < 8; ++j)
                    f[j] = w1x * bf2f(a0[j]) + wx * bf2f(a1[j]);
                v = make_uint4(cvtpk2(f[0], f[1]), cvtpk2(f[2], f[3]),
                               cvtpk2(f[4], f[5]), cvtpk2(f[6], f[7]));
            }
            *(uint4*)(&smem[g * PSU + (t8 * 66 + xi) * 8]) = v;
        } else {
            // skip part: 4 planes x 4 full-res rows x 66 cols, pure copy
            int jI  = i - 792;
            int g   = jI & 3;
            int rem = jI >> 2;          // 0..263
            int xi  = rem % 66;
            int t   = rem / 66;         // 0..3
            int yg  = 2 * yp + t - 1;
            int xg  = x0 - 1 + xi;
            uint4 v = make_uint4(0, 0, 0, 0);
            if (yg >= 0 && yg < 128 && xg >= 0 && xg < 128)
                v = *(const uint4*)(x2t + (((size_t)(b * 128 + yg) * 128 + xg) * 32 + g * 8));
            *(uint4*)(&smem[SOFF + g * PSS + (t * 66 + xi) * 8]) = v;
        }
    }
    __syncthreads();

    const int rr  = wv >> 1;                // output row parity py
    const int pxl = (wv & 1) * 32 + n;

    f32x16 acc;
#pragma unroll
    for (int i = 0; i < 16; ++i) acc[i] = 0.f;

    const int cls = (yp == 0) ? 0 : ((yp == 63) ? 2 : 1);
    const unsigned short* wE = wpk8e + (size_t)(cls * 2 + rr) * 9216 + lane * 8;
    const unsigned short* wS = wpk8 + lane * 8;

#pragma unroll
    for (int s = 0; s < 9; ++s) {
        const int dr = s / 3, dxx = s % 3;
#pragma unroll
        for (int kst = 0; kst < 2; ++kst) {
            const int g = kst * 2 + q;
            bf16x8 bfrag = *(const bf16x8*)(&smem[g * PSU + (dr * 66 + pxl + dxx) * 8]);
            bf16x8 a = *(const bf16x8*)(wE + (s * 2 + kst) * 512);
            acc = __builtin_amdgcn_mfma_f32_32x32x16_bf16(a, bfrag, acc, 0, 0, 0);
        }
#pragma unroll
        for (int kst = 0; kst < 2; ++kst) {
            const int g = kst * 2 + q;
            bf16x8 bfrag = *(const bf16x8*)(&smem[SOFF + g * PSS + ((rr + dr) * 66 + pxl + dxx) * 8]);
            bf16x8 a = *(const bf16x8*)(wS + (s * 4 + kst + 2) * 512);
            acc = __builtin_amdgcn_mfma_f32_32x32x16_bf16(a, bfrag, acc, 0, 0, 0);
        }
    }

    size_t base = ((size_t)(b * 128 + 2 * yp + rr) * 128 + x0 + pxl) * 32;
#pragma unroll
    for (int rg = 0; rg < 4; ++rg) {
        int oc0 = 8 * rg + 4 * q;
        float v0 = fmaxf(acc[rg * 4 + 0] + bias[oc0 + 0], 0.f);
        float v1 = fmaxf(acc[rg * 4 + 1] + bias[oc0 + 1], 0.f);
        float v2 = fmaxf(acc[rg * 4 + 2] + bias[oc0 + 2], 0.f);
        float v3 = fmaxf(acc[rg * 4 + 3] + bias[oc0 + 3], 0.f);
        *(uint2*)(x8t + base + oc0) = make_uint2(cvtpk2(v0, v1), cvtpk2(v2, v3));
    }
}

// ---------------------------------------------------------------------------
// conv9 MFMA, y-composite + cvt_pk (unchanged from round 7).
// ---------------------------------------------------------------------------
__global__ __launch_bounds__(256)
void conv9f_mfma(const unsigned short* __restrict__ x8t,
                 const unsigned short* __restrict__ x1t,
                 const unsigned short* __restrict__ wpk,     // original (kst=2 slice used)
                 const unsigned short* __restrict__ wpk9e,   // composite tables
                 const float* __restrict__ bias,
                 unsigned short* __restrict__ fm)
{
    constexpr int PS8X = 3 * 66 * 8 + 8;   // 1592 shorts per x8 plane
    constexpr int PS1  = 4 * 66 * 8 + 8;   // 2120 shorts per x1 plane
    constexpr int X1OFF = 4 * PS8X;        // 6368
    __shared__ __align__(16) unsigned short smem[4 * PS8X + 2 * PS1];  // 21216 B

    const int tid  = threadIdx.x;
    const int lane = tid & 63;
    const int wv   = tid >> 6;
    const int n    = lane & 31;
    const int q    = lane >> 5;
    const int x0   = (blockIdx.x & 3) * 64;
    const int yp   = blockIdx.x >> 2;       // 0..127 (= low-res row i)
    const int b    = blockIdx.y;

    for (int i = tid; i < 792 + 528; i += 256) {
        if (i < 792) {
            // x8 part: 4 planes x 3 low-res rows x 66 cols, x-lerp only
            int g   = i & 3;
            int rem = i >> 2;           // 0..197
            int xi  = rem % 66;
            int t8  = rem / 66;         // 0..2  (low-res row i-1+t8)
            int r   = yp - 1 + t8;
            int xg  = x0 - 1 + xi;
            uint4 v = make_uint4(0, 0, 0, 0);
            if (r >= 0 && r < 128 && xg >= 0 && xg < 256) {
                int ix0, ix1; float wx;
                up2_setup(xg, 128, ix0, ix1, wx);
                const unsigned short* S = x8t + ((size_t)(b * 128 + r) * 128) * 32 + g * 8;
                u16x8 a0 = *(const u16x8*)(S + ix0 * 32);
                u16x8 a1 = *(const u16x8*)(S + ix1 * 32);
                float w1x = 1.f - wx;
                float f[8];
#pragma unroll
                for (int j = 0; j < 8; ++j)
                    f[j] = w1x * bf2f(a0[j]) + wx * bf2f(a1[j]);
                v = make_uint4(cvtpk2(f[0], f[1]), cvtpk2(f[2], f[3]),
                               cvtpk2(f[4], f[5]), cvtpk2(f[6], f[7]));
            }
            *(uint4*)(&smem[g * PS8X + (t8 * 66 + xi) * 8]) = v;
        } else {
            // x1 part: 2 planes x 4 full-res rows x 66 cols, pure copy
            int jI  = i - 792;
            int g   = jI & 1;
            int rem = jI >> 1;          // 0..263
            int xi  = rem % 66;
            int t   = rem / 66;         // 0..3
            int yg  = 2 * yp + t - 1;
            int xg  = x0 - 1 + xi;
            uint4 v = make_uint4(0, 0, 0, 0);
            if (yg >= 0 && yg < 256 && xg >= 0 && xg < 256)
                v = *(const uint4*)(x1t + (((size_t)(b * 256 + yg) * 256 + xg) * 16 + g * 8));
            *(uint4*)(&smem[X1OFF + g * PS1 + (t * 66 + xi) * 8]) = v;
        }
    }
    __syncthreads();

    const int rr  = wv >> 1;                 // output row parity py
    const int pxl = (wv & 1) * 32 + n;

    f32x16 acc0, acc1;
#pragma unroll
    for (int i = 0; i < 16; ++i) { acc0[i] = 0.f; acc1[i] = 0.f; }

    const int cls = (yp == 0) ? 0 : ((yp == 127) ? 2 : 1);
    const unsigned short* wE  = wpk9e + (size_t)(cls * 2 + rr) * 18432 + lane * 8;
    const unsigned short* w2b = wpk + lane * 8;

#pragma unroll
    for (int s = 0; s < 9; ++s) {
        const int dr = s / 3, dxx = s % 3;
#pragma unroll
        for (int kst = 0; kst < 2; ++kst) {
            const int g = kst * 2 + q;
            bf16x8 bfrag = *(const bf16x8*)(&smem[g * PS8X + (dr * 66 + pxl + dxx) * 8]);
            bf16x8 a0 = *(const bf16x8*)(wE + ((s * 2 + kst) * 2 + 0) * 512);
            bf16x8 a1 = *(const bf16x8*)(wE + ((s * 2 + kst) * 2 + 1) * 512);
            acc0 = __builtin_amdgcn_mfma_f32_32x32x16_bf16(a0, bfrag, acc0, 0, 0, 0);
            acc1 = __builtin_amdgcn_mfma_f32_32x32x16_bf16(a1, bfrag, acc1, 0, 0, 0);
        }
        {
            bf16x8 bfrag = *(const bf16x8*)(&smem[X1OFF + q * PS1 + ((rr + dr) * 66 + pxl + dxx) * 8]);
            bf16x8 a0 = *(const bf16x8*)(w2b + ((s * 3 + 2) * 2 + 0) * 512);
            bf16x8 a1 = *(const bf16x8*)(w2b + ((s * 3 + 2) * 2 + 1) * 512);
            acc0 = __builtin_amdgcn_mfma_f32_32x32x16_bf16(a0, bfrag, acc0, 0, 0, 0);
            acc1 = __builtin_amdgcn_mfma_f32_32x32x16_bf16(a1, bfrag, acc1, 0, 0, 0);
        }
    }

    // --- epilogue: LDS transpose -> vectorized NCHW stores ---
    __syncthreads();                       // staging buffer is now dead
    unsigned short* lout = smem;           // [64 oc][128 px] = 8192 shorts
    const int pb = rr * 64 + pxl + q * 512;   // px index + 4q row fold (4*128)
#pragma unroll
    for (int reg = 0; reg < 16; reg += 2) {
        const int rb = (reg & 3) + 8 * (reg >> 2);        // pairs -> rows rb, rb+1
        float a0 = fast_tanh(acc0[reg]     + bias[rb + 4 * q]);
        float a1 = fast_tanh(acc0[reg + 1] + bias[rb + 1 + 4 * q]);
        unsigned p0 = cvtpk2(a0, a1);
        lout[rb * 128 + pb]       = (unsigned short)p0;
        lout[(rb + 1) * 128 + pb] = (unsigned short)(p0 >> 16);
        float b0 = fast_tanh(acc1[reg]     + bias[rb + 4 * q + 32]);
        float b1 = fast_tanh(acc1[reg + 1] + bias[rb + 1 + 4 * q + 32]);
        unsigned p1 = cvtpk2(b0, b1);
        lout[(rb + 32) * 128 + pb] = (unsigned short)p1;
        lout[(rb + 33) * 128 + pb] = (unsigned short)(p1 >> 16);
    }
    __syncthreads();

    const size_t fmb = (size_t)b * 64 * 65536 + (size_t)(2 * yp) * 256 + x0;
    for (int i = tid; i < 1024; i += 256) {
        int oc  = i >> 4;
        int p0  = (i & 15) * 8;        // 0..120
        int rr2 = p0 >> 6;             // output row within pair
        int pl  = p0 & 63;             // x within 64-px strip
        uint4 v = *(const uint4*)(lout + oc * 128 + p0);
        *(uint4*)(fm + fmb + (size_t)oc * 65536 + rr2 * 256 + pl) = v;
    }
}

// ---------------------------------------------------------------------------
// Segmented W-direction LRNN pair -> rnnW NCHW bf16.
// Round-8: tx stored as bf16 with +8/32 padding (stride 40 shorts per
// 32-block, row 312) -> staging is 6 pure ds_write_b128 copies and scan
// passes read via ds_read_b128 (24 loads vs 192 scalar). LDS 73K -> 52K.
// ---------------------------------------------------------------------------
__global__ __launch_bounds__(256)
void lrnn_w_seg(const unsigned short* __restrict__ X, const unsigned short* __restrict__ FM,
                unsigned short* __restrict__ rnnW)
{
    __shared__ __align__(16) unsigned short tx[3][16][312];
    __shared__ __align__(16) unsigned short outm[2][16][256];
    __shared__ float segres[2][16][8][4];
    __shared__ float hin[2][16][8][2];

    const int tid = threadIdx.x;
    const int bid = blockIdx.x;
    const int yt = bid & 15;
    const int c  = (bid >> 4) & 15;
    const int b  = bid >> 8;
    const int y0 = yt * 16;

    const size_t xb  = ((size_t)(b * 16 + c) * 256 + y0) * 256;
    const size_t p1b = ((size_t)(b * 64 + c) * 256 + y0) * 256;
    const size_t p2b = ((size_t)(b * 64 + 32 + c) * 256 + y0) * 256;

    for (int i = tid; i < 1536; i += 256) {
        int s = i >> 9;
        int r = i & 511;
        int y = r >> 5;
        int g = r & 31;
        const unsigned short* sp = (s == 0) ? (X + xb) : (s == 1 ? FM + p1b : FM + p2b);
        uint4 v = *(const uint4*)(sp + (size_t)y * 256 + g * 8);
        *(uint4*)(&tx[s][y][8 * g + 8 * (g >> 2)]) = v;   // padded col of x=8g
    }
    __syncthreads();

    const int y  = tid & 15;
    const int sg = (tid >> 4) & 7;
    const int d  = tid >> 7;

    {   // pass 1
        float h1 = 0.f, h2 = 0.f, A1 = 1.f, A2 = 1.f;
        if (d == 0) {
            const int base = 40 * sg;
#pragma unroll
            for (int k = 0; k < 4; ++k) {
                u16x8 xv8 = *(const u16x8*)&tx[0][y][base + 8 * k];
                u16x8 p18 = *(const u16x8*)&tx[1][y][base + 8 * k];
                u16x8 p28 = *(const u16x8*)&tx[2][y][base + 8 * k];
#pragma unroll
                for (int j = 0; j < 8; ++j) {
                    float xv = bf2f(xv8[j]), p1 = bf2f(p18[j]), p2 = bf2f(p28[j]);
                    h1 = fmaf(p1, h1 - xv, xv); A1 *= p1;
                    h2 = fmaf(p2, h2 - xv, xv); A2 *= p2;
                }
            }
        } else {
            const int m = 7 - sg;
#pragma unroll
            for (int k = 0; k < 4; ++k) {
                const int base = 40 * m + 24 - 8 * k;
                u16x8 xv8 = *(const u16x8*)&tx[0][y][base];
                u16x8 p18 = *(const u16x8*)&tx[1][y][base];
                u16x8 p28 = *(const u16x8*)&tx[2][y][base];
#pragma unroll
                for (int j = 7; j >= 0; --j) {
                    float xv = bf2f(xv8[j]), p1 = bf2f(p18[j]), p2 = bf2f(p28[j]);
                    h1 = fmaf(p1, h1 - xv, xv); A1 *= p1;
                    h2 = fmaf(p2, h2 - xv, xv); A2 *= p2;
                }
            }
        }
        segres[d][y][sg][0] = h1; segres[d][y][sg][1] = A1;
        segres[d][y][sg][2] = h2; segres[d][y][sg][3] = A2;
    }
    __syncthreads();

    if (tid < 32) {
        int yy = tid & 15, dd = tid >> 4;
        float c1 = 0.f, c2 = 0.f;
        for (int s = 0; s < 8; ++s) {
            hin[dd][yy][s][0] = c1;
            hin[dd][yy][s][1] = c2;
            c1 = segres[dd][yy][s][0] + segres[dd][yy][s][1] * c1;
            c2 = segres[dd][yy][s][2] + segres[dd][yy][s][3] * c2;
        }
    }
    __syncthreads();

    {   // pass 2: vector reads + 8-wide buffered vector outm writes
        float h1 = hin[d][y][sg][0], h2 = hin[d][y][sg][1];
        if (d == 0) {
            const int base = 40 * sg;
            const int xs = 32 * sg;
#pragma unroll
            for (int k = 0; k < 4; ++k) {
                u16x8 xv8 = *(const u16x8*)&tx[0][y][base + 8 * k];
                u16x8 p18 = *(const u16x8*)&tx[1][y][base + 8 * k];
                u16x8 p28 = *(const u16x8*)&tx[2][y][base + 8 * k];
                float mres[8];
#pragma unroll
                for (int j = 0; j < 8; ++j) {
                    float xv = bf2f(xv8[j]), p1 = bf2f(p18[j]), p2 = bf2f(p28[j]);
                    h1 = fmaf(p1, h1 - xv, xv);
                    h2 = fmaf(p2, h2 - xv, xv);
                    mres[j] = fmaxf(h1, h2);
                }
                *(uint4*)&outm[0][y][xs + 8 * k] =
                    make_uint4(cvtpk2(mres[0], mres[1]), cvtpk2(mres[2], mres[3]),
                               cvtpk2(mres[4], mres[5]), cvtpk2(mres[6], mres[7]));
            }
        } else {
            const int m = 7 - sg;
            const int ts = 32 * sg;
#pragma unroll
            for (int k = 0; k < 4; ++k) {
                const int base = 40 * m + 24 - 8 * k;
                u16x8 xv8 = *(const u16x8*)&tx[0][y][base];
                u16x8 p18 = *(const u16x8*)&tx[1][y][base];
                u16x8 p28 = *(const u16x8*)&tx[2][y][base];
                float mres[8];
#pragma unroll
                for (int j = 7; j >= 0; --j) {
                    float xv = bf2f(xv8[j]), p1 = bf2f(p18[j]), p2 = bf2f(p28[j]);
                    h1 = fmaf(p1, h1 - xv, xv);
                    h2 = fmaf(p2, h2 - xv, xv);
                    mres[7 - j] = fmaxf(h1, h2);
                }
                *(uint4*)&outm[1][y][ts + 8 * k] =
                    make_uint4(cvtpk2(mres[0], mres[1]), cvtpk2(mres[2], mres[3]),
                               cvtpk2(mres[4], mres[5]), cvtpk2(mres[6], mres[7]));
            }
        }
    }
    __syncthreads();

    // final: thread tid owns x=tid, rows 0..15 (paired conversions)
    {
        const int x = tid;
#pragma unroll
        for (int yy = 0; yy < 16; yy += 2) {
            float m0 = fmaxf(bf2f(outm[0][yy][x]),     bf2f(outm[1][yy][x]));
            float m1 = fmaxf(bf2f(outm[0][yy + 1][x]), bf2f(outm[1][yy + 1][x]));
            unsigned p = cvtpk2(m0, m1);
            rnnW[xb + (size_t)yy * 256 + x]       = (unsigned short)p;
            rnnW[xb + (size_t)(yy + 1) * 256 + x] = (unsigned short)(p >> 16);
        }
    }
}

// ---------------------------------------------------------------------------
// Segmented H-direction LRNN pair; fuses max(rnnW, rnnH) -> rnnM.
// Round-8: tx stored TRANSPOSED as bf16 [s][x][pad(y)] so scans read
// consecutively via ds_read_b128; outm transposed [d][x][264].
// ---------------------------------------------------------------------------
__global__ __launch_bounds__(256)
void lrnn_h_seg(const unsigned short* __restrict__ X, const unsigned short* __restrict__ FM,
                const unsigned short* __restrict__ rnnW, unsigned short* __restrict__ rnnM)
{
    __shared__ __align__(16) unsigned short tx[3][16][312];
    __shared__ __align__(16) unsigned short outm[2][16][264];
    __shared__ float segres[2][16][8][4];
    __shared__ float hin[2][16][8][2];

    const int tid = threadIdx.x;
    const int bid = blockIdx.x;
    const int xt = bid & 15;
    const int c  = (bid >> 4) & 15;
    const int b  = bid >> 8;
    const int x0 = xt * 16;

    const size_t xb  = (size_t)(b * 16 + c) * 65536 + x0;
    const size_t p1b = (size_t)(b * 64 + 16 + c) * 65536 + x0;
    const size_t p2b = (size_t)(b * 64 + 48 + c) * 65536 + x0;

    for (int i = tid; i < 1536; i += 256) {
        int s = i >> 9;
        int r = i & 511;
        int y = r >> 1;
        int g = r & 1;
        const unsigned short* sp = (s == 0) ? (X + xb) : (s == 1 ? FM + p1b : FM + p2b);
        u16x8 v = *(const u16x8*)(sp + (size_t)y * 256 + g * 8);
        int pc = y + 8 * (y >> 5);        // padded col for y
#pragma unroll
        for (int j = 0; j < 8; ++j) tx[s][g * 8 + j][pc] = v[j];
    }
    __syncthreads();

    const int x  = tid & 15;
    const int sg = (tid >> 4) & 7;
    const int d  = tid >> 7;

    {   // pass 1
        float h1 = 0.f, h2 = 0.f, A1 = 1.f, A2 = 1.f;
        if (d == 0) {
            const int base = 40 * sg;
#pragma unroll
            for (int k = 0; k < 4; ++k) {
                u16x8 xv8 = *(const u16x8*)&tx[0][x][base + 8 * k];
                u16x8 p18 = *(const u16x8*)&tx[1][x][base + 8 * k];
                u16x8 p28 = *(const u16x8*)&tx[2][x][base + 8 * k];
#pragma unroll
                for (int j = 0; j < 8; ++j) {
                    float xv = bf2f(xv8[j]), p1 = bf2f(p18[j]), p2 = bf2f(p28[j]);
                    h1 = fmaf(p1, h1 - xv, xv); A1 *= p1;
                    h2 = fmaf(p2, h2 - xv, xv); A2 *= p2;
                }
            }
        } else {
            const int m = 7 - sg;
#pragma unroll
            for (int k = 0; k < 4; ++k) {
                const int base = 40 * m + 24 - 8 * k;
                u16x8 xv8 = *(const u16x8*)&tx[0][x][base];
                u16x8 p18 = *(const u16x8*)&tx[1][x][base];
                u16x8 p28 = *(const u16x8*)&tx[2][x][base];
#pragma unroll
                for (int j = 7; j >= 0; --j) {
                    float xv = bf2f(xv8[j]), p1 = bf2f(p18[j]), p2 = bf2f(p28[j]);
                    h1 = fmaf(p1, h1 - xv, xv); A1 *= p1;
                    h2 = fmaf(p2, h2 - xv, xv); A2 *= p2;
                }
            }
        }
        segres[d][x][sg][0] = h1; segres[d][x][sg][1] = A1;
        segres[d][x][sg][2] = h2; segres[d][x][sg][3] = A2;
    }
    __syncthreads();

    if (tid < 32) {
        int xx = tid & 15, dd = tid >> 4;
        float c1 = 0.f, c2 = 0.f;
        for (int s = 0; s < 8; ++s) {
            hin[dd][xx][s][0] = c1;
            hin[dd][xx][s][1] = c2;
            c1 = segres[dd][xx][s][0] + segres[dd][xx][s][1] * c1;
            c2 = segres[dd][xx][s][2] + segres[dd][xx][s][3] * c2;
        }
    }
    __syncthreads();

    {   // pass 2: vector reads + 8-wide buffered vector outm writes
        float h1 = hin[d][x][sg][0], h2 = hin[d][x][sg][1];
        if (d == 0) {
            const int base = 40 * sg;
            const int ys = 32 * sg;
#pragma unroll
            for (int k = 0; k < 4; ++k) {
                u16x8 xv8 = *(const u16x8*)&tx[0][x][base + 8 * k];
                u16x8 p18 = *(const u16x8*)&tx[1][x][base + 8 * k];
                u16x8 p28 = *(const u16x8*)&tx[2][x][base + 8 * k];
                float mres[8];
#pragma unroll
                for (int j = 0; j < 8; ++j) {
                    float xv = bf2f(xv8[j]), p1 = bf2f(p18[j]), p2 = bf2f(p28[j]);
                    h1 = fmaf(p1, h1 - xv, xv);
                    h2 = fmaf(p2, h2 - xv, xv);
                    mres[j] = fmaxf(h1, h2);
                }
                *(uint4*)&outm[0][x][ys + 8 * k] =
                    make_uint4(cvtpk2(mres[0], mres[1]), cvtpk2(mres[2], mres[3]),
                               cvtpk2(mres[4], mres[5]), cvtpk2(mres[6], mres[7]));
            }
        } else {
            const int m = 7 - sg;
            const int ts = 32 * sg;
#pragma unroll
            for (int k = 0; k < 4; ++k) {
                const int base = 40 * m + 24 - 8 * k;
                u16x8 xv8 = *(const u16x8*)&tx[0][x][base];
                u16x8 p18 = *(const u16x8*)&tx[1][x][base];
                u16x8 p28 = *(const u16x8*)&tx[2][x][base];
                float mres[8];
#pragma unroll
                for (int j = 7; j >= 0; --j) {
                    float xv = bf2f(xv8[j]), p1 = bf2f(p18[j]), p2 = bf2f(p28[j]);
                    h1 = fmaf(p1, h1 - xv, xv);
                    h2 = fmaf(p2, h2 - xv, xv);
                    mres[7 - j] = fmaxf(h1, h2);
                }
                *(uint4*)&outm[1][x][ts + 8 * k] =
                    make_uint4(cvtpk2(mres[0], mres[1]), cvtpk2(mres[2], mres[3]),
                               cvtpk2(mres[4], mres[5]), cvtpk2(mres[6], mres[7]));
            }
        }
    }
    __syncthreads();

    // final: thread handles xx = tid&15, yy = (tid>>4) + 16k (paired k)
    {
        const int xx = tid & 15;
        const int yy0 = tid >> 4;
#pragma unroll
        for (int k = 0; k < 16; k += 2) {
            int ya = yy0 + 16 * k, yb = yy0 + 16 * (k + 1);
            size_t offA = xb + (size_t)ya * 256 + xx;
            size_t offB = xb + (size_t)yb * 256 + xx;
            float ma = fmaxf(fmaxf(bf2f(outm[0][xx][ya]), bf2f(outm[1][xx][ya])),
                             bf2f(rnnW[offA]));
            float mb = fmaxf(fmaxf(bf2f(outm[0][xx][yb]), bf2f(outm[1][xx][yb])),
                             bf2f(rnnW[offB]));
            unsigned p = cvtpk2(ma, mb);
            rnnM[offA] = (unsigned short)p;
            rnnM[offB] = (unsigned short)(p >> 16);
        }
    }
}

// ---------------------------------------------------------------------------
// Output head MFMA: rnnM -> 3x3 conv (Cin16, Cout3), sigmoid -> fp32 out.
// 4 output rows x 128 px per block; xi-fastest coalesced staging.
// ---------------------------------------------------------------------------
__global__ __launch_bounds__(256)
void convo_mfma(const unsigned short* __restrict__ rnnM,
                const unsigned short* __restrict__ wpko,
                const float* __restrict__ bo,
                float* __restrict__ outp)
{
    constexpr int PSo = 6 * 130 * 8 + 8;   // 6248 shorts per channel-group plane
    __shared__ __align__(16) unsigned short smem[2 * PSo];   // 24992 B

    const int tid  = threadIdx.x;
    const int lane = tid & 63;
    const int wv   = tid >> 6;
    const int n    = lane & 31;
    const int q    = lane >> 5;
    const int x0   = (blockIdx.x & 1) * 128;
    const int yq   = blockIdx.x >> 1;       // 0..63
    const int b    = blockIdx.y;

    for (int i = tid; i < 6 * 16 * 130; i += 256) {
        int xi = i % 130;          // fastest: consecutive lanes -> consecutive x
        int t  = i / 130;          // 0..95
        int ch = t & 15;
        int r  = t >> 4;           // 0..5
        int yg = 4 * yq + r - 1;
        int xg = x0 - 1 + xi;
        unsigned short m = 0;
        if (yg >= 0 && yg < 256 && xg >= 0 && xg < 256)
            m = rnnM[(size_t)(b * 16 + ch) * 65536 + (size_t)yg * 256 + xg];
        int g = ch >> 3, j = ch & 7;
        smem[g * PSo + (r * 130 + xi) * 8 + j] = m;
    }
    __syncthreads();

    const unsigned short* wbase = wpko + lane * 8;
    const int y = 4 * yq + wv;              // wave wv owns one output row

#pragma unroll
    for (int xt = 0; xt < 4; ++xt) {
        const int pxl = xt * 32 + n;
        f32x16 acc;
#pragma unroll
        for (int i = 0; i < 16; ++i) acc[i] = 0.f;
#pragma unroll
        for (int s = 0; s < 9; ++s) {
            const int dy = s / 3, dx = s % 3;
            bf16x8 bfrag = *(const bf16x8*)(&smem[q * PSo + ((wv + dy) * 130 + pxl + dx) * 8]);
            bf16x8 a = *(const bf16x8*)(wbase + s * 512);
            acc = __builtin_amdgcn_mfma_f32_32x32x16_bf16(a, bfrag, acc, 0, 0, 0);
        }
        if (q == 0) {
            const int px = x0 + pxl;
#pragma unroll
            for (int oc = 0; oc < 3; ++oc) {
                float r2 = acc[oc] + bo[oc];
                outp[((size_t)(b * 3 + oc) * 256 + y) * 256 + px] = 1.f / (1.f + __expf(-r2));
            }
        }
    }
}

// ---------------------------------------------------------------------------
extern "C" void kernel_launch(void* const* d_in, const int* in_sizes, int n_in,
                              void* d_out, int out_size, void* d_ws, size_t ws_size,
                              hipStream_t stream)
{
    const float* img = (const float*)d_in[0];
    const float* w1 = (const float*)d_in[1];  const float* b1 = (const float*)d_in[2];
    const float* w2 = (const float*)d_in[3];  const float* b2 = (const float*)d_in[4];
    const float* w3 = (const float*)d_in[5];  const float* b3 = (const float*)d_in[6];
    const float* w4 = (const float*)d_in[7];  const float* b4 = (const float*)d_in[8];
    const float* w5 = (const float*)d_in[9];  const float* b5 = (const float*)d_in[10];
    const float* w6 = (const float*)d_in[11]; const float* b6 = (const float*)d_in[12];
    const float* w7 = (const float*)d_in[13]; const float* b7 = (const float*)d_in[14];
    const float* w8 = (const float*)d_in[15]; const float* b8 = (const float*)d_in[16];
    const float* w9 = (const float*)d_in[17]; const float* b9 = (const float*)d_in[18];
    const float* wi = (const float*)d_in[19]; const float* bi = (const float*)d_in[20];
    const float* wo = (const float*)d_in[21]; const float* bo = (const float*)d_in[22];

    char* wsb = (char*)d_ws;
    const size_t MB = (size_t)(1u << 20);
    unsigned short* imgT  = (unsigned short*)(wsb);             // [0,16) dead after conv1i
    unsigned short* x1t   = (unsigned short*)(wsb + 16 * MB);   // [16,32) till conv9f
    unsigned short* x2t   = (unsigned short*)(wsb + 32 * MB);   // [32,40) till conv8
    unsigned short* x3t   = (unsigned short*)(wsb + 40 * MB);   // [40,42) till conv7
    unsigned short* x4t   = (unsigned short*)(wsb + 42 * MB);   // [42,42.5) till conv6
    unsigned short* x5t   = (unsigned short*)(wsb + 43 * MB);   // [43,43.25)
    unsigned short* x6t   = (unsigned short*)(wsb + 46 * MB);   // [46,46.5)
    unsigned short* x7t   = (unsigned short*)(wsb + 51 * MB);   // [51,53) till conv8
    unsigned short* x8t   = (unsigned short*)(wsb + 70 * MB);   // [70,78) till conv9f
    unsigned short* fm16  = (unsigned short*)(wsb + 112 * MB);  // [112,176) NCHW bf16
    unsigned short* xin16 = (unsigned short*)(wsb + 176 * MB);  // [176,192) NCHW bf16
    unsigned short* rnnW  = (unsigned short*)(wsb);             // [0,16)  (imgT dead)
    unsigned short* rnnM  = (unsigned short*)(wsb + 16 * MB);   // [16,32) (x1t dead)
    unsigned short* wpk9 = (unsigned short*)(wsb + 192 * MB);
    unsigned short* wpk8 = wpk9 + 27648;
    unsigned short* wpk1 = wpk8 + 18432;
    unsigned short* wpki = wpk1 + 12800;
    unsigned short* wpko = wpki + 4608;
    unsigned short* wpk2 = wpko + 4608;
    unsigned short* wpk3 = wpk2 + 4608;
    unsigned short* wpk4 = wpk3 + 9216;
    unsigned short* wpk5 = wpk4 + 9216;
    unsigned short* wpk6 = wpk5 + 18432;
    unsigned short* wpk7 = wpk6 + 27648;
    unsigned short* wpk9e = wpk7 + 18432;    // 110592 shorts (conv9 composite)
    unsigned short* wpk8e = wpk9e + 110592;  // 55296 shorts (conv8 composite)
    float* outp = (float*)d_out;

    // --- single weight-pack dispatch + img transpose ---
    wprep_mega<<<1256, 256, 0, stream>>>(w9, w8, w1, wi, wo, w2, w3, w4, w5, w6, w7,
                                         wpk9, wpk8, wpk1, wpki, wpko,
                                         wpk2, wpk3, wpk4, wpk5, wpk6, wpk7,
                                         wpk9e, wpk8e);
    imgT_bf16<<<2048, 256, 0, stream>>>(img, imgT);

    // --- fused conv1 (relu -> x1t NHWC) + input projection (xin16 NCHW bf16) ---
    { dim3 grd(512, 8);
      conv1i_mfma<<<grd, 256, 0, stream>>>(imgT, wpk1, wpki, b1, bi, x1t, xin16); }

    // --- encoder: pools fused into conv staging ---
    convN_mfma<16, 32, 128, 128, 1, 1><<<dim3(128, 8), 256, 0, stream>>>(x1t, wpk2, b2, x2t);
    convN_mfma<32, 32, 64, 64, 2, 1><<<dim3(32, 8), 256, 0, stream>>>(x2t, wpk3, b3, x3t);
    convN_mfma<32, 32, 32, 32, 4, 1><<<dim3(8, 8), 256, 0, stream>>>(x3t, wpk4, b4, x4t);
    convN_mfma<32, 64, 16, 16, 8, 1><<<dim3(2, 8), 256, 0, stream>>>(x4t, wpk5, b5, x5t);

    // --- decoder: upcat fused into conv6/conv7/conv8 staging ---
    convU_mfma<64, 32, 32, 32, 32, 4><<<dim3(8, 8), 256, 0, stream>>>(x5t, x4t, wpk6, b6, x6t);
    convU_mfma<32, 32, 32, 64, 64, 2><<<dim3(32, 8), 256, 0, stream>>>(x6t, x3t, wpk7, b7, x7t);
    { dim3 grd(128, 8);
      conv8_mfma<<<grd, 256, 0, stream>>>(x7t, x2t, wpk8, wpk8e, b8, x8t); }

    // --- stage 9: y-composite conv9 (512 blocks) ---
    { dim3 grd(512, 8);
      conv9f_mfma<<<grd, 256, 0, stream>>>(x8t, x1t, wpk9, wpk9e, b9, fm16); }

    // --- spatial RNN: segmented scans; lrnn_h fuses max(rnnW, rnnH) -> rnnM ---
    lrnn_w_seg<<<2048, 256, 0, stream>>>(xin16, fm16, rnnW);
    lrnn_h_seg<<<2048, 256, 0, stream>>>(xin16, fm16, rnnW, rnnM);

    // --- output head: 4-row blocks, single input tensor ---
    { dim3 grd(128, 8);
      convo_mfma<<<grd, 256, 0, stream>>>(rnnM, wpko, bo, outp); }
}

// Round 9
// 356.097 us; speedup vs baseline: 1.1620x; 1.0019x over previous
//
#include <hip/hip_runtime.h>
#include <math.h>

typedef __attribute__((ext_vector_type(8)))  short bf16x8;
typedef __attribute__((ext_vector_type(8)))  unsigned short u16x8;
typedef __attribute__((ext_vector_type(16))) float f32x16;

__device__ __forceinline__ unsigned short f2bf(float f) {
    unsigned u = __float_as_uint(f);
    unsigned r = (u + 0x7FFFu + ((u >> 16) & 1u)) >> 16;
    return (unsigned short)r;
}
__device__ __forceinline__ float bf2f(unsigned short h) {
    return __uint_as_float(((unsigned)h) << 16);
}
__device__ __forceinline__ unsigned pack2(unsigned short a, unsigned short b) {
    return (unsigned)a | ((unsigned)b << 16);
}
// HW packed f32->bf16 RNE: 1 VALU op converts 2 values (== manual f2bf RNE).
__device__ __forceinline__ unsigned cvtpk2(float a, float b) {
    unsigned r;
    asm("v_cvt_pk_bf16_f32 %0, %1, %2" : "=v"(r) : "v"(a), "v"(b));
    return r;
}
__device__ __forceinline__ float fast_tanh(float x) {
    float e = __expf(2.f * x);
    return 1.f - 2.f / (e + 1.f);
}

__device__ __forceinline__ void bilin_setup(int y, int x, int Hi, int Wi,
                                            int& i00, int& i01, int& i10, int& i11,
                                            float& wy, float& wx)
{
    float fy = 0.5f * y - 0.25f;
    float fx = 0.5f * x - 0.25f;
    float y0f = floorf(fy), x0f = floorf(fx);
    wy = fy - y0f; wx = fx - x0f;
    int yA = (int)y0f, xA = (int)x0f;
    int yB = yA + 1, xB = xA + 1;
    yA = yA < 0 ? 0 : (yA > Hi - 1 ? Hi - 1 : yA);
    yB = yB < 0 ? 0 : (yB > Hi - 1 ? Hi - 1 : yB);
    xA = xA < 0 ? 0 : (xA > Wi - 1 ? Wi - 1 : xA);
    xB = xB < 0 ? 0 : (xB > Wi - 1 ? Wi - 1 : xB);
    i00 = yA * Wi + xA; i01 = yA * Wi + xB;
    i10 = yB * Wi + xA; i11 = yB * Wi + xB;
}

// 2x upsample w/ half-pixel centers: fixed parity weights, no floorf needed.
__device__ __forceinline__ void up2_setup(int v, int Hi, int& i0, int& i1, float& w)
{
    int a = (v - 1) >> 1;           // arithmetic shift: v=0 -> -1
    i0 = a < 0 ? 0 : a;
    int b = a + 1;
    i1 = b > Hi - 1 ? Hi - 1 : b;
    w = (v & 1) ? 0.25f : 0.75f;
}

__device__ __forceinline__ uint4 bilin8u(const unsigned short* __restrict__ sb,
                                         int i00, int i01, int i10, int i11,
                                         float wy, float wx, int stride)
{
    u16x8 v00 = *(const u16x8*)(sb + (size_t)i00 * stride);
    u16x8 v01 = *(const u16x8*)(sb + (size_t)i01 * stride);
    u16x8 v10 = *(const u16x8*)(sb + (size_t)i10 * stride);
    u16x8 v11 = *(const u16x8*)(sb + (size_t)i11 * stride);
    float w00 = (1.f - wy) * (1.f - wx), w01 = (1.f - wy) * wx;
    float w10 = wy * (1.f - wx),         w11 = wy * wx;
    float f[8];
#pragma unroll
    for (int j = 0; j < 8; ++j)
        f[j] = w00 * bf2f(v00[j]) + w01 * bf2f(v01[j]) +
               w10 * bf2f(v10[j]) + w11 * bf2f(v11[j]);
    return make_uint4(cvtpk2(f[0], f[1]), cvtpk2(f[2], f[3]),
                      cvtpk2(f[4], f[5]), cvtpk2(f[6], f[7]));
}

// y-interp composite coefficients: ALPH[cls][py][dy][dr]
__device__ const float ALPH[3][2][3][3] = {
    { { {0.f,0.f,0.f},      {0.f,1.f,0.f},       {0.f,0.75f,0.25f} },
      { {0.f,1.f,0.f},      {0.f,0.75f,0.25f},   {0.f,0.25f,0.75f} } },
    { { {0.75f,0.25f,0.f},  {0.25f,0.75f,0.f},   {0.f,0.75f,0.25f} },
      { {0.25f,0.75f,0.f},  {0.f,0.75f,0.25f},   {0.f,0.25f,0.75f} } },
    { { {0.75f,0.25f,0.f},  {0.25f,0.75f,0.f},   {0.f,1.f,0.f} },
      { {0.25f,0.75f,0.f},  {0.f,1.f,0.f},       {0.f,0.f,0.f} } }
};

// ---------------------------------------------------------------------------
// img [8][15][256][256] fp32 -> imgT [b][y][x][16] bf16 (ch15 = 0)
// ---------------------------------------------------------------------------
__global__ void imgT_bf16(const float* __restrict__ img, unsigned short* __restrict__ dst)
{
    int idx = blockIdx.x * 256 + threadIdx.x;
    if (idx >= 8 * 256 * 256) return;
    int x = idx & 255, y = (idx >> 8) & 255, b = idx >> 16;
    float f[15];
#pragma unroll
    for (int c = 0; c < 15; ++c)
        f[c] = img[(size_t)(b * 15 + c) * 65536 + y * 256 + x];
    uint4 lo = make_uint4(cvtpk2(f[0], f[1]), cvtpk2(f[2], f[3]),
                          cvtpk2(f[4], f[5]), cvtpk2(f[6], f[7]));
    uint4 hi = make_uint4(cvtpk2(f[8], f[9]), cvtpk2(f[10], f[11]),
                          cvtpk2(f[12], f[13]), cvtpk2(f[14], 0.f));
    *(uint4*)(dst + (size_t)idx * 16)     = lo;
    *(uint4*)(dst + (size_t)idx * 16 + 8) = hi;
}

// ---------------------------------------------------------------------------
// Mega weight-pack: all packs in one dispatch (incl. y-composite tables).
// ---------------------------------------------------------------------------
__device__ __forceinline__ void pack33(const float* __restrict__ w,
                                       unsigned short* __restrict__ dst,
                                       int i, int Cin, int Cout)
{
    int KST = Cin >> 4, MT = Cout >> 5;
    int j = i & 7;
    int lane = (i >> 3) & 63;
    int t = i >> 9;
    int mt = t % MT; t /= MT;
    int kst = t % KST;
    int s = t / KST;
    int oc = mt * 32 + (lane & 31);
    int ci = kst * 16 + (lane >> 5) * 8 + j;
    dst[i] = f2bf(w[(oc * Cin + ci) * 9 + s]);
}

__global__ void wprep_mega(const float* __restrict__ w9, const float* __restrict__ w8,
                           const float* __restrict__ w1, const float* __restrict__ wi,
                           const float* __restrict__ wo, const float* __restrict__ w2,
                           const float* __restrict__ w3, const float* __restrict__ w4,
                           const float* __restrict__ w5, const float* __restrict__ w6,
                           const float* __restrict__ w7,
                           unsigned short* __restrict__ wpk9, unsigned short* __restrict__ wpk8,
                           unsigned short* __restrict__ wpk1, unsigned short* __restrict__ wpki,
                           unsigned short* __restrict__ wpko, unsigned short* __restrict__ wpk2,
                           unsigned short* __restrict__ wpk3, unsigned short* __restrict__ wpk4,
                           unsigned short* __restrict__ wpk5, unsigned short* __restrict__ wpk6,
                           unsigned short* __restrict__ wpk7, unsigned short* __restrict__ wpk9e,
                           unsigned short* __restrict__ wpk8e)
{
    int idx = blockIdx.x * 256 + threadIdx.x;
    if (idx < 27648)       pack33(w9, wpk9, idx, 48, 64);
    else if (idx < 46080)  pack33(w8, wpk8, idx - 27648, 64, 32);
    else if (idx < 58880) {
        int i = idx - 46080;
        int j = i & 7;
        int lane = (i >> 3) & 63;
        int s = i >> 9;                 // 0..24
        int oc = lane & 31;
        int ci = (lane >> 5) * 8 + j;   // 0..15
        float v = 0.f;
        if (oc < 16 && ci < 15) v = w1[((oc * 15 + ci) * 5 + s / 5) * 5 + s % 5];
        wpk1[i] = f2bf(v);
    } else if (idx < 63488) {
        int i = idx - 58880;
        int j = i & 7;
        int lane = (i >> 3) & 63;
        int s = i >> 9;                 // 0..8
        int oc = lane & 31;
        int ci = (lane >> 5) * 8 + j;
        float v = 0.f;
        if (oc < 16 && ci < 15) v = wi[((oc * 15 + ci) * 3 + s / 3) * 3 + s % 3];
        wpki[i] = f2bf(v);
    } else if (idx < 68096) {
        int i = idx - 63488;
        int j = i & 7;
        int lane = (i >> 3) & 63;
        int s = i >> 9;
        int oc = lane & 31;
        int ci = (lane >> 5) * 8 + j;
        float v = 0.f;
        if (oc < 3) v = wo[((oc * 16 + ci) * 3 + s / 3) * 3 + s % 3];
        wpko[i] = f2bf(v);
    }
    else if (idx < 72704)  pack33(w2, wpk2, idx - 68096, 16, 32);
    else if (idx < 81920)  pack33(w3, wpk3, idx - 72704, 32, 32);
    else if (idx < 91136)  pack33(w4, wpk4, idx - 81920, 32, 32);
    else if (idx < 109568) pack33(w5, wpk5, idx - 91136, 32, 64);
    else if (idx < 137216) pack33(w6, wpk6, idx - 109568, 96, 32);
    else if (idx < 155648) pack33(w7, wpk7, idx - 137216, 64, 32);
    else if (idx < 266240) {
        // conv9 y-composite tables: [cls][py][s=dr*3+dx][kst][half] x 512
        int i = idx - 155648;
        int j = i & 7;
        int lane = (i >> 3) & 63;
        int t = i >> 9;                 // 0..215
        int half = t & 1; t >>= 1;
        int kst  = t & 1; t >>= 1;
        int s    = t % 9; t /= 9;
        int py   = t & 1;
        int cls  = t >> 1;              // 0..2
        int dr = s / 3, dx = s % 3;
        int oc = half * 32 + (lane & 31);
        int ci = kst * 16 + (lane >> 5) * 8 + j;   // x8 channels 0..31
        float v = 0.f;
#pragma unroll
        for (int dy = 0; dy < 3; ++dy)
            v += ALPH[cls][py][dy][dr] * w9[((oc * 48 + ci) * 3 + dy) * 3 + dx];
        wpk9e[i] = f2bf(v);
    }
    else if (idx < 321536) {
        // conv8 y-composite tables (up channels 0..31): [cls][py][s][kst] x 512
        int i = idx - 266240;
        int j = i & 7;
        int lane = (i >> 3) & 63;
        int t = i >> 9;                 // 0..107
        int kst = t & 1; t >>= 1;
        int s   = t % 9; t /= 9;
        int py  = t & 1;
        int cls = t >> 1;               // 0..2
        int dr = s / 3, dx = s % 3;
        int oc = lane & 31;
        int ci = kst * 16 + (lane >> 5) * 8 + j;   // up channels 0..31
        float v = 0.f;
#pragma unroll
        for (int dy = 0; dy < 3; ++dy)
            v += ALPH[cls][py][dy][dr] * w8[((oc * 64 + ci) * 3 + dy) * 3 + dx];
        wpk8e[i] = f2bf(v);
    }
}

// ---------------------------------------------------------------------------
// Generic NHWC bf16 MFMA conv (3x3, pad 1, relu -> NHWC bf16).
// POOL=1: input is [8, 2H, 2W, CIN]; staging applies 2x2 maxpool on the fly.
// ---------------------------------------------------------------------------
template<int CIN, int COUT, int H, int W, int ROWS, int POOL>
__global__ __launch_bounds__(256)
void convN_mfma(const unsigned short* __restrict__ in,
                const unsigned short* __restrict__ wpk,
                const float* __restrict__ bias,
                unsigned short* __restrict__ out)
{
    constexpr int G = CIN / 8;
    constexpr int KST = CIN / 16;
    constexpr int MT = COUT / 32;
    constexpr int TR = ROWS + 2;
    constexpr int TWd = W + 2;
    constexpr int PS = TR * TWd * 8 + 8;
    __shared__ __align__(16) unsigned short smem[G * PS];

    const int tid  = threadIdx.x;
    const int lane = tid & 63;
    const int wv   = tid >> 6;
    const int q    = lane >> 5;
    const int y0   = blockIdx.x * ROWS;
    const int b    = blockIdx.y;

    for (int i = tid; i < G * TR * TWd; i += 256) {
        int g = i % G;
        int u = (i / G) % TWd;
        int t = i / (G * TWd);
        int yg = y0 + t - 1, xg = u - 1;
        uint4 v = make_uint4(0, 0, 0, 0);
        if (yg >= 0 && yg < H && xg >= 0 && xg < W) {
            if (POOL) {
                const unsigned short* q0 =
                    in + (((size_t)(b * 2 * H + 2 * yg) * 2 * W + 2 * xg) * CIN + g * 8);
                u16x8 a0 = *(const u16x8*)q0;
                u16x8 a1 = *(const u16x8*)(q0 + CIN);
                u16x8 a2 = *(const u16x8*)(q0 + (size_t)2 * W * CIN);
                u16x8 a3 = *(const u16x8*)(q0 + (size_t)2 * W * CIN + CIN);
                float f[8];
#pragma unroll
                for (int j = 0; j < 8; ++j)
                    f[j] = fmaxf(fmaxf(bf2f(a0[j]), bf2f(a1[j])),
                                 fmaxf(bf2f(a2[j]), bf2f(a3[j])));
                v = make_uint4(cvtpk2(f[0], f[1]), cvtpk2(f[2], f[3]),
                               cvtpk2(f[4], f[5]), cvtpk2(f[6], f[7]));
            } else {
                v = *(const uint4*)(in + (((size_t)(b * H + yg) * W + xg) * CIN + g * 8));
            }
        }
        *(uint4*)(&smem[g * PS + (t * TWd + u) * 8]) = v;
    }
    __syncthreads();

    const int p = wv * 32 + (lane & 31);
    const int r = p / W;
    const int x = p % W;

    f32x16 acc[MT];
#pragma unroll
    for (int mt = 0; mt < MT; ++mt)
#pragma unroll
        for (int i = 0; i < 16; ++i) acc[mt][i] = 0.f;

    const unsigned short* wbase = wpk + lane * 8;

#pragma unroll
    for (int s = 0; s < 9; ++s) {
        const int dy = s / 3, dx = s % 3;
#pragma unroll
        for (int kst = 0; kst < KST; ++kst) {
            const int g = kst * 2 + q;
            bf16x8 bfrag = *(const bf16x8*)(&smem[g * PS + ((r + dy) * TWd + (x + dx)) * 8]);
#pragma unroll
            for (int mt = 0; mt < MT; ++mt) {
                bf16x8 a = *(const bf16x8*)(wbase + ((s * KST + kst) * MT + mt) * 512);
                acc[mt] = __builtin_amdgcn_mfma_f32_32x32x16_bf16(a, bfrag, acc[mt], 0, 0, 0);
            }
        }
    }

    size_t base = ((size_t)(b * H + y0 + r) * W + x) * COUT;
#pragma unroll
    for (int mt = 0; mt < MT; ++mt)
#pragma unroll
        for (int rg = 0; rg < 4; ++rg) {
            int oc = mt * 32 + 8 * rg + 4 * q;
            float v0 = fmaxf(acc[mt][rg * 4 + 0] + bias[oc + 0], 0.f);
            float v1 = fmaxf(acc[mt][rg * 4 + 1] + bias[oc + 1], 0.f);
            float v2 = fmaxf(acc[mt][rg * 4 + 2] + bias[oc + 2], 0.f);
            float v3 = fmaxf(acc[mt][rg * 4 + 3] + bias[oc + 3], 0.f);
            *(uint2*)(out + base + oc) = make_uint2(cvtpk2(v0, v1), cvtpk2(v2, v3));
        }
}

// ---------------------------------------------------------------------------
// convU: 3x3 conv with FUSED upsample+concat staging (decoder stages 6,7).
// ---------------------------------------------------------------------------
template<int UPC, int CSKIP, int COUT, int H, int W, int ROWS>
__global__ __launch_bounds__(256)
void convU_mfma(const unsigned short* __restrict__ up,
                const unsigned short* __restrict__ skip,
                const unsigned short* __restrict__ wpk,
                const float* __restrict__ bias,
                unsigned short* __restrict__ out)
{
    constexpr int CIN = UPC + CSKIP;
    constexpr int G = CIN / 8;
    constexpr int GU = UPC / 8;
    constexpr int KST = CIN / 16;
    constexpr int MT = COUT / 32;
    constexpr int TR = ROWS + 2;
    constexpr int TWd = W + 2;
    constexpr int PS = TR * TWd * 8 + 8;
    __shared__ __align__(16) unsigned short smem[G * PS];

    const int tid  = threadIdx.x;
    const int lane = tid & 63;
    const int wv   = tid >> 6;
    const int q    = lane >> 5;
    const int y0   = blockIdx.x * ROWS;
    const int b    = blockIdx.y;

    for (int i = tid; i < G * TR * TWd; i += 256) {
        int g = i % G;
        int u = (i / G) % TWd;
        int t = i / (G * TWd);
        int yg = y0 + t - 1, xg = u - 1;
        uint4 v = make_uint4(0, 0, 0, 0);
        if (yg >= 0 && yg < H && xg >= 0 && xg < W) {
            if (g < GU) {
                int i00, i01, i10, i11; float wy, wx;
                bilin_setup(yg, xg, H / 2, W / 2, i00, i01, i10, i11, wy, wx);
                v = bilin8u(up + (size_t)b * (H / 2) * (W / 2) * UPC + g * 8,
                            i00, i01, i10, i11, wy, wx, UPC);
            } else {
                v = *(const uint4*)(skip + (((size_t)(b * H + yg) * W + xg) * CSKIP
                                            + (g - GU) * 8));
            }
        }
        *(uint4*)(&smem[g * PS + (t * TWd + u) * 8]) = v;
    }
    __syncthreads();

    const int p = wv * 32 + (lane & 31);
    const int r = p / W;
    const int x = p % W;

    f32x16 acc[MT];
#pragma unroll
    for (int mt = 0; mt < MT; ++mt)
#pragma unroll
        for (int i = 0; i < 16; ++i) acc[mt][i] = 0.f;

    const unsigned short* wbase = wpk + lane * 8;

#pragma unroll
    for (int s = 0; s < 9; ++s) {
        const int dy = s / 3, dx = s % 3;
#pragma unroll
        for (int kst = 0; kst < KST; ++kst) {
            const int g = kst * 2 + q;
            bf16x8 bfrag = *(const bf16x8*)(&smem[g * PS + ((r + dy) * TWd + (x + dx)) * 8]);
#pragma unroll
            for (int mt = 0; mt < MT; ++mt) {
                bf16x8 a = *(const bf16x8*)(wbase + ((s * KST + kst) * MT + mt) * 512);
                acc[mt] = __builtin_amdgcn_mfma_f32_32x32x16_bf16(a, bfrag, acc[mt], 0, 0, 0);
            }
        }
    }

    size_t base = ((size_t)(b * H + y0 + r) * W + x) * COUT;
#pragma unroll
    for (int mt = 0; mt < MT; ++mt)
#pragma unroll
        for (int rg = 0; rg < 4; ++rg) {
            int oc = mt * 32 + 8 * rg + 4 * q;
            float v0 = fmaxf(acc[mt][rg * 4 + 0] + bias[oc + 0], 0.f);
            float v1 = fmaxf(acc[mt][rg * 4 + 1] + bias[oc + 1], 0.f);
            float v2 = fmaxf(acc[mt][rg * 4 + 2] + bias[oc + 2], 0.f);
            float v3 = fmaxf(acc[mt][rg * 4 + 3] + bias[oc + 3], 0.f);
            *(uint2*)(out + base + oc) = make_uint2(cvtpk2(v0, v1), cvtpk2(v2, v3));
        }
}

// ---------------------------------------------------------------------------
// Fused conv1 (5x5, relu -> x1t NHWC bf16) + conv_i (3x3 -> xin NCHW bf16).
// ---------------------------------------------------------------------------
__global__ __launch_bounds__(256)
void conv1i_mfma(const unsigned short* __restrict__ imgT,
                 const unsigned short* __restrict__ wpk1,
                 const unsigned short* __restrict__ wpki,
                 const float* __restrict__ b1, const float* __restrict__ bi,
                 unsigned short* __restrict__ x1t, unsigned short* __restrict__ xin)
{
    __shared__ __align__(16) unsigned short smem[2 * 5 * 132 * 8];

    const int tid  = threadIdx.x;
    const int lane = tid & 63;
    const int wv   = tid >> 6;
    const int n    = lane & 31;
    const int q    = lane >> 5;
    const int y    = blockIdx.x >> 1;
    const int x0   = (blockIdx.x & 1) * 128;
    const int b    = blockIdx.y;

    for (int i = tid; i < 5 * 132 * 2; i += 256) {
        int r   = i / 264;
        int rem = i - r * 264;
        int xi  = rem >> 1;
        int g   = rem & 1;
        int yg = y + r - 2;
        int xg = x0 - 2 + xi;
        uint4 v = make_uint4(0, 0, 0, 0);
        if (yg >= 0 && yg < 256 && xg >= 0 && xg < 256)
            v = *(const uint4*)(imgT + (((size_t)(b * 256 + yg) * 256 + xg) * 16 + g * 8));
        *(uint4*)(&smem[((g * 5 + r) * 132 + xi) * 8]) = v;
    }
    __syncthreads();

    f32x16 acc1, acci;
#pragma unroll
    for (int i = 0; i < 16; ++i) { acc1[i] = 0.f; acci[i] = 0.f; }

    const int pxl = wv * 32 + n;
    const unsigned short* wb1 = wpk1 + lane * 8;
    const unsigned short* wbi = wpki + lane * 8;

#pragma unroll
    for (int s = 0; s < 25; ++s) {
        const int dy = s / 5, dx = s % 5;
        bf16x8 bfrag = *(const bf16x8*)(&smem[((q * 5 + dy) * 132 + pxl + dx) * 8]);
        bf16x8 a = *(const bf16x8*)(wb1 + s * 512);
        acc1 = __builtin_amdgcn_mfma_f32_32x32x16_bf16(a, bfrag, acc1, 0, 0, 0);
    }
#pragma unroll
    for (int s = 0; s < 9; ++s) {
        const int dy = s / 3, dx = s % 3;
        bf16x8 bfrag = *(const bf16x8*)(&smem[((q * 5 + dy + 1) * 132 + pxl + dx + 1) * 8]);
        bf16x8 a = *(const bf16x8*)(wbi + s * 512);
        acci = __builtin_amdgcn_mfma_f32_32x32x16_bf16(a, bfrag, acci, 0, 0, 0);
    }

    const int px = x0 + pxl;
    size_t base1 = ((size_t)(b * 256 + y) * 256 + px) * 16;
#pragma unroll
    for (int rg = 0; rg < 2; ++rg) {
        int oc = 8 * rg + 4 * q;
        float v0 = fmaxf(acc1[rg * 4 + 0] + b1[oc + 0], 0.f);
        float v1 = fmaxf(acc1[rg * 4 + 1] + b1[oc + 1], 0.f);
        float v2 = fmaxf(acc1[rg * 4 + 2] + b1[oc + 2], 0.f);
        float v3 = fmaxf(acc1[rg * 4 + 3] + b1[oc + 3], 0.f);
        *(uint2*)(x1t + base1 + oc) = make_uint2(cvtpk2(v0, v1), cvtpk2(v2, v3));
    }
#pragma unroll
    for (int reg = 0; reg < 8; reg += 2) {
        int row = (reg & 3) + 8 * (reg >> 2) + 4 * q;   // reg even: rows row,row+1
        unsigned p = cvtpk2(acci[reg] + bi[row], acci[reg + 1] + bi[row + 1]);
        xin[((size_t)(b * 16 + row)     * 256 + y) * 256 + px] = (unsigned short)p;
        xin[((size_t)(b * 16 + row + 1) * 256 + y) * 256 + px] = (unsigned short)(p >> 16);
    }
}

// ---------------------------------------------------------------------------
// conv8 MFMA, y-composite + cvt_pk (unchanged from round 7).
// ---------------------------------------------------------------------------
__global__ __launch_bounds__(256)
void conv8_mfma(const unsigned short* __restrict__ x7t,
                const unsigned short* __restrict__ x2t,
                const unsigned short* __restrict__ wpk8,   // original (skip ksts)
                const unsigned short* __restrict__ wpk8e,  // composite up tables
                const float* __restrict__ bias,
                unsigned short* __restrict__ x8t)
{
    constexpr int PSU = 3 * 66 * 8 + 8;   // 1592 shorts per up plane
    constexpr int PSS = 4 * 66 * 8 + 8;   // 2120 shorts per skip plane
    constexpr int SOFF = 4 * PSU;         // 6368
    __shared__ __align__(16) unsigned short smem[4 * PSU + 4 * PSS]; // 29696 B

    const int tid  = threadIdx.x;
    const int lane = tid & 63;
    const int wv   = tid >> 6;
    const int n    = lane & 31;
    const int q    = lane >> 5;
    const int x0   = (blockIdx.x & 1) * 64;
    const int yp   = blockIdx.x >> 1;       // low-res row i, 0..63
    const int b    = blockIdx.y;

    for (int i = tid; i < 792 + 1056; i += 256) {
        if (i < 792) {
            // up part: 4 planes x 3 low-res rows x 66 cols, x-lerp only
            int g   = i & 3;
            int rem = i >> 2;           // 0..197
            int xi  = rem % 66;
            int t8  = rem / 66;         // 0..2  (low-res row yp-1+t8)
            int r   = yp - 1 + t8;
            int xg  = x0 - 1 + xi;
            uint4 v = make_uint4(0, 0, 0, 0);
            if (r >= 0 && r < 64 && xg >= 0 && xg < 128) {
                int ix0, ix1; float wx;
                up2_setup(xg, 64, ix0, ix1, wx);
                const unsigned short* S = x7t + ((size_t)(b * 64 + r) * 64) * 32 + g * 8;
                u16x8 a0 = *(const u16x8*)(S + ix0 * 32);
                u16x8 a1 = *(const u16x8*)(S + ix1 * 32);
                float w1x = 1.f - wx;
                float f[8];
#pragma unroll
                for (int j = 0; j < 8; ++j)
                    f[j] = w1x * bf2f(a0[j]) + wx * bf2f(a1[j]);
                v = make_uint4(cvtpk2(f[0], f[1]), cvtpk2(f[2], f[3]),
                               cvtpk2(f[4], f[5]), cvtpk2(f[6], f[7]));
            }
            *(uint4*)(&smem[g * PSU + (t8 * 66 + xi) * 8]) = v;
        } else {
            // skip part: 4 planes x 4 full-res rows x 66 cols, pure copy
            int jI  = i - 792;
            int g   = jI & 3;
            int rem = jI >> 2;          // 0..263
            int xi  = rem % 66;
            int t   = rem / 66;         // 0..3
            int yg  = 2 * yp + t - 1;
            int xg  = x0 - 1 + xi;
            uint4 v = make_uint4(0, 0, 0, 0);
            if (yg >= 0 && yg < 128 && xg >= 0 && xg < 128)
                v = *(const uint4*)(x2t + (((size_t)(b * 128 + yg) * 128 + xg) * 32 + g * 8));
            *(uint4*)(&smem[SOFF + g * PSS + (t * 66 + xi) * 8]) = v;
        }
    }
    __syncthreads();

    const int rr  = wv >> 1;                // output row parity py
    const int pxl = (wv & 1) * 32 + n;

    f32x16 acc;
#pragma unroll
    for (int i = 0; i < 16; ++i) acc[i] = 0.f;

    const int cls = (yp == 0) ? 0 : ((yp == 63) ? 2 : 1);
    const unsigned short* wE = wpk8e + (size_t)(cls * 2 + rr) * 9216 + lane * 8;
    const unsigned short* wS = wpk8 + lane * 8;

#pragma unroll
    for (int s = 0; s < 9; ++s) {
        const int dr = s / 3, dxx = s % 3;
#pragma unroll
        for (int kst = 0; kst < 2; ++kst) {
            const int g = kst * 2 + q;
            bf16x8 bfrag = *(const bf16x8*)(&smem[g * PSU + (dr * 66 + pxl + dxx) * 8]);
            bf16x8 a = *(const bf16x8*)(wE + (s * 2 + kst) * 512);
            acc = __builtin_amdgcn_mfma_f32_32x32x16_bf16(a, bfrag, acc, 0, 0, 0);
        }
#pragma unroll
        for (int kst = 0; kst < 2; ++kst) {
            const int g = kst * 2 + q;
            bf16x8 bfrag = *(const bf16x8*)(&smem[SOFF + g * PSS + ((rr + dr) * 66 + pxl + dxx) * 8]);
            bf16x8 a = *(const bf16x8*)(wS + (s * 4 + kst + 2) * 512);
            acc = __builtin_amdgcn_mfma_f32_32x32x16_bf16(a, bfrag, acc, 0, 0, 0);
        }
    }

    size_t base = ((size_t)(b * 128 + 2 * yp + rr) * 128 + x0 + pxl) * 32;
#pragma unroll
    for (int rg = 0; rg < 4; ++rg) {
        int oc0 = 8 * rg + 4 * q;
        float v0 = fmaxf(acc[rg * 4 + 0] + bias[oc0 + 0], 0.f);
        float v1 = fmaxf(acc[rg * 4 + 1] + bias[oc0 + 1], 0.f);
        float v2 = fmaxf(acc[rg * 4 + 2] + bias[oc0 + 2], 0.f);
        float v3 = fmaxf(acc[rg * 4 + 3] + bias[oc0 + 3], 0.f);
        *(uint2*)(x8t + base + oc0) = make_uint2(cvtpk2(v0, v1), cvtpk2(v2, v3));
    }
}

// ---------------------------------------------------------------------------
// conv9 MFMA, y-composite, ROWS=4 / 512-thread restructure (this round):
//  - 8 waves/block: waves rr=wv>>1 own output rows 4yq+rr (parity py=rr&1,
//    low-res row lr=2yq+(rr>>1)); x half = wv&1.
//  - staging: x8 4 low-res rows (halo 2:1 vs 3:1) + x1 6 full-res rows.
//  - LDS 32KB (staging 29.7K, epilogue lout 64x256=32K) -> 4 blocks/CU
//    = 32 waves/CU vs round-8's ~12. Occupancy is the lever.
// ---------------------------------------------------------------------------
__global__ __launch_bounds__(512)
void conv9f_mfma(const unsigned short* __restrict__ x8t,
                 const unsigned short* __restrict__ x1t,
                 const unsigned short* __restrict__ wpk,     // original (kst=2 slice used)
                 const unsigned short* __restrict__ wpk9e,   // composite tables
                 const float* __restrict__ bias,
                 unsigned short* __restrict__ fm)
{
    constexpr int PS8X = 4 * 66 * 8 + 8;   // 2120 shorts per x8 plane (4 low-res rows)
    constexpr int PS1  = 6 * 66 * 8 + 8;   // 3176 shorts per x1 plane (6 rows)
    constexpr int X1OFF = 4 * PS8X;        // 8480
    __shared__ __align__(16) unsigned short smem[16384];     // 32768 B (staging 14832)

    const int tid  = threadIdx.x;
    const int lane = tid & 63;
    const int wv   = tid >> 6;              // 0..7
    const int n    = lane & 31;
    const int q    = lane >> 5;
    const int x0   = (blockIdx.x & 3) * 64;
    const int yq   = blockIdx.x >> 2;       // 0..63 (4-row output tile)
    const int b    = blockIdx.y;

    for (int i = tid; i < 1056 + 792; i += 512) {
        if (i < 1056) {
            // x8 part: 4 planes x 4 low-res rows x 66 cols, x-lerp only
            int g   = i & 3;
            int rem = i >> 2;           // 0..263
            int xi  = rem % 66;
            int t8  = rem / 66;         // 0..3  (low-res row 2yq-1+t8)
            int r   = 2 * yq - 1 + t8;
            int xg  = x0 - 1 + xi;
            uint4 v = make_uint4(0, 0, 0, 0);
            if (r >= 0 && r < 128 && xg >= 0 && xg < 256) {
                int ix0, ix1; float wx;
                up2_setup(xg, 128, ix0, ix1, wx);
                const unsigned short* S = x8t + ((size_t)(b * 128 + r) * 128) * 32 + g * 8;
                u16x8 a0 = *(const u16x8*)(S + ix0 * 32);
                u16x8 a1 = *(const u16x8*)(S + ix1 * 32);
                float w1x = 1.f - wx;
                float f[8];
#pragma unroll
                for (int j = 0; j < 8; ++j)
                    f[j] = w1x * bf2f(a0[j]) + wx * bf2f(a1[j]);
                v = make_uint4(cvtpk2(f[0], f[1]), cvtpk2(f[2], f[3]),
                               cvtpk2(f[4], f[5]), cvtpk2(f[6], f[7]));
            }
            *(uint4*)(&smem[g * PS8X + (t8 * 66 + xi) * 8]) = v;
        } else {
            // x1 part: 2 planes x 6 full-res rows x 66 cols, pure copy
            int jI  = i - 1056;
            int g   = jI & 1;
            int rem = jI >> 1;          // 0..395
            int xi  = rem % 66;
            int t   = rem / 66;         // 0..5
            int yg  = 4 * yq + t - 1;
            int xg  = x0 - 1 + xi;
            uint4 v = make_uint4(0, 0, 0, 0);
            if (yg >= 0 && yg < 256 && xg >= 0 && xg < 256)
                v = *(const uint4*)(x1t + (((size_t)(b * 256 + yg) * 256 + xg) * 16 + g * 8));
            *(uint4*)(&smem[X1OFF + g * PS1 + (t * 66 + xi) * 8]) = v;
        }
    }
    __syncthreads();

    const int rr  = wv >> 1;                 // output row 0..3 within tile
    const int py  = rr & 1;                  // parity
    const int lrh = rr >> 1;                 // low-res sub-row 0..1
    const int lr  = 2 * yq + lrh;            // absolute low-res row
    const int pxl = (wv & 1) * 32 + n;

    f32x16 acc0, acc1;
#pragma unroll
    for (int i = 0; i < 16; ++i) { acc0[i] = 0.f; acc1[i] = 0.f; }

    const int cls = (lr == 0) ? 0 : ((lr == 127) ? 2 : 1);
    const unsigned short* wE  = wpk9e + (size_t)(cls * 2 + py) * 18432 + lane * 8;
    const unsigned short* w2b = wpk + lane * 8;

#pragma unroll
    for (int s = 0; s < 9; ++s) {
        const int dr = s / 3, dxx = s % 3;
        // x8 part: kst 0,1 — B rows are low-res rows lrh+dr (0..3)
#pragma unroll
        for (int kst = 0; kst < 2; ++kst) {
            const int g = kst * 2 + q;
            bf16x8 bfrag = *(const bf16x8*)(&smem[g * PS8X + ((lrh + dr) * 66 + pxl + dxx) * 8]);
            bf16x8 a0 = *(const bf16x8*)(wE + ((s * 2 + kst) * 2 + 0) * 512);
            bf16x8 a1 = *(const bf16x8*)(wE + ((s * 2 + kst) * 2 + 1) * 512);
            acc0 = __builtin_amdgcn_mfma_f32_32x32x16_bf16(a0, bfrag, acc0, 0, 0, 0);
            acc1 = __builtin_amdgcn_mfma_f32_32x32x16_bf16(a1, bfrag, acc1, 0, 0, 0);
        }
        // x1 part: kst=2 — full-res rows rr+dr (0..5), original weights
        {
            bf16x8 bfrag = *(const bf16x8*)(&smem[X1OFF + q * PS1 + ((rr + dr) * 66 + pxl + dxx) * 8]);
            bf16x8 a0 = *(const bf16x8*)(w2b + ((s * 3 + 2) * 2 + 0) * 512);
            bf16x8 a1 = *(const bf16x8*)(w2b + ((s * 3 + 2) * 2 + 1) * 512);
            acc0 = __builtin_amdgcn_mfma_f32_32x32x16_bf16(a0, bfrag, acc0, 0, 0, 0);
            acc1 = __builtin_amdgcn_mfma_f32_32x32x16_bf16(a1, bfrag, acc1, 0, 0, 0);
        }
    }

    // --- epilogue: LDS transpose -> vectorized NCHW stores ---
    __syncthreads();                       // staging buffer is now dead
    unsigned short* lout = smem;           // [64 oc][256 = 4 rows x 64 px]
    const int col = rr * 64 + pxl;
#pragma unroll
    for (int reg = 0; reg < 16; reg += 2) {
        const int rb = (reg & 3) + 8 * (reg >> 2);        // pairs -> rows rb, rb+1
        float a0 = fast_tanh(acc0[reg]     + bias[rb + 4 * q]);
        float a1 = fast_tanh(acc0[reg + 1] + bias[rb + 1 + 4 * q]);
        unsigned p0 = cvtpk2(a0, a1);
        lout[(rb + 4 * q) * 256 + col]     = (unsigned short)p0;
        lout[(rb + 1 + 4 * q) * 256 + col] = (unsigned short)(p0 >> 16);
        float b0 = fast_tanh(acc1[reg]     + bias[rb + 4 * q + 32]);
        float b1 = fast_tanh(acc1[reg + 1] + bias[rb + 1 + 4 * q + 32]);
        unsigned p1 = cvtpk2(b0, b1);
        lout[(rb + 4 * q + 32) * 256 + col] = (unsigned short)p1;
        lout[(rb + 4 * q + 33) * 256 + col] = (unsigned short)(p1 >> 16);
    }
    __syncthreads();

    const size_t fmb = (size_t)b * 64 * 65536 + (size_t)(4 * yq) * 256 + x0;
    for (int i = tid; i < 2048; i += 512) {
        int oc = i >> 5;               // 0..63
        int c8 = (i & 31) * 8;         // 0..248
        int rl = c8 >> 6;              // local row 0..3
        int pl = c8 & 63;              // x within strip
        uint4 v = *(const uint4*)(lout + oc * 256 + c8);
        *(uint4*)(fm + fmb + (size_t)oc * 65536 + rl * 256 + pl) = v;
    }
}

// ---------------------------------------------------------------------------
// Segmented W-direction LRNN pair -> rnnW NCHW bf16 (round-8 bf16 LDS).
// ---------------------------------------------------------------------------
__global__ __launch_bounds__(256)
void lrnn_w_seg(const unsigned short* __restrict__ X, const unsigned short* __restrict__ FM,
                unsigned short* __restrict__ rnnW)
{
    __shared__ __align__(16) unsigned short tx[3][16][312];
    __shared__ __align__(16) unsigned short outm[2][16][256];
    __shared__ float segres[2][16][8][4];
    __shared__ float hin[2][16][8][2];

    const int tid = threadIdx.x;
    const int bid = blockIdx.x;
    const int yt = bid & 15;
    const int c  = (bid >> 4) & 15;
    const int b  = bid >> 8;
    const int y0 = yt * 16;

    const size_t xb  = ((size_t)(b * 16 + c) * 256 + y0) * 256;
    const size_t p1b = ((size_t)(b * 64 + c) * 256 + y0) * 256;
    const size_t p2b = ((size_t)(b * 64 + 32 + c) * 256 + y0) * 256;

    for (int i = tid; i < 1536; i += 256) {
        int s = i >> 9;
        int r = i & 511;
        int y = r >> 5;
        int g = r & 31;
        const unsigned short* sp = (s == 0) ? (X + xb) : (s == 1 ? FM + p1b : FM + p2b);
        uint4 v = *(const uint4*)(sp + (size_t)y * 256 + g * 8);
        *(uint4*)(&tx[s][y][8 * g + 8 * (g >> 2)]) = v;   // padded col of x=8g
    }
    __syncthreads();

    const int y  = tid & 15;
    const int sg = (tid >> 4) & 7;
    const int d  = tid >> 7;

    {   // pass 1
        float h1 = 0.f, h2 = 0.f, A1 = 1.f, A2 = 1.f;
        if (d == 0) {
            const int base = 40 * sg;
#pragma unroll
            for (int k = 0; k < 4; ++k) {
                u16x8 xv8 = *(const u16x8*)&tx[0][y][base + 8 * k];
                u16x8 p18 = *(const u16x8*)&tx[1][y][base + 8 * k];
                u16x8 p28 = *(const u16x8*)&tx[2][y][base + 8 * k];
#pragma unroll
                for (int j = 0; j < 8; ++j) {
                    float xv = bf2f(xv8[j]), p1 = bf2f(p18[j]), p2 = bf2f(p28[j]);
                    h1 = fmaf(p1, h1 - xv, xv); A1 *= p1;
                    h2 = fmaf(p2, h2 - xv, xv); A2 *= p2;
                }
            }
        } else {
            const int m = 7 - sg;
#pragma unroll
            for (int k = 0; k < 4; ++k) {
                const int base = 40 * m + 24 - 8 * k;
                u16x8 xv8 = *(const u16x8*)&tx[0][y][base];
                u16x8 p18 = *(const u16x8*)&tx[1][y][base];
                u16x8 p28 = *(const u16x8*)&tx[2][y][base];
#pragma unroll
                for (int j = 7; j >= 0; --j) {
                    float xv = bf2f(xv8[j]), p1 = bf2f(p18[j]), p2 = bf2f(p28[j]);
                    h1 = fmaf(p1, h1 - xv, xv); A1 *= p1;
                    h2 = fmaf(p2, h2 - xv, xv); A2 *= p2;
                }
            }
        }
        segres[d][y][sg][0] = h1; segres[d][y][sg][1] = A1;
        segres[d][y][sg][2] = h2; segres[d][y][sg][3] = A2;
    }
    __syncthreads();

    if (tid < 32) {
        int yy = tid & 15, dd = tid >> 4;
        float c1 = 0.f, c2 = 0.f;
        for (int s = 0; s < 8; ++s) {
            hin[dd][yy][s][0] = c1;
            hin[dd][yy][s][1] = c2;
            c1 = segres[dd][yy][s][0] + segres[dd][yy][s][1] * c1;
            c2 = segres[dd][yy][s][2] + segres[dd][yy][s][3] * c2;
        }
    }
    __syncthreads();

    {   // pass 2: vector reads + 8-wide buffered vector outm writes
        float h1 = hin[d][y][sg][0], h2 = hin[d][y][sg][1];
        if (d == 0) {
            const int base = 40 * sg;
            const int xs = 32 * sg;
#pragma unroll
            for (int k = 0; k < 4; ++k) {
                u16x8 xv8 = *(const u16x8*)&tx[0][y][base + 8 * k];
                u16x8 p18 = *(const u16x8*)&tx[1][y][base + 8 * k];
                u16x8 p28 = *(const u16x8*)&tx[2][y][base + 8 * k];
                float mres[8];
#pragma unroll
                for (int j = 0; j < 8; ++j) {
                    float xv = bf2f(xv8[j]), p1 = bf2f(p18[j]), p2 = bf2f(p28[j]);
                    h1 = fmaf(p1, h1 - xv, xv);
                    h2 = fmaf(p2, h2 - xv, xv);
                    mres[j] = fmaxf(h1, h2);
                }
                *(uint4*)&outm[0][y][xs + 8 * k] =
                    make_uint4(cvtpk2(mres[0], mres[1]), cvtpk2(mres[2], mres[3]),
                               cvtpk2(mres[4], mres[5]), cvtpk2(mres[6], mres[7]));
            }
        } else {
            const int m = 7 - sg;
            const int ts = 32 * sg;
#pragma unroll
            for (int k = 0; k < 4; ++k) {
                const int base = 40 * m + 24 - 8 * k;
                u16x8 xv8 = *(const u16x8*)&tx[0][y][base];
                u16x8 p18 = *(const u16x8*)&tx[1][y][base];
                u16x8 p28 = *(const u16x8*)&tx[2][y][base];
                float mres[8];
#pragma unroll
                for (int j = 7; j >= 0; --j) {
                    float xv = bf2f(xv8[j]), p1 = bf2f(p18[j]), p2 = bf2f(p28[j]);
                    h1 = fmaf(p1, h1 - xv, xv);
                    h2 = fmaf(p2, h2 - xv, xv);
                    mres[7 - j] = fmaxf(h1, h2);
                }
                *(uint4*)&outm[1][y][ts + 8 * k] =
                    make_uint4(cvtpk2(mres[0], mres[1]), cvtpk2(mres[2], mres[3]),
                               cvtpk2(mres[4], mres[5]), cvtpk2(mres[6], mres[7]));
            }
        }
    }
    __syncthreads();

    // final: thread tid owns x=tid, rows 0..15 (paired conversions)
    {
        const int x = tid;
#pragma unroll
        for (int yy = 0; yy < 16; yy += 2) {
            float m0 = fmaxf(bf2f(outm[0][yy][x]),     bf2f(outm[1][yy][x]));
            float m1 = fmaxf(bf2f(outm[0][yy + 1][x]), bf2f(outm[1][yy + 1][x]));
            unsigned p = cvtpk2(m0, m1);
            rnnW[xb + (size_t)yy * 256 + x]       = (unsigned short)p;
            rnnW[xb + (size_t)(yy + 1) * 256 + x] = (unsigned short)(p >> 16);
        }
    }
}

// ---------------------------------------------------------------------------
// Segmented H-direction LRNN pair; fuses max(rnnW, rnnH) -> rnnM.
// (round-8 transposed bf16 LDS)
// ---------------------------------------------------------------------------
__global__ __launch_bounds__(256)
void lrnn_h_seg(const unsigned short* __restrict__ X, const unsigned short* __restrict__ FM,
                const unsigned short* __restrict__ rnnW, unsigned short* __restrict__ rnnM)
{
    __shared__ __align__(16) unsigned short tx[3][16][312];
    __shared__ __align__(16) unsigned short outm[2][16][264];
    __shared__ float segres[2][16][8][4];
    __shared__ float hin[2][16][8][2];

    const int tid = threadIdx.x;
    const int bid = blockIdx.x;
    const int xt = bid & 15;
    const int c  = (bid >> 4) & 15;
    const int b  = bid >> 8;
    const int x0 = xt * 16;

    const size_t xb  = (size_t)(b * 16 + c) * 65536 + x0;
    const size_t p1b = (size_t)(b * 64 + 16 + c) * 65536 + x0;
    const size_t p2b = (size_t)(b * 64 + 48 + c) * 65536 + x0;

    for (int i = tid; i < 1536; i += 256) {
        int s = i >> 9;
        int r = i & 511;
        int y = r >> 1;
        int g = r & 1;
        const unsigned short* sp = (s == 0) ? (X + xb) : (s == 1 ? FM + p1b : FM + p2b);
        u16x8 v = *(const u16x8*)(sp + (size_t)y * 256 + g * 8);
        int pc = y + 8 * (y >> 5);        // padded col for y
#pragma unroll
        for (int j = 0; j < 8; ++j) tx[s][g * 8 + j][pc] = v[j];
    }
    __syncthreads();

    const int x  = tid & 15;
    const int sg = (tid >> 4) & 7;
    const int d  = tid >> 7;

    {   // pass 1
        float h1 = 0.f, h2 = 0.f, A1 = 1.f, A2 = 1.f;
        if (d == 0) {
            const int base = 40 * sg;
#pragma unroll
            for (int k = 0; k < 4; ++k) {
                u16x8 xv8 = *(const u16x8*)&tx[0][x][base + 8 * k];
                u16x8 p18 = *(const u16x8*)&tx[1][x][base + 8 * k];
                u16x8 p28 = *(const u16x8*)&tx[2][x][base + 8 * k];
#pragma unroll
                for (int j = 0; j < 8; ++j) {
                    float xv = bf2f(xv8[j]), p1 = bf2f(p18[j]), p2 = bf2f(p28[j]);
                    h1 = fmaf(p1, h1 - xv, xv); A1 *= p1;
                    h2 = fmaf(p2, h2 - xv, xv); A2 *= p2;
                }
            }
        } else {
            const int m = 7 - sg;
#pragma unroll
            for (int k = 0; k < 4; ++k) {
                const int base = 40 * m + 24 - 8 * k;
                u16x8 xv8 = *(const u16x8*)&tx[0][x][base];
                u16x8 p18 = *(const u16x8*)&tx[1][x][base];
                u16x8 p28 = *(const u16x8*)&tx[2][x][base];
#pragma unroll
                for (int j = 7; j >= 0; --j) {
                    float xv = bf2f(xv8[j]), p1 = bf2f(p18[j]), p2 = bf2f(p28[j]);
                    h1 = fmaf(p1, h1 - xv, xv); A1 *= p1;
                    h2 = fmaf(p2, h2 - xv, xv); A2 *= p2;
                }
            }
        }
        segres[d][x][sg][0] = h1; segres[d][x][sg][1] = A1;
        segres[d][x][sg][2] = h2; segres[d][x][sg][3] = A2;
    }
    __syncthreads();

    if (tid < 32) {
        int xx = tid & 15, dd = tid >> 4;
        float c1 = 0.f, c2 = 0.f;
        for (int s = 0; s < 8; ++s) {
            hin[dd][xx][s][0] = c1;
            hin[dd][xx][s][1] = c2;
            c1 = segres[dd][xx][s][0] + segres[dd][xx][s][1] * c1;
            c2 = segres[dd][xx][s][2] + segres[dd][xx][s][3] * c2;
        }
    }
    __syncthreads();

    {   // pass 2: vector reads + 8-wide buffered vector outm writes
        float h1 = hin[d][x][sg][0], h2 = hin[d][x][sg][1];
        if (d == 0) {
            const int base = 40 * sg;
            const int ys = 32 * sg;
#pragma unroll
            for (int k = 0; k < 4; ++k) {
                u16x8 xv8 = *(const u16x8*)&tx[0][x][base + 8 * k];
                u16x8 p18 = *(const u16x8*)&tx[1][x][base + 8 * k];
                u16x8 p28 = *(const u16x8*)&tx[2][x][base + 8 * k];
                float mres[8];
#pragma unroll
                for (int j = 0; j < 8; ++j) {
                    float xv = bf2f(xv8[j]), p1 = bf2f(p18[j]), p2 = bf2f(p28[j]);
                    h1 = fmaf(p1, h1 - xv, xv);
                    h2 = fmaf(p2, h2 - xv, xv);
                    mres[j] = fmaxf(h1, h2);
                }
                *(uint4*)&outm[0][x][ys + 8 * k] =
                    make_uint4(cvtpk2(mres[0], mres[1]), cvtpk2(mres[2], mres[3]),
                               cvtpk2(mres[4], mres[5]), cvtpk2(mres[6], mres[7]));
            }
        } else {
            const int m = 7 - sg;
            const int ts = 32 * sg;
#pragma unroll
            for (int k = 0; k < 4; ++k) {
                const int base = 40 * m + 24 - 8 * k;
                u16x8 xv8 = *(const u16x8*)&tx[0][x][base];
                u16x8 p18 = *(const u16x8*)&tx[1][x][base];
                u16x8 p28 = *(const u16x8*)&tx[2][x][base];
                float mres[8];
#pragma unroll
                for (int j = 7; j >= 0; --j) {
                    float xv = bf2f(xv8[j]), p1 = bf2f(p18[j]), p2 = bf2f(p28[j]);
                    h1 = fmaf(p1, h1 - xv, xv);
                    h2 = fmaf(p2, h2 - xv, xv);
                    mres[7 - j] = fmaxf(h1, h2);
                }
                *(uint4*)&outm[1][x][ts + 8 * k] =
                    make_uint4(cvtpk2(mres[0], mres[1]), cvtpk2(mres[2], mres[3]),
                               cvtpk2(mres[4], mres[5]), cvtpk2(mres[6], mres[7]));
            }
        }
    }
    __syncthreads();

    // final: thread handles xx = tid&15, yy = (tid>>4) + 16k (paired k)
    {
        const int xx = tid & 15;
        const int yy0 = tid >> 4;
#pragma unroll
        for (int k = 0; k < 16; k += 2) {
            int ya = yy0 + 16 * k, yb = yy0 + 16 * (k + 1);
            size_t offA = xb + (size_t)ya * 256 + xx;
            size_t offB = xb + (size_t)yb * 256 + xx;
            float ma = fmaxf(fmaxf(bf2f(outm[0][xx][ya]), bf2f(outm[1][xx][ya])),
                             bf2f(rnnW[offA]));
            float mb = fmaxf(fmaxf(bf2f(outm[0][xx][yb]), bf2f(outm[1][xx][yb])),
                             bf2f(rnnW[offB]));
            unsigned p = cvtpk2(ma, mb);
            rnnM[offA] = (unsigned short)p;
            rnnM[offB] = (unsigned short)(p >> 16);
        }
    }
}

// ---------------------------------------------------------------------------
// Output head MFMA: rnnM -> 3x3 conv (Cin16, Cout3), sigmoid -> fp32 out.
// 4 output rows x 128 px per block; xi-fastest coalesced staging.
// ---------------------------------------------------------------------------
__global__ __launch_bounds__(256)
void convo_mfma(const unsigned short* __restrict__ rnnM,
                const unsigned short* __restrict__ wpko,
                const float* __restrict__ bo,
                float* __restrict__ outp)
{
    constexpr int PSo = 6 * 130 * 8 + 8;   // 6248 shorts per channel-group plane
    __shared__ __align__(16) unsigned short smem[2 * PSo];   // 24992 B

    const int tid  = threadIdx.x;
    const int lane = tid & 63;
    const int wv   = tid >> 6;
    const int n    = lane & 31;
    const int q    = lane >> 5;
    const int x0   = (blockIdx.x & 1) * 128;
    const int yq   = blockIdx.x >> 1;       // 0..63
    const int b    = blockIdx.y;

    for (int i = tid; i < 6 * 16 * 130; i += 256) {
        int xi = i % 130;          // fastest: consecutive lanes -> consecutive x
        int t  = i / 130;          // 0..95
        int ch = t & 15;
        int r  = t >> 4;           // 0..5
        int yg = 4 * yq + r - 1;
        int xg = x0 - 1 + xi;
        unsigned short m = 0;
        if (yg >= 0 && yg < 256 && xg >= 0 && xg < 256)
            m = rnnM[(size_t)(b * 16 + ch) * 65536 + (size_t)yg * 256 + xg];
        int g = ch >> 3, j = ch & 7;
        smem[g * PSo + (r * 130 + xi) * 8 + j] = m;
    }
    __syncthreads();

    const unsigned short* wbase = wpko + lane * 8;
    const int y = 4 * yq + wv;              // wave wv owns one output row

#pragma unroll
    for (int xt = 0; xt < 4; ++xt) {
        const int pxl = xt * 32 + n;
        f32x16 acc;
#pragma unroll
        for (int i = 0; i < 16; ++i) acc[i] = 0.f;
#pragma unroll
        for (int s = 0; s < 9; ++s) {
            const int dy = s / 3, dx = s % 3;
            bf16x8 bfrag = *(const bf16x8*)(&smem[q * PSo + ((wv + dy) * 130 + pxl + dx) * 8]);
            bf16x8 a = *(const bf16x8*)(wbase + s * 512);
            acc = __builtin_amdgcn_mfma_f32_32x32x16_bf16(a, bfrag, acc, 0, 0, 0);
        }
        if (q == 0) {
            const int px = x0 + pxl;
#pragma unroll
            for (int oc = 0; oc < 3; ++oc) {
                float r2 = acc[oc] + bo[oc];
                outp[((size_t)(b * 3 + oc) * 256 + y) * 256 + px] = 1.f / (1.f + __expf(-r2));
            }
        }
    }
}

// ---------------------------------------------------------------------------
extern "C" void kernel_launch(void* const* d_in, const int* in_sizes, int n_in,
                              void* d_out, int out_size, void* d_ws, size_t ws_size,
                              hipStream_t stream)
{
    const float* img = (const float*)d_in[0];
    const float* w1 = (const float*)d_in[1];  const float* b1 = (const float*)d_in[2];
    const float* w2 = (const float*)d_in[3];  const float* b2 = (const float*)d_in[4];
    const float* w3 = (const float*)d_in[5];  const float* b3 = (const float*)d_in[6];
    const float* w4 = (const float*)d_in[7];  const float* b4 = (const float*)d_in[8];
    const float* w5 = (const float*)d_in[9];  const float* b5 = (const float*)d_in[10];
    const float* w6 = (const float*)d_in[11]; const float* b6 = (const float*)d_in[12];
    const float* w7 = (const float*)d_in[13]; const float* b7 = (const float*)d_in[14];
    const float* w8 = (const float*)d_in[15]; const float* b8 = (const float*)d_in[16];
    const float* w9 = (const float*)d_in[17]; const float* b9 = (const float*)d_in[18];
    const float* wi = (const float*)d_in[19]; const float* bi = (const float*)d_in[20];
    const float* wo = (const float*)d_in[21]; const float* bo = (const float*)d_in[22];

    char* wsb = (char*)d_ws;
    const size_t MB = (size_t)(1u << 20);
    unsigned short* imgT  = (unsigned short*)(wsb);             // [0,16) dead after conv1i
    unsigned short* x1t   = (unsigned short*)(wsb + 16 * MB);   // [16,32) till conv9f
    unsigned short* x2t   = (unsigned short*)(wsb + 32 * MB);   // [32,40) till conv8
    unsigned short* x3t   = (unsigned short*)(wsb + 40 * MB);   // [40,42) till conv7
    unsigned short* x4t   = (unsigned short*)(wsb + 42 * MB);   // [42,42.5) till conv6
    unsigned short* x5t   = (unsigned short*)(wsb + 43 * MB);   // [43,43.25)
    unsigned short* x6t   = (unsigned short*)(wsb + 46 * MB);   // [46,46.5)
    unsigned short* x7t   = (unsigned short*)(wsb + 51 * MB);   // [51,53) till conv8
    unsigned short* x8t   = (unsigned short*)(wsb + 70 * MB);   // [70,78) till conv9f
    unsigned short* fm16  = (unsigned short*)(wsb + 112 * MB);  // [112,176) NCHW bf16
    unsigned short* xin16 = (unsigned short*)(wsb + 176 * MB);  // [176,192) NCHW bf16
    unsigned short* rnnW  = (unsigned short*)(wsb);             // [0,16)  (imgT dead)
    unsigned short* rnnM  = (unsigned short*)(wsb + 16 * MB);   // [16,32) (x1t dead)
    unsigned short* wpk9 = (unsigned short*)(wsb + 192 * MB);
    unsigned short* wpk8 = wpk9 + 27648;
    unsigned short* wpk1 = wpk8 + 18432;
    unsigned short* wpki = wpk1 + 12800;
    unsigned short* wpko = wpki + 4608;
    unsigned short* wpk2 = wpko + 4608;
    unsigned short* wpk3 = wpk2 + 4608;
    unsigned short* wpk4 = wpk3 + 9216;
    unsigned short* wpk5 = wpk4 + 9216;
    unsigned short* wpk6 = wpk5 + 18432;
    unsigned short* wpk7 = wpk6 + 27648;
    unsigned short* wpk9e = wpk7 + 18432;    // 110592 shorts (conv9 composite)
    unsigned short* wpk8e = wpk9e + 110592;  // 55296 shorts (conv8 composite)
    float* outp = (float*)d_out;

    // --- single weight-pack dispatch + img transpose ---
    wprep_mega<<<1256, 256, 0, stream>>>(w9, w8, w1, wi, wo, w2, w3, w4, w5, w6, w7,
                                         wpk9, wpk8, wpk1, wpki, wpko,
                                         wpk2, wpk3, wpk4, wpk5, wpk6, wpk7,
                                         wpk9e, wpk8e);
    imgT_bf16<<<2048, 256, 0, stream>>>(img, imgT);

    // --- fused conv1 (relu -> x1t NHWC) + input projection (xin16 NCHW bf16) ---
    { dim3 grd(512, 8);
      conv1i_mfma<<<grd, 256, 0, stream>>>(imgT, wpk1, wpki, b1, bi, x1t, xin16); }

    // --- encoder: pools fused into conv staging ---
    convN_mfma<16, 32, 128, 128, 1, 1><<<dim3(128, 8), 256, 0, stream>>>(x1t, wpk2, b2, x2t);
    convN_mfma<32, 32, 64, 64, 2, 1><<<dim3(32, 8), 256, 0, stream>>>(x2t, wpk3, b3, x3t);
    convN_mfma<32, 32, 32, 32, 4, 1><<<dim3(8, 8), 256, 0, stream>>>(x3t, wpk4, b4, x4t);
    convN_mfma<32, 64, 16, 16, 8, 1><<<dim3(2, 8), 256, 0, stream>>>(x4t, wpk5, b5, x5t);

    // --- decoder: upcat fused into conv6/conv7/conv8 staging ---
    convU_mfma<64, 32, 32, 32, 32, 4><<<dim3(8, 8), 256, 0, stream>>>(x5t, x4t, wpk6, b6, x6t);
    convU_mfma<32, 32, 32, 64, 64, 2><<<dim3(32, 8), 256, 0, stream>>>(x6t, x3t, wpk7, b7, x7t);
    { dim3 grd(128, 8);
      conv8_mfma<<<grd, 256, 0, stream>>>(x7t, x2t, wpk8, wpk8e, b8, x8t); }

    // --- stage 9: y-composite ROWS=4 conv9 (256 blocks x 512 threads) ---
    { dim3 grd(256, 8);
      conv9f_mfma<<<grd, 512, 0, stream>>>(x8t, x1t, wpk9, wpk9e, b9, fm16); }

    // --- spatial RNN: segmented scans; lrnn_h fuses max(rnnW, rnnH) -> rnnM ---
    lrnn_w_seg<<<2048, 256, 0, stream>>>(xin16, fm16, rnnW);
    lrnn_h_seg<<<2048, 256, 0, stream>>>(xin16, fm16, rnnW, rnnM);

    // --- output head: 4-row blocks, single input tensor ---
    { dim3 grd(128, 8);
      convo_mfma<<<grd, 256, 0, stream>>>(rnnM, wpko, bo, outp); }
}

// Round 10
// 353.899 us; speedup vs baseline: 1.1692x; 1.0062x over previous
//
#include <hip/hip_runtime.h>
#include <math.h>

typedef __attribute__((ext_vector_type(8)))  short bf16x8;
typedef __attribute__((ext_vector_type(8)))  unsigned short u16x8;
typedef __attribute__((ext_vector_type(16))) float f32x16;

__device__ __forceinline__ unsigned short f2bf(float f) {
    unsigned u = __float_as_uint(f);
    unsigned r = (u + 0x7FFFu + ((u >> 16) & 1u)) >> 16;
    return (unsigned short)r;
}
__device__ __forceinline__ float bf2f(unsigned short h) {
    return __uint_as_float(((unsigned)h) << 16);
}
__device__ __forceinline__ unsigned pack2(unsigned short a, unsigned short b) {
    return (unsigned)a | ((unsigned)b << 16);
}
// HW packed f32->bf16 RNE: 1 VALU op converts 2 values (== manual f2bf RNE).
__device__ __forceinline__ unsigned cvtpk2(float a, float b) {
    unsigned r;
    asm("v_cvt_pk_bf16_f32 %0, %1, %2" : "=v"(r) : "v"(a), "v"(b));
    return r;
}
__device__ __forceinline__ float fast_tanh(float x) {
    float e = __expf(2.f * x);
    return 1.f - 2.f / (e + 1.f);
}

__device__ __forceinline__ void bilin_setup(int y, int x, int Hi, int Wi,
                                            int& i00, int& i01, int& i10, int& i11,
                                            float& wy, float& wx)
{
    float fy = 0.5f * y - 0.25f;
    float fx = 0.5f * x - 0.25f;
    float y0f = floorf(fy), x0f = floorf(fx);
    wy = fy - y0f; wx = fx - x0f;
    int yA = (int)y0f, xA = (int)x0f;
    int yB = yA + 1, xB = xA + 1;
    yA = yA < 0 ? 0 : (yA > Hi - 1 ? Hi - 1 : yA);
    yB = yB < 0 ? 0 : (yB > Hi - 1 ? Hi - 1 : yB);
    xA = xA < 0 ? 0 : (xA > Wi - 1 ? Wi - 1 : xA);
    xB = xB < 0 ? 0 : (xB > Wi - 1 ? Wi - 1 : xB);
    i00 = yA * Wi + xA; i01 = yA * Wi + xB;
    i10 = yB * Wi + xA; i11 = yB * Wi + xB;
}

// 2x upsample w/ half-pixel centers: fixed parity weights, no floorf needed.
__device__ __forceinline__ void up2_setup(int v, int Hi, int& i0, int& i1, float& w)
{
    int a = (v - 1) >> 1;           // arithmetic shift: v=0 -> -1
    i0 = a < 0 ? 0 : a;
    int b = a + 1;
    i1 = b > Hi - 1 ? Hi - 1 : b;
    w = (v & 1) ? 0.25f : 0.75f;
}

__device__ __forceinline__ uint4 bilin8u(const unsigned short* __restrict__ sb,
                                         int i00, int i01, int i10, int i11,
                                         float wy, float wx, int stride)
{
    u16x8 v00 = *(const u16x8*)(sb + (size_t)i00 * stride);
    u16x8 v01 = *(const u16x8*)(sb + (size_t)i01 * stride);
    u16x8 v10 = *(const u16x8*)(sb + (size_t)i10 * stride);
    u16x8 v11 = *(const u16x8*)(sb + (size_t)i11 * stride);
    float w00 = (1.f - wy) * (1.f - wx), w01 = (1.f - wy) * wx;
    float w10 = wy * (1.f - wx),         w11 = wy * wx;
    float f[8];
#pragma unroll
    for (int j = 0; j < 8; ++j)
        f[j] = w00 * bf2f(v00[j]) + w01 * bf2f(v01[j]) +
               w10 * bf2f(v10[j]) + w11 * bf2f(v11[j]);
    return make_uint4(cvtpk2(f[0], f[1]), cvtpk2(f[2], f[3]),
                      cvtpk2(f[4], f[5]), cvtpk2(f[6], f[7]));
}

// y-interp composite coefficients: ALPH[cls][py][dy][dr]
__device__ const float ALPH[3][2][3][3] = {
    { { {0.f,0.f,0.f},      {0.f,1.f,0.f},       {0.f,0.75f,0.25f} },
      { {0.f,1.f,0.f},      {0.f,0.75f,0.25f},   {0.f,0.25f,0.75f} } },
    { { {0.75f,0.25f,0.f},  {0.25f,0.75f,0.f},   {0.f,0.75f,0.25f} },
      { {0.25f,0.75f,0.f},  {0.f,0.75f,0.25f},   {0.f,0.25f,0.75f} } },
    { { {0.75f,0.25f,0.f},  {0.25f,0.75f,0.f},   {0.f,1.f,0.f} },
      { {0.25f,0.75f,0.f},  {0.f,1.f,0.f},       {0.f,0.f,0.f} } }
};

// ---------------------------------------------------------------------------
// Mega weight-pack: all packs in one dispatch (incl. y-composite tables).
// ---------------------------------------------------------------------------
__device__ __forceinline__ void pack33(const float* __restrict__ w,
                                       unsigned short* __restrict__ dst,
                                       int i, int Cin, int Cout)
{
    int KST = Cin >> 4, MT = Cout >> 5;
    int j = i & 7;
    int lane = (i >> 3) & 63;
    int t = i >> 9;
    int mt = t % MT; t /= MT;
    int kst = t % KST;
    int s = t / KST;
    int oc = mt * 32 + (lane & 31);
    int ci = kst * 16 + (lane >> 5) * 8 + j;
    dst[i] = f2bf(w[(oc * Cin + ci) * 9 + s]);
}

__global__ void wprep_mega(const float* __restrict__ w9, const float* __restrict__ w8,
                           const float* __restrict__ w1, const float* __restrict__ wi,
                           const float* __restrict__ wo, const float* __restrict__ w2,
                           const float* __restrict__ w3, const float* __restrict__ w4,
                           const float* __restrict__ w5, const float* __restrict__ w6,
                           const float* __restrict__ w7,
                           unsigned short* __restrict__ wpk9, unsigned short* __restrict__ wpk8,
                           unsigned short* __restrict__ wpk1, unsigned short* __restrict__ wpki,
                           unsigned short* __restrict__ wpko, unsigned short* __restrict__ wpk2,
                           unsigned short* __restrict__ wpk3, unsigned short* __restrict__ wpk4,
                           unsigned short* __restrict__ wpk5, unsigned short* __restrict__ wpk6,
                           unsigned short* __restrict__ wpk7, unsigned short* __restrict__ wpk9e,
                           unsigned short* __restrict__ wpk8e)
{
    int idx = blockIdx.x * 256 + threadIdx.x;
    if (idx < 27648)       pack33(w9, wpk9, idx, 48, 64);
    else if (idx < 46080)  pack33(w8, wpk8, idx - 27648, 64, 32);
    else if (idx < 58880) {
        int i = idx - 46080;
        int j = i & 7;
        int lane = (i >> 3) & 63;
        int s = i >> 9;                 // 0..24
        int oc = lane & 31;
        int ci = (lane >> 5) * 8 + j;   // 0..15
        float v = 0.f;
        if (oc < 16 && ci < 15) v = w1[((oc * 15 + ci) * 5 + s / 5) * 5 + s % 5];
        wpk1[i] = f2bf(v);
    } else if (idx < 63488) {
        int i = idx - 58880;
        int j = i & 7;
        int lane = (i >> 3) & 63;
        int s = i >> 9;                 // 0..8
        int oc = lane & 31;
        int ci = (lane >> 5) * 8 + j;
        float v = 0.f;
        if (oc < 16 && ci < 15) v = wi[((oc * 15 + ci) * 3 + s / 3) * 3 + s % 3];
        wpki[i] = f2bf(v);
    } else if (idx < 68096) {
        int i = idx - 63488;
        int j = i & 7;
        int lane = (i >> 3) & 63;
        int s = i >> 9;
        int oc = lane & 31;
        int ci = (lane >> 5) * 8 + j;
        float v = 0.f;
        if (oc < 3) v = wo[((oc * 16 + ci) * 3 + s / 3) * 3 + s % 3];
        wpko[i] = f2bf(v);
    }
    else if (idx < 72704)  pack33(w2, wpk2, idx - 68096, 16, 32);
    else if (idx < 81920)  pack33(w3, wpk3, idx - 72704, 32, 32);
    else if (idx < 91136)  pack33(w4, wpk4, idx - 81920, 32, 32);
    else if (idx < 109568) pack33(w5, wpk5, idx - 91136, 32, 64);
    else if (idx < 137216) pack33(w6, wpk6, idx - 109568, 96, 32);
    else if (idx < 155648) pack33(w7, wpk7, idx - 137216, 64, 32);
    else if (idx < 266240) {
        // conv9 y-composite tables: [cls][py][s=dr*3+dx][kst][half] x 512
        int i = idx - 155648;
        int j = i & 7;
        int lane = (i >> 3) & 63;
        int t = i >> 9;                 // 0..215
        int half = t & 1; t >>= 1;
        int kst  = t & 1; t >>= 1;
        int s    = t % 9; t /= 9;
        int py   = t & 1;
        int cls  = t >> 1;              // 0..2
        int dr = s / 3, dx = s % 3;
        int oc = half * 32 + (lane & 31);
        int ci = kst * 16 + (lane >> 5) * 8 + j;   // x8 channels 0..31
        float v = 0.f;
#pragma unroll
        for (int dy = 0; dy < 3; ++dy)
            v += ALPH[cls][py][dy][dr] * w9[((oc * 48 + ci) * 3 + dy) * 3 + dx];
        wpk9e[i] = f2bf(v);
    }
    else if (idx < 321536) {
        // conv8 y-composite tables (up channels 0..31): [cls][py][s][kst] x 512
        int i = idx - 266240;
        int j = i & 7;
        int lane = (i >> 3) & 63;
        int t = i >> 9;                 // 0..107
        int kst = t & 1; t >>= 1;
        int s   = t % 9; t /= 9;
        int py  = t & 1;
        int cls = t >> 1;               // 0..2
        int dr = s / 3, dx = s % 3;
        int oc = lane & 31;
        int ci = kst * 16 + (lane >> 5) * 8 + j;   // up channels 0..31
        float v = 0.f;
#pragma unroll
        for (int dy = 0; dy < 3; ++dy)
            v += ALPH[cls][py][dy][dr] * w8[((oc * 64 + ci) * 3 + dy) * 3 + dx];
        wpk8e[i] = f2bf(v);
    }
}

// ---------------------------------------------------------------------------
// Generic NHWC bf16 MFMA conv (3x3, pad 1, relu -> NHWC bf16).
// POOL=1: input is [8, 2H, 2W, CIN]; staging applies 2x2 maxpool on the fly.
// ---------------------------------------------------------------------------
template<int CIN, int COUT, int H, int W, int ROWS, int POOL>
__global__ __launch_bounds__(256)
void convN_mfma(const unsigned short* __restrict__ in,
                const unsigned short* __restrict__ wpk,
                const float* __restrict__ bias,
                unsigned short* __restrict__ out)
{
    constexpr int G = CIN / 8;
    constexpr int KST = CIN / 16;
    constexpr int MT = COUT / 32;
    constexpr int TR = ROWS + 2;
    constexpr int TWd = W + 2;
    constexpr int PS = TR * TWd * 8 + 8;
    __shared__ __align__(16) unsigned short smem[G * PS];

    const int tid  = threadIdx.x;
    const int lane = tid & 63;
    const int wv   = tid >> 6;
    const int q    = lane >> 5;
    const int y0   = blockIdx.x * ROWS;
    const int b    = blockIdx.y;

    for (int i = tid; i < G * TR * TWd; i += 256) {
        int g = i % G;
        int u = (i / G) % TWd;
        int t = i / (G * TWd);
        int yg = y0 + t - 1, xg = u - 1;
        uint4 v = make_uint4(0, 0, 0, 0);
        if (yg >= 0 && yg < H && xg >= 0 && xg < W) {
            if (POOL) {
                const unsigned short* q0 =
                    in + (((size_t)(b * 2 * H + 2 * yg) * 2 * W + 2 * xg) * CIN + g * 8);
                u16x8 a0 = *(const u16x8*)q0;
                u16x8 a1 = *(const u16x8*)(q0 + CIN);
                u16x8 a2 = *(const u16x8*)(q0 + (size_t)2 * W * CIN);
                u16x8 a3 = *(const u16x8*)(q0 + (size_t)2 * W * CIN + CIN);
                float f[8];
#pragma unroll
                for (int j = 0; j < 8; ++j)
                    f[j] = fmaxf(fmaxf(bf2f(a0[j]), bf2f(a1[j])),
                                 fmaxf(bf2f(a2[j]), bf2f(a3[j])));
                v = make_uint4(cvtpk2(f[0], f[1]), cvtpk2(f[2], f[3]),
                               cvtpk2(f[4], f[5]), cvtpk2(f[6], f[7]));
            } else {
                v = *(const uint4*)(in + (((size_t)(b * H + yg) * W + xg) * CIN + g * 8));
            }
        }
        *(uint4*)(&smem[g * PS + (t * TWd + u) * 8]) = v;
    }
    __syncthreads();

    const int p = wv * 32 + (lane & 31);
    const int r = p / W;
    const int x = p % W;

    f32x16 acc[MT];
#pragma unroll
    for (int mt = 0; mt < MT; ++mt)
#pragma unroll
        for (int i = 0; i < 16; ++i) acc[mt][i] = 0.f;

    const unsigned short* wbase = wpk + lane * 8;

#pragma unroll
    for (int s = 0; s < 9; ++s) {
        const int dy = s / 3, dx = s % 3;
#pragma unroll
        for (int kst = 0; kst < KST; ++kst) {
            const int g = kst * 2 + q;
            bf16x8 bfrag = *(const bf16x8*)(&smem[g * PS + ((r + dy) * TWd + (x + dx)) * 8]);
#pragma unroll
            for (int mt = 0; mt < MT; ++mt) {
                bf16x8 a = *(const bf16x8*)(wbase + ((s * KST + kst) * MT + mt) * 512);
                acc[mt] = __builtin_amdgcn_mfma_f32_32x32x16_bf16(a, bfrag, acc[mt], 0, 0, 0);
            }
        }
    }

    size_t base = ((size_t)(b * H + y0 + r) * W + x) * COUT;
#pragma unroll
    for (int mt = 0; mt < MT; ++mt)
#pragma unroll
        for (int rg = 0; rg < 4; ++rg) {
            int oc = mt * 32 + 8 * rg + 4 * q;
            float v0 = fmaxf(acc[mt][rg * 4 + 0] + bias[oc + 0], 0.f);
            float v1 = fmaxf(acc[mt][rg * 4 + 1] + bias[oc + 1], 0.f);
            float v2 = fmaxf(acc[mt][rg * 4 + 2] + bias[oc + 2], 0.f);
            float v3 = fmaxf(acc[mt][rg * 4 + 3] + bias[oc + 3], 0.f);
            *(uint2*)(out + base + oc) = make_uint2(cvtpk2(v0, v1), cvtpk2(v2, v3));
        }
}

// ---------------------------------------------------------------------------
// convU: 3x3 conv with FUSED upsample+concat staging (decoder stages 6,7).
// ---------------------------------------------------------------------------
template<int UPC, int CSKIP, int COUT, int H, int W, int ROWS>
__global__ __launch_bounds__(256)
void convU_mfma(const unsigned short* __restrict__ up,
                const unsigned short* __restrict__ skip,
                const unsigned short* __restrict__ wpk,
                const float* __restrict__ bias,
                unsigned short* __restrict__ out)
{
    constexpr int CIN = UPC + CSKIP;
    constexpr int G = CIN / 8;
    constexpr int GU = UPC / 8;
    constexpr int KST = CIN / 16;
    constexpr int MT = COUT / 32;
    constexpr int TR = ROWS + 2;
    constexpr int TWd = W + 2;
    constexpr int PS = TR * TWd * 8 + 8;
    __shared__ __align__(16) unsigned short smem[G * PS];

    const int tid  = threadIdx.x;
    const int lane = tid & 63;
    const int wv   = tid >> 6;
    const int q    = lane >> 5;
    const int y0   = blockIdx.x * ROWS;
    const int b    = blockIdx.y;

    for (int i = tid; i < G * TR * TWd; i += 256) {
        int g = i % G;
        int u = (i / G) % TWd;
        int t = i / (G * TWd);
        int yg = y0 + t - 1, xg = u - 1;
        uint4 v = make_uint4(0, 0, 0, 0);
        if (yg >= 0 && yg < H && xg >= 0 && xg < W) {
            if (g < GU) {
                int i00, i01, i10, i11; float wy, wx;
                bilin_setup(yg, xg, H / 2, W / 2, i00, i01, i10, i11, wy, wx);
                v = bilin8u(up + (size_t)b * (H / 2) * (W / 2) * UPC + g * 8,
                            i00, i01, i10, i11, wy, wx, UPC);
            } else {
                v = *(const uint4*)(skip + (((size_t)(b * H + yg) * W + xg) * CSKIP
                                            + (g - GU) * 8));
            }
        }
        *(uint4*)(&smem[g * PS + (t * TWd + u) * 8]) = v;
    }
    __syncthreads();

    const int p = wv * 32 + (lane & 31);
    const int r = p / W;
    const int x = p % W;

    f32x16 acc[MT];
#pragma unroll
    for (int mt = 0; mt < MT; ++mt)
#pragma unroll
        for (int i = 0; i < 16; ++i) acc[mt][i] = 0.f;

    const unsigned short* wbase = wpk + lane * 8;

#pragma unroll
    for (int s = 0; s < 9; ++s) {
        const int dy = s / 3, dx = s % 3;
#pragma unroll
        for (int kst = 0; kst < KST; ++kst) {
            const int g = kst * 2 + q;
            bf16x8 bfrag = *(const bf16x8*)(&smem[g * PS + ((r + dy) * TWd + (x + dx)) * 8]);
#pragma unroll
            for (int mt = 0; mt < MT; ++mt) {
                bf16x8 a = *(const bf16x8*)(wbase + ((s * KST + kst) * MT + mt) * 512);
                acc[mt] = __builtin_amdgcn_mfma_f32_32x32x16_bf16(a, bfrag, acc[mt], 0, 0, 0);
            }
        }
    }

    size_t base = ((size_t)(b * H + y0 + r) * W + x) * COUT;
#pragma unroll
    for (int mt = 0; mt < MT; ++mt)
#pragma unroll
        for (int rg = 0; rg < 4; ++rg) {
            int oc = mt * 32 + 8 * rg + 4 * q;
            float v0 = fmaxf(acc[mt][rg * 4 + 0] + bias[oc + 0], 0.f);
            float v1 = fmaxf(acc[mt][rg * 4 + 1] + bias[oc + 1], 0.f);
            float v2 = fmaxf(acc[mt][rg * 4 + 2] + bias[oc + 2], 0.f);
            float v3 = fmaxf(acc[mt][rg * 4 + 3] + bias[oc + 3], 0.f);
            *(uint2*)(out + base + oc) = make_uint2(cvtpk2(v0, v1), cvtpk2(v2, v3));
        }
}

// ---------------------------------------------------------------------------
// Fused conv1 (5x5, relu -> x1t NHWC bf16) + conv_i (3x3 -> xin NCHW bf16).
// Round-10: imgT pre-pass FUSED into staging — reads raw img fp32 planes
// (coalesced along x), converts once with cvt_pk (bit-identical to the old
// imgT path). Deletes the imgT kernel + 32MB of HBM round-trip.
// ---------------------------------------------------------------------------
__global__ __launch_bounds__(256)
void conv1i_mfma(const float* __restrict__ img,
                 const unsigned short* __restrict__ wpk1,
                 const unsigned short* __restrict__ wpki,
                 const float* __restrict__ b1, const float* __restrict__ bi,
                 unsigned short* __restrict__ x1t, unsigned short* __restrict__ xin)
{
    __shared__ __align__(16) unsigned short smem[2 * 5 * 132 * 8];

    const int tid  = threadIdx.x;
    const int lane = tid & 63;
    const int wv   = tid >> 6;
    const int n    = lane & 31;
    const int q    = lane >> 5;
    const int y    = blockIdx.x >> 1;
    const int x0   = (blockIdx.x & 1) * 128;
    const int b    = blockIdx.y;

    for (int i = tid; i < 5 * 132 * 2; i += 256) {
        int r   = i / 264;
        int rem = i - r * 264;
        int xi  = rem >> 1;
        int g   = rem & 1;
        int yg = y + r - 2;
        int xg = x0 - 2 + xi;
        uint4 v = make_uint4(0, 0, 0, 0);
        if (yg >= 0 && yg < 256 && xg >= 0 && xg < 256) {
            const float* ip = img + (size_t)(b * 15 + g * 8) * 65536
                                  + (size_t)yg * 256 + xg;
            float f[8];
            if (g == 0) {
#pragma unroll
                for (int j = 0; j < 8; ++j) f[j] = ip[(size_t)j * 65536];
            } else {
#pragma unroll
                for (int j = 0; j < 7; ++j) f[j] = ip[(size_t)j * 65536];
                f[7] = 0.f;                 // channel 15 pad
            }
            v = make_uint4(cvtpk2(f[0], f[1]), cvtpk2(f[2], f[3]),
                           cvtpk2(f[4], f[5]), cvtpk2(f[6], f[7]));
        }
        *(uint4*)(&smem[((g * 5 + r) * 132 + xi) * 8]) = v;
    }
    __syncthreads();

    f32x16 acc1, acci;
#pragma unroll
    for (int i = 0; i < 16; ++i) { acc1[i] = 0.f; acci[i] = 0.f; }

    const int pxl = wv * 32 + n;
    const unsigned short* wb1 = wpk1 + lane * 8;
    const unsigned short* wbi = wpki + lane * 8;

#pragma unroll
    for (int s = 0; s < 25; ++s) {
        const int dy = s / 5, dx = s % 5;
        bf16x8 bfrag = *(const bf16x8*)(&smem[((q * 5 + dy) * 132 + pxl + dx) * 8]);
        bf16x8 a = *(const bf16x8*)(wb1 + s * 512);
        acc1 = __builtin_amdgcn_mfma_f32_32x32x16_bf16(a, bfrag, acc1, 0, 0, 0);
    }
#pragma unroll
    for (int s = 0; s < 9; ++s) {
        const int dy = s / 3, dx = s % 3;
        bf16x8 bfrag = *(const bf16x8*)(&smem[((q * 5 + dy + 1) * 132 + pxl + dx + 1) * 8]);
        bf16x8 a = *(const bf16x8*)(wbi + s * 512);
        acci = __builtin_amdgcn_mfma_f32_32x32x16_bf16(a, bfrag, acci, 0, 0, 0);
    }

    const int px = x0 + pxl;
    size_t base1 = ((size_t)(b * 256 + y) * 256 + px) * 16;
#pragma unroll
    for (int rg = 0; rg < 2; ++rg) {
        int oc = 8 * rg + 4 * q;
        float v0 = fmaxf(acc1[rg * 4 + 0] + b1[oc + 0], 0.f);
        float v1 = fmaxf(acc1[rg * 4 + 1] + b1[oc + 1], 0.f);
        float v2 = fmaxf(acc1[rg * 4 + 2] + b1[oc + 2], 0.f);
        float v3 = fmaxf(acc1[rg * 4 + 3] + b1[oc + 3], 0.f);
        *(uint2*)(x1t + base1 + oc) = make_uint2(cvtpk2(v0, v1), cvtpk2(v2, v3));
    }
#pragma unroll
    for (int reg = 0; reg < 8; reg += 2) {
        int row = (reg & 3) + 8 * (reg >> 2) + 4 * q;   // reg even: rows row,row+1
        unsigned p = cvtpk2(acci[reg] + bi[row], acci[reg + 1] + bi[row + 1]);
        xin[((size_t)(b * 16 + row)     * 256 + y) * 256 + px] = (unsigned short)p;
        xin[((size_t)(b * 16 + row + 1) * 256 + y) * 256 + px] = (unsigned short)(p >> 16);
    }
}

// ---------------------------------------------------------------------------
// conv8 MFMA, y-composite + cvt_pk (unchanged).
// ---------------------------------------------------------------------------
__global__ __launch_bounds__(256)
void conv8_mfma(const unsigned short* __restrict__ x7t,
                const unsigned short* __restrict__ x2t,
                const unsigned short* __restrict__ wpk8,   // original (skip ksts)
                const unsigned short* __restrict__ wpk8e,  // composite up tables
                const float* __restrict__ bias,
                unsigned short* __restrict__ x8t)
{
    constexpr int PSU = 3 * 66 * 8 + 8;   // 1592 shorts per up plane
    constexpr int PSS = 4 * 66 * 8 + 8;   // 2120 shorts per skip plane
    constexpr int SOFF = 4 * PSU;         // 6368
    __shared__ __align__(16) unsigned short smem[4 * PSU + 4 * PSS]; // 29696 B

    const int tid  = threadIdx.x;
    const int lane = tid & 63;
    const int wv   = tid >> 6;
    const int n    = lane & 31;
    const int q    = lane >> 5;
    const int x0   = (blockIdx.x & 1) * 64;
    const int yp   = blockIdx.x >> 1;       // low-res row i, 0..63
    const int b    = blockIdx.y;

    for (int i = tid; i < 792 + 1056; i += 256) {
        if (i < 792) {
            // up part: 4 planes x 3 low-res rows x 66 cols, x-lerp only
            int g   = i & 3;
            int rem = i >> 2;           // 0..197
            int xi  = rem % 66;
            int t8  = rem / 66;         // 0..2  (low-res row yp-1+t8)
            int r   = yp - 1 + t8;
            int xg  = x0 - 1 + xi;
            uint4 v = make_uint4(0, 0, 0, 0);
            if (r >= 0 && r < 64 && xg >= 0 && xg < 128) {
                int ix0, ix1; float wx;
                up2_setup(xg, 64, ix0, ix1, wx);
                const unsigned short* S = x7t + ((size_t)(b * 64 + r) * 64) * 32 + g * 8;
                u16x8 a0 = *(const u16x8*)(S + ix0 * 32);
                u16x8 a1 = *(const u16x8*)(S + ix1 * 32);
                float w1x = 1.f - wx;
                float f[8];
#pragma unroll
                for (int j = 0; j < 8; ++j)
                    f[j] = w1x * bf2f(a0[j]) + wx * bf2f(a1[j]);
                v = make_uint4(cvtpk2(f[0], f[1]), cvtpk2(f[2], f[3]),
                               cvtpk2(f[4], f[5]), cvtpk2(f[6], f[7]));
            }
            *(uint4*)(&smem[g * PSU + (t8 * 66 + xi) * 8]) = v;
        } else {
            // skip part: 4 planes x 4 full-res rows x 66 cols, pure copy
            int jI  = i - 792;
            int g   = jI & 3;
            int rem = jI >> 2;          // 0..263
            int xi  = rem % 66;
            int t   = rem / 66;         // 0..3
            int yg  = 2 * yp + t - 1;
            int xg  = x0 - 1 + xi;
            uint4 v = make_uint4(0, 0, 0, 0);
            if (yg >= 0 && yg < 128 && xg >= 0 && xg < 128)
                v = *(const uint4*)(x2t + (((size_t)(b * 128 + yg) * 128 + xg) * 32 + g * 8));
            *(uint4*)(&smem[SOFF + g * PSS + (t * 66 + xi) * 8]) = v;
        }
    }
    __syncthreads();

    const int rr  = wv >> 1;                // output row parity py
    const int pxl = (wv & 1) * 32 + n;

    f32x16 acc;
#pragma unroll
    for (int i = 0; i < 16; ++i) acc[i] = 0.f;

    const int cls = (yp == 0) ? 0 : ((yp == 63) ? 2 : 1);
    const unsigned short* wE = wpk8e + (size_t)(cls * 2 + rr) * 9216 + lane * 8;
    const unsigned short* wS = wpk8 + lane * 8;

#pragma unroll
    for (int s = 0; s < 9; ++s) {
        const int dr = s / 3, dxx = s % 3;
#pragma unroll
        for (int kst = 0; kst < 2; ++kst) {
            const int g = kst * 2 + q;
            bf16x8 bfrag = *(const bf16x8*)(&smem[g * PSU + (dr * 66 + pxl + dxx) * 8]);
            bf16x8 a = *(const bf16x8*)(wE + (s * 2 + kst) * 512);
            acc = __builtin_amdgcn_mfma_f32_32x32x16_bf16(a, bfrag, acc, 0, 0, 0);
        }
#pragma unroll
        for (int kst = 0; kst < 2; ++kst) {
            const int g = kst * 2 + q;
            bf16x8 bfrag = *(const bf16x8*)(&smem[SOFF + g * PSS + ((rr + dr) * 66 + pxl + dxx) * 8]);
            bf16x8 a = *(const bf16x8*)(wS + (s * 4 + kst + 2) * 512);
            acc = __builtin_amdgcn_mfma_f32_32x32x16_bf16(a, bfrag, acc, 0, 0, 0);
        }
    }

    size_t base = ((size_t)(b * 128 + 2 * yp + rr) * 128 + x0 + pxl) * 32;
#pragma unroll
    for (int rg = 0; rg < 4; ++rg) {
        int oc0 = 8 * rg + 4 * q;
        float v0 = fmaxf(acc[rg * 4 + 0] + bias[oc0 + 0], 0.f);
        float v1 = fmaxf(acc[rg * 4 + 1] + bias[oc0 + 1], 0.f);
        float v2 = fmaxf(acc[rg * 4 + 2] + bias[oc0 + 2], 0.f);
        float v3 = fmaxf(acc[rg * 4 + 3] + bias[oc0 + 3], 0.f);
        *(uint2*)(x8t + base + oc0) = make_uint2(cvtpk2(v0, v1), cvtpk2(v2, v3));
    }
}

// ---------------------------------------------------------------------------
// conv9 MFMA, y-composite, ROWS=4 / 512-thread (unchanged from round 9).
// ---------------------------------------------------------------------------
__global__ __launch_bounds__(512)
void conv9f_mfma(const unsigned short* __restrict__ x8t,
                 const unsigned short* __restrict__ x1t,
                 const unsigned short* __restrict__ wpk,     // original (kst=2 slice used)
                 const unsigned short* __restrict__ wpk9e,   // composite tables
                 const float* __restrict__ bias,
                 unsigned short* __restrict__ fm)
{
    constexpr int PS8X = 4 * 66 * 8 + 8;   // 2120 shorts per x8 plane (4 low-res rows)
    constexpr int PS1  = 6 * 66 * 8 + 8;   // 3176 shorts per x1 plane (6 rows)
    constexpr int X1OFF = 4 * PS8X;        // 8480
    __shared__ __align__(16) unsigned short smem[16384];     // 32768 B (staging 14832)

    const int tid  = threadIdx.x;
    const int lane = tid & 63;
    const int wv   = tid >> 6;              // 0..7
    const int n    = lane & 31;
    const int q    = lane >> 5;
    const int x0   = (blockIdx.x & 3) * 64;
    const int yq   = blockIdx.x >> 2;       // 0..63 (4-row output tile)
    const int b    = blockIdx.y;

    for (int i = tid; i < 1056 + 792; i += 512) {
        if (i < 1056) {
            // x8 part: 4 planes x 4 low-res rows x 66 cols, x-lerp only
            int g   = i & 3;
            int rem = i >> 2;           // 0..263
            int xi  = rem % 66;
            int t8  = rem / 66;         // 0..3  (low-res row 2yq-1+t8)
            int r   = 2 * yq - 1 + t8;
            int xg  = x0 - 1 + xi;
            uint4 v = make_uint4(0, 0, 0, 0);
            if (r >= 0 && r < 128 && xg >= 0 && xg < 256) {
                int ix0, ix1; float wx;
                up2_setup(xg, 128, ix0, ix1, wx);
                const unsigned short* S = x8t + ((size_t)(b * 128 + r) * 128) * 32 + g * 8;
                u16x8 a0 = *(const u16x8*)(S + ix0 * 32);
                u16x8 a1 = *(const u16x8*)(S + ix1 * 32);
                float w1x = 1.f - wx;
                float f[8];
#pragma unroll
                for (int j = 0; j < 8; ++j)
                    f[j] = w1x * bf2f(a0[j]) + wx * bf2f(a1[j]);
                v = make_uint4(cvtpk2(f[0], f[1]), cvtpk2(f[2], f[3]),
                               cvtpk2(f[4], f[5]), cvtpk2(f[6], f[7]));
            }
            *(uint4*)(&smem[g * PS8X + (t8 * 66 + xi) * 8]) = v;
        } else {
            // x1 part: 2 planes x 6 full-res rows x 66 cols, pure copy
            int jI  = i - 1056;
            int g   = jI & 1;
            int rem = jI >> 1;          // 0..395
            int xi  = rem % 66;
            int t   = rem / 66;         // 0..5
            int yg  = 4 * yq + t - 1;
            int xg  = x0 - 1 + xi;
            uint4 v = make_uint4(0, 0, 0, 0);
            if (yg >= 0 && yg < 256 && xg >= 0 && xg < 256)
                v = *(const uint4*)(x1t + (((size_t)(b * 256 + yg) * 256 + xg) * 16 + g * 8));
            *(uint4*)(&smem[X1OFF + g * PS1 + (t * 66 + xi) * 8]) = v;
        }
    }
    __syncthreads();

    const int rr  = wv >> 1;                 // output row 0..3 within tile
    const int py  = rr & 1;                  // parity
    const int lrh = rr >> 1;                 // low-res sub-row 0..1
    const int lr  = 2 * yq + lrh;            // absolute low-res row
    const int pxl = (wv & 1) * 32 + n;

    f32x16 acc0, acc1;
#pragma unroll
    for (int i = 0; i < 16; ++i) { acc0[i] = 0.f; acc1[i] = 0.f; }

    const int cls = (lr == 0) ? 0 : ((lr == 127) ? 2 : 1);
    const unsigned short* wE  = wpk9e + (size_t)(cls * 2 + py) * 18432 + lane * 8;
    const unsigned short* w2b = wpk + lane * 8;

#pragma unroll
    for (int s = 0; s < 9; ++s) {
        const int dr = s / 3, dxx = s % 3;
        // x8 part: kst 0,1 — B rows are low-res rows lrh+dr (0..3)
#pragma unroll
        for (int kst = 0; kst < 2; ++kst) {
            const int g = kst * 2 + q;
            bf16x8 bfrag = *(const bf16x8*)(&smem[g * PS8X + ((lrh + dr) * 66 + pxl + dxx) * 8]);
            bf16x8 a0 = *(const bf16x8*)(wE + ((s * 2 + kst) * 2 + 0) * 512);
            bf16x8 a1 = *(const bf16x8*)(wE + ((s * 2 + kst) * 2 + 1) * 512);
            acc0 = __builtin_amdgcn_mfma_f32_32x32x16_bf16(a0, bfrag, acc0, 0, 0, 0);
            acc1 = __builtin_amdgcn_mfma_f32_32x32x16_bf16(a1, bfrag, acc1, 0, 0, 0);
        }
        // x1 part: kst=2 — full-res rows rr+dr (0..5), original weights
        {
            bf16x8 bfrag = *(const bf16x8*)(&smem[X1OFF + q * PS1 + ((rr + dr) * 66 + pxl + dxx) * 8]);
            bf16x8 a0 = *(const bf16x8*)(w2b + ((s * 3 + 2) * 2 + 0) * 512);
            bf16x8 a1 = *(const bf16x8*)(w2b + ((s * 3 + 2) * 2 + 1) * 512);
            acc0 = __builtin_amdgcn_mfma_f32_32x32x16_bf16(a0, bfrag, acc0, 0, 0, 0);
            acc1 = __builtin_amdgcn_mfma_f32_32x32x16_bf16(a1, bfrag, acc1, 0, 0, 0);
        }
    }

    // --- epilogue: LDS transpose -> vectorized NCHW stores ---
    __syncthreads();                       // staging buffer is now dead
    unsigned short* lout = smem;           // [64 oc][256 = 4 rows x 64 px]
    const int col = rr * 64 + pxl;
#pragma unroll
    for (int reg = 0; reg < 16; reg += 2) {
        const int rb = (reg & 3) + 8 * (reg >> 2);        // pairs -> rows rb, rb+1
        float a0 = fast_tanh(acc0[reg]     + bias[rb + 4 * q]);
        float a1 = fast_tanh(acc0[reg + 1] + bias[rb + 1 + 4 * q]);
        unsigned p0 = cvtpk2(a0, a1);
        lout[(rb + 4 * q) * 256 + col]     = (unsigned short)p0;
        lout[(rb + 1 + 4 * q) * 256 + col] = (unsigned short)(p0 >> 16);
        float b0 = fast_tanh(acc1[reg]     + bias[rb + 4 * q + 32]);
        float b1 = fast_tanh(acc1[reg + 1] + bias[rb + 1 + 4 * q + 32]);
        unsigned p1 = cvtpk2(b0, b1);
        lout[(rb + 4 * q + 32) * 256 + col] = (unsigned short)p1;
        lout[(rb + 4 * q + 33) * 256 + col] = (unsigned short)(p1 >> 16);
    }
    __syncthreads();

    const size_t fmb = (size_t)b * 64 * 65536 + (size_t)(4 * yq) * 256 + x0;
    for (int i = tid; i < 2048; i += 512) {
        int oc = i >> 5;               // 0..63
        int c8 = (i & 31) * 8;         // 0..248
        int rl = c8 >> 6;              // local row 0..3
        int pl = c8 & 63;              // x within strip
        uint4 v = *(const uint4*)(lout + oc * 256 + c8);
        *(uint4*)(fm + fmb + (size_t)oc * 65536 + rl * 256 + pl) = v;
    }
}

// ---------------------------------------------------------------------------
// Segmented W-direction LRNN pair -> rnnW NCHW bf16 (round-8 bf16 LDS).
// ---------------------------------------------------------------------------
__global__ __launch_bounds__(256)
void lrnn_w_seg(const unsigned short* __restrict__ X, const unsigned short* __restrict__ FM,
                unsigned short* __restrict__ rnnW)
{
    __shared__ __align__(16) unsigned short tx[3][16][312];
    __shared__ __align__(16) unsigned short outm[2][16][256];
    __shared__ float segres[2][16][8][4];
    __shared__ float hin[2][16][8][2];

    const int tid = threadIdx.x;
    const int bid = blockIdx.x;
    const int yt = bid & 15;
    const int c  = (bid >> 4) & 15;
    const int b  = bid >> 8;
    const int y0 = yt * 16;

    const size_t xb  = ((size_t)(b * 16 + c) * 256 + y0) * 256;
    const size_t p1b = ((size_t)(b * 64 + c) * 256 + y0) * 256;
    const size_t p2b = ((size_t)(b * 64 + 32 + c) * 256 + y0) * 256;

    for (int i = tid; i < 1536; i += 256) {
        int s = i >> 9;
        int r = i & 511;
        int y = r >> 5;
        int g = r & 31;
        const unsigned short* sp = (s == 0) ? (X + xb) : (s == 1 ? FM + p1b : FM + p2b);
        uint4 v = *(const uint4*)(sp + (size_t)y * 256 + g * 8);
        *(uint4*)(&tx[s][y][8 * g + 8 * (g >> 2)]) = v;   // padded col of x=8g
    }
    __syncthreads();

    const int y  = tid & 15;
    const int sg = (tid >> 4) & 7;
    const int d  = tid >> 7;

    {   // pass 1
        float h1 = 0.f, h2 = 0.f, A1 = 1.f, A2 = 1.f;
        if (d == 0) {
            const int base = 40 * sg;
#pragma unroll
            for (int k = 0; k < 4; ++k) {
                u16x8 xv8 = *(const u16x8*)&tx[0][y][base + 8 * k];
                u16x8 p18 = *(const u16x8*)&tx[1][y][base + 8 * k];
                u16x8 p28 = *(const u16x8*)&tx[2][y][base + 8 * k];
#pragma unroll
                for (int j = 0; j < 8; ++j) {
                    float xv = bf2f(xv8[j]), p1 = bf2f(p18[j]), p2 = bf2f(p28[j]);
                    h1 = fmaf(p1, h1 - xv, xv); A1 *= p1;
                    h2 = fmaf(p2, h2 - xv, xv); A2 *= p2;
                }
            }
        } else {
            const int m = 7 - sg;
#pragma unroll
            for (int k = 0; k < 4; ++k) {
                const int base = 40 * m + 24 - 8 * k;
                u16x8 xv8 = *(const u16x8*)&tx[0][y][base];
                u16x8 p18 = *(const u16x8*)&tx[1][y][base];
                u16x8 p28 = *(const u16x8*)&tx[2][y][base];
#pragma unroll
                for (int j = 7; j >= 0; --j) {
                    float xv = bf2f(xv8[j]), p1 = bf2f(p18[j]), p2 = bf2f(p28[j]);
                    h1 = fmaf(p1, h1 - xv, xv); A1 *= p1;
                    h2 = fmaf(p2, h2 - xv, xv); A2 *= p2;
                }
            }
        }
        segres[d][y][sg][0] = h1; segres[d][y][sg][1] = A1;
        segres[d][y][sg][2] = h2; segres[d][y][sg][3] = A2;
    }
    __syncthreads();

    if (tid < 32) {
        int yy = tid & 15, dd = tid >> 4;
        float c1 = 0.f, c2 = 0.f;
        for (int s = 0; s < 8; ++s) {
            hin[dd][yy][s][0] = c1;
            hin[dd][yy][s][1] = c2;
            c1 = segres[dd][yy][s][0] + segres[dd][yy][s][1] * c1;
            c2 = segres[dd][yy][s][2] + segres[dd][yy][s][3] * c2;
        }
    }
    __syncthreads();

    {   // pass 2: vector reads + 8-wide buffered vector outm writes
        float h1 = hin[d][y][sg][0], h2 = hin[d][y][sg][1];
        if (d == 0) {
            const int base = 40 * sg;
            const int xs = 32 * sg;
#pragma unroll
            for (int k = 0; k < 4; ++k) {
                u16x8 xv8 = *(const u16x8*)&tx[0][y][base + 8 * k];
                u16x8 p18 = *(const u16x8*)&tx[1][y][base + 8 * k];
                u16x8 p28 = *(const u16x8*)&tx[2][y][base + 8 * k];
                float mres[8];
#pragma unroll
                for (int j = 0; j < 8; ++j) {
                    float xv = bf2f(xv8[j]), p1 = bf2f(p18[j]), p2 = bf2f(p28[j]);
                    h1 = fmaf(p1, h1 - xv, xv);
                    h2 = fmaf(p2, h2 - xv, xv);
                    mres[j] = fmaxf(h1, h2);
                }
                *(uint4*)&outm[0][y][xs + 8 * k] =
                    make_uint4(cvtpk2(mres[0], mres[1]), cvtpk2(mres[2], mres[3]),
                               cvtpk2(mres[4], mres[5]), cvtpk2(mres[6], mres[7]));
            }
        } else {
            const int m = 7 - sg;
            const int ts = 32 * sg;
#pragma unroll
            for (int k = 0; k < 4; ++k) {
                const int base = 40 * m + 24 - 8 * k;
                u16x8 xv8 = *(const u16x8*)&tx[0][y][base];
                u16x8 p18 = *(const u16x8*)&tx[1][y][base];
                u16x8 p28 = *(const u16x8*)&tx[2][y][base];
                float mres[8];
#pragma unroll
                for (int j = 7; j >= 0; --j) {
                    float xv = bf2f(xv8[j]), p1 = bf2f(p18[j]), p2 = bf2f(p28[j]);
                    h1 = fmaf(p1, h1 - xv, xv);
                    h2 = fmaf(p2, h2 - xv, xv);
                    mres[7 - j] = fmaxf(h1, h2);
                }
                *(uint4*)&outm[1][y][ts + 8 * k] =
                    make_uint4(cvtpk2(mres[0], mres[1]), cvtpk2(mres[2], mres[3]),
                               cvtpk2(mres[4], mres[5]), cvtpk2(mres[6], mres[7]));
            }
        }
    }
    __syncthreads();

    // final: thread tid owns x=tid, rows 0..15 (paired conversions)
    {
        const int x = tid;
#pragma unroll
        for (int yy = 0; yy < 16; yy += 2) {
            float m0 = fmaxf(bf2f(outm[0][yy][x]),     bf2f(outm[1][yy][x]));
            float m1 = fmaxf(bf2f(outm[0][yy + 1][x]), bf2f(outm[1][yy + 1][x]));
            unsigned p = cvtpk2(m0, m1);
            rnnW[xb + (size_t)yy * 256 + x]       = (unsigned short)p;
            rnnW[xb + (size_t)(yy + 1) * 256 + x] = (unsigned short)(p >> 16);
        }
    }
}

// ---------------------------------------------------------------------------
// Segmented H-direction LRNN pair; fuses max(rnnW, rnnH) -> rnnM.
// (round-8 transposed bf16 LDS)
// ---------------------------------------------------------------------------
__global__ __launch_bounds__(256)
void lrnn_h_seg(const unsigned short* __restrict__ X, const unsigned short* __restrict__ FM,
                const unsigned short* __restrict__ rnnW, unsigned short* __restrict__ rnnM)
{
    __shared__ __align__(16) unsigned short tx[3][16][312];
    __shared__ __align__(16) unsigned short outm[2][16][264];
    __shared__ float segres[2][16][8][4];
    __shared__ float hin[2][16][8][2];

    const int tid = threadIdx.x;
    const int bid = blockIdx.x;
    const int xt = bid & 15;
    const int c  = (bid >> 4) & 15;
    const int b  = bid >> 8;
    const int x0 = xt * 16;

    const size_t xb  = (size_t)(b * 16 + c) * 65536 + x0;
    const size_t p1b = (size_t)(b * 64 + 16 + c) * 65536 + x0;
    const size_t p2b = (size_t)(b * 64 + 48 + c) * 65536 + x0;

    for (int i = tid; i < 1536; i += 256) {
        int s = i >> 9;
        int r = i & 511;
        int y = r >> 1;
        int g = r & 1;
        const unsigned short* sp = (s == 0) ? (X + xb) : (s == 1 ? FM + p1b : FM + p2b);
        u16x8 v = *(const u16x8*)(sp + (size_t)y * 256 + g * 8);
        int pc = y + 8 * (y >> 5);        // padded col for y
#pragma unroll
        for (int j = 0; j < 8; ++j) tx[s][g * 8 + j][pc] = v[j];
    }
    __syncthreads();

    const int x  = tid & 15;
    const int sg = (tid >> 4) & 7;
    const int d  = tid >> 7;

    {   // pass 1
        float h1 = 0.f, h2 = 0.f, A1 = 1.f, A2 = 1.f;
        if (d == 0) {
            const int base = 40 * sg;
#pragma unroll
            for (int k = 0; k < 4; ++k) {
                u16x8 xv8 = *(const u16x8*)&tx[0][x][base + 8 * k];
                u16x8 p18 = *(const u16x8*)&tx[1][x][base + 8 * k];
                u16x8 p28 = *(const u16x8*)&tx[2][x][base + 8 * k];
#pragma unroll
                for (int j = 0; j < 8; ++j) {
                    float xv = bf2f(xv8[j]), p1 = bf2f(p18[j]), p2 = bf2f(p28[j]);
                    h1 = fmaf(p1, h1 - xv, xv); A1 *= p1;
                    h2 = fmaf(p2, h2 - xv, xv); A2 *= p2;
                }
            }
        } else {
            const int m = 7 - sg;
#pragma unroll
            for (int k = 0; k < 4; ++k) {
                const int base = 40 * m + 24 - 8 * k;
                u16x8 xv8 = *(const u16x8*)&tx[0][x][base];
                u16x8 p18 = *(const u16x8*)&tx[1][x][base];
                u16x8 p28 = *(const u16x8*)&tx[2][x][base];
#pragma unroll
                for (int j = 7; j >= 0; --j) {
                    float xv = bf2f(xv8[j]), p1 = bf2f(p18[j]), p2 = bf2f(p28[j]);
                    h1 = fmaf(p1, h1 - xv, xv); A1 *= p1;
                    h2 = fmaf(p2, h2 - xv, xv); A2 *= p2;
                }
            }
        }
        segres[d][x][sg][0] = h1; segres[d][x][sg][1] = A1;
        segres[d][x][sg][2] = h2; segres[d][x][sg][3] = A2;
    }
    __syncthreads();

    if (tid < 32) {
        int xx = tid & 15, dd = tid >> 4;
        float c1 = 0.f, c2 = 0.f;
        for (int s = 0; s < 8; ++s) {
            hin[dd][xx][s][0] = c1;
            hin[dd][xx][s][1] = c2;
            c1 = segres[dd][xx][s][0] + segres[dd][xx][s][1] * c1;
            c2 = segres[dd][xx][s][2] + segres[dd][xx][s][3] * c2;
        }
    }
    __syncthreads();

    {   // pass 2: vector reads + 8-wide buffered vector outm writes
        float h1 = hin[d][x][sg][0], h2 = hin[d][x][sg][1];
        if (d == 0) {
            const int base = 40 * sg;
            const int ys = 32 * sg;
#pragma unroll
            for (int k = 0; k < 4; ++k) {
                u16x8 xv8 = *(const u16x8*)&tx[0][x][base + 8 * k];
                u16x8 p18 = *(const u16x8*)&tx[1][x][base + 8 * k];
                u16x8 p28 = *(const u16x8*)&tx[2][x][base + 8 * k];
                float mres[8];
#pragma unroll
                for (int j = 0; j < 8; ++j) {
                    float xv = bf2f(xv8[j]), p1 = bf2f(p18[j]), p2 = bf2f(p28[j]);
                    h1 = fmaf(p1, h1 - xv, xv);
                    h2 = fmaf(p2, h2 - xv, xv);
                    mres[j] = fmaxf(h1, h2);
                }
                *(uint4*)&outm[0][x][ys + 8 * k] =
                    make_uint4(cvtpk2(mres[0], mres[1]), cvtpk2(mres[2], mres[3]),
                               cvtpk2(mres[4], mres[5]), cvtpk2(mres[6], mres[7]));
            }
        } else {
            const int m = 7 - sg;
            const int ts = 32 * sg;
#pragma unroll
            for (int k = 0; k < 4; ++k) {
                const int base = 40 * m + 24 - 8 * k;
                u16x8 xv8 = *(const u16x8*)&tx[0][x][base];
                u16x8 p18 = *(const u16x8*)&tx[1][x][base];
                u16x8 p28 = *(const u16x8*)&tx[2][x][base];
                float mres[8];
#pragma unroll
                for (int j = 7; j >= 0; --j) {
                    float xv = bf2f(xv8[j]), p1 = bf2f(p18[j]), p2 = bf2f(p28[j]);
                    h1 = fmaf(p1, h1 - xv, xv);
                    h2 = fmaf(p2, h2 - xv, xv);
                    mres[7 - j] = fmaxf(h1, h2);
                }
                *(uint4*)&outm[1][x][ts + 8 * k] =
                    make_uint4(cvtpk2(mres[0], mres[1]), cvtpk2(mres[2], mres[3]),
                               cvtpk2(mres[4], mres[5]), cvtpk2(mres[6], mres[7]));
            }
        }
    }
    __syncthreads();

    // final: thread handles xx = tid&15, yy = (tid>>4) + 16k (paired k)
    {
        const int xx = tid & 15;
        const int yy0 = tid >> 4;
#pragma unroll
        for (int k = 0; k < 16; k += 2) {
            int ya = yy0 + 16 * k, yb = yy0 + 16 * (k + 1);
            size_t offA = xb + (size_t)ya * 256 + xx;
            size_t offB = xb + (size_t)yb * 256 + xx;
            float ma = fmaxf(fmaxf(bf2f(outm[0][xx][ya]), bf2f(outm[1][xx][ya])),
                             bf2f(rnnW[offA]));
            float mb = fmaxf(fmaxf(bf2f(outm[0][xx][yb]), bf2f(outm[1][xx][yb])),
                             bf2f(rnnW[offB]));
            unsigned p = cvtpk2(ma, mb);
            rnnM[offA] = (unsigned short)p;
            rnnM[offB] = (unsigned short)(p >> 16);
        }
    }
}

// ---------------------------------------------------------------------------
// Output head MFMA: rnnM -> 3x3 conv (Cin16, Cout3), sigmoid -> fp32 out.
// Round-10: staging via ALIGNED u16x8 chunk loads (18 chunks/row, per-elem
// predicated LDS scatter) — ~7x fewer load instructions, coalescing kept.
// ---------------------------------------------------------------------------
__global__ __launch_bounds__(256)
void convo_mfma(const unsigned short* __restrict__ rnnM,
                const unsigned short* __restrict__ wpko,
                const float* __restrict__ bo,
                float* __restrict__ outp)
{
    constexpr int PSo = 6 * 130 * 8 + 8;   // 6248 shorts per channel-group plane
    __shared__ __align__(16) unsigned short smem[2 * PSo];   // 24992 B

    const int tid  = threadIdx.x;
    const int lane = tid & 63;
    const int wv   = tid >> 6;
    const int n    = lane & 31;
    const int q    = lane >> 5;
    const int x0   = (blockIdx.x & 1) * 128;
    const int yq   = blockIdx.x >> 1;       // 0..63
    const int b    = blockIdx.y;

    for (int i = tid; i < 6 * 16 * 18; i += 256) {
        int c  = i % 18;           // aligned 8-chunk index over [x0-8, x0+136)
        int t  = i / 18;           // 0..95
        int ch = t & 15;
        int r  = t >> 4;           // 0..5
        int yg = 4 * yq + r - 1;
        int g = ch >> 3, j = ch & 7;
        unsigned short* sb = &smem[g * PSo + (r * 130) * 8 + j];
        int xg0 = x0 + 8 * (c - 1);        // 8-aligned global x base
        int xi0 = 8 * c - 7;               // xi of first element
        if (yg >= 0 && yg < 256 && xg0 >= 0 && xg0 < 256) {
            size_t off = (size_t)(b * 16 + ch) * 65536 + (size_t)yg * 256;
            u16x8 v = *(const u16x8*)(rnnM + off + xg0);
#pragma unroll
            for (int k = 0; k < 8; ++k) {
                int xi = xi0 + k;
                if (xi >= 0 && xi < 130) sb[xi * 8] = v[k];
            }
        } else {
#pragma unroll
            for (int k = 0; k < 8; ++k) {
                int xi = xi0 + k;
                if (xi >= 0 && xi < 130) sb[xi * 8] = 0;
            }
        }
    }
    __syncthreads();

    const unsigned short* wbase = wpko + lane * 8;
    const int y = 4 * yq + wv;              // wave wv owns one output row

#pragma unroll
    for (int xt = 0; xt < 4; ++xt) {
        const int pxl = xt * 32 + n;
        f32x16 acc;
#pragma unroll
        for (int i = 0; i < 16; ++i) acc[i] = 0.f;
#pragma unroll
        for (int s = 0; s < 9; ++s) {
            const int dy = s / 3, dx = s % 3;
            bf16x8 bfrag = *(const bf16x8*)(&smem[q * PSo + ((wv + dy) * 130 + pxl + dx) * 8]);
            bf16x8 a = *(const bf16x8*)(wbase + s * 512);
            acc = __builtin_amdgcn_mfma_f32_32x32x16_bf16(a, bfrag, acc, 0, 0, 0);
        }
        if (q == 0) {
            const int px = x0 + pxl;
#pragma unroll
            for (int oc = 0; oc < 3; ++oc) {
                float r2 = acc[oc] + bo[oc];
                outp[((size_t)(b * 3 + oc) * 256 + y) * 256 + px] = 1.f / (1.f + __expf(-r2));
            }
        }
    }
}

// ---------------------------------------------------------------------------
extern "C" void kernel_launch(void* const* d_in, const int* in_sizes, int n_in,
                              void* d_out, int out_size, void* d_ws, size_t ws_size,
                              hipStream_t stream)
{
    const float* img = (const float*)d_in[0];
    const float* w1 = (const float*)d_in[1];  const float* b1 = (const float*)d_in[2];
    const float* w2 = (const float*)d_in[3];  const float* b2 = (const float*)d_in[4];
    const float* w3 = (const float*)d_in[5];  const float* b3 = (const float*)d_in[6];
    const float* w4 = (const float*)d_in[7];  const float* b4 = (const float*)d_in[8];
    const float* w5 = (const float*)d_in[9];  const float* b5 = (const float*)d_in[10];
    const float* w6 = (const float*)d_in[11]; const float* b6 = (const float*)d_in[12];
    const float* w7 = (const float*)d_in[13]; const float* b7 = (const float*)d_in[14];
    const float* w8 = (const float*)d_in[15]; const float* b8 = (const float*)d_in[16];
    const float* w9 = (const float*)d_in[17]; const float* b9 = (const float*)d_in[18];
    const float* wi = (const float*)d_in[19]; const float* bi = (const float*)d_in[20];
    const float* wo = (const float*)d_in[21]; const float* bo = (const float*)d_in[22];

    char* wsb = (char*)d_ws;
    const size_t MB = (size_t)(1u << 20);
    unsigned short* x1t   = (unsigned short*)(wsb + 16 * MB);   // [16,32) till conv9f
    unsigned short* x2t   = (unsigned short*)(wsb + 32 * MB);   // [32,40) till conv8
    unsigned short* x3t   = (unsigned short*)(wsb + 40 * MB);   // [40,42) till conv7
    unsigned short* x4t   = (unsigned short*)(wsb + 42 * MB);   // [42,42.5) till conv6
    unsigned short* x5t   = (unsigned short*)(wsb + 43 * MB);   // [43,43.25)
    unsigned short* x6t   = (unsigned short*)(wsb + 46 * MB);   // [46,46.5)
    unsigned short* x7t   = (unsigned short*)(wsb + 51 * MB);   // [51,53) till conv8
    unsigned short* x8t   = (unsigned short*)(wsb + 70 * MB);   // [70,78) till conv9f
    unsigned short* fm16  = (unsigned short*)(wsb + 112 * MB);  // [112,176) NCHW bf16
    unsigned short* xin16 = (unsigned short*)(wsb + 176 * MB);  // [176,192) NCHW bf16
    unsigned short* rnnW  = (unsigned short*)(wsb);             // [0,16)
    unsigned short* rnnM  = (unsigned short*)(wsb + 16 * MB);   // [16,32) (x1t dead)
    unsigned short* wpk9 = (unsigned short*)(wsb + 192 * MB);
    unsigned short* wpk8 = wpk9 + 27648;
    unsigned short* wpk1 = wpk8 + 18432;
    unsigned short* wpki = wpk1 + 12800;
    unsigned short* wpko = wpki + 4608;
    unsigned short* wpk2 = wpko + 4608;
    unsigned short* wpk3 = wpk2 + 4608;
    unsigned short* wpk4 = wpk3 + 9216;
    unsigned short* wpk5 = wpk4 + 9216;
    unsigned short* wpk6 = wpk5 + 18432;
    unsigned short* wpk7 = wpk6 + 27648;
    unsigned short* wpk9e = wpk7 + 18432;    // 110592 shorts (conv9 composite)
    unsigned short* wpk8e = wpk9e + 110592;  // 55296 shorts (conv8 composite)
    float* outp = (float*)d_out;

    // --- single weight-pack dispatch ---
    wprep_mega<<<1256, 256, 0, stream>>>(w9, w8, w1, wi, wo, w2, w3, w4, w5, w6, w7,
                                         wpk9, wpk8, wpk1, wpki, wpko,
                                         wpk2, wpk3, wpk4, wpk5, wpk6, wpk7,
                                         wpk9e, wpk8e);

    // --- fused img transpose + conv1 (relu -> x1t NHWC) + input projection ---
    { dim3 grd(512, 8);
      conv1i_mfma<<<grd, 256, 0, stream>>>(img, wpk1, wpki, b1, bi, x1t, xin16); }

    // --- encoder: pools fused into conv staging ---
    convN_mfma<16, 32, 128, 128, 1, 1><<<dim3(128, 8), 256, 0, stream>>>(x1t, wpk2, b2, x2t);
    convN_mfma<32, 32, 64, 64, 2, 1><<<dim3(32, 8), 256, 0, stream>>>(x2t, wpk3, b3, x3t);
    convN_mfma<32, 32, 32, 32, 4, 1><<<dim3(8, 8), 256, 0, stream>>>(x3t, wpk4, b4, x4t);
    convN_mfma<32, 64, 16, 16, 8, 1><<<dim3(2, 8), 256, 0, stream>>>(x4t, wpk5, b5, x5t);

    // --- decoder: upcat fused into conv6/conv7/conv8 staging ---
    convU_mfma<64, 32, 32, 32, 32, 4><<<dim3(8, 8), 256, 0, stream>>>(x5t, x4t, wpk6, b6, x6t);
    convU_mfma<32, 32, 32, 64, 64, 2><<<dim3(32, 8), 256, 0, stream>>>(x6t, x3t, wpk7, b7, x7t);
    { dim3 grd(128, 8);
      conv8_mfma<<<grd, 256, 0, stream>>>(x7t, x2t, wpk8, wpk8e, b8, x8t); }

    // --- stage 9: y-composite ROWS=4 conv9 (256 blocks x 512 threads) ---
    { dim3 grd(256, 8);
      conv9f_mfma<<<grd, 512, 0, stream>>>(x8t, x1t, wpk9, wpk9e, b9, fm16); }

    // --- spatial RNN: segmented scans; lrnn_h fuses max(rnnW, rnnH) -> rnnM ---
    lrnn_w_seg<<<2048, 256, 0, stream>>>(xin16, fm16, rnnW);
    lrnn_h_seg<<<2048, 256, 0, stream>>>(xin16, fm16, rnnW, rnnM);

    // --- output head: 4-row blocks, single input tensor ---
    { dim3 grd(128, 8);
      convo_mfma<<<grd, 256, 0, stream>>>(rnnM, wpko, bo, outp); }
}

// Round 11
// 343.541 us; speedup vs baseline: 1.2045x; 1.0302x over previous
//
#include <hip/hip_runtime.h>
#include <math.h>

typedef __attribute__((ext_vector_type(8)))  short bf16x8;
typedef __attribute__((ext_vector_type(8)))  unsigned short u16x8;
typedef __attribute__((ext_vector_type(16))) float f32x16;

__device__ __forceinline__ unsigned short f2bf(float f) {
    unsigned u = __float_as_uint(f);
    unsigned r = (u + 0x7FFFu + ((u >> 16) & 1u)) >> 16;
    return (unsigned short)r;
}
__device__ __forceinline__ float bf2f(unsigned short h) {
    return __uint_as_float(((unsigned)h) << 16);
}
__device__ __forceinline__ unsigned pack2(unsigned short a, unsigned short b) {
    return (unsigned)a | ((unsigned)b << 16);
}
// HW packed f32->bf16 RNE: 1 VALU op converts 2 values (== manual f2bf RNE).
__device__ __forceinline__ unsigned cvtpk2(float a, float b) {
    unsigned r;
    asm("v_cvt_pk_bf16_f32 %0, %1, %2" : "=v"(r) : "v"(a), "v"(b));
    return r;
}
__device__ __forceinline__ float fast_tanh(float x) {
    float e = __expf(2.f * x);
    return 1.f - 2.f / (e + 1.f);
}

__device__ __forceinline__ void bilin_setup(int y, int x, int Hi, int Wi,
                                            int& i00, int& i01, int& i10, int& i11,
                                            float& wy, float& wx)
{
    float fy = 0.5f * y - 0.25f;
    float fx = 0.5f * x - 0.25f;
    float y0f = floorf(fy), x0f = floorf(fx);
    wy = fy - y0f; wx = fx - x0f;
    int yA = (int)y0f, xA = (int)x0f;
    int yB = yA + 1, xB = xA + 1;
    yA = yA < 0 ? 0 : (yA > Hi - 1 ? Hi - 1 : yA);
    yB = yB < 0 ? 0 : (yB > Hi - 1 ? Hi - 1 : yB);
    xA = xA < 0 ? 0 : (xA > Wi - 1 ? Wi - 1 : xA);
    xB = xB < 0 ? 0 : (xB > Wi - 1 ? Wi - 1 : xB);
    i00 = yA * Wi + xA; i01 = yA * Wi + xB;
    i10 = yB * Wi + xA; i11 = yB * Wi + xB;
}

// 2x upsample w/ half-pixel centers: fixed parity weights, no floorf needed.
__device__ __forceinline__ void up2_setup(int v, int Hi, int& i0, int& i1, float& w)
{
    int a = (v - 1) >> 1;           // arithmetic shift: v=0 -> -1
    i0 = a < 0 ? 0 : a;
    int b = a + 1;
    i1 = b > Hi - 1 ? Hi - 1 : b;
    w = (v & 1) ? 0.25f : 0.75f;
}

__device__ __forceinline__ uint4 bilin8u(const unsigned short* __restrict__ sb,
                                         int i00, int i01, int i10, int i11,
                                         float wy, float wx, int stride)
{
    u16x8 v00 = *(const u16x8*)(sb + (size_t)i00 * stride);
    u16x8 v01 = *(const u16x8*)(sb + (size_t)i01 * stride);
    u16x8 v10 = *(const u16x8*)(sb + (size_t)i10 * stride);
    u16x8 v11 = *(const u16x8*)(sb + (size_t)i11 * stride);
    float w00 = (1.f - wy) * (1.f - wx), w01 = (1.f - wy) * wx;
    float w10 = wy * (1.f - wx),         w11 = wy * wx;
    float f[8];
#pragma unroll
    for (int j = 0; j < 8; ++j)
        f[j] = w00 * bf2f(v00[j]) + w01 * bf2f(v01[j]) +
               w10 * bf2f(v10[j]) + w11 * bf2f(v11[j]);
    return make_uint4(cvtpk2(f[0], f[1]), cvtpk2(f[2], f[3]),
                      cvtpk2(f[4], f[5]), cvtpk2(f[6], f[7]));
}

// y-interp composite coefficients: ALPH[cls][py][dy][dr]
__device__ const float ALPH[3][2][3][3] = {
    { { {0.f,0.f,0.f},      {0.f,1.f,0.f},       {0.f,0.75f,0.25f} },
      { {0.f,1.f,0.f},      {0.f,0.75f,0.25f},   {0.f,0.25f,0.75f} } },
    { { {0.75f,0.25f,0.f},  {0.25f,0.75f,0.f},   {0.f,0.75f,0.25f} },
      { {0.25f,0.75f,0.f},  {0.f,0.75f,0.25f},   {0.f,0.25f,0.75f} } },
    { { {0.75f,0.25f,0.f},  {0.25f,0.75f,0.f},   {0.f,1.f,0.f} },
      { {0.25f,0.75f,0.f},  {0.f,1.f,0.f},       {0.f,0.f,0.f} } }
};

// ---------------------------------------------------------------------------
// Mega weight-pack: all packs in one dispatch (incl. y-composite tables).
// ---------------------------------------------------------------------------
__device__ __forceinline__ void pack33(const float* __restrict__ w,
                                       unsigned short* __restrict__ dst,
                                       int i, int Cin, int Cout)
{
    int KST = Cin >> 4, MT = Cout >> 5;
    int j = i & 7;
    int lane = (i >> 3) & 63;
    int t = i >> 9;
    int mt = t % MT; t /= MT;
    int kst = t % KST;
    int s = t / KST;
    int oc = mt * 32 + (lane & 31);
    int ci = kst * 16 + (lane >> 5) * 8 + j;
    dst[i] = f2bf(w[(oc * Cin + ci) * 9 + s]);
}

__global__ void wprep_mega(const float* __restrict__ w9, const float* __restrict__ w8,
                           const float* __restrict__ w1, const float* __restrict__ wi,
                           const float* __restrict__ wo, const float* __restrict__ w2,
                           const float* __restrict__ w3, const float* __restrict__ w4,
                           const float* __restrict__ w5, const float* __restrict__ w6,
                           const float* __restrict__ w7,
                           unsigned short* __restrict__ wpk9, unsigned short* __restrict__ wpk8,
                           unsigned short* __restrict__ wpk1, unsigned short* __restrict__ wpki,
                           unsigned short* __restrict__ wpko, unsigned short* __restrict__ wpk2,
                           unsigned short* __restrict__ wpk3, unsigned short* __restrict__ wpk4,
                           unsigned short* __restrict__ wpk5, unsigned short* __restrict__ wpk6,
                           unsigned short* __restrict__ wpk7, unsigned short* __restrict__ wpk9e,
                           unsigned short* __restrict__ wpk8e)
{
    int idx = blockIdx.x * 256 + threadIdx.x;
    if (idx < 27648)       pack33(w9, wpk9, idx, 48, 64);
    else if (idx < 46080)  pack33(w8, wpk8, idx - 27648, 64, 32);
    else if (idx < 58880) {
        int i = idx - 46080;
        int j = i & 7;
        int lane = (i >> 3) & 63;
        int s = i >> 9;                 // 0..24
        int oc = lane & 31;
        int ci = (lane >> 5) * 8 + j;   // 0..15
        float v = 0.f;
        if (oc < 16 && ci < 15) v = w1[((oc * 15 + ci) * 5 + s / 5) * 5 + s % 5];
        wpk1[i] = f2bf(v);
    } else if (idx < 63488) {
        int i = idx - 58880;
        int j = i & 7;
        int lane = (i >> 3) & 63;
        int s = i >> 9;                 // 0..8
        int oc = lane & 31;
        int ci = (lane >> 5) * 8 + j;
        float v = 0.f;
        if (oc < 16 && ci < 15) v = wi[((oc * 15 + ci) * 3 + s / 3) * 3 + s % 3];
        wpki[i] = f2bf(v);
    } else if (idx < 68096) {
        int i = idx - 63488;
        int j = i & 7;
        int lane = (i >> 3) & 63;
        int s = i >> 9;
        int oc = lane & 31;
        int ci = (lane >> 5) * 8 + j;
        float v = 0.f;
        if (oc < 3) v = wo[((oc * 16 + ci) * 3 + s / 3) * 3 + s % 3];
        wpko[i] = f2bf(v);
    }
    else if (idx < 72704)  pack33(w2, wpk2, idx - 68096, 16, 32);
    else if (idx < 81920)  pack33(w3, wpk3, idx - 72704, 32, 32);
    else if (idx < 91136)  pack33(w4, wpk4, idx - 81920, 32, 32);
    else if (idx < 109568) pack33(w5, wpk5, idx - 91136, 32, 64);
    else if (idx < 137216) pack33(w6, wpk6, idx - 109568, 96, 32);
    else if (idx < 155648) pack33(w7, wpk7, idx - 137216, 64, 32);
    else if (idx < 266240) {
        // conv9 y-composite tables: [cls][py][s=dr*3+dx][kst][half] x 512
        int i = idx - 155648;
        int j = i & 7;
        int lane = (i >> 3) & 63;
        int t = i >> 9;                 // 0..215
        int half = t & 1; t >>= 1;
        int kst  = t & 1; t >>= 1;
        int s    = t % 9; t /= 9;
        int py   = t & 1;
        int cls  = t >> 1;              // 0..2
        int dr = s / 3, dx = s % 3;
        int oc = half * 32 + (lane & 31);
        int ci = kst * 16 + (lane >> 5) * 8 + j;   // x8 channels 0..31
        float v = 0.f;
#pragma unroll
        for (int dy = 0; dy < 3; ++dy)
            v += ALPH[cls][py][dy][dr] * w9[((oc * 48 + ci) * 3 + dy) * 3 + dx];
        wpk9e[i] = f2bf(v);
    }
    else if (idx < 321536) {
        // conv8 y-composite tables (up channels 0..31): [cls][py][s][kst] x 512
        int i = idx - 266240;
        int j = i & 7;
        int lane = (i >> 3) & 63;
        int t = i >> 9;                 // 0..107
        int kst = t & 1; t >>= 1;
        int s   = t % 9; t /= 9;
        int py  = t & 1;
        int cls = t >> 1;               // 0..2
        int dr = s / 3, dx = s % 3;
        int oc = lane & 31;
        int ci = kst * 16 + (lane >> 5) * 8 + j;   // up channels 0..31
        float v = 0.f;
#pragma unroll
        for (int dy = 0; dy < 3; ++dy)
            v += ALPH[cls][py][dy][dr] * w8[((oc * 64 + ci) * 3 + dy) * 3 + dx];
        wpk8e[i] = f2bf(v);
    }
}

// ---------------------------------------------------------------------------
// Generic NHWC bf16 MFMA conv (3x3, pad 1, relu -> NHWC bf16).
// POOL=1: input is [8, 2H, 2W, CIN]; staging applies 2x2 maxpool on the fly.
// ---------------------------------------------------------------------------
template<int CIN, int COUT, int H, int W, int ROWS, int POOL>
__global__ __launch_bounds__(256)
void convN_mfma(const unsigned short* __restrict__ in,
                const unsigned short* __restrict__ wpk,
                const float* __restrict__ bias,
                unsigned short* __restrict__ out)
{
    constexpr int G = CIN / 8;
    constexpr int KST = CIN / 16;
    constexpr int MT = COUT / 32;
    constexpr int TR = ROWS + 2;
    constexpr int TWd = W + 2;
    constexpr int PS = TR * TWd * 8 + 8;
    __shared__ __align__(16) unsigned short smem[G * PS];

    const int tid  = threadIdx.x;
    const int lane = tid & 63;
    const int wv   = tid >> 6;
    const int q    = lane >> 5;
    const int y0   = blockIdx.x * ROWS;
    const int b    = blockIdx.y;

    for (int i = tid; i < G * TR * TWd; i += 256) {
        int g = i % G;
        int u = (i / G) % TWd;
        int t = i / (G * TWd);
        int yg = y0 + t - 1, xg = u - 1;
        uint4 v = make_uint4(0, 0, 0, 0);
        if (yg >= 0 && yg < H && xg >= 0 && xg < W) {
            if (POOL) {
                const unsigned short* q0 =
                    in + (((size_t)(b * 2 * H + 2 * yg) * 2 * W + 2 * xg) * CIN + g * 8);
                u16x8 a0 = *(const u16x8*)q0;
                u16x8 a1 = *(const u16x8*)(q0 + CIN);
                u16x8 a2 = *(const u16x8*)(q0 + (size_t)2 * W * CIN);
                u16x8 a3 = *(const u16x8*)(q0 + (size_t)2 * W * CIN + CIN);
                float f[8];
#pragma unroll
                for (int j = 0; j < 8; ++j)
                    f[j] = fmaxf(fmaxf(bf2f(a0[j]), bf2f(a1[j])),
                                 fmaxf(bf2f(a2[j]), bf2f(a3[j])));
                v = make_uint4(cvtpk2(f[0], f[1]), cvtpk2(f[2], f[3]),
                               cvtpk2(f[4], f[5]), cvtpk2(f[6], f[7]));
            } else {
                v = *(const uint4*)(in + (((size_t)(b * H + yg) * W + xg) * CIN + g * 8));
            }
        }
        *(uint4*)(&smem[g * PS + (t * TWd + u) * 8]) = v;
    }
    __syncthreads();

    const int p = wv * 32 + (lane & 31);
    const int r = p / W;
    const int x = p % W;

    f32x16 acc[MT];
#pragma unroll
    for (int mt = 0; mt < MT; ++mt)
#pragma unroll
        for (int i = 0; i < 16; ++i) acc[mt][i] = 0.f;

    const unsigned short* wbase = wpk + lane * 8;

#pragma unroll
    for (int s = 0; s < 9; ++s) {
        const int dy = s / 3, dx = s % 3;
#pragma unroll
        for (int kst = 0; kst < KST; ++kst) {
            const int g = kst * 2 + q;
            bf16x8 bfrag = *(const bf16x8*)(&smem[g * PS + ((r + dy) * TWd + (x + dx)) * 8]);
#pragma unroll
            for (int mt = 0; mt < MT; ++mt) {
                bf16x8 a = *(const bf16x8*)(wbase + ((s * KST + kst) * MT + mt) * 512);
                acc[mt] = __builtin_amdgcn_mfma_f32_32x32x16_bf16(a, bfrag, acc[mt], 0, 0, 0);
            }
        }
    }

    size_t base = ((size_t)(b * H + y0 + r) * W + x) * COUT;
#pragma unroll
    for (int mt = 0; mt < MT; ++mt)
#pragma unroll
        for (int rg = 0; rg < 4; ++rg) {
            int oc = mt * 32 + 8 * rg + 4 * q;
            float v0 = fmaxf(acc[mt][rg * 4 + 0] + bias[oc + 0], 0.f);
            float v1 = fmaxf(acc[mt][rg * 4 + 1] + bias[oc + 1], 0.f);
            float v2 = fmaxf(acc[mt][rg * 4 + 2] + bias[oc + 2], 0.f);
            float v3 = fmaxf(acc[mt][rg * 4 + 3] + bias[oc + 3], 0.f);
            *(uint2*)(out + base + oc) = make_uint2(cvtpk2(v0, v1), cvtpk2(v2, v3));
        }
}

// ---------------------------------------------------------------------------
// convU: 3x3 conv with FUSED upsample+concat staging (decoder stages 6,7).
// ---------------------------------------------------------------------------
template<int UPC, int CSKIP, int COUT, int H, int W, int ROWS>
__global__ __launch_bounds__(256)
void convU_mfma(const unsigned short* __restrict__ up,
                const unsigned short* __restrict__ skip,
                const unsigned short* __restrict__ wpk,
                const float* __restrict__ bias,
                unsigned short* __restrict__ out)
{
    constexpr int CIN = UPC + CSKIP;
    constexpr int G = CIN / 8;
    constexpr int GU = UPC / 8;
    constexpr int KST = CIN / 16;
    constexpr int MT = COUT / 32;
    constexpr int TR = ROWS + 2;
    constexpr int TWd = W + 2;
    constexpr int PS = TR * TWd * 8 + 8;
    __shared__ __align__(16) unsigned short smem[G * PS];

    const int tid  = threadIdx.x;
    const int lane = tid & 63;
    const int wv   = tid >> 6;
    const int q    = lane >> 5;
    const int y0   = blockIdx.x * ROWS;
    const int b    = blockIdx.y;

    for (int i = tid; i < G * TR * TWd; i += 256) {
        int g = i % G;
        int u = (i / G) % TWd;
        int t = i / (G * TWd);
        int yg = y0 + t - 1, xg = u - 1;
        uint4 v = make_uint4(0, 0, 0, 0);
        if (yg >= 0 && yg < H && xg >= 0 && xg < W) {
            if (g < GU) {
                int i00, i01, i10, i11; float wy, wx;
                bilin_setup(yg, xg, H / 2, W / 2, i00, i01, i10, i11, wy, wx);
                v = bilin8u(up + (size_t)b * (H / 2) * (W / 2) * UPC + g * 8,
                            i00, i01, i10, i11, wy, wx, UPC);
            } else {
                v = *(const uint4*)(skip + (((size_t)(b * H + yg) * W + xg) * CSKIP
                                            + (g - GU) * 8));
            }
        }
        *(uint4*)(&smem[g * PS + (t * TWd + u) * 8]) = v;
    }
    __syncthreads();

    const int p = wv * 32 + (lane & 31);
    const int r = p / W;
    const int x = p % W;

    f32x16 acc[MT];
#pragma unroll
    for (int mt = 0; mt < MT; ++mt)
#pragma unroll
        for (int i = 0; i < 16; ++i) acc[mt][i] = 0.f;

    const unsigned short* wbase = wpk + lane * 8;

#pragma unroll
    for (int s = 0; s < 9; ++s) {
        const int dy = s / 3, dx = s % 3;
#pragma unroll
        for (int kst = 0; kst < KST; ++kst) {
            const int g = kst * 2 + q;
            bf16x8 bfrag = *(const bf16x8*)(&smem[g * PS + ((r + dy) * TWd + (x + dx)) * 8]);
#pragma unroll
            for (int mt = 0; mt < MT; ++mt) {
                bf16x8 a = *(const bf16x8*)(wbase + ((s * KST + kst) * MT + mt) * 512);
                acc[mt] = __builtin_amdgcn_mfma_f32_32x32x16_bf16(a, bfrag, acc[mt], 0, 0, 0);
            }
        }
    }

    size_t base = ((size_t)(b * H + y0 + r) * W + x) * COUT;
#pragma unroll
    for (int mt = 0; mt < MT; ++mt)
#pragma unroll
        for (int rg = 0; rg < 4; ++rg) {
            int oc = mt * 32 + 8 * rg + 4 * q;
            float v0 = fmaxf(acc[mt][rg * 4 + 0] + bias[oc + 0], 0.f);
            float v1 = fmaxf(acc[mt][rg * 4 + 1] + bias[oc + 1], 0.f);
            float v2 = fmaxf(acc[mt][rg * 4 + 2] + bias[oc + 2], 0.f);
            float v3 = fmaxf(acc[mt][rg * 4 + 3] + bias[oc + 3], 0.f);
            *(uint2*)(out + base + oc) = make_uint2(cvtpk2(v0, v1), cvtpk2(v2, v3));
        }
}

// ---------------------------------------------------------------------------
// Fused img transpose + conv1 (5x5, relu -> x1t NHWC bf16) + conv_i (3x3 ->
// xin NCHW bf16).  Round-11: ROWS=4 / 512-thread — 8 staged rows per 4
// output rows (halo 2x vs round-10's 5x), 64-px strips.
// ---------------------------------------------------------------------------
__global__ __launch_bounds__(512)
void conv1i_mfma(const float* __restrict__ img,
                 const unsigned short* __restrict__ wpk1,
                 const unsigned short* __restrict__ wpki,
                 const float* __restrict__ b1, const float* __restrict__ bi,
                 unsigned short* __restrict__ x1t, unsigned short* __restrict__ xin)
{
    __shared__ __align__(16) unsigned short smem[2 * 8 * 68 * 8];   // 17408 B

    const int tid  = threadIdx.x;
    const int lane = tid & 63;
    const int wv   = tid >> 6;              // 0..7
    const int n    = lane & 31;
    const int q    = lane >> 5;
    const int x0   = (blockIdx.x & 3) * 64;
    const int yq   = blockIdx.x >> 2;       // 0..63 (4-row output tile)
    const int b    = blockIdx.y;

    for (int i = tid; i < 2 * 8 * 68; i += 512) {
        int g   = i & 1;
        int rem = i >> 1;           // 0..543
        int xi  = rem % 68;
        int r   = rem / 68;         // 0..7
        int yg = 4 * yq + r - 2;
        int xg = x0 - 2 + xi;
        uint4 v = make_uint4(0, 0, 0, 0);
        if (yg >= 0 && yg < 256 && xg >= 0 && xg < 256) {
            const float* ip = img + (size_t)(b * 15 + g * 8) * 65536
                                  + (size_t)yg * 256 + xg;
            float f[8];
            if (g == 0) {
#pragma unroll
                for (int j = 0; j < 8; ++j) f[j] = ip[(size_t)j * 65536];
            } else {
#pragma unroll
                for (int j = 0; j < 7; ++j) f[j] = ip[(size_t)j * 65536];
                f[7] = 0.f;                 // channel 15 pad
            }
            v = make_uint4(cvtpk2(f[0], f[1]), cvtpk2(f[2], f[3]),
                           cvtpk2(f[4], f[5]), cvtpk2(f[6], f[7]));
        }
        *(uint4*)(&smem[((g * 8 + r) * 68 + xi) * 8]) = v;
    }
    __syncthreads();

    const int rr  = wv >> 1;                // output row 0..3 within tile
    const int pxl = (wv & 1) * 32 + n;      // 0..63

    f32x16 acc1, acci;
#pragma unroll
    for (int i = 0; i < 16; ++i) { acc1[i] = 0.f; acci[i] = 0.f; }

    const unsigned short* wb1 = wpk1 + lane * 8;
    const unsigned short* wbi = wpki + lane * 8;

#pragma unroll
    for (int s = 0; s < 25; ++s) {
        const int dy = s / 5, dx = s % 5;
        bf16x8 bfrag = *(const bf16x8*)(&smem[((q * 8 + rr + dy) * 68 + pxl + dx) * 8]);
        bf16x8 a = *(const bf16x8*)(wb1 + s * 512);
        acc1 = __builtin_amdgcn_mfma_f32_32x32x16_bf16(a, bfrag, acc1, 0, 0, 0);
    }
#pragma unroll
    for (int s = 0; s < 9; ++s) {
        const int dy = s / 3, dx = s % 3;
        bf16x8 bfrag = *(const bf16x8*)(&smem[((q * 8 + rr + dy + 1) * 68 + pxl + dx + 1) * 8]);
        bf16x8 a = *(const bf16x8*)(wbi + s * 512);
        acci = __builtin_amdgcn_mfma_f32_32x32x16_bf16(a, bfrag, acci, 0, 0, 0);
    }

    const int y  = 4 * yq + rr;
    const int px = x0 + pxl;
    size_t base1 = ((size_t)(b * 256 + y) * 256 + px) * 16;
#pragma unroll
    for (int rg = 0; rg < 2; ++rg) {
        int oc = 8 * rg + 4 * q;
        float v0 = fmaxf(acc1[rg * 4 + 0] + b1[oc + 0], 0.f);
        float v1 = fmaxf(acc1[rg * 4 + 1] + b1[oc + 1], 0.f);
        float v2 = fmaxf(acc1[rg * 4 + 2] + b1[oc + 2], 0.f);
        float v3 = fmaxf(acc1[rg * 4 + 3] + b1[oc + 3], 0.f);
        *(uint2*)(x1t + base1 + oc) = make_uint2(cvtpk2(v0, v1), cvtpk2(v2, v3));
    }
#pragma unroll
    for (int reg = 0; reg < 8; reg += 2) {
        int row = (reg & 3) + 8 * (reg >> 2) + 4 * q;   // reg even: rows row,row+1
        unsigned p = cvtpk2(acci[reg] + bi[row], acci[reg + 1] + bi[row + 1]);
        xin[((size_t)(b * 16 + row)     * 256 + y) * 256 + px] = (unsigned short)p;
        xin[((size_t)(b * 16 + row + 1) * 256 + y) * 256 + px] = (unsigned short)(p >> 16);
    }
}

// ---------------------------------------------------------------------------
// conv8 MFMA, y-composite + cvt_pk (unchanged).
// ---------------------------------------------------------------------------
__global__ __launch_bounds__(256)
void conv8_mfma(const unsigned short* __restrict__ x7t,
                const unsigned short* __restrict__ x2t,
                const unsigned short* __restrict__ wpk8,   // original (skip ksts)
                const unsigned short* __restrict__ wpk8e,  // composite up tables
                const float* __restrict__ bias,
                unsigned short* __restrict__ x8t)
{
    constexpr int PSU = 3 * 66 * 8 + 8;   // 1592 shorts per up plane
    constexpr int PSS = 4 * 66 * 8 + 8;   // 2120 shorts per skip plane
    constexpr int SOFF = 4 * PSU;         // 6368
    __shared__ __align__(16) unsigned short smem[4 * PSU + 4 * PSS]; // 29696 B

    const int tid  = threadIdx.x;
    const int lane = tid & 63;
    const int wv   = tid >> 6;
    const int n    = lane & 31;
    const int q    = lane >> 5;
    const int x0   = (blockIdx.x & 1) * 64;
    const int yp   = blockIdx.x >> 1;       // low-res row i, 0..63
    const int b    = blockIdx.y;

    for (int i = tid; i < 792 + 1056; i += 256) {
        if (i < 792) {
            // up part: 4 planes x 3 low-res rows x 66 cols, x-lerp only
            int g   = i & 3;
            int rem = i >> 2;           // 0..197
            int xi  = rem % 66;
            int t8  = rem / 66;         // 0..2  (low-res row yp-1+t8)
            int r   = yp - 1 + t8;
            int xg  = x0 - 1 + xi;
            uint4 v = make_uint4(0, 0, 0, 0);
            if (r >= 0 && r < 64 && xg >= 0 && xg < 128) {
                int ix0, ix1; float wx;
                up2_setup(xg, 64, ix0, ix1, wx);
                const unsigned short* S = x7t + ((size_t)(b * 64 + r) * 64) * 32 + g * 8;
                u16x8 a0 = *(const u16x8*)(S + ix0 * 32);
                u16x8 a1 = *(const u16x8*)(S + ix1 * 32);
                float w1x = 1.f - wx;
                float f[8];
#pragma unroll
                for (int j = 0; j < 8; ++j)
                    f[j] = w1x * bf2f(a0[j]) + wx * bf2f(a1[j]);
                v = make_uint4(cvtpk2(f[0], f[1]), cvtpk2(f[2], f[3]),
                               cvtpk2(f[4], f[5]), cvtpk2(f[6], f[7]));
            }
            *(uint4*)(&smem[g * PSU + (t8 * 66 + xi) * 8]) = v;
        } else {
            // skip part: 4 planes x 4 full-res rows x 66 cols, pure copy
            int jI  = i - 792;
            int g   = jI & 3;
            int rem = jI >> 2;          // 0..263
            int xi  = rem % 66;
            int t   = rem / 66;         // 0..3
            int yg  = 2 * yp + t - 1;
            int xg  = x0 - 1 + xi;
            uint4 v = make_uint4(0, 0, 0, 0);
            if (yg >= 0 && yg < 128 && xg >= 0 && xg < 128)
                v = *(const uint4*)(x2t + (((size_t)(b * 128 + yg) * 128 + xg) * 32 + g * 8));
            *(uint4*)(&smem[SOFF + g * PSS + (t * 66 + xi) * 8]) = v;
        }
    }
    __syncthreads();

    const int rr  = wv >> 1;                // output row parity py
    const int pxl = (wv & 1) * 32 + n;

    f32x16 acc;
#pragma unroll
    for (int i = 0; i < 16; ++i) acc[i] = 0.f;

    const int cls = (yp == 0) ? 0 : ((yp == 63) ? 2 : 1);
    const unsigned short* wE = wpk8e + (size_t)(cls * 2 + rr) * 9216 + lane * 8;
    const unsigned short* wS = wpk8 + lane * 8;

#pragma unroll
    for (int s = 0; s < 9; ++s) {
        const int dr = s / 3, dxx = s % 3;
#pragma unroll
        for (int kst = 0; kst < 2; ++kst) {
            const int g = kst * 2 + q;
            bf16x8 bfrag = *(const bf16x8*)(&smem[g * PSU + (dr * 66 + pxl + dxx) * 8]);
            bf16x8 a = *(const bf16x8*)(wE + (s * 2 + kst) * 512);
            acc = __builtin_amdgcn_mfma_f32_32x32x16_bf16(a, bfrag, acc, 0, 0, 0);
        }
#pragma unroll
        for (int kst = 0; kst < 2; ++kst) {
            const int g = kst * 2 + q;
            bf16x8 bfrag = *(const bf16x8*)(&smem[SOFF + g * PSS + ((rr + dr) * 66 + pxl + dxx) * 8]);
            bf16x8 a = *(const bf16x8*)(wS + (s * 4 + kst + 2) * 512);
            acc = __builtin_amdgcn_mfma_f32_32x32x16_bf16(a, bfrag, acc, 0, 0, 0);
        }
    }

    size_t base = ((size_t)(b * 128 + 2 * yp + rr) * 128 + x0 + pxl) * 32;
#pragma unroll
    for (int rg = 0; rg < 4; ++rg) {
        int oc0 = 8 * rg + 4 * q;
        float v0 = fmaxf(acc[rg * 4 + 0] + bias[oc0 + 0], 0.f);
        float v1 = fmaxf(acc[rg * 4 + 1] + bias[oc0 + 1], 0.f);
        float v2 = fmaxf(acc[rg * 4 + 2] + bias[oc0 + 2], 0.f);
        float v3 = fmaxf(acc[rg * 4 + 3] + bias[oc0 + 3], 0.f);
        *(uint2*)(x8t + base + oc0) = make_uint2(cvtpk2(v0, v1), cvtpk2(v2, v3));
    }
}

// ---------------------------------------------------------------------------
// conv9 MFMA, y-composite, ROWS=4 / 512-thread (unchanged from round 9).
// ---------------------------------------------------------------------------
__global__ __launch_bounds__(512)
void conv9f_mfma(const unsigned short* __restrict__ x8t,
                 const unsigned short* __restrict__ x1t,
                 const unsigned short* __restrict__ wpk,     // original (kst=2 slice used)
                 const unsigned short* __restrict__ wpk9e,   // composite tables
                 const float* __restrict__ bias,
                 unsigned short* __restrict__ fm)
{
    constexpr int PS8X = 4 * 66 * 8 + 8;   // 2120 shorts per x8 plane (4 low-res rows)
    constexpr int PS1  = 6 * 66 * 8 + 8;   // 3176 shorts per x1 plane (6 rows)
    constexpr int X1OFF = 4 * PS8X;        // 8480
    __shared__ __align__(16) unsigned short smem[16384];     // 32768 B (staging 14832)

    const int tid  = threadIdx.x;
    const int lane = tid & 63;
    const int wv   = tid >> 6;              // 0..7
    const int n    = lane & 31;
    const int q    = lane >> 5;
    const int x0   = (blockIdx.x & 3) * 64;
    const int yq   = blockIdx.x >> 2;       // 0..63 (4-row output tile)
    const int b    = blockIdx.y;

    for (int i = tid; i < 1056 + 792; i += 512) {
        if (i < 1056) {
            // x8 part: 4 planes x 4 low-res rows x 66 cols, x-lerp only
            int g   = i & 3;
            int rem = i >> 2;           // 0..263
            int xi  = rem % 66;
            int t8  = rem / 66;         // 0..3  (low-res row 2yq-1+t8)
            int r   = 2 * yq - 1 + t8;
            int xg  = x0 - 1 + xi;
            uint4 v = make_uint4(0, 0, 0, 0);
            if (r >= 0 && r < 128 && xg >= 0 && xg < 256) {
                int ix0, ix1; float wx;
                up2_setup(xg, 128, ix0, ix1, wx);
                const unsigned short* S = x8t + ((size_t)(b * 128 + r) * 128) * 32 + g * 8;
                u16x8 a0 = *(const u16x8*)(S + ix0 * 32);
                u16x8 a1 = *(const u16x8*)(S + ix1 * 32);
                float w1x = 1.f - wx;
                float f[8];
#pragma unroll
                for (int j = 0; j < 8; ++j)
                    f[j] = w1x * bf2f(a0[j]) + wx * bf2f(a1[j]);
                v = make_uint4(cvtpk2(f[0], f[1]), cvtpk2(f[2], f[3]),
                               cvtpk2(f[4], f[5]), cvtpk2(f[6], f[7]));
            }
            *(uint4*)(&smem[g * PS8X + (t8 * 66 + xi) * 8]) = v;
        } else {
            // x1 part: 2 planes x 6 full-res rows x 66 cols, pure copy
            int jI  = i - 1056;
            int g   = jI & 1;
            int rem = jI >> 1;          // 0..395
            int xi  = rem % 66;
            int t   = rem / 66;         // 0..5
            int yg  = 4 * yq + t - 1;
            int xg  = x0 - 1 + xi;
            uint4 v = make_uint4(0, 0, 0, 0);
            if (yg >= 0 && yg < 256 && xg >= 0 && xg < 256)
                v = *(const uint4*)(x1t + (((size_t)(b * 256 + yg) * 256 + xg) * 16 + g * 8));
            *(uint4*)(&smem[X1OFF + g * PS1 + (t * 66 + xi) * 8]) = v;
        }
    }
    __syncthreads();

    const int rr  = wv >> 1;                 // output row 0..3 within tile
    const int py  = rr & 1;                  // parity
    const int lrh = rr >> 1;                 // low-res sub-row 0..1
    const int lr  = 2 * yq + lrh;            // absolute low-res row
    const int pxl = (wv & 1) * 32 + n;

    f32x16 acc0, acc1;
#pragma unroll
    for (int i = 0; i < 16; ++i) { acc0[i] = 0.f; acc1[i] = 0.f; }

    const int cls = (lr == 0) ? 0 : ((lr == 127) ? 2 : 1);
    const unsigned short* wE  = wpk9e + (size_t)(cls * 2 + py) * 18432 + lane * 8;
    const unsigned short* w2b = wpk + lane * 8;

#pragma unroll
    for (int s = 0; s < 9; ++s) {
        const int dr = s / 3, dxx = s % 3;
        // x8 part: kst 0,1 — B rows are low-res rows lrh+dr (0..3)
#pragma unroll
        for (int kst = 0; kst < 2; ++kst) {
            const int g = kst * 2 + q;
            bf16x8 bfrag = *(const bf16x8*)(&smem[g * PS8X + ((lrh + dr) * 66 + pxl + dxx) * 8]);
            bf16x8 a0 = *(const bf16x8*)(wE + ((s * 2 + kst) * 2 + 0) * 512);
            bf16x8 a1 = *(const bf16x8*)(wE + ((s * 2 + kst) * 2 + 1) * 512);
            acc0 = __builtin_amdgcn_mfma_f32_32x32x16_bf16(a0, bfrag, acc0, 0, 0, 0);
            acc1 = __builtin_amdgcn_mfma_f32_32x32x16_bf16(a1, bfrag, acc1, 0, 0, 0);
        }
        // x1 part: kst=2 — full-res rows rr+dr (0..5), original weights
        {
            bf16x8 bfrag = *(const bf16x8*)(&smem[X1OFF + q * PS1 + ((rr + dr) * 66 + pxl + dxx) * 8]);
            bf16x8 a0 = *(const bf16x8*)(w2b + ((s * 3 + 2) * 2 + 0) * 512);
            bf16x8 a1 = *(const bf16x8*)(w2b + ((s * 3 + 2) * 2 + 1) * 512);
            acc0 = __builtin_amdgcn_mfma_f32_32x32x16_bf16(a0, bfrag, acc0, 0, 0, 0);
            acc1 = __builtin_amdgcn_mfma_f32_32x32x16_bf16(a1, bfrag, acc1, 0, 0, 0);
        }
    }

    // --- epilogue: LDS transpose -> vectorized NCHW stores ---
    __syncthreads();                       // staging buffer is now dead
    unsigned short* lout = smem;           // [64 oc][256 = 4 rows x 64 px]
    const int col = rr * 64 + pxl;
#pragma unroll
    for (int reg = 0; reg < 16; reg += 2) {
        const int rb = (reg & 3) + 8 * (reg >> 2);        // pairs -> rows rb, rb+1
        float a0 = fast_tanh(acc0[reg]     + bias[rb + 4 * q]);
        float a1 = fast_tanh(acc0[reg + 1] + bias[rb + 1 + 4 * q]);
        unsigned p0 = cvtpk2(a0, a1);
        lout[(rb + 4 * q) * 256 + col]     = (unsigned short)p0;
        lout[(rb + 1 + 4 * q) * 256 + col] = (unsigned short)(p0 >> 16);
        float b0 = fast_tanh(acc1[reg]     + bias[rb + 4 * q + 32]);
        float b1 = fast_tanh(acc1[reg + 1] + bias[rb + 1 + 4 * q + 32]);
        unsigned p1 = cvtpk2(b0, b1);
        lout[(rb + 4 * q + 32) * 256 + col] = (unsigned short)p1;
        lout[(rb + 4 * q + 33) * 256 + col] = (unsigned short)(p1 >> 16);
    }
    __syncthreads();

    const size_t fmb = (size_t)b * 64 * 65536 + (size_t)(4 * yq) * 256 + x0;
    for (int i = tid; i < 2048; i += 512) {
        int oc = i >> 5;               // 0..63
        int c8 = (i & 31) * 8;         // 0..248
        int rl = c8 >> 6;              // local row 0..3
        int pl = c8 & 63;              // x within strip
        uint4 v = *(const uint4*)(lout + oc * 256 + c8);
        *(uint4*)(fm + fmb + (size_t)oc * 65536 + rl * 256 + pl) = v;
    }
}

// ---------------------------------------------------------------------------
// Segmented W-direction LRNN pair -> rnnW NCHW bf16 (round-8 bf16 LDS).
// ---------------------------------------------------------------------------
__global__ __launch_bounds__(256)
void lrnn_w_seg(const unsigned short* __restrict__ X, const unsigned short* __restrict__ FM,
                unsigned short* __restrict__ rnnW)
{
    __shared__ __align__(16) unsigned short tx[3][16][312];
    __shared__ __align__(16) unsigned short outm[2][16][256];
    __shared__ float segres[2][16][8][4];
    __shared__ float hin[2][16][8][2];

    const int tid = threadIdx.x;
    const int bid = blockIdx.x;
    const int yt = bid & 15;
    const int c  = (bid >> 4) & 15;
    const int b  = bid >> 8;
    const int y0 = yt * 16;

    const size_t xb  = ((size_t)(b * 16 + c) * 256 + y0) * 256;
    const size_t p1b = ((size_t)(b * 64 + c) * 256 + y0) * 256;
    const size_t p2b = ((size_t)(b * 64 + 32 + c) * 256 + y0) * 256;

    for (int i = tid; i < 1536; i += 256) {
        int s = i >> 9;
        int r = i & 511;
        int y = r >> 5;
        int g = r & 31;
        const unsigned short* sp = (s == 0) ? (X + xb) : (s == 1 ? FM + p1b : FM + p2b);
        uint4 v = *(const uint4*)(sp + (size_t)y * 256 + g * 8);
        *(uint4*)(&tx[s][y][8 * g + 8 * (g >> 2)]) = v;   // padded col of x=8g
    }
    __syncthreads();

    const int y  = tid & 15;
    const int sg = (tid >> 4) & 7;
    const int d  = tid >> 7;

    {   // pass 1
        float h1 = 0.f, h2 = 0.f, A1 = 1.f, A2 = 1.f;
        if (d == 0) {
            const int base = 40 * sg;
#pragma unroll
            for (int k = 0; k < 4; ++k) {
                u16x8 xv8 = *(const u16x8*)&tx[0][y][base + 8 * k];
                u16x8 p18 = *(const u16x8*)&tx[1][y][base + 8 * k];
                u16x8 p28 = *(const u16x8*)&tx[2][y][base + 8 * k];
#pragma unroll
                for (int j = 0; j < 8; ++j) {
                    float xv = bf2f(xv8[j]), p1 = bf2f(p18[j]), p2 = bf2f(p28[j]);
                    h1 = fmaf(p1, h1 - xv, xv); A1 *= p1;
                    h2 = fmaf(p2, h2 - xv, xv); A2 *= p2;
                }
            }
        } else {
            const int m = 7 - sg;
#pragma unroll
            for (int k = 0; k < 4; ++k) {
                const int base = 40 * m + 24 - 8 * k;
                u16x8 xv8 = *(const u16x8*)&tx[0][y][base];
                u16x8 p18 = *(const u16x8*)&tx[1][y][base];
                u16x8 p28 = *(const u16x8*)&tx[2][y][base];
#pragma unroll
                for (int j = 7; j >= 0; --j) {
                    float xv = bf2f(xv8[j]), p1 = bf2f(p18[j]), p2 = bf2f(p28[j]);
                    h1 = fmaf(p1, h1 - xv, xv); A1 *= p1;
                    h2 = fmaf(p2, h2 - xv, xv); A2 *= p2;
                }
            }
        }
        segres[d][y][sg][0] = h1; segres[d][y][sg][1] = A1;
        segres[d][y][sg][2] = h2; segres[d][y][sg][3] = A2;
    }
    __syncthreads();

    if (tid < 32) {
        int yy = tid & 15, dd = tid >> 4;
        float c1 = 0.f, c2 = 0.f;
        for (int s = 0; s < 8; ++s) {
            hin[dd][yy][s][0] = c1;
            hin[dd][yy][s][1] = c2;
            c1 = segres[dd][yy][s][0] + segres[dd][yy][s][1] * c1;
            c2 = segres[dd][yy][s][2] + segres[dd][yy][s][3] * c2;
        }
    }
    __syncthreads();

    {   // pass 2: vector reads + 8-wide buffered vector outm writes
        float h1 = hin[d][y][sg][0], h2 = hin[d][y][sg][1];
        if (d == 0) {
            const int base = 40 * sg;
            const int xs = 32 * sg;
#pragma unroll
            for (int k = 0; k < 4; ++k) {
                u16x8 xv8 = *(const u16x8*)&tx[0][y][base + 8 * k];
                u16x8 p18 = *(const u16x8*)&tx[1][y][base + 8 * k];
                u16x8 p28 = *(const u16x8*)&tx[2][y][base + 8 * k];
                float mres[8];
#pragma unroll
                for (int j = 0; j < 8; ++j) {
                    float xv = bf2f(xv8[j]), p1 = bf2f(p18[j]), p2 = bf2f(p28[j]);
                    h1 = fmaf(p1, h1 - xv, xv);
                    h2 = fmaf(p2, h2 - xv, xv);
                    mres[j] = fmaxf(h1, h2);
                }
                *(uint4*)&outm[0][y][xs + 8 * k] =
                    make_uint4(cvtpk2(mres[0], mres[1]), cvtpk2(mres[2], mres[3]),
                               cvtpk2(mres[4], mres[5]), cvtpk2(mres[6], mres[7]));
            }
        } else {
            const int m = 7 - sg;
            const int ts = 32 * sg;
#pragma unroll
            for (int k = 0; k < 4; ++k) {
                const int base = 40 * m + 24 - 8 * k;
                u16x8 xv8 = *(const u16x8*)&tx[0][y][base];
                u16x8 p18 = *(const u16x8*)&tx[1][y][base];
                u16x8 p28 = *(const u16x8*)&tx[2][y][base];
                float mres[8];
#pragma unroll
                for (int j = 7; j >= 0; --j) {
                    float xv = bf2f(xv8[j]), p1 = bf2f(p18[j]), p2 = bf2f(p28[j]);
                    h1 = fmaf(p1, h1 - xv, xv);
                    h2 = fmaf(p2, h2 - xv, xv);
                    mres[7 - j] = fmaxf(h1, h2);
                }
                *(uint4*)&outm[1][y][ts + 8 * k] =
                    make_uint4(cvtpk2(mres[0], mres[1]), cvtpk2(mres[2], mres[3]),
                               cvtpk2(mres[4], mres[5]), cvtpk2(mres[6], mres[7]));
            }
        }
    }
    __syncthreads();

    // final: thread tid owns x=tid, rows 0..15 (paired conversions)
    {
        const int x = tid;
#pragma unroll
        for (int yy = 0; yy < 16; yy += 2) {
            float m0 = fmaxf(bf2f(outm[0][yy][x]),     bf2f(outm[1][yy][x]));
            float m1 = fmaxf(bf2f(outm[0][yy + 1][x]), bf2f(outm[1][yy + 1][x]));
            unsigned p = cvtpk2(m0, m1);
            rnnW[xb + (size_t)yy * 256 + x]       = (unsigned short)p;
            rnnW[xb + (size_t)(yy + 1) * 256 + x] = (unsigned short)(p >> 16);
        }
    }
}

// ---------------------------------------------------------------------------
// Segmented H-direction LRNN pair; fuses max(rnnW, rnnH) -> rnnM.
// (round-8 transposed bf16 LDS)
// ---------------------------------------------------------------------------
__global__ __launch_bounds__(256)
void lrnn_h_seg(const unsigned short* __restrict__ X, const unsigned short* __restrict__ FM,
                const unsigned short* __restrict__ rnnW, unsigned short* __restrict__ rnnM)
{
    __shared__ __align__(16) unsigned short tx[3][16][312];
    __shared__ __align__(16) unsigned short outm[2][16][264];
    __shared__ float segres[2][16][8][4];
    __shared__ float hin[2][16][8][2];

    const int tid = threadIdx.x;
    const int bid = blockIdx.x;
    const int xt = bid & 15;
    const int c  = (bid >> 4) & 15;
    const int b  = bid >> 8;
    const int x0 = xt * 16;

    const size_t xb  = (size_t)(b * 16 + c) * 65536 + x0;
    const size_t p1b = (size_t)(b * 64 + 16 + c) * 65536 + x0;
    const size_t p2b = (size_t)(b * 64 + 48 + c) * 65536 + x0;

    for (int i = tid; i < 1536; i += 256) {
        int s = i >> 9;
        int r = i & 511;
        int y = r >> 1;
        int g = r & 1;
        const unsigned short* sp = (s == 0) ? (X + xb) : (s == 1 ? FM + p1b : FM + p2b);
        u16x8 v = *(const u16x8*)(sp + (size_t)y * 256 + g * 8);
        int pc = y + 8 * (y >> 5);        // padded col for y
#pragma unroll
        for (int j = 0; j < 8; ++j) tx[s][g * 8 + j][pc] = v[j];
    }
    __syncthreads();

    const int x  = tid & 15;
    const int sg = (tid >> 4) & 7;
    const int d  = tid >> 7;

    {   // pass 1
        float h1 = 0.f, h2 = 0.f, A1 = 1.f, A2 = 1.f;
        if (d == 0) {
            const int base = 40 * sg;
#pragma unroll
            for (int k = 0; k < 4; ++k) {
                u16x8 xv8 = *(const u16x8*)&tx[0][x][base + 8 * k];
                u16x8 p18 = *(const u16x8*)&tx[1][x][base + 8 * k];
                u16x8 p28 = *(const u16x8*)&tx[2][x][base + 8 * k];
#pragma unroll
                for (int j = 0; j < 8; ++j) {
                    float xv = bf2f(xv8[j]), p1 = bf2f(p18[j]), p2 = bf2f(p28[j]);
                    h1 = fmaf(p1, h1 - xv, xv); A1 *= p1;
                    h2 = fmaf(p2, h2 - xv, xv); A2 *= p2;
                }
            }
        } else {
            const int m = 7 - sg;
#pragma unroll
            for (int k = 0; k < 4; ++k) {
                const int base = 40 * m + 24 - 8 * k;
                u16x8 xv8 = *(const u16x8*)&tx[0][x][base];
                u16x8 p18 = *(const u16x8*)&tx[1][x][base];
                u16x8 p28 = *(const u16x8*)&tx[2][x][base];
#pragma unroll
                for (int j = 7; j >= 0; --j) {
                    float xv = bf2f(xv8[j]), p1 = bf2f(p18[j]), p2 = bf2f(p28[j]);
                    h1 = fmaf(p1, h1 - xv, xv); A1 *= p1;
                    h2 = fmaf(p2, h2 - xv, xv); A2 *= p2;
                }
            }
        }
        segres[d][x][sg][0] = h1; segres[d][x][sg][1] = A1;
        segres[d][x][sg][2] = h2; segres[d][x][sg][3] = A2;
    }
    __syncthreads();

    if (tid < 32) {
        int xx = tid & 15, dd = tid >> 4;
        float c1 = 0.f, c2 = 0.f;
        for (int s = 0; s < 8; ++s) {
            hin[dd][xx][s][0] = c1;
            hin[dd][xx][s][1] = c2;
            c1 = segres[dd][xx][s][0] + segres[dd][xx][s][1] * c1;
            c2 = segres[dd][xx][s][2] + segres[dd][xx][s][3] * c2;
        }
    }
    __syncthreads();

    {   // pass 2: vector reads + 8-wide buffered vector outm writes
        float h1 = hin[d][x][sg][0], h2 = hin[d][x][sg][1];
        if (d == 0) {
            const int base = 40 * sg;
            const int ys = 32 * sg;
#pragma unroll
            for (int k = 0; k < 4; ++k) {
                u16x8 xv8 = *(const u16x8*)&tx[0][x][base + 8 * k];
                u16x8 p18 = *(const u16x8*)&tx[1][x][base + 8 * k];
                u16x8 p28 = *(const u16x8*)&tx[2][x][base + 8 * k];
                float mres[8];
#pragma unroll
                for (int j = 0; j < 8; ++j) {
                    float xv = bf2f(xv8[j]), p1 = bf2f(p18[j]), p2 = bf2f(p28[j]);
                    h1 = fmaf(p1, h1 - xv, xv);
                    h2 = fmaf(p2, h2 - xv, xv);
                    mres[j] = fmaxf(h1, h2);
                }
                *(uint4*)&outm[0][x][ys + 8 * k] =
                    make_uint4(cvtpk2(mres[0], mres[1]), cvtpk2(mres[2], mres[3]),
                               cvtpk2(mres[4], mres[5]), cvtpk2(mres[6], mres[7]));
            }
        } else {
            const int m = 7 - sg;
            const int ts = 32 * sg;
#pragma unroll
            for (int k = 0; k < 4; ++k) {
                const int base = 40 * m + 24 - 8 * k;
                u16x8 xv8 = *(const u16x8*)&tx[0][x][base];
                u16x8 p18 = *(const u16x8*)&tx[1][x][base];
                u16x8 p28 = *(const u16x8*)&tx[2][x][base];
                float mres[8];
#pragma unroll
                for (int j = 7; j >= 0; --j) {
                    float xv = bf2f(xv8[j]), p1 = bf2f(p18[j]), p2 = bf2f(p28[j]);
                    h1 = fmaf(p1, h1 - xv, xv);
                    h2 = fmaf(p2, h2 - xv, xv);
                    mres[7 - j] = fmaxf(h1, h2);
                }
                *(uint4*)&outm[1][x][ts + 8 * k] =
                    make_uint4(cvtpk2(mres[0], mres[1]), cvtpk2(mres[2], mres[3]),
                               cvtpk2(mres[4], mres[5]), cvtpk2(mres[6], mres[7]));
            }
        }
    }
    __syncthreads();

    // final: thread handles xx = tid&15, yy = (tid>>4) + 16k (paired k)
    {
        const int xx = tid & 15;
        const int yy0 = tid >> 4;
#pragma unroll
        for (int k = 0; k < 16; k += 2) {
            int ya = yy0 + 16 * k, yb = yy0 + 16 * (k + 1);
            size_t offA = xb + (size_t)ya * 256 + xx;
            size_t offB = xb + (size_t)yb * 256 + xx;
            float ma = fmaxf(fmaxf(bf2f(outm[0][xx][ya]), bf2f(outm[1][xx][ya])),
                             bf2f(rnnW[offA]));
            float mb = fmaxf(fmaxf(bf2f(outm[0][xx][yb]), bf2f(outm[1][xx][yb])),
                             bf2f(rnnW[offB]));
            unsigned p = cvtpk2(ma, mb);
            rnnM[offA] = (unsigned short)p;
            rnnM[offB] = (unsigned short)(p >> 16);
        }
    }
}

// ---------------------------------------------------------------------------
// Output head MFMA: rnnM -> 3x3 conv (Cin16, Cout3), sigmoid -> fp32 out.
// Aligned u16x8 chunk staging (round-10).
// ---------------------------------------------------------------------------
__global__ __launch_bounds__(256)
void convo_mfma(const unsigned short* __restrict__ rnnM,
                const unsigned short* __restrict__ wpko,
                const float* __restrict__ bo,
                float* __restrict__ outp)
{
    constexpr int PSo = 6 * 130 * 8 + 8;   // 6248 shorts per channel-group plane
    __shared__ __align__(16) unsigned short smem[2 * PSo];   // 24992 B

    const int tid  = threadIdx.x;
    const int lane = tid & 63;
    const int wv   = tid >> 6;
    const int n    = lane & 31;
    const int q    = lane >> 5;
    const int x0   = (blockIdx.x & 1) * 128;
    const int yq   = blockIdx.x >> 1;       // 0..63
    const int b    = blockIdx.y;

    for (int i = tid; i < 6 * 16 * 18; i += 256) {
        int c  = i % 18;           // aligned 8-chunk index over [x0-8, x0+136)
        int t  = i / 18;           // 0..95
        int ch = t & 15;
        int r  = t >> 4;           // 0..5
        int yg = 4 * yq + r - 1;
        int g = ch >> 3, j = ch & 7;
        unsigned short* sb = &smem[g * PSo + (r * 130) * 8 + j];
        int xg0 = x0 + 8 * (c - 1);        // 8-aligned global x base
        int xi0 = 8 * c - 7;               // xi of first element
        if (yg >= 0 && yg < 256 && xg0 >= 0 && xg0 < 256) {
            size_t off = (size_t)(b * 16 + ch) * 65536 + (size_t)yg * 256;
            u16x8 v = *(const u16x8*)(rnnM + off + xg0);
#pragma unroll
            for (int k = 0; k < 8; ++k) {
                int xi = xi0 + k;
                if (xi >= 0 && xi < 130) sb[xi * 8] = v[k];
            }
        } else {
#pragma unroll
            for (int k = 0; k < 8; ++k) {
                int xi = xi0 + k;
                if (xi >= 0 && xi < 130) sb[xi * 8] = 0;
            }
        }
    }
    __syncthreads();

    const unsigned short* wbase = wpko + lane * 8;
    const int y = 4 * yq + wv;              // wave wv owns one output row

#pragma unroll
    for (int xt = 0; xt < 4; ++xt) {
        const int pxl = xt * 32 + n;
        f32x16 acc;
#pragma unroll
        for (int i = 0; i < 16; ++i) acc[i] = 0.f;
#pragma unroll
        for (int s = 0; s < 9; ++s) {
            const int dy = s / 3, dx = s % 3;
            bf16x8 bfrag = *(const bf16x8*)(&smem[q * PSo + ((wv + dy) * 130 + pxl + dx) * 8]);
            bf16x8 a = *(const bf16x8*)(wbase + s * 512);
            acc = __builtin_amdgcn_mfma_f32_32x32x16_bf16(a, bfrag, acc, 0, 0, 0);
        }
        if (q == 0) {
            const int px = x0 + pxl;
#pragma unroll
            for (int oc = 0; oc < 3; ++oc) {
                float r2 = acc[oc] + bo[oc];
                outp[((size_t)(b * 3 + oc) * 256 + y) * 256 + px] = 1.f / (1.f + __expf(-r2));
            }
        }
    }
}

// ---------------------------------------------------------------------------
extern "C" void kernel_launch(void* const* d_in, const int* in_sizes, int n_in,
                              void* d_out, int out_size, void* d_ws, size_t ws_size,
                              hipStream_t stream)
{
    const float* img = (const float*)d_in[0];
    const float* w1 = (const float*)d_in[1];  const float* b1 = (const float*)d_in[2];
    const float* w2 = (const float*)d_in[3];  const float* b2 = (const float*)d_in[4];
    const float* w3 = (const float*)d_in[5];  const float* b3 = (const float*)d_in[6];
    const float* w4 = (const float*)d_in[7];  const float* b4 = (const float*)d_in[8];
    const float* w5 = (const float*)d_in[9];  const float* b5 = (const float*)d_in[10];
    const float* w6 = (const float*)d_in[11]; const float* b6 = (const float*)d_in[12];
    const float* w7 = (const float*)d_in[13]; const float* b7 = (const float*)d_in[14];
    const float* w8 = (const float*)d_in[15]; const float* b8 = (const float*)d_in[16];
    const float* w9 = (const float*)d_in[17]; const float* b9 = (const float*)d_in[18];
    const float* wi = (const float*)d_in[19]; const float* bi = (const float*)d_in[20];
    const float* wo = (const float*)d_in[21]; const float* bo = (const float*)d_in[22];

    char* wsb = (char*)d_ws;
    const size_t MB = (size_t)(1u << 20);
    unsigned short* x1t   = (unsigned short*)(wsb + 16 * MB);   // [16,32) till conv9f
    unsigned short* x2t   = (unsigned short*)(wsb + 32 * MB);   // [32,40) till conv8
    unsigned short* x3t   = (unsigned short*)(wsb + 40 * MB);   // [40,42) till conv7
    unsigned short* x4t   = (unsigned short*)(wsb + 42 * MB);   // [42,42.5) till conv6
    unsigned short* x5t   = (unsigned short*)(wsb + 43 * MB);   // [43,43.25)
    unsigned short* x6t   = (unsigned short*)(wsb + 46 * MB);   // [46,46.5)
    unsigned short* x7t   = (unsigned short*)(wsb + 51 * MB);   // [51,53) till conv8
    unsigned short* x8t   = (unsigned short*)(wsb + 70 * MB);   // [70,78) till conv9f
    unsigned short* fm16  = (unsigned short*)(wsb + 112 * MB);  // [112,176) NCHW bf16
    unsigned short* xin16 = (unsigned short*)(wsb + 176 * MB);  // [176,192) NCHW bf16
    unsigned short* rnnW  = (unsigned short*)(wsb);             // [0,16)
    unsigned short* rnnM  = (unsigned short*)(wsb + 16 * MB);   // [16,32) (x1t dead)
    unsigned short* wpk9 = (unsigned short*)(wsb + 192 * MB);
    unsigned short* wpk8 = wpk9 + 27648;
    unsigned short* wpk1 = wpk8 + 18432;
    unsigned short* wpki = wpk1 + 12800;
    unsigned short* wpko = wpki + 4608;
    unsigned short* wpk2 = wpko + 4608;
    unsigned short* wpk3 = wpk2 + 4608;
    unsigned short* wpk4 = wpk3 + 9216;
    unsigned short* wpk5 = wpk4 + 9216;
    unsigned short* wpk6 = wpk5 + 18432;
    unsigned short* wpk7 = wpk6 + 27648;
    unsigned short* wpk9e = wpk7 + 18432;    // 110592 shorts (conv9 composite)
    unsigned short* wpk8e = wpk9e + 110592;  // 55296 shorts (conv8 composite)
    float* outp = (float*)d_out;

    // --- single weight-pack dispatch ---
    wprep_mega<<<1256, 256, 0, stream>>>(w9, w8, w1, wi, wo, w2, w3, w4, w5, w6, w7,
                                         wpk9, wpk8, wpk1, wpki, wpko,
                                         wpk2, wpk3, wpk4, wpk5, wpk6, wpk7,
                                         wpk9e, wpk8e);

    // --- fused img transpose + conv1 + input projection (ROWS=4, 512 thr) ---
    { dim3 grd(256, 8);
      conv1i_mfma<<<grd, 512, 0, stream>>>(img, wpk1, wpki, b1, bi, x1t, xin16); }

    // --- encoder: pools fused into conv staging ---
    convN_mfma<16, 32, 128, 128, 1, 1><<<dim3(128, 8), 256, 0, stream>>>(x1t, wpk2, b2, x2t);
    convN_mfma<32, 32, 64, 64, 2, 1><<<dim3(32, 8), 256, 0, stream>>>(x2t, wpk3, b3, x3t);
    convN_mfma<32, 32, 32, 32, 4, 1><<<dim3(8, 8), 256, 0, stream>>>(x3t, wpk4, b4, x4t);
    convN_mfma<32, 64, 16, 16, 8, 1><<<dim3(2, 8), 256, 0, stream>>>(x4t, wpk5, b5, x5t);

    // --- decoder: upcat fused into conv6/conv7/conv8 staging ---
    convU_mfma<64, 32, 32, 32, 32, 4><<<dim3(8, 8), 256, 0, stream>>>(x5t, x4t, wpk6, b6, x6t);
    convU_mfma<32, 32, 32, 64, 64, 2><<<dim3(32, 8), 256, 0, stream>>>(x6t, x3t, wpk7, b7, x7t);
    { dim3 grd(128, 8);
      conv8_mfma<<<grd, 256, 0, stream>>>(x7t, x2t, wpk8, wpk8e, b8, x8t); }

    // --- stage 9: y-composite ROWS=4 conv9 (256 blocks x 512 threads) ---
    { dim3 grd(256, 8);
      conv9f_mfma<<<grd, 512, 0, stream>>>(x8t, x1t, wpk9, wpk9e, b9, fm16); }

    // --- spatial RNN: segmented scans; lrnn_h fuses max(rnnW, rnnH) -> rnnM ---
    lrnn_w_seg<<<2048, 256, 0, stream>>>(xin16, fm16, rnnW);
    lrnn_h_seg<<<2048, 256, 0, stream>>>(xin16, fm16, rnnW, rnnM);

    // --- output head: 4-row blocks, single input tensor ---
    { dim3 grd(128, 8);
      convo_mfma<<<grd, 256, 0, stream>>>(rnnM, wpko, bo, outp); }
}